// Round 8
// baseline (1279.792 us; speedup 1.0000x reference)
//
#include <hip/hip_runtime.h>
#include <hip/hip_bf16.h>
#include <math.h>

#define DEVFN __device__ __forceinline__

typedef __attribute__((ext_vector_type(8))) short bf16x8;
typedef __attribute__((ext_vector_type(8))) unsigned short u16x8;
typedef __attribute__((ext_vector_type(4))) float f32x4;

static constexpr int Bn = 4, Sn = 256, En = 1024, Hn = 16;
static constexpr int Mn = 65536, Kt = 32, FFn = 4096;
static constexpr int NT = Bn * Sn;           // 1024 tokens

DEVFN unsigned short f2b(float f) {          // f32 -> bf16 RNE
  unsigned int u = __float_as_uint(f);
  unsigned int r = (u + 0x7FFFu + ((u >> 16) & 1u)) >> 16;
  return (unsigned short)r;
}

DEVFN unsigned okey16(unsigned short u) {    // order-preserving bf16 -> u16
  return (unsigned)(u ^ ((u >> 15) ? 0xFFFFu : 0x8000u)) & 0xFFFFu;
}

typedef const __attribute__((address_space(1))) void* as1cv_t;
typedef __attribute__((address_space(3))) void* as3v_t;
DEVFN void gload16(const void* g, void* l) {   // async global->LDS, 16B/lane
  __builtin_amdgcn_global_load_lds((as1cv_t)g, (as3v_t)l, 16, 0, 0);
}
#define MEMFENCE asm volatile("" ::: "memory")

// ---------------- transpose W[R][C] f32 -> out[C][R] bf16 ----------------
__global__ __launch_bounds__(256) void k_transpose_bf16(
    const float* __restrict__ in, unsigned short* __restrict__ out, int R, int C) {
  __shared__ float tile[64][65];
  int tx = threadIdx.x & 63, ty = threadIdx.x >> 6;
  int c0 = blockIdx.x * 64, r0 = blockIdx.y * 64;
  #pragma unroll
  for (int i = 0; i < 16; i++) {
    int r = ty + i * 4;
    tile[tx][r] = in[(size_t)(r0 + r) * C + (c0 + tx)];
  }
  __syncthreads();
  #pragma unroll
  for (int i = 0; i < 16; i++) {
    int c = ty + i * 4;
    out[(size_t)(c0 + c) * R + (r0 + tx)] = f2b(tile[c][tx]);
  }
}

// ---------------- f32 -> bf16 elementwise (x4) ----------------
__global__ __launch_bounds__(256) void k_cvt_bf16(
    const float* __restrict__ in, unsigned short* __restrict__ out, int n4) {
  int i = blockIdx.x * 256 + threadIdx.x;
  if (i >= n4) return;
  float4 v = ((const float4*)in)[i];
  uint2 o;
  o.x = (unsigned int)f2b(v.x) | ((unsigned int)f2b(v.y) << 16);
  o.y = (unsigned int)f2b(v.z) | ((unsigned int)f2b(v.w) << 16);
  ((uint2*)out)[i] = o;
}

// ---------------- concat up to 3 x 1024-f32 vectors ----------------
__global__ __launch_bounds__(256) void k_concat3(
    const float* __restrict__ a, const float* __restrict__ b,
    const float* __restrict__ c, float* __restrict__ o) {
  int i = blockIdx.x * 256 + threadIdx.x;
  float v = (i < 1024) ? a[i] : (i < 2048) ? b[i - 1024] : c[i - 2048];
  o[i] = v;
}

// ---- mem_keys row-normalize + cvt to bf16 (folds cosine norm into B) ----
__global__ __launch_bounds__(256) void k_normcvt(
    const float* __restrict__ mk, unsigned short* __restrict__ out) {
  int m = blockIdx.x, t = threadIdx.x;
  float4 v = ((const float4*)(mk + (size_t)m * En))[t];
  float ss = v.x*v.x + v.y*v.y + v.z*v.z + v.w*v.w;
  #pragma unroll
  for (int d = 32; d; d >>= 1) ss += __shfl_down(ss, d);
  __shared__ float red[4];
  int lane = t & 63, w = t >> 6;
  if (lane == 0) red[w] = ss;
  __syncthreads();
  float rs = 1.0f / fmaxf(sqrtf(red[0] + red[1] + red[2] + red[3]), 1e-12f);
  uint2 o;
  o.x = (unsigned int)f2b(v.x * rs) | ((unsigned int)f2b(v.y * rs) << 16);
  o.y = (unsigned int)f2b(v.z * rs) | ((unsigned int)f2b(v.w * rs) << 16);
  ((uint2*)(out + (size_t)m * En))[t] = o;
}

// ---------------- LayerNorm over rows of [NT][En] ----------------
__global__ __launch_bounds__(256) void k_layernorm(
    const float* __restrict__ in, const float* __restrict__ g, const float* __restrict__ bb,
    float* __restrict__ outf, unsigned short* __restrict__ outb) {
  int n = blockIdx.x, t = threadIdx.x;
  float4 v = ((const float4*)(in + (size_t)n * En))[t];
  float s  = v.x + v.y + v.z + v.w;
  float s2 = v.x*v.x + v.y*v.y + v.z*v.z + v.w*v.w;
  #pragma unroll
  for (int d = 32; d; d >>= 1) { s += __shfl_down(s, d); s2 += __shfl_down(s2, d); }
  __shared__ float rs[4], rq[4];
  int lane = t & 63, w = t >> 6;
  if (lane == 0) { rs[w] = s; rq[w] = s2; }
  __syncthreads();
  float mean = (rs[0]+rs[1]+rs[2]+rs[3]) * (1.0f/En);
  float var  = (rq[0]+rq[1]+rq[2]+rq[3]) * (1.0f/En) - mean*mean;
  float rstd = rsqrtf(var + 1e-5f);
  float4 gg = ((const float4*)g)[t];
  float4 bv = ((const float4*)bb)[t];
  float o0 = (v.x-mean)*rstd*gg.x + bv.x;
  float o1 = (v.y-mean)*rstd*gg.y + bv.y;
  float o2 = (v.z-mean)*rstd*gg.z + bv.z;
  float o3 = (v.w-mean)*rstd*gg.w + bv.w;
  if (outf) { float4 ov = {o0,o1,o2,o3}; ((float4*)(outf + (size_t)n*En))[t] = ov; }
  if (outb) {
    uint2 o;
    o.x = (unsigned int)f2b(o0) | ((unsigned int)f2b(o1) << 16);
    o.y = (unsigned int)f2b(o2) | ((unsigned int)f2b(o3) << 16);
    ((uint2*)(outb + (size_t)n*En))[t] = o;
  }
}

// ======== 256x256 GEMM, 4 half-tile ring buffers + counted vmcnt (T1..T5) ========
// EPI 4: f32 out | EPI 5: bf16 out no-bias | EPI 0 + NOUT2: bf16 out (+bias), split N
// LDS 128 KiB: 4 half-buffers x (A[256][32] + B[256][32]) bf16, st_16x32 swizzle.
template<int EPI, bool AGATHER, int NOUT, int LSWZ>
__global__ __launch_bounds__(512) void k_gemm256(
    const unsigned short* __restrict__ Ab, const unsigned short* __restrict__ Bb,
    const int* __restrict__ gidx, const float* __restrict__ bias,
    float* __restrict__ Cf, unsigned short* __restrict__ cb0, unsigned short* __restrict__ cb1,
    int Ndim, int Kdim, int nRT, int nCT) {
  extern __shared__ unsigned short lds[];
  const int t = threadIdx.x, lane = t & 63, w = t >> 6;
  const int wr = w >> 2, wc = w & 3, l15 = lane & 15, l4 = lane >> 4;
  const int lr2 = lane >> 2;
  const int cg  = (lane & 3) ^ (((lane >> 5) & 1) << 1);   // source pre-swizzle (involution)

  // bijective chunked XCD map
  const int nwg = nRT * nCT;
  int lb = ((int)blockIdx.x % 8) * (nwg >> 3) + ((int)blockIdx.x >> 3);
  int rowT, colT;
  if (LSWZ == 0) { rowT = lb % nRT; colT = lb / nRT; }
  else           { colT = lb % nCT; rowT = lb / nCT; }
  const int row0 = rowT * 256, col0 = colT * 256;

  auto pa = [&](int h) -> unsigned short* { return lds + h * 16384; };
  auto pb = [&](int h) -> unsigned short* { return lds + h * 16384 + 8192; };

  const unsigned short *aSrc0, *aSrc1;
  if constexpr (AGATHER) {
    aSrc0 = Ab + (size_t)gidx[row0 + w * 32 + lr2] * Kdim + cg * 8;
    aSrc1 = Ab + (size_t)gidx[row0 + w * 32 + 16 + lr2] * Kdim + cg * 8;
  } else {
    aSrc0 = Ab + (size_t)(row0 + w * 32 + lr2) * Kdim + cg * 8;
    aSrc1 = aSrc0 + (size_t)16 * Kdim;
  }
  const unsigned short* bSrc0 = Bb + (size_t)(col0 + w * 32 + lr2) * Kdim + cg * 8;
  const unsigned short* bSrc1 = bSrc0 + (size_t)16 * Kdim;

  f32x4 acc[8][4];
  #pragma unroll
  for (int i = 0; i < 8; i++)
    #pragma unroll
    for (int j = 0; j < 4; j++) acc[i][j] = (f32x4){0.f, 0.f, 0.f, 0.f};

  const int NH = Kdim >> 5;                 // K half-tiles of 32
  #pragma unroll
  for (int h = 0; h < 3; ++h) {
    const int ko = h * 32;
    gload16(aSrc0 + ko, pa(h) + w*32*32);
    gload16(aSrc1 + ko, pa(h) + (w*32+16)*32);
    gload16(bSrc0 + ko, pb(h) + w*32*32);
    gload16(bSrc1 + ko, pb(h) + (w*32+16)*32);
  }
  asm volatile("s_waitcnt vmcnt(8)" ::: "memory");   // half 0 landed
  __builtin_amdgcn_s_barrier();
  MEMFENCE;

  for (int hs = 0; hs < NH; ++hs) {
    const int cur = hs & 3;
    const unsigned short* Ap = pa(cur);
    const unsigned short* Bp = pb(cur);
    const int h3 = (hs + 3) & 3, ko3 = (hs + 3) * 32;
    const bool pf = (hs + 3) < NH;
    bf16x8 bfr[4], af[4];

    // ---- phase 0: B frags + A rows 0..63 ----
    #pragma unroll
    for (int ni = 0; ni < 4; ni++) {
      int row = wc * 64 + ni * 16 + l15;
      int c8 = l4 ^ (((row >> 3) & 1) << 1);
      bfr[ni] = *(const bf16x8*)&Bp[row * 32 + c8 * 8];
    }
    #pragma unroll
    for (int m = 0; m < 4; m++) {
      int row = wr * 128 + m * 16 + l15;
      int c8 = l4 ^ (((row >> 3) & 1) << 1);
      af[m] = *(const bf16x8*)&Ap[row * 32 + c8 * 8];
    }
    if (pf) {
      gload16(aSrc0 + ko3, pa(h3) + w*32*32);
      gload16(aSrc1 + ko3, pa(h3) + (w*32+16)*32);
    }
    MEMFENCE; __builtin_amdgcn_s_barrier(); MEMFENCE;
    __builtin_amdgcn_s_setprio(1);
    #pragma unroll
    for (int m = 0; m < 4; m++)
      #pragma unroll
      for (int ni = 0; ni < 4; ni++)
        acc[m][ni] = __builtin_amdgcn_mfma_f32_16x16x32_bf16(af[m], bfr[ni], acc[m][ni], 0, 0, 0);
    __builtin_amdgcn_s_setprio(0);
    MEMFENCE; __builtin_amdgcn_s_barrier(); MEMFENCE;

    // ---- phase 1: A rows 64..127 ----
    #pragma unroll
    for (int m = 0; m < 4; m++) {
      int row = wr * 128 + (4 + m) * 16 + l15;
      int c8 = l4 ^ (((row >> 3) & 1) << 1);
      af[m] = *(const bf16x8*)&Ap[row * 32 + c8 * 8];
    }
    if (pf) {
      gload16(bSrc0 + ko3, pb(h3) + w*32*32);
      gload16(bSrc1 + ko3, pb(h3) + (w*32+16)*32);
    }
    MEMFENCE; __builtin_amdgcn_s_barrier(); MEMFENCE;
    __builtin_amdgcn_s_setprio(1);
    #pragma unroll
    for (int m = 0; m < 4; m++)
      #pragma unroll
      for (int ni = 0; ni < 4; ni++)
        acc[4 + m][ni] = __builtin_amdgcn_mfma_f32_16x16x32_bf16(af[m], bfr[ni], acc[4 + m][ni], 0, 0, 0);
    __builtin_amdgcn_s_setprio(0);

    if (hs + 1 < NH) {
      const int rem = NH - 2 - hs;          // prefetched halves beyond hs+1
      if (rem >= 2)      asm volatile("s_waitcnt vmcnt(8)" ::: "memory");
      else if (rem == 1) asm volatile("s_waitcnt vmcnt(4)" ::: "memory");
      else               asm volatile("s_waitcnt vmcnt(0)" ::: "memory");
      __builtin_amdgcn_s_barrier();
      MEMFENCE;
    }
  }

  #pragma unroll
  for (int m = 0; m < 8; m++) {
    #pragma unroll
    for (int ni = 0; ni < 4; ni++) {
      int col  = col0 + wc * 64 + ni * 16 + l15;
      int rowb = row0 + wr * 128 + m * 16 + l4 * 4;
      #pragma unroll
      for (int r = 0; r < 4; r++) {
        float v = acc[m][ni][r];
        if constexpr (EPI == 4) {
          Cf[(size_t)(rowb + r) * Ndim + col] = v;
        } else if constexpr (EPI == 5) {
          cb0[(size_t)(rowb + r) * Ndim + col] = f2b(v);
        } else {
          unsigned short* cb = (col >> 10) ? cb1 : cb0;
          cb[(size_t)(rowb + r) * 1024 + (col & 1023)] = f2b(v + bias[col]);
        }
      }
    }
  }
}

// ---------------- GEMM 128x128 (2-phase) for the small GEMMs ----------------
template<int EPI, bool AGATHER, bool SWAPG, int NOUT>
__global__ __launch_bounds__(256) void k_gemm(
    const unsigned short* __restrict__ Ab, const unsigned short* __restrict__ Bb,
    const int* __restrict__ gidx,
    const float* __restrict__ bias, const float* __restrict__ resid,
    float* __restrict__ Cf, unsigned short* __restrict__ cb0,
    unsigned short* __restrict__ cb1, unsigned short* __restrict__ cb2,
    int Ndim, int Kdim) {
  __shared__ unsigned short As[128][32];
  __shared__ unsigned short Bs[128][32];
  const int t = threadIdx.x, lane = t & 63, w = t >> 6;
  const int wr = w >> 1, wc = w & 1, l15 = lane & 15, l4 = lane >> 4;
  const int row0 = (SWAPG ? blockIdx.x : blockIdx.y) * 128;
  const int col0 = (SWAPG ? blockIdx.y : blockIdx.x) * 128;
  const int c8  = (lane & 3) * 8;
  const int r16 = lane >> 2;
  const int rA0 = w * 32 + r16, rA1 = rA0 + 16;

  size_t raA0, raA1, raB0, raB1;
  if constexpr (AGATHER) {
    raA0 = (size_t)gidx[row0 + rA0] * Kdim;
    raA1 = (size_t)gidx[row0 + rA1] * Kdim;
  } else {
    raA0 = (size_t)(row0 + rA0) * Kdim;
    raA1 = (size_t)(row0 + rA1) * Kdim;
  }
  raB0 = (size_t)(col0 + rA0) * Kdim;
  raB1 = (size_t)(col0 + rA1) * Kdim;

  f32x4 acc[4][4];
  #pragma unroll
  for (int i = 0; i < 4; i++)
    #pragma unroll
    for (int j = 0; j < 4; j++) acc[i][j] = (f32x4){0.f,0.f,0.f,0.f};

  for (int kt0 = 0; kt0 < Kdim; kt0 += 32) {
    __syncthreads();
    gload16(Ab + raA0 + kt0 + c8, &As[w * 32][0]);
    gload16(Ab + raA1 + kt0 + c8, &As[w * 32 + 16][0]);
    gload16(Bb + raB0 + kt0 + c8, &Bs[w * 32][0]);
    gload16(Bb + raB1 + kt0 + c8, &Bs[w * 32 + 16][0]);
    __syncthreads();
    bf16x8 af[4], bfr[4];
    #pragma unroll
    for (int mi = 0; mi < 4; mi++) af[mi]  = *(const bf16x8*)&As[wr*64 + mi*16 + l15][l4*8];
    #pragma unroll
    for (int ni = 0; ni < 4; ni++) bfr[ni] = *(const bf16x8*)&Bs[wc*64 + ni*16 + l15][l4*8];
    #pragma unroll
    for (int mi = 0; mi < 4; mi++)
      #pragma unroll
      for (int ni = 0; ni < 4; ni++)
        acc[mi][ni] = __builtin_amdgcn_mfma_f32_16x16x32_bf16(af[mi], bfr[ni], acc[mi][ni], 0, 0, 0);
  }

  unsigned short* cbase = cb0;
  int colsub = 0;
  if constexpr (NOUT > 1) {
    int which = col0 >> 10;
    cbase = (which == 0) ? cb0 : (which == 1) ? cb1 : cb2;
    colsub = col0 & 1023;
  }

  #pragma unroll
  for (int mi = 0; mi < 4; mi++) {
    #pragma unroll
    for (int ni = 0; ni < 4; ni++) {
      int col  = col0 + wc*64 + ni*16 + l15;
      int rowb = row0 + wr*64 + mi*16 + l4*4;
      #pragma unroll
      for (int r = 0; r < 4; r++) {
        float v = acc[mi][ni][r];
        size_t off = (size_t)(rowb + r) * Ndim + col;
        if constexpr (EPI == 0) {
          if constexpr (NOUT > 1) {
            int c2 = colsub + wc*64 + ni*16 + l15;
            cbase[(size_t)(rowb + r) * 1024 + c2] = f2b(v + bias[col]);
          } else {
            cb0[off] = f2b(v + bias[col]);
          }
        } else if constexpr (EPI == 1) {
          Cf[off] = v + bias[col] + resid[off];
        } else if constexpr (EPI == 2) {
          float u = v + bias[col];
          u = 0.5f * u * (1.0f + erff(u * 0.70710678118654752f));
          cb0[off] = f2b(u);
        } else {
          Cf[off] = v;
        }
      }
    }
  }
}

// ---------------- fused attention (flash-style) with optional KV-split ----------------
template<int SPLIT>
__global__ __launch_bounds__(256) void k_attn(
    const unsigned short* __restrict__ Qp, const unsigned short* __restrict__ Kp,
    const unsigned short* __restrict__ Vp, unsigned short* __restrict__ Op,
    float* __restrict__ PO, float* __restrict__ PM, float* __restrict__ PL, int Lk) {
  __shared__ unsigned short Ks[64][72];
  __shared__ unsigned short Vt[64][72];   // V transposed (k-chunk XOR-swizzled by d>>3)
  __shared__ float Ps[4][16][68];         // per-wave P transpose buffer
  const int b = blockIdx.z / SPLIT, sp = blockIdx.z % SPLIT;
  const int h = blockIdx.y, q0 = blockIdx.x * 64;
  const int t = threadIdx.x, lane = t & 63, w = t >> 6;
  const int l15 = lane & 15, l4 = lane >> 4;

  const int qrow = q0 + w * 16 + l15;
  const unsigned short* qptr = Qp + (size_t)(b * Sn + qrow) * En + h * 64 + l4 * 8;
  bf16x8 qf0 = *(const bf16x8*)qptr;
  bf16x8 qf1 = *(const bf16x8*)(qptr + 32);

  f32x4 oacc[4];
  #pragma unroll
  for (int i = 0; i < 4; i++) oacc[i] = (f32x4){0.f,0.f,0.f,0.f};
  float m_[4] = {-INFINITY, -INFINITY, -INFINITY, -INFINITY};
  float l_[4] = {0.f, 0.f, 0.f, 0.f};

  const int nkt = Lk / (64 * SPLIT);
  for (int kt = sp * nkt; kt < (sp + 1) * nkt; ++kt) {
    __syncthreads();
    #pragma unroll
    for (int i = 0; i < 2; i++) {
      int ld = t + i * 256;
      int kr = ld >> 3, d8 = (ld & 7) * 8;
      size_t base = (size_t)(b * Lk + kt * 64 + kr) * En + h * 64 + d8;
      *(uint4*)&Ks[kr][d8] = *(const uint4*)(Kp + base);
      bf16x8 vv = *(const bf16x8*)(Vp + base);
      int colswz = kr ^ ((t & 7) << 3);
      #pragma unroll
      for (int j = 0; j < 8; j++) Vt[d8 + j][colswz] = ((unsigned short*)&vv)[j];
    }
    __syncthreads();

    f32x4 s[4];
    #pragma unroll
    for (int ni = 0; ni < 4; ni++) {
      s[ni] = (f32x4){0.f,0.f,0.f,0.f};
      bf16x8 kb0 = *(const bf16x8*)&Ks[ni*16 + l15][l4*8];
      bf16x8 kb1 = *(const bf16x8*)&Ks[ni*16 + l15][l4*8 + 32];
      s[ni] = __builtin_amdgcn_mfma_f32_16x16x32_bf16(qf0, kb0, s[ni], 0, 0, 0);
      s[ni] = __builtin_amdgcn_mfma_f32_16x16x32_bf16(qf1, kb1, s[ni], 0, 0, 0);
    }

    #pragma unroll
    for (int r = 0; r < 4; r++) {
      #pragma unroll
      for (int ni = 0; ni < 4; ni++) s[ni][r] *= 0.125f;
      float mx = fmaxf(fmaxf(s[0][r], s[1][r]), fmaxf(s[2][r], s[3][r]));
      #pragma unroll
      for (int d2 = 1; d2 < 16; d2 <<= 1) mx = fmaxf(mx, __shfl_xor(mx, d2));
      float mn = fmaxf(m_[r], mx);
      float alpha = expf(m_[r] - mn);
      float rsum = 0.f;
      #pragma unroll
      for (int ni = 0; ni < 4; ni++) { float p = expf(s[ni][r] - mn); s[ni][r] = p; rsum += p; }
      #pragma unroll
      for (int d2 = 1; d2 < 16; d2 <<= 1) rsum += __shfl_xor(rsum, d2);
      l_[r] = l_[r] * alpha + rsum;
      m_[r] = mn;
      #pragma unroll
      for (int nd = 0; nd < 4; nd++) oacc[nd][r] *= alpha;
    }

    #pragma unroll
    for (int ni = 0; ni < 4; ni++)
      #pragma unroll
      for (int r = 0; r < 4; r++)
        Ps[w][l4*4 + r][ni*16 + l15] = s[ni][r];
    asm volatile("s_waitcnt lgkmcnt(0)" ::: "memory");

    #pragma unroll
    for (int half = 0; half < 2; half++) {
      float4 pv0 = *(const float4*)&Ps[w][l15][half*32 + l4*8];
      float4 pv1 = *(const float4*)&Ps[w][l15][half*32 + l4*8 + 4];
      bf16x8 pa;
      pa[0]=(short)f2b(pv0.x); pa[1]=(short)f2b(pv0.y); pa[2]=(short)f2b(pv0.z); pa[3]=(short)f2b(pv0.w);
      pa[4]=(short)f2b(pv1.x); pa[5]=(short)f2b(pv1.y); pa[6]=(short)f2b(pv1.z); pa[7]=(short)f2b(pv1.w);
      #pragma unroll
      for (int nd = 0; nd < 4; nd++) {
        int dd = nd*16 + l15;
        bf16x8 vb = *(const bf16x8*)&Vt[dd][(half*32 + l4*8) ^ (((dd >> 3) & 7) << 3)];
        oacc[nd] = __builtin_amdgcn_mfma_f32_16x16x32_bf16(pa, vb, oacc[nd], 0, 0, 0);
      }
    }
  }

  if constexpr (SPLIT == 1) {
    #pragma unroll
    for (int nd = 0; nd < 4; nd++)
      #pragma unroll
      for (int r = 0; r < 4; r++) {
        int q = q0 + w*16 + l4*4 + r;
        Op[(size_t)(b * Sn + q) * En + h * 64 + nd*16 + l15] = f2b(oacc[nd][r] / l_[r]);
      }
  } else {
    const int slot = ((b * Hn + h) * 4 + blockIdx.x) * SPLIT + sp;
    #pragma unroll
    for (int nd = 0; nd < 4; nd++)
      #pragma unroll
      for (int r = 0; r < 4; r++)
        PO[slot * 4096 + (w*16 + l4*4 + r) * 64 + nd*16 + l15] = oacc[nd][r];
    if (l15 == 0) {
      #pragma unroll
      for (int r = 0; r < 4; r++) {
        PM[slot * 64 + w*16 + l4*4 + r] = m_[r];
        PL[slot * 64 + w*16 + l4*4 + r] = l_[r];
      }
    }
  }
}

// ---------------- combine split-K attention partials (SPLIT=4) ----------------
__global__ __launch_bounds__(256) void k_attn_comb(
    const float* __restrict__ PO, const float* __restrict__ PM,
    const float* __restrict__ PL, unsigned short* __restrict__ Op) {
  const int W = blockIdx.x * 4 + (threadIdx.x >> 6);
  const int lane = threadIdx.x & 63;
  const int bh = W >> 8, q = W & 255;
  const int qb = q >> 6, qq = q & 63;
  const int slotBase = (bh * 4 + qb) * 4;
  float ms[4];
  float M = -INFINITY;
  #pragma unroll
  for (int s = 0; s < 4; s++) { ms[s] = PM[(slotBase + s) * 64 + qq]; M = fmaxf(M, ms[s]); }
  float L = 0.f, acc = 0.f;
  #pragma unroll
  for (int s = 0; s < 4; s++) {
    float wgt = expf(ms[s] - M);
    L += PL[(slotBase + s) * 64 + qq] * wgt;
    acc += wgt * PO[(size_t)(slotBase + s) * 4096 + qq * 64 + lane];
  }
  const int b = bh >> 4, h = bh & 15;
  Op[(size_t)(b * Sn + q) * En + h * 64 + lane] = f2b(acc / L);
}

// ------------- helpers for radix top-k -------------
DEVFN unsigned blk_exscan(unsigned part, volatile unsigned* wsum, int lane, int wid) {
  unsigned v = part;
  #pragma unroll
  for (int d = 1; d < 64; d <<= 1) { unsigned o = __shfl_up(v, d); if (lane >= d) v += o; }
  if (lane == 63) wsum[wid] = v;
  __syncthreads();
  unsigned woff = 0;
  for (int i = 0; i < wid; i++) woff += wsum[i];
  unsigned r = woff + v - part;
  __syncthreads();
  return r;
}

DEVFN void find_thr(const unsigned* hist, int NB, unsigned need,
                    int t, int lane, int wid, volatile unsigned* wsum,
                    volatile int* s_thr, volatile unsigned* s_above) {
  int per = NB >> 9;
  int lo = NB - per * (t + 1);
  unsigned part = 0;
  for (int j = 0; j < per; j++) part += hist[lo + j];
  unsigned ex = blk_exscan(part, wsum, lane, wid);
  if (ex < need && ex + part >= need) {
    unsigned c = ex;
    for (int j = per - 1; j >= 0; j--) {
      unsigned h = hist[lo + j];
      if (c + h >= need) { *s_thr = lo + j; *s_above = c; break; }
      c += h;
    }
  }
  __syncthreads();
}

// ------- exact top-32 per row on bf16 keys: 11-bit + 5-bit radix + tie pass -------
// Single shared histogram (8 KiB LDS) -- occupancy/MLP is the limiter, not atomics.
__global__ __launch_bounds__(512) void k_topk16(
    const unsigned short* __restrict__ simsb, int* __restrict__ oidx) {
  const int n = blockIdx.x, t = threadIdx.x;
  const int lane = t & 63, wid = t >> 6;
  const u16x8* row8 = (const u16x8*)(simsb + (size_t)n * Mn);
  __shared__ unsigned hist[2048];
  __shared__ unsigned wsum[8];
  __shared__ int s_thr;
  __shared__ unsigned s_above;
  __shared__ unsigned h2[32];
  __shared__ int slist[32];
  __shared__ unsigned sL, sneedEq, stie;

  for (int i = t; i < 2048; i += 512) hist[i] = 0;
  if (t < 32) h2[t] = 0;
  __syncthreads();
  #pragma unroll 4
  for (int p = 0; p < 16; p++) {
    u16x8 v = row8[p * 512 + t];
    #pragma unroll
    for (int j = 0; j < 8; j++) atomicAdd(&hist[okey16(v[j]) >> 5], 1u);
  }
  __syncthreads();
  find_thr(hist, 2048, 32, t, lane, wid, wsum, &s_thr, &s_above);
  const unsigned T1 = (unsigned)s_thr;
  const unsigned need2 = 32 - s_above;
  const unsigned cnt1 = hist[T1];

  unsigned L, istar = 0xFFFFFFFFu;
  if (cnt1 == need2) {
    L = T1 << 5;                                   // whole bin accepted
  } else {
    // P2: low-5-bit histogram within bin T1 (L2/L3-resident re-read)
    for (int p = 0; p < 16; p++) {
      u16x8 v = row8[p * 512 + t];
      #pragma unroll
      for (int j = 0; j < 8; j++) {
        unsigned k = okey16(v[j]);
        if ((k >> 5) == T1) atomicAdd(&h2[k & 31], 1u);
      }
    }
    __syncthreads();
    if (t == 0) {
      unsigned cum = 0; int T3 = 0; unsigned above = 0;
      for (int j = 31; j >= 0; j--) {
        if (cum + h2[j] >= need2) { T3 = j; above = cum; break; }
        cum += h2[j];
      }
      sL = (T1 << 5) | (unsigned)T3;
      sneedEq = need2 - above;
      stie = (h2[T3] != need2 - above);            // excess exact ties?
    }
    __syncthreads();
    L = sL;
    if (stie) {
      // ordered compaction over contiguous per-thread segments -> smallest needEq indices
      const unsigned short* rowp = simsb + (size_t)n * Mn;
      unsigned cntLoc = 0;
      for (int j = 0; j < 128; j++)
        if (okey16(rowp[t * 128 + j]) == L) cntLoc++;
      unsigned pre = blk_exscan(cntLoc, wsum, lane, wid);
      unsigned c = 0;
      for (int j = 0; j < 128; j++)
        if (okey16(rowp[t * 128 + j]) == L) { if (pre + c < 32) slist[pre + c] = t * 128 + j; c++; }
      __syncthreads();
      istar = (unsigned)slist[sneedEq - 1];
    }
  }
  __syncthreads();

  // emit (set-exact; order deterministic via exscan)
  unsigned cnt = 0;
  for (int p = 0; p < 16; p++) {
    u16x8 v = row8[p * 512 + t];
    unsigned i0 = (unsigned)(p * 512 + t) * 8;
    #pragma unroll
    for (int j = 0; j < 8; j++) {
      unsigned k = okey16(v[j]);
      cnt += (k > L || (k == L && i0 + j <= istar));
    }
  }
  unsigned pos = blk_exscan(cnt, wsum, lane, wid);
  for (int p = 0; p < 16; p++) {
    u16x8 v = row8[p * 512 + t];
    unsigned i0 = (unsigned)(p * 512 + t) * 8;
    #pragma unroll
    for (int j = 0; j < 8; j++) {
      unsigned k = okey16(v[j]);
      if (k > L || (k == L && i0 + j <= istar)) oidx[n * Kt + pos++] = (int)(i0 + j);
    }
  }
}

// =============================== host ===============================
extern "C" void kernel_launch(void* const* d_in, const int* in_sizes, int n_in,
                              void* d_out, int out_size, void* d_ws, size_t ws_size,
                              hipStream_t stream) {
  (void)in_sizes; (void)n_in; (void)out_size;
  const float* x      = (const float*)d_in[0];
  const float* mem_k  = (const float*)d_in[1];
  const float* mem_v  = (const float*)d_in[2];
  const float* sa_w[4] = {(const float*)d_in[3], (const float*)d_in[4], (const float*)d_in[5], (const float*)d_in[6]};
  const float* sa_b[4] = {(const float*)d_in[7], (const float*)d_in[8], (const float*)d_in[9], (const float*)d_in[10]};
  const float* ma_w[4] = {(const float*)d_in[11], (const float*)d_in[12], (const float*)d_in[13], (const float*)d_in[14]};
  const float* ma_b[4] = {(const float*)d_in[15], (const float*)d_in[16], (const float*)d_in[17], (const float*)d_in[18]};
  const float* ln_g[3] = {(const float*)d_in[19], (const float*)d_in[21], (const float*)d_in[23]};
  const float* ln_b[3] = {(const float*)d_in[20], (const float*)d_in[22], (const float*)d_in[24]};
  const float* fc1_w = (const float*)d_in[25];
  const float* fc1_b = (const float*)d_in[26];
  const float* fc2_w = (const float*)d_in[27];
  const float* fc2_b = (const float*)d_in[28];
  float* out = (float*)d_out;

  char* ws = (char*)d_ws;
  size_t off = 0;
  auto alloc = [&](size_t bytes) -> char* {
    char* p = ws + off;
    off = (off + bytes + 255) & ~(size_t)255;
    return p;
  };

  unsigned short* wt[8];
  for (int i = 0; i < 8; i++) wt[i] = (unsigned short*)alloc((size_t)En * En * 2);  // contiguous
  unsigned short* fc1t  = (unsigned short*)alloc((size_t)FFn * En * 2);
  unsigned short* fc2t  = (unsigned short*)alloc((size_t)En * FFn * 2);
  unsigned short* xb    = (unsigned short*)alloc((size_t)NT * En * 2);
  unsigned short* Qb    = (unsigned short*)alloc((size_t)NT * En * 2);
  unsigned short* Kb    = (unsigned short*)alloc((size_t)NT * En * 2);
  unsigned short* Vb    = (unsigned short*)alloc((size_t)NT * En * 2);
  unsigned short* at1b  = (unsigned short*)alloc((size_t)NT * En * 2);
  float*          t1    = (float*)alloc((size_t)NT * En * 4);
  float*          x1f   = (float*)alloc((size_t)NT * En * 4);
  unsigned short* x1b   = (unsigned short*)alloc((size_t)NT * En * 2);
  char*           simsRaw = alloc((size_t)NT * Mn * 4);                // 256 MiB region
  int*            idx   = (int*)alloc((size_t)NT * Kt * 4);
  unsigned short* K2b   = (unsigned short*)alloc((size_t)NT * Kt * En * 2);  // 64 MiB
  unsigned short* V2b   = (unsigned short*)alloc((size_t)NT * Kt * En * 2);  // contiguous after K2b
  unsigned short* Q2b   = (unsigned short*)alloc((size_t)NT * En * 2);
  unsigned short* at2b  = (unsigned short*)alloc((size_t)NT * En * 2);
  float*          t2    = (float*)alloc((size_t)NT * En * 4);
  float*          x2f   = (float*)alloc((size_t)NT * En * 4);
  unsigned short* x2b   = (unsigned short*)alloc((size_t)NT * En * 2);
  unsigned short* hb    = (unsigned short*)alloc((size_t)NT * FFn * 2);
  float*          t3    = (float*)alloc((size_t)NT * En * 4);
  float*          bcat_sa = (float*)alloc(3072 * 4);
  float*          bcat_ma = (float*)alloc(2048 * 4);

  if (off > ws_size) return;   // insufficient workspace: leave output poisoned (fail loudly)

  // Overlays (dead-region reuse):
  unsigned short* simsb = (unsigned short*)simsRaw;   // bf16 sims: 128 MiB of the region
  unsigned short* mkb = (unsigned short*)K2b;         // until sims GEMM done
  unsigned short* mvb = (unsigned short*)simsRaw;     // after topk
  float* PO = (float*)(simsRaw + (size_t)128 * 1024 * 1024);
  float* PM = PO + (size_t)1024 * 4096;
  float* PL = PM + (size_t)1024 * 64;

  // allow 128 KiB dynamic LDS for the 256^2 kernels (best effort)
  (void)hipFuncSetAttribute((const void*)&k_gemm256<5,false,1,0>,
                            hipFuncAttributeMaxDynamicSharedMemorySize, 131072);
  (void)hipFuncSetAttribute((const void*)&k_gemm256<0,true,2,1>,
                            hipFuncAttributeMaxDynamicSharedMemorySize, 131072);

  // ---- prep: weight transposes to bf16 [N][K], bias concats ----
  for (int i = 0; i < 4; i++)
    k_transpose_bf16<<<dim3(16, 16), 256, 0, stream>>>(sa_w[i], wt[i], En, En);
  for (int i = 0; i < 4; i++)
    k_transpose_bf16<<<dim3(16, 16), 256, 0, stream>>>(ma_w[i], wt[4 + i], En, En);
  k_transpose_bf16<<<dim3(64, 16), 256, 0, stream>>>(fc1_w, fc1t, En, FFn);
  k_transpose_bf16<<<dim3(16, 64), 256, 0, stream>>>(fc2_w, fc2t, FFn, En);
  k_concat3<<<dim3(12), 256, 0, stream>>>(sa_b[0], sa_b[1], sa_b[2], bcat_sa);
  k_concat3<<<dim3(8),  256, 0, stream>>>(ma_b[1], ma_b[2], ma_b[2], bcat_ma);

  k_cvt_bf16<<<dim3(NT * En / 4 / 256), 256, 0, stream>>>(x, xb, NT * En / 4);
  k_normcvt<<<dim3(Mn), 256, 0, stream>>>(mem_k, mkb);

  const dim3 g1(En / 128, NT / 128);   // (8,8)

  // ---- self-attention (QKV fused: N=3072 over contiguous wt[0..2]) ----
  k_gemm<0,false,false,3><<<dim3(24, 8), 256, 0, stream>>>(xb, wt[0], nullptr, bcat_sa, nullptr, nullptr, Qb, Kb, Vb, 3072, En);
  k_attn<1><<<dim3(Sn / 64, Hn, Bn), 256, 0, stream>>>(Qb, Kb, Vb, at1b, nullptr, nullptr, nullptr, Sn);
  k_gemm<1,false,false,1><<<g1, 256, 0, stream>>>(at1b, wt[3], nullptr, sa_b[3], x, t1, nullptr, nullptr, nullptr, En, En);
  k_layernorm<<<NT, 256, 0, stream>>>(t1, ln_g[0], ln_b[0], x1f, x1b);

  // ---- retrieval: sims in bf16 (L3-resident) + 16-bit radix top-k ----
  k_gemm256<5,false,1,0><<<dim3(1024), 512, 131072, stream>>>(
      x1b, mkb, nullptr, nullptr, nullptr, simsb, nullptr, Mn, En, NT / 256, Mn / 256);
  k_topk16<<<NT, 512, 0, stream>>>(simsb, idx);

  // ---- memory cross-attention (K2/V2 fused 256^2 over contiguous wt[5..6]) ----
  k_cvt_bf16<<<dim3(Mn * En / 4 / 256), 256, 0, stream>>>(mem_v, mvb, Mn * En / 4);
  k_gemm256<0,true,2,1><<<dim3(1024), 512, 131072, stream>>>(
      mvb, wt[5], idx, bcat_ma, nullptr, K2b, V2b, 2048, En, NT * Kt / 256, 2048 / 256);
  k_gemm<0,false,false,1><<<g1, 256, 0, stream>>>(x1b, wt[4], nullptr, ma_b[0], nullptr, nullptr, Q2b, nullptr, nullptr, En, En);
  k_attn<4><<<dim3(Sn / 64, Hn, Bn * 4), 256, 0, stream>>>(Q2b, K2b, V2b, nullptr, PO, PM, PL, Sn * Kt);
  k_attn_comb<<<dim3(Bn * Hn * Sn / 4), 256, 0, stream>>>(PO, PM, PL, at2b);
  k_gemm<1,false,false,1><<<g1, 256, 0, stream>>>(at2b, wt[7], nullptr, ma_b[3], x1f, t2, nullptr, nullptr, nullptr, En, En);
  k_layernorm<<<NT, 256, 0, stream>>>(t2, ln_g[1], ln_b[1], x2f, x2b);

  // ---- FFN ----
  k_gemm<2,false,false,1><<<dim3(FFn / 128, NT / 128), 256, 0, stream>>>(x2b, fc1t, nullptr, fc1_b, nullptr, nullptr, hb, nullptr, nullptr, FFn, En);
  k_gemm<1,false,false,1><<<g1, 256, 0, stream>>>(hb, fc2t, nullptr, fc2_b, x2f, t3, nullptr, nullptr, nullptr, En, FFn);
  k_layernorm<<<NT, 256, 0, stream>>>(t3, ln_g[2], ln_b[2], out, nullptr);
}

// Round 9
// 997.537 us; speedup vs baseline: 1.2830x; 1.2830x over previous
//
#include <hip/hip_runtime.h>
#include <hip/hip_bf16.h>
#include <math.h>

#define DEVFN __device__ __forceinline__

typedef __attribute__((ext_vector_type(8))) short bf16x8;
typedef __attribute__((ext_vector_type(8))) unsigned short u16x8;
typedef __attribute__((ext_vector_type(4))) float f32x4;

static constexpr int Bn = 4, Sn = 256, En = 1024, Hn = 16;
static constexpr int Mn = 65536, Kt = 32, FFn = 4096;
static constexpr int NT = Bn * Sn;           // 1024 tokens

DEVFN unsigned short f2b(float f) {          // f32 -> bf16 RNE
  unsigned int u = __float_as_uint(f);
  unsigned int r = (u + 0x7FFFu + ((u >> 16) & 1u)) >> 16;
  return (unsigned short)r;
}

DEVFN unsigned okey16(unsigned short u) {    // order-preserving bf16 -> u16
  return (unsigned)(u ^ ((u >> 15) ? 0xFFFFu : 0x8000u)) & 0xFFFFu;
}

typedef const __attribute__((address_space(1))) void* as1cv_t;
typedef __attribute__((address_space(3))) void* as3v_t;
DEVFN void gload16(const void* g, void* l) {   // async global->LDS, 16B/lane
  __builtin_amdgcn_global_load_lds((as1cv_t)g, (as3v_t)l, 16, 0, 0);
}
#define MEMFENCE asm volatile("" ::: "memory")

// ---------------- transpose W[R][C] f32 -> out[C][R] bf16 ----------------
__global__ __launch_bounds__(256) void k_transpose_bf16(
    const float* __restrict__ in, unsigned short* __restrict__ out, int R, int C) {
  __shared__ float tile[64][65];
  int tx = threadIdx.x & 63, ty = threadIdx.x >> 6;
  int c0 = blockIdx.x * 64, r0 = blockIdx.y * 64;
  #pragma unroll
  for (int i = 0; i < 16; i++) {
    int r = ty + i * 4;
    tile[tx][r] = in[(size_t)(r0 + r) * C + (c0 + tx)];
  }
  __syncthreads();
  #pragma unroll
  for (int i = 0; i < 16; i++) {
    int c = ty + i * 4;
    out[(size_t)(c0 + c) * R + (r0 + tx)] = f2b(tile[c][tx]);
  }
}

// ---------------- f32 -> bf16 elementwise (x4) ----------------
__global__ __launch_bounds__(256) void k_cvt_bf16(
    const float* __restrict__ in, unsigned short* __restrict__ out, int n4) {
  int i = blockIdx.x * 256 + threadIdx.x;
  if (i >= n4) return;
  float4 v = ((const float4*)in)[i];
  uint2 o;
  o.x = (unsigned int)f2b(v.x) | ((unsigned int)f2b(v.y) << 16);
  o.y = (unsigned int)f2b(v.z) | ((unsigned int)f2b(v.w) << 16);
  ((uint2*)out)[i] = o;
}

// ---------------- concat up to 3 x 1024-f32 vectors ----------------
__global__ __launch_bounds__(256) void k_concat3(
    const float* __restrict__ a, const float* __restrict__ b,
    const float* __restrict__ c, float* __restrict__ o) {
  int i = blockIdx.x * 256 + threadIdx.x;
  float v = (i < 1024) ? a[i] : (i < 2048) ? b[i - 1024] : c[i - 2048];
  o[i] = v;
}

// ---- mem_keys row-normalize + cvt to bf16 (folds cosine norm into B) ----
__global__ __launch_bounds__(256) void k_normcvt(
    const float* __restrict__ mk, unsigned short* __restrict__ out) {
  int m = blockIdx.x, t = threadIdx.x;
  float4 v = ((const float4*)(mk + (size_t)m * En))[t];
  float ss = v.x*v.x + v.y*v.y + v.z*v.z + v.w*v.w;
  #pragma unroll
  for (int d = 32; d; d >>= 1) ss += __shfl_down(ss, d);
  __shared__ float red[4];
  int lane = t & 63, w = t >> 6;
  if (lane == 0) red[w] = ss;
  __syncthreads();
  float rs = 1.0f / fmaxf(sqrtf(red[0] + red[1] + red[2] + red[3]), 1e-12f);
  uint2 o;
  o.x = (unsigned int)f2b(v.x * rs) | ((unsigned int)f2b(v.y * rs) << 16);
  o.y = (unsigned int)f2b(v.z * rs) | ((unsigned int)f2b(v.w * rs) << 16);
  ((uint2*)(out + (size_t)m * En))[t] = o;
}

// ---------------- LayerNorm over rows of [NT][En] ----------------
__global__ __launch_bounds__(256) void k_layernorm(
    const float* __restrict__ in, const float* __restrict__ g, const float* __restrict__ bb,
    float* __restrict__ outf, unsigned short* __restrict__ outb) {
  int n = blockIdx.x, t = threadIdx.x;
  float4 v = ((const float4*)(in + (size_t)n * En))[t];
  float s  = v.x + v.y + v.z + v.w;
  float s2 = v.x*v.x + v.y*v.y + v.z*v.z + v.w*v.w;
  #pragma unroll
  for (int d = 32; d; d >>= 1) { s += __shfl_down(s, d); s2 += __shfl_down(s2, d); }
  __shared__ float rs[4], rq[4];
  int lane = t & 63, w = t >> 6;
  if (lane == 0) { rs[w] = s; rq[w] = s2; }
  __syncthreads();
  float mean = (rs[0]+rs[1]+rs[2]+rs[3]) * (1.0f/En);
  float var  = (rq[0]+rq[1]+rq[2]+rq[3]) * (1.0f/En) - mean*mean;
  float rstd = rsqrtf(var + 1e-5f);
  float4 gg = ((const float4*)g)[t];
  float4 bv = ((const float4*)bb)[t];
  float o0 = (v.x-mean)*rstd*gg.x + bv.x;
  float o1 = (v.y-mean)*rstd*gg.y + bv.y;
  float o2 = (v.z-mean)*rstd*gg.z + bv.z;
  float o3 = (v.w-mean)*rstd*gg.w + bv.w;
  if (outf) { float4 ov = {o0,o1,o2,o3}; ((float4*)(outf + (size_t)n*En))[t] = ov; }
  if (outb) {
    uint2 o;
    o.x = (unsigned int)f2b(o0) | ((unsigned int)f2b(o1) << 16);
    o.y = (unsigned int)f2b(o2) | ((unsigned int)f2b(o3) << 16);
    ((uint2*)(outb + (size_t)n*En))[t] = o;
  }
}

// ======== 256x256 GEMM, 4 half-tile ring buffers + counted vmcnt (T1..T5) ========
// EPI 4: f32 out | EPI 5: bf16 out no-bias | EPI 0 + NOUT2: bf16 out (+bias), split N
// LDS 128 KiB: 4 half-buffers x (A[256][32] + B[256][32]) bf16, st_16x32 swizzle.
template<int EPI, bool AGATHER, int NOUT, int LSWZ>
__global__ __launch_bounds__(512) void k_gemm256(
    const unsigned short* __restrict__ Ab, const unsigned short* __restrict__ Bb,
    const int* __restrict__ gidx, const float* __restrict__ bias,
    float* __restrict__ Cf, unsigned short* __restrict__ cb0, unsigned short* __restrict__ cb1,
    int Ndim, int Kdim, int nRT, int nCT) {
  extern __shared__ unsigned short lds[];
  const int t = threadIdx.x, lane = t & 63, w = t >> 6;
  const int wr = w >> 2, wc = w & 3, l15 = lane & 15, l4 = lane >> 4;
  const int lr2 = lane >> 2;
  const int cg  = (lane & 3) ^ (((lane >> 5) & 1) << 1);   // source pre-swizzle (involution)

  // bijective chunked XCD map
  const int nwg = nRT * nCT;
  int lb = ((int)blockIdx.x % 8) * (nwg >> 3) + ((int)blockIdx.x >> 3);
  int rowT, colT;
  if (LSWZ == 0) { rowT = lb % nRT; colT = lb / nRT; }
  else           { colT = lb % nCT; rowT = lb / nCT; }
  const int row0 = rowT * 256, col0 = colT * 256;

  auto pa = [&](int h) -> unsigned short* { return lds + h * 16384; };
  auto pb = [&](int h) -> unsigned short* { return lds + h * 16384 + 8192; };

  const unsigned short *aSrc0, *aSrc1;
  if constexpr (AGATHER) {
    aSrc0 = Ab + (size_t)gidx[row0 + w * 32 + lr2] * Kdim + cg * 8;
    aSrc1 = Ab + (size_t)gidx[row0 + w * 32 + 16 + lr2] * Kdim + cg * 8;
  } else {
    aSrc0 = Ab + (size_t)(row0 + w * 32 + lr2) * Kdim + cg * 8;
    aSrc1 = aSrc0 + (size_t)16 * Kdim;
  }
  const unsigned short* bSrc0 = Bb + (size_t)(col0 + w * 32 + lr2) * Kdim + cg * 8;
  const unsigned short* bSrc1 = bSrc0 + (size_t)16 * Kdim;

  f32x4 acc[8][4];
  #pragma unroll
  for (int i = 0; i < 8; i++)
    #pragma unroll
    for (int j = 0; j < 4; j++) acc[i][j] = (f32x4){0.f, 0.f, 0.f, 0.f};

  const int NH = Kdim >> 5;                 // K half-tiles of 32
  #pragma unroll
  for (int h = 0; h < 3; ++h) {
    const int ko = h * 32;
    gload16(aSrc0 + ko, pa(h) + w*32*32);
    gload16(aSrc1 + ko, pa(h) + (w*32+16)*32);
    gload16(bSrc0 + ko, pb(h) + w*32*32);
    gload16(bSrc1 + ko, pb(h) + (w*32+16)*32);
  }
  asm volatile("s_waitcnt vmcnt(8)" ::: "memory");   // half 0 landed
  __builtin_amdgcn_s_barrier();
  MEMFENCE;

  for (int hs = 0; hs < NH; ++hs) {
    const int cur = hs & 3;
    const unsigned short* Ap = pa(cur);
    const unsigned short* Bp = pb(cur);
    const int h3 = (hs + 3) & 3, ko3 = (hs + 3) * 32;
    const bool pf = (hs + 3) < NH;
    bf16x8 bfr[4], af[4];

    // ---- phase 0: B frags + A rows 0..63 ----
    #pragma unroll
    for (int ni = 0; ni < 4; ni++) {
      int row = wc * 64 + ni * 16 + l15;
      int c8 = l4 ^ (((row >> 3) & 1) << 1);
      bfr[ni] = *(const bf16x8*)&Bp[row * 32 + c8 * 8];
    }
    #pragma unroll
    for (int m = 0; m < 4; m++) {
      int row = wr * 128 + m * 16 + l15;
      int c8 = l4 ^ (((row >> 3) & 1) << 1);
      af[m] = *(const bf16x8*)&Ap[row * 32 + c8 * 8];
    }
    if (pf) {
      gload16(aSrc0 + ko3, pa(h3) + w*32*32);
      gload16(aSrc1 + ko3, pa(h3) + (w*32+16)*32);
    }
    MEMFENCE; __builtin_amdgcn_s_barrier(); MEMFENCE;
    __builtin_amdgcn_s_setprio(1);
    #pragma unroll
    for (int m = 0; m < 4; m++)
      #pragma unroll
      for (int ni = 0; ni < 4; ni++)
        acc[m][ni] = __builtin_amdgcn_mfma_f32_16x16x32_bf16(af[m], bfr[ni], acc[m][ni], 0, 0, 0);
    __builtin_amdgcn_s_setprio(0);
    MEMFENCE; __builtin_amdgcn_s_barrier(); MEMFENCE;

    // ---- phase 1: A rows 64..127 ----
    #pragma unroll
    for (int m = 0; m < 4; m++) {
      int row = wr * 128 + (4 + m) * 16 + l15;
      int c8 = l4 ^ (((row >> 3) & 1) << 1);
      af[m] = *(const bf16x8*)&Ap[row * 32 + c8 * 8];
    }
    if (pf) {
      gload16(bSrc0 + ko3, pb(h3) + w*32*32);
      gload16(bSrc1 + ko3, pb(h3) + (w*32+16)*32);
    }
    MEMFENCE; __builtin_amdgcn_s_barrier(); MEMFENCE;
    __builtin_amdgcn_s_setprio(1);
    #pragma unroll
    for (int m = 0; m < 4; m++)
      #pragma unroll
      for (int ni = 0; ni < 4; ni++)
        acc[4 + m][ni] = __builtin_amdgcn_mfma_f32_16x16x32_bf16(af[m], bfr[ni], acc[4 + m][ni], 0, 0, 0);
    __builtin_amdgcn_s_setprio(0);

    if (hs + 1 < NH) {
      const int rem = NH - 2 - hs;          // prefetched halves beyond hs+1
      if (rem >= 2)      asm volatile("s_waitcnt vmcnt(8)" ::: "memory");
      else if (rem == 1) asm volatile("s_waitcnt vmcnt(4)" ::: "memory");
      else               asm volatile("s_waitcnt vmcnt(0)" ::: "memory");
      __builtin_amdgcn_s_barrier();
      MEMFENCE;
    }
  }

  #pragma unroll
  for (int m = 0; m < 8; m++) {
    #pragma unroll
    for (int ni = 0; ni < 4; ni++) {
      int col  = col0 + wc * 64 + ni * 16 + l15;
      int rowb = row0 + wr * 128 + m * 16 + l4 * 4;
      #pragma unroll
      for (int r = 0; r < 4; r++) {
        float v = acc[m][ni][r];
        if constexpr (EPI == 4) {
          Cf[(size_t)(rowb + r) * Ndim + col] = v;
        } else if constexpr (EPI == 5) {
          cb0[(size_t)(rowb + r) * Ndim + col] = f2b(v);
        } else {
          unsigned short* cb = (col >> 10) ? cb1 : cb0;
          cb[(size_t)(rowb + r) * 1024 + (col & 1023)] = f2b(v + bias[col]);
        }
      }
    }
  }
}

// ---------------- GEMM 128x128 (2-phase) for the small GEMMs ----------------
template<int EPI, bool AGATHER, bool SWAPG, int NOUT>
__global__ __launch_bounds__(256) void k_gemm(
    const unsigned short* __restrict__ Ab, const unsigned short* __restrict__ Bb,
    const int* __restrict__ gidx,
    const float* __restrict__ bias, const float* __restrict__ resid,
    float* __restrict__ Cf, unsigned short* __restrict__ cb0,
    unsigned short* __restrict__ cb1, unsigned short* __restrict__ cb2,
    int Ndim, int Kdim) {
  __shared__ unsigned short As[128][32];
  __shared__ unsigned short Bs[128][32];
  const int t = threadIdx.x, lane = t & 63, w = t >> 6;
  const int wr = w >> 1, wc = w & 1, l15 = lane & 15, l4 = lane >> 4;
  const int row0 = (SWAPG ? blockIdx.x : blockIdx.y) * 128;
  const int col0 = (SWAPG ? blockIdx.y : blockIdx.x) * 128;
  const int c8  = (lane & 3) * 8;
  const int r16 = lane >> 2;
  const int rA0 = w * 32 + r16, rA1 = rA0 + 16;

  size_t raA0, raA1, raB0, raB1;
  if constexpr (AGATHER) {
    raA0 = (size_t)gidx[row0 + rA0] * Kdim;
    raA1 = (size_t)gidx[row0 + rA1] * Kdim;
  } else {
    raA0 = (size_t)(row0 + rA0) * Kdim;
    raA1 = (size_t)(row0 + rA1) * Kdim;
  }
  raB0 = (size_t)(col0 + rA0) * Kdim;
  raB1 = (size_t)(col0 + rA1) * Kdim;

  f32x4 acc[4][4];
  #pragma unroll
  for (int i = 0; i < 4; i++)
    #pragma unroll
    for (int j = 0; j < 4; j++) acc[i][j] = (f32x4){0.f,0.f,0.f,0.f};

  for (int kt0 = 0; kt0 < Kdim; kt0 += 32) {
    __syncthreads();
    gload16(Ab + raA0 + kt0 + c8, &As[w * 32][0]);
    gload16(Ab + raA1 + kt0 + c8, &As[w * 32 + 16][0]);
    gload16(Bb + raB0 + kt0 + c8, &Bs[w * 32][0]);
    gload16(Bb + raB1 + kt0 + c8, &Bs[w * 32 + 16][0]);
    __syncthreads();
    bf16x8 af[4], bfr[4];
    #pragma unroll
    for (int mi = 0; mi < 4; mi++) af[mi]  = *(const bf16x8*)&As[wr*64 + mi*16 + l15][l4*8];
    #pragma unroll
    for (int ni = 0; ni < 4; ni++) bfr[ni] = *(const bf16x8*)&Bs[wc*64 + ni*16 + l15][l4*8];
    #pragma unroll
    for (int mi = 0; mi < 4; mi++)
      #pragma unroll
      for (int ni = 0; ni < 4; ni++)
        acc[mi][ni] = __builtin_amdgcn_mfma_f32_16x16x32_bf16(af[mi], bfr[ni], acc[mi][ni], 0, 0, 0);
  }

  unsigned short* cbase = cb0;
  int colsub = 0;
  if constexpr (NOUT > 1) {
    int which = col0 >> 10;
    cbase = (which == 0) ? cb0 : (which == 1) ? cb1 : cb2;
    colsub = col0 & 1023;
  }

  #pragma unroll
  for (int mi = 0; mi < 4; mi++) {
    #pragma unroll
    for (int ni = 0; ni < 4; ni++) {
      int col  = col0 + wc*64 + ni*16 + l15;
      int rowb = row0 + wr*64 + mi*16 + l4*4;
      #pragma unroll
      for (int r = 0; r < 4; r++) {
        float v = acc[mi][ni][r];
        size_t off = (size_t)(rowb + r) * Ndim + col;
        if constexpr (EPI == 0) {
          if constexpr (NOUT > 1) {
            int c2 = colsub + wc*64 + ni*16 + l15;
            cbase[(size_t)(rowb + r) * 1024 + c2] = f2b(v + bias[col]);
          } else {
            cb0[off] = f2b(v + bias[col]);
          }
        } else if constexpr (EPI == 1) {
          Cf[off] = v + bias[col] + resid[off];
        } else if constexpr (EPI == 2) {
          float u = v + bias[col];
          u = 0.5f * u * (1.0f + erff(u * 0.70710678118654752f));
          cb0[off] = f2b(u);
        } else {
          Cf[off] = v;
        }
      }
    }
  }
}

// ---------------- fused attention (flash-style) with optional KV-split ----------------
template<int SPLIT>
__global__ __launch_bounds__(256) void k_attn(
    const unsigned short* __restrict__ Qp, const unsigned short* __restrict__ Kp,
    const unsigned short* __restrict__ Vp, unsigned short* __restrict__ Op,
    float* __restrict__ PO, float* __restrict__ PM, float* __restrict__ PL, int Lk) {
  __shared__ unsigned short Ks[64][72];
  __shared__ unsigned short Vt[64][72];   // V transposed (k-chunk XOR-swizzled by d>>3)
  __shared__ float Ps[4][16][68];         // per-wave P transpose buffer
  const int b = blockIdx.z / SPLIT, sp = blockIdx.z % SPLIT;
  const int h = blockIdx.y, q0 = blockIdx.x * 64;
  const int t = threadIdx.x, lane = t & 63, w = t >> 6;
  const int l15 = lane & 15, l4 = lane >> 4;

  const int qrow = q0 + w * 16 + l15;
  const unsigned short* qptr = Qp + (size_t)(b * Sn + qrow) * En + h * 64 + l4 * 8;
  bf16x8 qf0 = *(const bf16x8*)qptr;
  bf16x8 qf1 = *(const bf16x8*)(qptr + 32);

  f32x4 oacc[4];
  #pragma unroll
  for (int i = 0; i < 4; i++) oacc[i] = (f32x4){0.f,0.f,0.f,0.f};
  float m_[4] = {-INFINITY, -INFINITY, -INFINITY, -INFINITY};
  float l_[4] = {0.f, 0.f, 0.f, 0.f};

  const int nkt = Lk / (64 * SPLIT);
  for (int kt = sp * nkt; kt < (sp + 1) * nkt; ++kt) {
    __syncthreads();
    #pragma unroll
    for (int i = 0; i < 2; i++) {
      int ld = t + i * 256;
      int kr = ld >> 3, d8 = (ld & 7) * 8;
      size_t base = (size_t)(b * Lk + kt * 64 + kr) * En + h * 64 + d8;
      *(uint4*)&Ks[kr][d8] = *(const uint4*)(Kp + base);
      bf16x8 vv = *(const bf16x8*)(Vp + base);
      int colswz = kr ^ ((t & 7) << 3);
      #pragma unroll
      for (int j = 0; j < 8; j++) Vt[d8 + j][colswz] = ((unsigned short*)&vv)[j];
    }
    __syncthreads();

    f32x4 s[4];
    #pragma unroll
    for (int ni = 0; ni < 4; ni++) {
      s[ni] = (f32x4){0.f,0.f,0.f,0.f};
      bf16x8 kb0 = *(const bf16x8*)&Ks[ni*16 + l15][l4*8];
      bf16x8 kb1 = *(const bf16x8*)&Ks[ni*16 + l15][l4*8 + 32];
      s[ni] = __builtin_amdgcn_mfma_f32_16x16x32_bf16(qf0, kb0, s[ni], 0, 0, 0);
      s[ni] = __builtin_amdgcn_mfma_f32_16x16x32_bf16(qf1, kb1, s[ni], 0, 0, 0);
    }

    #pragma unroll
    for (int r = 0; r < 4; r++) {
      #pragma unroll
      for (int ni = 0; ni < 4; ni++) s[ni][r] *= 0.125f;
      float mx = fmaxf(fmaxf(s[0][r], s[1][r]), fmaxf(s[2][r], s[3][r]));
      #pragma unroll
      for (int d2 = 1; d2 < 16; d2 <<= 1) mx = fmaxf(mx, __shfl_xor(mx, d2));
      float mn = fmaxf(m_[r], mx);
      float alpha = expf(m_[r] - mn);
      float rsum = 0.f;
      #pragma unroll
      for (int ni = 0; ni < 4; ni++) { float p = expf(s[ni][r] - mn); s[ni][r] = p; rsum += p; }
      #pragma unroll
      for (int d2 = 1; d2 < 16; d2 <<= 1) rsum += __shfl_xor(rsum, d2);
      l_[r] = l_[r] * alpha + rsum;
      m_[r] = mn;
      #pragma unroll
      for (int nd = 0; nd < 4; nd++) oacc[nd][r] *= alpha;
    }

    #pragma unroll
    for (int ni = 0; ni < 4; ni++)
      #pragma unroll
      for (int r = 0; r < 4; r++)
        Ps[w][l4*4 + r][ni*16 + l15] = s[ni][r];
    asm volatile("s_waitcnt lgkmcnt(0)" ::: "memory");

    #pragma unroll
    for (int half = 0; half < 2; half++) {
      float4 pv0 = *(const float4*)&Ps[w][l15][half*32 + l4*8];
      float4 pv1 = *(const float4*)&Ps[w][l15][half*32 + l4*8 + 4];
      bf16x8 pa;
      pa[0]=(short)f2b(pv0.x); pa[1]=(short)f2b(pv0.y); pa[2]=(short)f2b(pv0.z); pa[3]=(short)f2b(pv0.w);
      pa[4]=(short)f2b(pv1.x); pa[5]=(short)f2b(pv1.y); pa[6]=(short)f2b(pv1.z); pa[7]=(short)f2b(pv1.w);
      #pragma unroll
      for (int nd = 0; nd < 4; nd++) {
        int dd = nd*16 + l15;
        bf16x8 vb = *(const bf16x8*)&Vt[dd][(half*32 + l4*8) ^ (((dd >> 3) & 7) << 3)];
        oacc[nd] = __builtin_amdgcn_mfma_f32_16x16x32_bf16(pa, vb, oacc[nd], 0, 0, 0);
      }
    }
  }

  if constexpr (SPLIT == 1) {
    #pragma unroll
    for (int nd = 0; nd < 4; nd++)
      #pragma unroll
      for (int r = 0; r < 4; r++) {
        int q = q0 + w*16 + l4*4 + r;
        Op[(size_t)(b * Sn + q) * En + h * 64 + nd*16 + l15] = f2b(oacc[nd][r] / l_[r]);
      }
  } else {
    const int slot = ((b * Hn + h) * 4 + blockIdx.x) * SPLIT + sp;
    #pragma unroll
    for (int nd = 0; nd < 4; nd++)
      #pragma unroll
      for (int r = 0; r < 4; r++)
        PO[slot * 4096 + (w*16 + l4*4 + r) * 64 + nd*16 + l15] = oacc[nd][r];
    if (l15 == 0) {
      #pragma unroll
      for (int r = 0; r < 4; r++) {
        PM[slot * 64 + w*16 + l4*4 + r] = m_[r];
        PL[slot * 64 + w*16 + l4*4 + r] = l_[r];
      }
    }
  }
}

// ---------------- combine split-K attention partials (SPLIT=4) ----------------
__global__ __launch_bounds__(256) void k_attn_comb(
    const float* __restrict__ PO, const float* __restrict__ PM,
    const float* __restrict__ PL, unsigned short* __restrict__ Op) {
  const int W = blockIdx.x * 4 + (threadIdx.x >> 6);
  const int lane = threadIdx.x & 63;
  const int bh = W >> 8, q = W & 255;
  const int qb = q >> 6, qq = q & 63;
  const int slotBase = (bh * 4 + qb) * 4;
  float ms[4];
  float M = -INFINITY;
  #pragma unroll
  for (int s = 0; s < 4; s++) { ms[s] = PM[(slotBase + s) * 64 + qq]; M = fmaxf(M, ms[s]); }
  float L = 0.f, acc = 0.f;
  #pragma unroll
  for (int s = 0; s < 4; s++) {
    float wgt = expf(ms[s] - M);
    L += PL[(slotBase + s) * 64 + qq] * wgt;
    acc += wgt * PO[(size_t)(slotBase + s) * 4096 + qq * 64 + lane];
  }
  const int b = bh >> 4, h = bh & 15;
  Op[(size_t)(b * Sn + q) * En + h * 64 + lane] = f2b(acc / L);
}

// ------------- helpers for radix top-k (1024-thread blocks) -------------
DEVFN unsigned blk_exscan16(unsigned part, volatile unsigned* wsum, int lane, int wid) {
  unsigned v = part;
  #pragma unroll
  for (int d = 1; d < 64; d <<= 1) { unsigned o = __shfl_up(v, d); if (lane >= d) v += o; }
  if (lane == 63) wsum[wid] = v;
  __syncthreads();
  unsigned woff = 0;
  for (int i = 0; i < wid; i++) woff += wsum[i];
  unsigned r = woff + v - part;
  __syncthreads();
  return r;
}

DEVFN void find_thr16(const unsigned* hist, int NB, unsigned need,
                      int t, int lane, int wid, volatile unsigned* wsum,
                      volatile int* s_thr, volatile unsigned* s_above) {
  int per = NB >> 10;                        // bins per thread (NB/1024)
  int lo = NB - per * (t + 1);
  unsigned part = 0;
  for (int j = 0; j < per; j++) part += hist[lo + j];
  unsigned ex = blk_exscan16(part, wsum, lane, wid);
  if (ex < need && ex + part >= need) {
    unsigned c = ex;
    for (int j = per - 1; j >= 0; j--) {
      unsigned h = hist[lo + j];
      if (c + h >= need) { *s_thr = lo + j; *s_above = c; break; }
      c += h;
    }
  }
  __syncthreads();
}

// ------- exact top-32 per row on bf16 keys: 2 global passes + in-LDS select -------
// Pass A: 11-bit histogram. Pass B: compact candidates (key >= bin-base) into LDS.
// All selection/tie-break/emit then runs on <=2048 LDS candidates (common path).
__global__ __launch_bounds__(1024) void k_topk16(
    const unsigned short* __restrict__ simsb, int* __restrict__ oidx) {
  const int n = blockIdx.x, t = threadIdx.x;
  const int lane = t & 63, wid = t >> 6;
  const u16x8* row8 = (const u16x8*)(simsb + (size_t)n * Mn);
  constexpr unsigned CAP = 2048;
  __shared__ unsigned hist[2048];
  __shared__ unsigned wsum[16];
  __shared__ int s_thr;
  __shared__ unsigned s_above;
  __shared__ unsigned h2[32];
  __shared__ unsigned s_cnt, s_na;
  __shared__ unsigned short ckey[CAP];
  __shared__ unsigned cidx[CAP];
  __shared__ int slist[32];
  __shared__ unsigned sL, sneedEq, scntEq, s_imin;

  for (int i = t; i < 2048; i += 1024) hist[i] = 0;
  if (t < 32) h2[t] = 0;
  if (t == 0) { s_cnt = 0; s_na = 0; }
  __syncthreads();

  // ---- Pass A: histogram over top-11 bits ----
  #pragma unroll
  for (int p = 0; p < 8; p++) {
    u16x8 v = row8[p * 1024 + t];
    #pragma unroll
    for (int j = 0; j < 8; j++) atomicAdd(&hist[okey16(v[j]) >> 5], 1u);
  }
  __syncthreads();
  find_thr16(hist, 2048, 32, t, lane, wid, wsum, &s_thr, &s_above);
  const unsigned T1 = (unsigned)s_thr;
  const unsigned need2 = 32 - s_above;
  const unsigned cnt1 = hist[T1];
  const unsigned base = T1 << 5;

  // ---- Pass B: compact candidates + low-5 histogram of bin T1 ----
  #pragma unroll
  for (int p = 0; p < 8; p++) {
    u16x8 v = row8[p * 1024 + t];
    unsigned i0 = (unsigned)(p * 1024 + t) * 8;
    #pragma unroll
    for (int j = 0; j < 8; j++) {
      unsigned k = okey16(v[j]);
      if (k >= base) {
        unsigned slot = atomicAdd(&s_cnt, 1u);
        if (slot < CAP) { ckey[slot] = (unsigned short)k; cidx[slot] = i0 + j; }
        if ((k >> 5) == T1) atomicAdd(&h2[k & 31], 1u);
      }
    }
  }
  __syncthreads();
  const unsigned total = s_cnt;                // = s_above + cnt1 >= 32

  unsigned L, istar = 0xFFFFFFFFu;
  if (cnt1 == need2) {
    L = base;                                   // whole bin accepted, no sub-select
  } else {
    if (t == 0) {
      unsigned cum = 0; int T3 = 0; unsigned above = 0;
      for (int j = 31; j >= 0; j--) {
        if (cum + h2[j] >= need2) { T3 = j; above = cum; break; }
        cum += h2[j];
      }
      sL = base | (unsigned)T3;
      sneedEq = need2 - above;
      scntEq = h2[T3];
    }
    __syncthreads();
    L = sL;
    if (scntEq != sneedEq) {                    // exact ties: need smallest-index subset
      if (total <= CAP) {
        // in-LDS iterative min over candidates
        int prev = -1;
        for (unsigned j = 0; j < sneedEq; j++) {
          if (t == 0) s_imin = 0xFFFFFFFFu;
          __syncthreads();
          for (unsigned i = t; i < total; i += 1024)
            if ((unsigned)ckey[i] == L && (int)cidx[i] > prev) atomicMin(&s_imin, cidx[i]);
          __syncthreads();
          prev = (int)s_imin;
          __syncthreads();
        }
        istar = (unsigned)prev;
      } else {
        // fallback: ordered compaction over global (per-thread contiguous segments)
        const unsigned short* rowp = simsb + (size_t)n * Mn;
        unsigned cntLoc = 0;
        for (int j = 0; j < 64; j++)
          if (okey16(rowp[t * 64 + j]) == L) cntLoc++;
        unsigned pre = blk_exscan16(cntLoc, wsum, lane, wid);
        unsigned c = 0;
        for (int j = 0; j < 64; j++)
          if (okey16(rowp[t * 64 + j]) == L) { if (pre + c < 32) slist[pre + c] = t * 64 + j; c++; }
        __syncthreads();
        istar = (unsigned)slist[sneedEq - 1];
        __syncthreads();
        if (t == 0) s_na = 0;                   // slist reused below
        __syncthreads();
      }
    }
  }
  __syncthreads();

  if (total <= CAP) {
    // ---- in-LDS accept + rank-sorted emit (deterministic) ----
    for (unsigned i = t; i < total; i += 1024) {
      unsigned k = (unsigned)ckey[i];
      if (k > L || (k == L && cidx[i] <= istar)) {
        unsigned s = atomicAdd(&s_na, 1u);
        slist[s] = (int)cidx[i];
      }
    }
    __syncthreads();
    if (t < 32) {
      int my = slist[t];
      int rank = 0;
      #pragma unroll
      for (int j = 0; j < 32; j++) rank += (slist[j] < my);
      oidx[n * Kt + rank] = my;
    }
  } else {
    // ---- fallback: global cnt + emit passes ----
    unsigned cnt = 0;
    for (int p = 0; p < 8; p++) {
      u16x8 v = row8[p * 1024 + t];
      unsigned i0 = (unsigned)(p * 1024 + t) * 8;
      #pragma unroll
      for (int j = 0; j < 8; j++) {
        unsigned k = okey16(v[j]);
        cnt += (k > L || (k == L && i0 + j <= istar));
      }
    }
    unsigned pos = blk_exscan16(cnt, wsum, lane, wid);
    for (int p = 0; p < 8; p++) {
      u16x8 v = row8[p * 1024 + t];
      unsigned i0 = (unsigned)(p * 1024 + t) * 8;
      #pragma unroll
      for (int j = 0; j < 8; j++) {
        unsigned k = okey16(v[j]);
        if (k > L || (k == L && i0 + j <= istar)) oidx[n * Kt + pos++] = (int)(i0 + j);
      }
    }
  }
}

// =============================== host ===============================
extern "C" void kernel_launch(void* const* d_in, const int* in_sizes, int n_in,
                              void* d_out, int out_size, void* d_ws, size_t ws_size,
                              hipStream_t stream) {
  (void)in_sizes; (void)n_in; (void)out_size;
  const float* x      = (const float*)d_in[0];
  const float* mem_k  = (const float*)d_in[1];
  const float* mem_v  = (const float*)d_in[2];
  const float* sa_w[4] = {(const float*)d_in[3], (const float*)d_in[4], (const float*)d_in[5], (const float*)d_in[6]};
  const float* sa_b[4] = {(const float*)d_in[7], (const float*)d_in[8], (const float*)d_in[9], (const float*)d_in[10]};
  const float* ma_w[4] = {(const float*)d_in[11], (const float*)d_in[12], (const float*)d_in[13], (const float*)d_in[14]};
  const float* ma_b[4] = {(const float*)d_in[15], (const float*)d_in[16], (const float*)d_in[17], (const float*)d_in[18]};
  const float* ln_g[3] = {(const float*)d_in[19], (const float*)d_in[21], (const float*)d_in[23]};
  const float* ln_b[3] = {(const float*)d_in[20], (const float*)d_in[22], (const float*)d_in[24]};
  const float* fc1_w = (const float*)d_in[25];
  const float* fc1_b = (const float*)d_in[26];
  const float* fc2_w = (const float*)d_in[27];
  const float* fc2_b = (const float*)d_in[28];
  float* out = (float*)d_out;

  char* ws = (char*)d_ws;
  size_t off = 0;
  auto alloc = [&](size_t bytes) -> char* {
    char* p = ws + off;
    off = (off + bytes + 255) & ~(size_t)255;
    return p;
  };

  unsigned short* wt[8];
  for (int i = 0; i < 8; i++) wt[i] = (unsigned short*)alloc((size_t)En * En * 2);  // contiguous
  unsigned short* fc1t  = (unsigned short*)alloc((size_t)FFn * En * 2);
  unsigned short* fc2t  = (unsigned short*)alloc((size_t)En * FFn * 2);
  unsigned short* xb    = (unsigned short*)alloc((size_t)NT * En * 2);
  unsigned short* Qb    = (unsigned short*)alloc((size_t)NT * En * 2);
  unsigned short* Kb    = (unsigned short*)alloc((size_t)NT * En * 2);
  unsigned short* Vb    = (unsigned short*)alloc((size_t)NT * En * 2);
  unsigned short* at1b  = (unsigned short*)alloc((size_t)NT * En * 2);
  float*          t1    = (float*)alloc((size_t)NT * En * 4);
  float*          x1f   = (float*)alloc((size_t)NT * En * 4);
  unsigned short* x1b   = (unsigned short*)alloc((size_t)NT * En * 2);
  char*           simsRaw = alloc((size_t)NT * Mn * 4);                // 256 MiB region
  int*            idx   = (int*)alloc((size_t)NT * Kt * 4);
  unsigned short* K2b   = (unsigned short*)alloc((size_t)NT * Kt * En * 2);  // 64 MiB
  unsigned short* V2b   = (unsigned short*)alloc((size_t)NT * Kt * En * 2);  // contiguous after K2b
  unsigned short* Q2b   = (unsigned short*)alloc((size_t)NT * En * 2);
  unsigned short* at2b  = (unsigned short*)alloc((size_t)NT * En * 2);
  float*          t2    = (float*)alloc((size_t)NT * En * 4);
  float*          x2f   = (float*)alloc((size_t)NT * En * 4);
  unsigned short* x2b   = (unsigned short*)alloc((size_t)NT * En * 2);
  unsigned short* hb    = (unsigned short*)alloc((size_t)NT * FFn * 2);
  float*          t3    = (float*)alloc((size_t)NT * En * 4);
  float*          bcat_sa = (float*)alloc(3072 * 4);
  float*          bcat_ma = (float*)alloc(2048 * 4);

  if (off > ws_size) return;   // insufficient workspace: leave output poisoned (fail loudly)

  // Overlays (dead-region reuse):
  unsigned short* simsb = (unsigned short*)simsRaw;   // bf16 sims: 128 MiB of the region
  unsigned short* mkb = (unsigned short*)K2b;         // until sims GEMM done
  unsigned short* mvb = (unsigned short*)simsRaw;     // after topk
  float* PO = (float*)(simsRaw + (size_t)128 * 1024 * 1024);
  float* PM = PO + (size_t)1024 * 4096;
  float* PL = PM + (size_t)1024 * 64;

  // allow 128 KiB dynamic LDS for the 256^2 kernels (best effort)
  (void)hipFuncSetAttribute((const void*)&k_gemm256<5,false,1,0>,
                            hipFuncAttributeMaxDynamicSharedMemorySize, 131072);
  (void)hipFuncSetAttribute((const void*)&k_gemm256<0,true,2,1>,
                            hipFuncAttributeMaxDynamicSharedMemorySize, 131072);

  // ---- prep: weight transposes to bf16 [N][K], bias concats ----
  for (int i = 0; i < 4; i++)
    k_transpose_bf16<<<dim3(16, 16), 256, 0, stream>>>(sa_w[i], wt[i], En, En);
  for (int i = 0; i < 4; i++)
    k_transpose_bf16<<<dim3(16, 16), 256, 0, stream>>>(ma_w[i], wt[4 + i], En, En);
  k_transpose_bf16<<<dim3(64, 16), 256, 0, stream>>>(fc1_w, fc1t, En, FFn);
  k_transpose_bf16<<<dim3(16, 64), 256, 0, stream>>>(fc2_w, fc2t, FFn, En);
  k_concat3<<<dim3(12), 256, 0, stream>>>(sa_b[0], sa_b[1], sa_b[2], bcat_sa);
  k_concat3<<<dim3(8),  256, 0, stream>>>(ma_b[1], ma_b[2], ma_b[2], bcat_ma);

  k_cvt_bf16<<<dim3(NT * En / 4 / 256), 256, 0, stream>>>(x, xb, NT * En / 4);
  k_normcvt<<<dim3(Mn), 256, 0, stream>>>(mem_k, mkb);

  const dim3 g1(En / 128, NT / 128);   // (8,8)

  // ---- self-attention (QKV fused: N=3072 over contiguous wt[0..2]) ----
  k_gemm<0,false,false,3><<<dim3(24, 8), 256, 0, stream>>>(xb, wt[0], nullptr, bcat_sa, nullptr, nullptr, Qb, Kb, Vb, 3072, En);
  k_attn<1><<<dim3(Sn / 64, Hn, Bn), 256, 0, stream>>>(Qb, Kb, Vb, at1b, nullptr, nullptr, nullptr, Sn);
  k_gemm<1,false,false,1><<<g1, 256, 0, stream>>>(at1b, wt[3], nullptr, sa_b[3], x, t1, nullptr, nullptr, nullptr, En, En);
  k_layernorm<<<NT, 256, 0, stream>>>(t1, ln_g[0], ln_b[0], x1f, x1b);

  // ---- retrieval: sims in bf16 + 2-pass candidate top-k ----
  k_gemm256<5,false,1,0><<<dim3(1024), 512, 131072, stream>>>(
      x1b, mkb, nullptr, nullptr, nullptr, simsb, nullptr, Mn, En, NT / 256, Mn / 256);
  k_topk16<<<NT, 1024, 0, stream>>>(simsb, idx);

  // ---- memory cross-attention (K2/V2 fused 256^2 over contiguous wt[5..6]) ----
  k_cvt_bf16<<<dim3(Mn * En / 4 / 256), 256, 0, stream>>>(mem_v, mvb, Mn * En / 4);
  k_gemm256<0,true,2,1><<<dim3(1024), 512, 131072, stream>>>(
      mvb, wt[5], idx, bcat_ma, nullptr, K2b, V2b, 2048, En, NT * Kt / 256, 2048 / 256);
  k_gemm<0,false,false,1><<<g1, 256, 0, stream>>>(x1b, wt[4], nullptr, ma_b[0], nullptr, nullptr, Q2b, nullptr, nullptr, En, En);
  k_attn<4><<<dim3(Sn / 64, Hn, Bn * 4), 256, 0, stream>>>(Q2b, K2b, V2b, nullptr, PO, PM, PL, Sn * Kt);
  k_attn_comb<<<dim3(Bn * Hn * Sn / 4), 256, 0, stream>>>(PO, PM, PL, at2b);
  k_gemm<1,false,false,1><<<g1, 256, 0, stream>>>(at2b, wt[7], nullptr, ma_b[3], x1f, t2, nullptr, nullptr, nullptr, En, En);
  k_layernorm<<<NT, 256, 0, stream>>>(t2, ln_g[1], ln_b[1], x2f, x2b);

  // ---- FFN ----
  k_gemm<2,false,false,1><<<dim3(FFn / 128, NT / 128), 256, 0, stream>>>(x2b, fc1t, nullptr, fc1_b, nullptr, nullptr, hb, nullptr, nullptr, FFn, En);
  k_gemm<1,false,false,1><<<g1, 256, 0, stream>>>(hb, fc2t, nullptr, fc2_b, x2f, t3, nullptr, nullptr, nullptr, En, FFn);
  k_layernorm<<<NT, 256, 0, stream>>>(t3, ln_g[2], ln_b[2], out, nullptr);
}

// Round 10
// 992.785 us; speedup vs baseline: 1.2891x; 1.0048x over previous
//
#include <hip/hip_runtime.h>
#include <hip/hip_bf16.h>
#include <math.h>

#define DEVFN __device__ __forceinline__

typedef __attribute__((ext_vector_type(8))) short bf16x8;
typedef __attribute__((ext_vector_type(8))) unsigned short u16x8;
typedef __attribute__((ext_vector_type(4))) unsigned short u16x4;
typedef __attribute__((ext_vector_type(4))) float f32x4;

static constexpr int Bn = 4, Sn = 256, En = 1024, Hn = 16;
static constexpr int Mn = 65536, Kt = 32, FFn = 4096;
static constexpr int NT = Bn * Sn;           // 1024 tokens

DEVFN unsigned short f2b(float f) {          // f32 -> bf16 RNE
  unsigned int u = __float_as_uint(f);
  unsigned int r = (u + 0x7FFFu + ((u >> 16) & 1u)) >> 16;
  return (unsigned short)r;
}

DEVFN unsigned okey16(unsigned short u) {    // order-preserving bf16 -> u16
  return (unsigned)(u ^ ((u >> 15) ? 0xFFFFu : 0x8000u)) & 0xFFFFu;
}

typedef const __attribute__((address_space(1))) void* as1cv_t;
typedef __attribute__((address_space(3))) void* as3v_t;
DEVFN void gload16(const void* g, void* l) {   // async global->LDS, 16B/lane
  __builtin_amdgcn_global_load_lds((as1cv_t)g, (as3v_t)l, 16, 0, 0);
}
#define MEMFENCE asm volatile("" ::: "memory")

// ---------------- transpose W[R][C] f32 -> out[C][R] bf16 ----------------
__global__ __launch_bounds__(256) void k_transpose_bf16(
    const float* __restrict__ in, unsigned short* __restrict__ out, int R, int C) {
  __shared__ float tile[64][65];
  int tx = threadIdx.x & 63, ty = threadIdx.x >> 6;
  int c0 = blockIdx.x * 64, r0 = blockIdx.y * 64;
  #pragma unroll
  for (int i = 0; i < 16; i++) {
    int r = ty + i * 4;
    tile[tx][r] = in[(size_t)(r0 + r) * C + (c0 + tx)];
  }
  __syncthreads();
  #pragma unroll
  for (int i = 0; i < 16; i++) {
    int c = ty + i * 4;
    out[(size_t)(c0 + c) * R + (r0 + tx)] = f2b(tile[c][tx]);
  }
}

// ---------------- f32 -> bf16 elementwise (x4) ----------------
__global__ __launch_bounds__(256) void k_cvt_bf16(
    const float* __restrict__ in, unsigned short* __restrict__ out, int n4) {
  int i = blockIdx.x * 256 + threadIdx.x;
  if (i >= n4) return;
  float4 v = ((const float4*)in)[i];
  uint2 o;
  o.x = (unsigned int)f2b(v.x) | ((unsigned int)f2b(v.y) << 16);
  o.y = (unsigned int)f2b(v.z) | ((unsigned int)f2b(v.w) << 16);
  ((uint2*)out)[i] = o;
}

// ---------------- concat up to 3 x 1024-f32 vectors ----------------
__global__ __launch_bounds__(256) void k_concat3(
    const float* __restrict__ a, const float* __restrict__ b,
    const float* __restrict__ c, float* __restrict__ o) {
  int i = blockIdx.x * 256 + threadIdx.x;
  float v = (i < 1024) ? a[i] : (i < 2048) ? b[i - 1024] : c[i - 2048];
  o[i] = v;
}

// ---- mem_keys row-normalize + cvt to bf16 (folds cosine norm into B) ----
__global__ __launch_bounds__(256) void k_normcvt(
    const float* __restrict__ mk, unsigned short* __restrict__ out) {
  int m = blockIdx.x, t = threadIdx.x;
  float4 v = ((const float4*)(mk + (size_t)m * En))[t];
  float ss = v.x*v.x + v.y*v.y + v.z*v.z + v.w*v.w;
  #pragma unroll
  for (int d = 32; d; d >>= 1) ss += __shfl_down(ss, d);
  __shared__ float red[4];
  int lane = t & 63, w = t >> 6;
  if (lane == 0) red[w] = ss;
  __syncthreads();
  float rs = 1.0f / fmaxf(sqrtf(red[0] + red[1] + red[2] + red[3]), 1e-12f);
  uint2 o;
  o.x = (unsigned int)f2b(v.x * rs) | ((unsigned int)f2b(v.y * rs) << 16);
  o.y = (unsigned int)f2b(v.z * rs) | ((unsigned int)f2b(v.w * rs) << 16);
  ((uint2*)(out + (size_t)m * En))[t] = o;
}

// ---------------- LayerNorm over rows of [NT][En] ----------------
__global__ __launch_bounds__(256) void k_layernorm(
    const float* __restrict__ in, const float* __restrict__ g, const float* __restrict__ bb,
    float* __restrict__ outf, unsigned short* __restrict__ outb) {
  int n = blockIdx.x, t = threadIdx.x;
  float4 v = ((const float4*)(in + (size_t)n * En))[t];
  float s  = v.x + v.y + v.z + v.w;
  float s2 = v.x*v.x + v.y*v.y + v.z*v.z + v.w*v.w;
  #pragma unroll
  for (int d = 32; d; d >>= 1) { s += __shfl_down(s, d); s2 += __shfl_down(s2, d); }
  __shared__ float rs[4], rq[4];
  int lane = t & 63, w = t >> 6;
  if (lane == 0) { rs[w] = s; rq[w] = s2; }
  __syncthreads();
  float mean = (rs[0]+rs[1]+rs[2]+rs[3]) * (1.0f/En);
  float var  = (rq[0]+rq[1]+rq[2]+rq[3]) * (1.0f/En) - mean*mean;
  float rstd = rsqrtf(var + 1e-5f);
  float4 gg = ((const float4*)g)[t];
  float4 bv = ((const float4*)bb)[t];
  float o0 = (v.x-mean)*rstd*gg.x + bv.x;
  float o1 = (v.y-mean)*rstd*gg.y + bv.y;
  float o2 = (v.z-mean)*rstd*gg.z + bv.z;
  float o3 = (v.w-mean)*rstd*gg.w + bv.w;
  if (outf) { float4 ov = {o0,o1,o2,o3}; ((float4*)(outf + (size_t)n*En))[t] = ov; }
  if (outb) {
    uint2 o;
    o.x = (unsigned int)f2b(o0) | ((unsigned int)f2b(o1) << 16);
    o.y = (unsigned int)f2b(o2) | ((unsigned int)f2b(o3) << 16);
    ((uint2*)(outb + (size_t)n*En))[t] = o;
  }
}

// ======== 256x256 GEMM, 4 half-tile ring buffers + counted vmcnt (T1..T5) ========
// EPI 4: f32 out | EPI 5: bf16 no-bias | EPI 0 + NOUT2: bf16 (+bias), split N
// EPI 6: split N=2048 -> cb0 row-major (+bias), cb1 TRANSPOSED [B][1024][8192] (+bias)
template<int EPI, bool AGATHER, int NOUT, int LSWZ>
__global__ __launch_bounds__(512) void k_gemm256(
    const unsigned short* __restrict__ Ab, const unsigned short* __restrict__ Bb,
    const int* __restrict__ gidx, const float* __restrict__ bias,
    float* __restrict__ Cf, unsigned short* __restrict__ cb0, unsigned short* __restrict__ cb1,
    int Ndim, int Kdim, int nRT, int nCT) {
  extern __shared__ unsigned short lds[];
  const int t = threadIdx.x, lane = t & 63, w = t >> 6;
  const int wr = w >> 2, wc = w & 3, l15 = lane & 15, l4 = lane >> 4;
  const int lr2 = lane >> 2;
  const int cg  = (lane & 3) ^ (((lane >> 5) & 1) << 1);   // source pre-swizzle (involution)

  // bijective chunked XCD map
  const int nwg = nRT * nCT;
  int lb = ((int)blockIdx.x % 8) * (nwg >> 3) + ((int)blockIdx.x >> 3);
  int rowT, colT;
  if (LSWZ == 0) { rowT = lb % nRT; colT = lb / nRT; }
  else           { colT = lb % nCT; rowT = lb / nCT; }
  const int row0 = rowT * 256, col0 = colT * 256;

  auto pa = [&](int h) -> unsigned short* { return lds + h * 16384; };
  auto pb = [&](int h) -> unsigned short* { return lds + h * 16384 + 8192; };

  const unsigned short *aSrc0, *aSrc1;
  if constexpr (AGATHER) {
    aSrc0 = Ab + (size_t)gidx[row0 + w * 32 + lr2] * Kdim + cg * 8;
    aSrc1 = Ab + (size_t)gidx[row0 + w * 32 + 16 + lr2] * Kdim + cg * 8;
  } else {
    aSrc0 = Ab + (size_t)(row0 + w * 32 + lr2) * Kdim + cg * 8;
    aSrc1 = aSrc0 + (size_t)16 * Kdim;
  }
  const unsigned short* bSrc0 = Bb + (size_t)(col0 + w * 32 + lr2) * Kdim + cg * 8;
  const unsigned short* bSrc1 = bSrc0 + (size_t)16 * Kdim;

  f32x4 acc[8][4];
  #pragma unroll
  for (int i = 0; i < 8; i++)
    #pragma unroll
    for (int j = 0; j < 4; j++) acc[i][j] = (f32x4){0.f, 0.f, 0.f, 0.f};

  const int NH = Kdim >> 5;                 // K half-tiles of 32
  #pragma unroll
  for (int h = 0; h < 3; ++h) {
    const int ko = h * 32;
    gload16(aSrc0 + ko, pa(h) + w*32*32);
    gload16(aSrc1 + ko, pa(h) + (w*32+16)*32);
    gload16(bSrc0 + ko, pb(h) + w*32*32);
    gload16(bSrc1 + ko, pb(h) + (w*32+16)*32);
  }
  asm volatile("s_waitcnt vmcnt(8)" ::: "memory");   // half 0 landed
  __builtin_amdgcn_s_barrier();
  MEMFENCE;

  for (int hs = 0; hs < NH; ++hs) {
    const int cur = hs & 3;
    const unsigned short* Ap = pa(cur);
    const unsigned short* Bp = pb(cur);
    const int h3 = (hs + 3) & 3, ko3 = (hs + 3) * 32;
    const bool pf = (hs + 3) < NH;
    bf16x8 bfr[4], af[4];

    // ---- phase 0: B frags + A rows 0..63 ----
    #pragma unroll
    for (int ni = 0; ni < 4; ni++) {
      int row = wc * 64 + ni * 16 + l15;
      int c8 = l4 ^ (((row >> 3) & 1) << 1);
      bfr[ni] = *(const bf16x8*)&Bp[row * 32 + c8 * 8];
    }
    #pragma unroll
    for (int m = 0; m < 4; m++) {
      int row = wr * 128 + m * 16 + l15;
      int c8 = l4 ^ (((row >> 3) & 1) << 1);
      af[m] = *(const bf16x8*)&Ap[row * 32 + c8 * 8];
    }
    if (pf) {
      gload16(aSrc0 + ko3, pa(h3) + w*32*32);
      gload16(aSrc1 + ko3, pa(h3) + (w*32+16)*32);
    }
    MEMFENCE; __builtin_amdgcn_s_barrier(); MEMFENCE;
    __builtin_amdgcn_s_setprio(1);
    #pragma unroll
    for (int m = 0; m < 4; m++)
      #pragma unroll
      for (int ni = 0; ni < 4; ni++)
        acc[m][ni] = __builtin_amdgcn_mfma_f32_16x16x32_bf16(af[m], bfr[ni], acc[m][ni], 0, 0, 0);
    __builtin_amdgcn_s_setprio(0);
    MEMFENCE; __builtin_amdgcn_s_barrier(); MEMFENCE;

    // ---- phase 1: A rows 64..127 ----
    #pragma unroll
    for (int m = 0; m < 4; m++) {
      int row = wr * 128 + (4 + m) * 16 + l15;
      int c8 = l4 ^ (((row >> 3) & 1) << 1);
      af[m] = *(const bf16x8*)&Ap[row * 32 + c8 * 8];
    }
    if (pf) {
      gload16(bSrc0 + ko3, pb(h3) + w*32*32);
      gload16(bSrc1 + ko3, pb(h3) + (w*32+16)*32);
    }
    MEMFENCE; __builtin_amdgcn_s_barrier(); MEMFENCE;
    __builtin_amdgcn_s_setprio(1);
    #pragma unroll
    for (int m = 0; m < 4; m++)
      #pragma unroll
      for (int ni = 0; ni < 4; ni++)
        acc[4 + m][ni] = __builtin_amdgcn_mfma_f32_16x16x32_bf16(af[m], bfr[ni], acc[4 + m][ni], 0, 0, 0);
    __builtin_amdgcn_s_setprio(0);

    if (hs + 1 < NH) {
      const int rem = NH - 2 - hs;          // prefetched halves beyond hs+1
      if (rem >= 2)      asm volatile("s_waitcnt vmcnt(8)" ::: "memory");
      else if (rem == 1) asm volatile("s_waitcnt vmcnt(4)" ::: "memory");
      else               asm volatile("s_waitcnt vmcnt(0)" ::: "memory");
      __builtin_amdgcn_s_barrier();
      MEMFENCE;
    }
  }

  #pragma unroll
  for (int m = 0; m < 8; m++) {
    #pragma unroll
    for (int ni = 0; ni < 4; ni++) {
      int col  = col0 + wc * 64 + ni * 16 + l15;
      int rowb = row0 + wr * 128 + m * 16 + l4 * 4;
      if constexpr (EPI == 6) {
        if (col < 1024) {
          #pragma unroll
          for (int r = 0; r < 4; r++)
            cb0[(size_t)(rowb + r) * 1024 + col] = f2b(acc[m][ni][r] + bias[col]);
        } else {
          int c = col - 1024;
          int bi = rowb >> 13, k0 = rowb & 8191;
          u16x4 o;
          #pragma unroll
          for (int r = 0; r < 4; r++) o[r] = f2b(acc[m][ni][r] + bias[col]);
          *(u16x4*)&cb1[((size_t)bi * 1024 + c) * 8192 + k0] = o;
        }
      } else {
        #pragma unroll
        for (int r = 0; r < 4; r++) {
          float v = acc[m][ni][r];
          if constexpr (EPI == 4) {
            Cf[(size_t)(rowb + r) * Ndim + col] = v;
          } else if constexpr (EPI == 5) {
            cb0[(size_t)(rowb + r) * Ndim + col] = f2b(v);
          } else {
            unsigned short* cb = (col >> 10) ? cb1 : cb0;
            cb[(size_t)(rowb + r) * 1024 + (col & 1023)] = f2b(v + bias[col]);
          }
        }
      }
    }
  }
}

// ---------------- GEMM 128x128 (2-phase) for the small GEMMs ----------------
template<int EPI, bool AGATHER, bool SWAPG, int NOUT>
__global__ __launch_bounds__(256) void k_gemm(
    const unsigned short* __restrict__ Ab, const unsigned short* __restrict__ Bb,
    const int* __restrict__ gidx,
    const float* __restrict__ bias, const float* __restrict__ resid,
    float* __restrict__ Cf, unsigned short* __restrict__ cb0,
    unsigned short* __restrict__ cb1, unsigned short* __restrict__ cb2,
    int Ndim, int Kdim) {
  __shared__ unsigned short As[128][32];
  __shared__ unsigned short Bs[128][32];
  const int t = threadIdx.x, lane = t & 63, w = t >> 6;
  const int wr = w >> 1, wc = w & 1, l15 = lane & 15, l4 = lane >> 4;
  const int row0 = (SWAPG ? blockIdx.x : blockIdx.y) * 128;
  const int col0 = (SWAPG ? blockIdx.y : blockIdx.x) * 128;
  const int c8  = (lane & 3) * 8;
  const int r16 = lane >> 2;
  const int rA0 = w * 32 + r16, rA1 = rA0 + 16;

  size_t raA0, raA1, raB0, raB1;
  if constexpr (AGATHER) {
    raA0 = (size_t)gidx[row0 + rA0] * Kdim;
    raA1 = (size_t)gidx[row0 + rA1] * Kdim;
  } else {
    raA0 = (size_t)(row0 + rA0) * Kdim;
    raA1 = (size_t)(row0 + rA1) * Kdim;
  }
  raB0 = (size_t)(col0 + rA0) * Kdim;
  raB1 = (size_t)(col0 + rA1) * Kdim;

  f32x4 acc[4][4];
  #pragma unroll
  for (int i = 0; i < 4; i++)
    #pragma unroll
    for (int j = 0; j < 4; j++) acc[i][j] = (f32x4){0.f,0.f,0.f,0.f};

  for (int kt0 = 0; kt0 < Kdim; kt0 += 32) {
    __syncthreads();
    gload16(Ab + raA0 + kt0 + c8, &As[w * 32][0]);
    gload16(Ab + raA1 + kt0 + c8, &As[w * 32 + 16][0]);
    gload16(Bb + raB0 + kt0 + c8, &Bs[w * 32][0]);
    gload16(Bb + raB1 + kt0 + c8, &Bs[w * 32 + 16][0]);
    __syncthreads();
    bf16x8 af[4], bfr[4];
    #pragma unroll
    for (int mi = 0; mi < 4; mi++) af[mi]  = *(const bf16x8*)&As[wr*64 + mi*16 + l15][l4*8];
    #pragma unroll
    for (int ni = 0; ni < 4; ni++) bfr[ni] = *(const bf16x8*)&Bs[wc*64 + ni*16 + l15][l4*8];
    #pragma unroll
    for (int mi = 0; mi < 4; mi++)
      #pragma unroll
      for (int ni = 0; ni < 4; ni++)
        acc[mi][ni] = __builtin_amdgcn_mfma_f32_16x16x32_bf16(af[mi], bfr[ni], acc[mi][ni], 0, 0, 0);
  }

  unsigned short* cbase = cb0;
  int colsub = 0;
  if constexpr (NOUT > 1) {
    int which = col0 >> 10;
    cbase = (which == 0) ? cb0 : (which == 1) ? cb1 : cb2;
    colsub = col0 & 1023;
  }

  #pragma unroll
  for (int mi = 0; mi < 4; mi++) {
    #pragma unroll
    for (int ni = 0; ni < 4; ni++) {
      int col  = col0 + wc*64 + ni*16 + l15;
      int rowb = row0 + wr*64 + mi*16 + l4*4;
      #pragma unroll
      for (int r = 0; r < 4; r++) {
        float v = acc[mi][ni][r];
        size_t off = (size_t)(rowb + r) * Ndim + col;
        if constexpr (EPI == 0) {
          if constexpr (NOUT > 1) {
            int c2 = colsub + wc*64 + ni*16 + l15;
            cbase[(size_t)(rowb + r) * 1024 + c2] = f2b(v + bias[col]);
          } else {
            cb0[off] = f2b(v + bias[col]);
          }
        } else if constexpr (EPI == 1) {
          Cf[off] = v + bias[col] + resid[off];
        } else if constexpr (EPI == 2) {
          float u = v + bias[col];
          u = 0.5f * u * (1.0f + erff(u * 0.70710678118654752f));
          cb0[off] = f2b(u);
        } else {
          Cf[off] = v;
        }
      }
    }
  }
}

// ---------------- fused attention (flash-style) with optional KV-split ----------------
// VT: Vp is pre-transposed [B][1024][Lk]; K/V staged via global_load_lds (swizzled src).
template<int SPLIT, bool VT>
__global__ __launch_bounds__(256) void k_attn(
    const unsigned short* __restrict__ Qp, const unsigned short* __restrict__ Kp,
    const unsigned short* __restrict__ Vp, unsigned short* __restrict__ Op,
    float* __restrict__ PO, float* __restrict__ PM, float* __restrict__ PL, int Lk) {
  constexpr int KST = VT ? 64 : 72;
  __shared__ unsigned short Ks[64 * KST];
  __shared__ unsigned short Vt[64 * KST];
  __shared__ float Ps[4][16][68];         // per-wave P transpose buffer
  const int b = blockIdx.z / SPLIT, sp = blockIdx.z % SPLIT;
  const int h = blockIdx.y, q0 = blockIdx.x * 64;
  const int t = threadIdx.x, lane = t & 63, w = t >> 6;
  const int l15 = lane & 15, l4 = lane >> 4;

  const int qrow = q0 + w * 16 + l15;
  const unsigned short* qptr = Qp + (size_t)(b * Sn + qrow) * En + h * 64 + l4 * 8;
  bf16x8 qf0 = *(const bf16x8*)qptr;
  bf16x8 qf1 = *(const bf16x8*)(qptr + 32);

  f32x4 oacc[4];
  #pragma unroll
  for (int i = 0; i < 4; i++) oacc[i] = (f32x4){0.f,0.f,0.f,0.f};
  float m_[4] = {-INFINITY, -INFINITY, -INFINITY, -INFINITY};
  float l_[4] = {0.f, 0.f, 0.f, 0.f};

  const int rbase = w * 16, l8 = lane >> 3, l7 = lane & 7;
  const int kswz = (l7 ^ l8) * 8;          // source pre-swizzle (row&7 == l8)

  const int nkt = Lk / (64 * SPLIT);
  for (int kt = sp * nkt; kt < (sp + 1) * nkt; ++kt) {
    __syncthreads();                       // protect LDS from previous iter readers
    if constexpr (VT) {
      #pragma unroll
      for (int i = 0; i < 2; i++) {
        int row = rbase + i * 8 + l8;
        gload16(Kp + (size_t)(b * Lk + kt * 64 + row) * En + h * 64 + kswz,
                &Ks[(rbase + i * 8) * 64]);
        gload16(Vp + ((size_t)b * 1024 + h * 64 + row) * (size_t)Lk + kt * 64 + kswz,
                &Vt[(rbase + i * 8) * 64]);
      }
    } else {
      #pragma unroll
      for (int i = 0; i < 2; i++) {
        int ld = t + i * 256;
        int kr = ld >> 3, d8 = (ld & 7) * 8;
        size_t base = (size_t)(b * Lk + kt * 64 + kr) * En + h * 64 + d8;
        *(uint4*)&Ks[kr * 72 + d8] = *(const uint4*)(Kp + base);
        bf16x8 vv = *(const bf16x8*)(Vp + base);
        int colswz = kr ^ ((t & 7) << 3);
        #pragma unroll
        for (int j = 0; j < 8; j++) Vt[(d8 + j) * 72 + colswz] = ((unsigned short*)&vv)[j];
      }
    }
    __syncthreads();                       // drains vmcnt (gloads) + lgkm

    // S = Q @ K^T  (per wave: 16 q-rows x 64 k-cols)
    f32x4 s[4];
    #pragma unroll
    for (int ni = 0; ni < 4; ni++) {
      s[ni] = (f32x4){0.f,0.f,0.f,0.f};
      bf16x8 kb0, kb1;
      if constexpr (VT) {
        int rowK = ni * 16 + l15, sw = (rowK & 7) * 8;
        kb0 = *(const bf16x8*)&Ks[rowK * 64 + ((l4 * 8) ^ sw)];
        kb1 = *(const bf16x8*)&Ks[rowK * 64 + ((l4 * 8 + 32) ^ sw)];
      } else {
        kb0 = *(const bf16x8*)&Ks[(ni*16 + l15) * 72 + l4*8];
        kb1 = *(const bf16x8*)&Ks[(ni*16 + l15) * 72 + l4*8 + 32];
      }
      s[ni] = __builtin_amdgcn_mfma_f32_16x16x32_bf16(qf0, kb0, s[ni], 0, 0, 0);
      s[ni] = __builtin_amdgcn_mfma_f32_16x16x32_bf16(qf1, kb1, s[ni], 0, 0, 0);
    }

    // online softmax per q-row (raw-score units; 1/8 scale folded into exp arg)
    #pragma unroll
    for (int r = 0; r < 4; r++) {
      float mx = fmaxf(fmaxf(s[0][r], s[1][r]), fmaxf(s[2][r], s[3][r]));
      #pragma unroll
      for (int d2 = 1; d2 < 16; d2 <<= 1) mx = fmaxf(mx, __shfl_xor(mx, d2));
      if (mx > m_[r]) {                    // rescale only on new max
        float alpha = __expf((m_[r] - mx) * 0.125f);
        l_[r] *= alpha;
        #pragma unroll
        for (int nd = 0; nd < 4; nd++) oacc[nd][r] *= alpha;
        m_[r] = mx;
      }
      float rsum = 0.f;
      #pragma unroll
      for (int ni = 0; ni < 4; ni++) {
        float p = __expf((s[ni][r] - m_[r]) * 0.125f);
        s[ni][r] = p; rsum += p;
      }
      #pragma unroll
      for (int d2 = 1; d2 < 16; d2 <<= 1) rsum += __shfl_xor(rsum, d2);
      l_[r] += rsum;
    }

    // transpose P through per-wave LDS into A-frag layout
    #pragma unroll
    for (int ni = 0; ni < 4; ni++)
      #pragma unroll
      for (int r = 0; r < 4; r++)
        Ps[w][l4*4 + r][ni*16 + l15] = s[ni][r];
    asm volatile("s_waitcnt lgkmcnt(0)" ::: "memory");

    #pragma unroll
    for (int half = 0; half < 2; half++) {
      float4 pv0 = *(const float4*)&Ps[w][l15][half*32 + l4*8];
      float4 pv1 = *(const float4*)&Ps[w][l15][half*32 + l4*8 + 4];
      bf16x8 pa;
      pa[0]=(short)f2b(pv0.x); pa[1]=(short)f2b(pv0.y); pa[2]=(short)f2b(pv0.z); pa[3]=(short)f2b(pv0.w);
      pa[4]=(short)f2b(pv1.x); pa[5]=(short)f2b(pv1.y); pa[6]=(short)f2b(pv1.z); pa[7]=(short)f2b(pv1.w);
      #pragma unroll
      for (int nd = 0; nd < 4; nd++) {
        int dd = nd*16 + l15;
        bf16x8 vb;
        if constexpr (VT) {
          vb = *(const bf16x8*)&Vt[dd * 64 + ((half*32 + l4*8) ^ ((dd & 7) * 8))];
        } else {
          vb = *(const bf16x8*)&Vt[dd * 72 + ((half*32 + l4*8) ^ (((dd >> 3) & 7) << 3))];
        }
        oacc[nd] = __builtin_amdgcn_mfma_f32_16x16x32_bf16(pa, vb, oacc[nd], 0, 0, 0);
      }
    }
  }

  if constexpr (SPLIT == 1) {
    #pragma unroll
    for (int nd = 0; nd < 4; nd++)
      #pragma unroll
      for (int r = 0; r < 4; r++) {
        int q = q0 + w*16 + l4*4 + r;
        Op[(size_t)(b * Sn + q) * En + h * 64 + nd*16 + l15] = f2b(oacc[nd][r] / l_[r]);
      }
  } else {
    const int slot = ((b * Hn + h) * 4 + blockIdx.x) * SPLIT + sp;
    #pragma unroll
    for (int nd = 0; nd < 4; nd++)
      #pragma unroll
      for (int r = 0; r < 4; r++)
        PO[slot * 4096 + (w*16 + l4*4 + r) * 64 + nd*16 + l15] = oacc[nd][r];
    if (l15 == 0) {
      #pragma unroll
      for (int r = 0; r < 4; r++) {
        PM[slot * 64 + w*16 + l4*4 + r] = m_[r];
        PL[slot * 64 + w*16 + l4*4 + r] = l_[r];
      }
    }
  }
}

// ---------------- combine split-K attention partials (SPLIT=4) ----------------
__global__ __launch_bounds__(256) void k_attn_comb(
    const float* __restrict__ PO, const float* __restrict__ PM,
    const float* __restrict__ PL, unsigned short* __restrict__ Op) {
  const int W = blockIdx.x * 4 + (threadIdx.x >> 6);
  const int lane = threadIdx.x & 63;
  const int bh = W >> 8, q = W & 255;
  const int qb = q >> 6, qq = q & 63;
  const int slotBase = (bh * 4 + qb) * 4;
  float ms[4];
  float M = -INFINITY;
  #pragma unroll
  for (int s = 0; s < 4; s++) { ms[s] = PM[(slotBase + s) * 64 + qq]; M = fmaxf(M, ms[s]); }
  float L = 0.f, acc = 0.f;
  #pragma unroll
  for (int s = 0; s < 4; s++) {
    float wgt = __expf((ms[s] - M) * 0.125f);
    L += PL[(slotBase + s) * 64 + qq] * wgt;
    acc += wgt * PO[(size_t)(slotBase + s) * 4096 + qq * 64 + lane];
  }
  const int b = bh >> 4, h = bh & 15;
  Op[(size_t)(b * Sn + q) * En + h * 64 + lane] = f2b(acc / L);
}

// ------------- helpers for radix top-k (1024-thread blocks) -------------
DEVFN unsigned blk_exscan16(unsigned part, volatile unsigned* wsum, int lane, int wid) {
  unsigned v = part;
  #pragma unroll
  for (int d = 1; d < 64; d <<= 1) { unsigned o = __shfl_up(v, d); if (lane >= d) v += o; }
  if (lane == 63) wsum[wid] = v;
  __syncthreads();
  unsigned woff = 0;
  for (int i = 0; i < wid; i++) woff += wsum[i];
  unsigned r = woff + v - part;
  __syncthreads();
  return r;
}

DEVFN void find_thr16(const unsigned* hist, int NB, unsigned need,
                      int t, int lane, int wid, volatile unsigned* wsum,
                      volatile int* s_thr, volatile unsigned* s_above) {
  int per = NB >> 10;                        // bins per thread (NB/1024)
  int lo = NB - per * (t + 1);
  unsigned part = 0;
  for (int j = 0; j < per; j++) part += hist[lo + j];
  unsigned ex = blk_exscan16(part, wsum, lane, wid);
  if (ex < need && ex + part >= need) {
    unsigned c = ex;
    for (int j = per - 1; j >= 0; j--) {
      unsigned h = hist[lo + j];
      if (c + h >= need) { *s_thr = lo + j; *s_above = c; break; }
      c += h;
    }
  }
  __syncthreads();
}

// ------- exact top-32 per row on bf16 keys: 2 global passes + in-LDS select -------
__global__ __launch_bounds__(1024) void k_topk16(
    const unsigned short* __restrict__ simsb, int* __restrict__ oidx) {
  const int n = blockIdx.x, t = threadIdx.x;
  const int lane = t & 63, wid = t >> 6;
  const u16x8* row8 = (const u16x8*)(simsb + (size_t)n * Mn);
  constexpr unsigned CAP = 2048;
  __shared__ unsigned hist[2048];
  __shared__ unsigned wsum[16];
  __shared__ int s_thr;
  __shared__ unsigned s_above;
  __shared__ unsigned h2[32];
  __shared__ unsigned s_cnt, s_na;
  __shared__ unsigned short ckey[CAP];
  __shared__ unsigned cidx[CAP];
  __shared__ int slist[32];
  __shared__ unsigned sL, sneedEq, scntEq, s_imin;

  for (int i = t; i < 2048; i += 1024) hist[i] = 0;
  if (t < 32) h2[t] = 0;
  if (t == 0) { s_cnt = 0; s_na = 0; }
  __syncthreads();

  // ---- Pass A: histogram over top-11 bits ----
  #pragma unroll
  for (int p = 0; p < 8; p++) {
    u16x8 v = row8[p * 1024 + t];
    #pragma unroll
    for (int j = 0; j < 8; j++) atomicAdd(&hist[okey16(v[j]) >> 5], 1u);
  }
  __syncthreads();
  find_thr16(hist, 2048, 32, t, lane, wid, wsum, &s_thr, &s_above);
  const unsigned T1 = (unsigned)s_thr;
  const unsigned need2 = 32 - s_above;
  const unsigned cnt1 = hist[T1];
  const unsigned base = T1 << 5;

  // ---- Pass B: compact candidates + low-5 histogram of bin T1 ----
  #pragma unroll
  for (int p = 0; p < 8; p++) {
    u16x8 v = row8[p * 1024 + t];
    unsigned i0 = (unsigned)(p * 1024 + t) * 8;
    #pragma unroll
    for (int j = 0; j < 8; j++) {
      unsigned k = okey16(v[j]);
      if (k >= base) {
        unsigned slot = atomicAdd(&s_cnt, 1u);
        if (slot < CAP) { ckey[slot] = (unsigned short)k; cidx[slot] = i0 + j; }
        if ((k >> 5) == T1) atomicAdd(&h2[k & 31], 1u);
      }
    }
  }
  __syncthreads();
  const unsigned total = s_cnt;

  unsigned L, istar = 0xFFFFFFFFu;
  if (cnt1 == need2) {
    L = base;
  } else {
    if (t == 0) {
      unsigned cum = 0; int T3 = 0; unsigned above = 0;
      for (int j = 31; j >= 0; j--) {
        if (cum + h2[j] >= need2) { T3 = j; above = cum; break; }
        cum += h2[j];
      }
      sL = base | (unsigned)T3;
      sneedEq = need2 - above;
      scntEq = h2[T3];
    }
    __syncthreads();
    L = sL;
    if (scntEq != sneedEq) {
      if (total <= CAP) {
        int prev = -1;
        for (unsigned j = 0; j < sneedEq; j++) {
          if (t == 0) s_imin = 0xFFFFFFFFu;
          __syncthreads();
          for (unsigned i = t; i < total; i += 1024)
            if ((unsigned)ckey[i] == L && (int)cidx[i] > prev) atomicMin(&s_imin, cidx[i]);
          __syncthreads();
          prev = (int)s_imin;
          __syncthreads();
        }
        istar = (unsigned)prev;
      } else {
        const unsigned short* rowp = simsb + (size_t)n * Mn;
        unsigned cntLoc = 0;
        for (int j = 0; j < 64; j++)
          if (okey16(rowp[t * 64 + j]) == L) cntLoc++;
        unsigned pre = blk_exscan16(cntLoc, wsum, lane, wid);
        unsigned c = 0;
        for (int j = 0; j < 64; j++)
          if (okey16(rowp[t * 64 + j]) == L) { if (pre + c < 32) slist[pre + c] = t * 64 + j; c++; }
        __syncthreads();
        istar = (unsigned)slist[sneedEq - 1];
        __syncthreads();
        if (t == 0) s_na = 0;
        __syncthreads();
      }
    }
  }
  __syncthreads();

  if (total <= CAP) {
    for (unsigned i = t; i < total; i += 1024) {
      unsigned k = (unsigned)ckey[i];
      if (k > L || (k == L && cidx[i] <= istar)) {
        unsigned s = atomicAdd(&s_na, 1u);
        slist[s] = (int)cidx[i];
      }
    }
    __syncthreads();
    if (t < 32) {
      int my = slist[t];
      int rank = 0;
      #pragma unroll
      for (int j = 0; j < 32; j++) rank += (slist[j] < my);
      oidx[n * Kt + rank] = my;
    }
  } else {
    unsigned cnt = 0;
    for (int p = 0; p < 8; p++) {
      u16x8 v = row8[p * 1024 + t];
      unsigned i0 = (unsigned)(p * 1024 + t) * 8;
      #pragma unroll
      for (int j = 0; j < 8; j++) {
        unsigned k = okey16(v[j]);
        cnt += (k > L || (k == L && i0 + j <= istar));
      }
    }
    unsigned pos = blk_exscan16(cnt, wsum, lane, wid);
    for (int p = 0; p < 8; p++) {
      u16x8 v = row8[p * 1024 + t];
      unsigned i0 = (unsigned)(p * 1024 + t) * 8;
      #pragma unroll
      for (int j = 0; j < 8; j++) {
        unsigned k = okey16(v[j]);
        if (k > L || (k == L && i0 + j <= istar)) oidx[n * Kt + pos++] = (int)(i0 + j);
      }
    }
  }
}

// =============================== host ===============================
extern "C" void kernel_launch(void* const* d_in, const int* in_sizes, int n_in,
                              void* d_out, int out_size, void* d_ws, size_t ws_size,
                              hipStream_t stream) {
  (void)in_sizes; (void)n_in; (void)out_size;
  const float* x      = (const float*)d_in[0];
  const float* mem_k  = (const float*)d_in[1];
  const float* mem_v  = (const float*)d_in[2];
  const float* sa_w[4] = {(const float*)d_in[3], (const float*)d_in[4], (const float*)d_in[5], (const float*)d_in[6]};
  const float* sa_b[4] = {(const float*)d_in[7], (const float*)d_in[8], (const float*)d_in[9], (const float*)d_in[10]};
  const float* ma_w[4] = {(const float*)d_in[11], (const float*)d_in[12], (const float*)d_in[13], (const float*)d_in[14]};
  const float* ma_b[4] = {(const float*)d_in[15], (const float*)d_in[16], (const float*)d_in[17], (const float*)d_in[18]};
  const float* ln_g[3] = {(const float*)d_in[19], (const float*)d_in[21], (const float*)d_in[23]};
  const float* ln_b[3] = {(const float*)d_in[20], (const float*)d_in[22], (const float*)d_in[24]};
  const float* fc1_w = (const float*)d_in[25];
  const float* fc1_b = (const float*)d_in[26];
  const float* fc2_w = (const float*)d_in[27];
  const float* fc2_b = (const float*)d_in[28];
  float* out = (float*)d_out;

  char* ws = (char*)d_ws;
  size_t off = 0;
  auto alloc = [&](size_t bytes) -> char* {
    char* p = ws + off;
    off = (off + bytes + 255) & ~(size_t)255;
    return p;
  };

  unsigned short* wt[8];
  for (int i = 0; i < 8; i++) wt[i] = (unsigned short*)alloc((size_t)En * En * 2);  // contiguous
  unsigned short* fc1t  = (unsigned short*)alloc((size_t)FFn * En * 2);
  unsigned short* fc2t  = (unsigned short*)alloc((size_t)En * FFn * 2);
  unsigned short* xb    = (unsigned short*)alloc((size_t)NT * En * 2);
  unsigned short* Qb    = (unsigned short*)alloc((size_t)NT * En * 2);
  unsigned short* Kb    = (unsigned short*)alloc((size_t)NT * En * 2);
  unsigned short* Vb    = (unsigned short*)alloc((size_t)NT * En * 2);
  unsigned short* at1b  = (unsigned short*)alloc((size_t)NT * En * 2);
  float*          t1    = (float*)alloc((size_t)NT * En * 4);
  float*          x1f   = (float*)alloc((size_t)NT * En * 4);
  unsigned short* x1b   = (unsigned short*)alloc((size_t)NT * En * 2);
  char*           simsRaw = alloc((size_t)NT * Mn * 4);                // 256 MiB region
  int*            idx   = (int*)alloc((size_t)NT * Kt * 4);
  unsigned short* K2b   = (unsigned short*)alloc((size_t)NT * Kt * En * 2);  // 64 MiB
  unsigned short* V2b   = (unsigned short*)alloc((size_t)NT * Kt * En * 2);  // V2t: [B][1024][8192]
  unsigned short* Q2b   = (unsigned short*)alloc((size_t)NT * En * 2);
  unsigned short* at2b  = (unsigned short*)alloc((size_t)NT * En * 2);
  float*          t2    = (float*)alloc((size_t)NT * En * 4);
  float*          x2f   = (float*)alloc((size_t)NT * En * 4);
  unsigned short* x2b   = (unsigned short*)alloc((size_t)NT * En * 2);
  unsigned short* hb    = (unsigned short*)alloc((size_t)NT * FFn * 2);
  float*          t3    = (float*)alloc((size_t)NT * En * 4);
  float*          bcat_sa = (float*)alloc(3072 * 4);
  float*          bcat_ma = (float*)alloc(2048 * 4);

  if (off > ws_size) return;   // insufficient workspace: leave output poisoned (fail loudly)

  // Overlays (dead-region reuse):
  unsigned short* simsb = (unsigned short*)simsRaw;   // bf16 sims: 128 MiB of the region
  unsigned short* mkb = (unsigned short*)K2b;         // until sims GEMM done
  unsigned short* mvb = (unsigned short*)simsRaw;     // after topk
  float* PO = (float*)(simsRaw + (size_t)128 * 1024 * 1024);
  float* PM = PO + (size_t)1024 * 4096;
  float* PL = PM + (size_t)1024 * 64;

  // allow 128 KiB dynamic LDS for the 256^2 kernels (best effort)
  (void)hipFuncSetAttribute((const void*)&k_gemm256<5,false,1,0>,
                            hipFuncAttributeMaxDynamicSharedMemorySize, 131072);
  (void)hipFuncSetAttribute((const void*)&k_gemm256<6,true,2,1>,
                            hipFuncAttributeMaxDynamicSharedMemorySize, 131072);

  // ---- prep: weight transposes to bf16 [N][K], bias concats ----
  for (int i = 0; i < 4; i++)
    k_transpose_bf16<<<dim3(16, 16), 256, 0, stream>>>(sa_w[i], wt[i], En, En);
  for (int i = 0; i < 4; i++)
    k_transpose_bf16<<<dim3(16, 16), 256, 0, stream>>>(ma_w[i], wt[4 + i], En, En);
  k_transpose_bf16<<<dim3(64, 16), 256, 0, stream>>>(fc1_w, fc1t, En, FFn);
  k_transpose_bf16<<<dim3(16, 64), 256, 0, stream>>>(fc2_w, fc2t, FFn, En);
  k_concat3<<<dim3(12), 256, 0, stream>>>(sa_b[0], sa_b[1], sa_b[2], bcat_sa);
  k_concat3<<<dim3(8),  256, 0, stream>>>(ma_b[1], ma_b[2], ma_b[2], bcat_ma);

  k_cvt_bf16<<<dim3(NT * En / 4 / 256), 256, 0, stream>>>(x, xb, NT * En / 4);
  k_normcvt<<<dim3(Mn), 256, 0, stream>>>(mem_k, mkb);

  const dim3 g1(En / 128, NT / 128);   // (8,8)

  // ---- self-attention (QKV fused: N=3072 over contiguous wt[0..2]) ----
  k_gemm<0,false,false,3><<<dim3(24, 8), 256, 0, stream>>>(xb, wt[0], nullptr, bcat_sa, nullptr, nullptr, Qb, Kb, Vb, 3072, En);
  k_attn<1,false><<<dim3(Sn / 64, Hn, Bn), 256, 0, stream>>>(Qb, Kb, Vb, at1b, nullptr, nullptr, nullptr, Sn);
  k_gemm<1,false,false,1><<<g1, 256, 0, stream>>>(at1b, wt[3], nullptr, sa_b[3], x, t1, nullptr, nullptr, nullptr, En, En);
  k_layernorm<<<NT, 256, 0, stream>>>(t1, ln_g[0], ln_b[0], x1f, x1b);

  // ---- retrieval: sims in bf16 + 2-pass candidate top-k ----
  k_gemm256<5,false,1,0><<<dim3(1024), 512, 131072, stream>>>(
      x1b, mkb, nullptr, nullptr, nullptr, simsb, nullptr, Mn, En, NT / 256, Mn / 256);
  k_topk16<<<NT, 1024, 0, stream>>>(simsb, idx);

  // ---- memory cross-attention (K2 row-major + V2 transposed, fused gather GEMM) ----
  k_cvt_bf16<<<dim3(Mn * En / 4 / 256), 256, 0, stream>>>(mem_v, mvb, Mn * En / 4);
  k_gemm256<6,true,2,1><<<dim3(1024), 512, 131072, stream>>>(
      mvb, wt[5], idx, bcat_ma, nullptr, K2b, V2b, 2048, En, NT * Kt / 256, 2048 / 256);
  k_gemm<0,false,false,1><<<g1, 256, 0, stream>>>(x1b, wt[4], nullptr, ma_b[0], nullptr, nullptr, Q2b, nullptr, nullptr, En, En);
  k_attn<4,true><<<dim3(Sn / 64, Hn, Bn * 4), 256, 0, stream>>>(Q2b, K2b, V2b, nullptr, PO, PM, PL, Sn * Kt);
  k_attn_comb<<<dim3(Bn * Hn * Sn / 4), 256, 0, stream>>>(PO, PM, PL, at2b);
  k_gemm<1,false,false,1><<<g1, 256, 0, stream>>>(at2b, wt[7], nullptr, ma_b[3], x1f, t2, nullptr, nullptr, nullptr, En, En);
  k_layernorm<<<NT, 256, 0, stream>>>(t2, ln_g[1], ln_b[1], x2f, x2b);

  // ---- FFN ----
  k_gemm<2,false,false,1><<<dim3(FFn / 128, NT / 128), 256, 0, stream>>>(x2b, fc1t, nullptr, fc1_b, nullptr, nullptr, hb, nullptr, nullptr, FFn, En);
  k_gemm<1,false,false,1><<<g1, 256, 0, stream>>>(hb, fc2t, nullptr, fc2_b, x2f, t3, nullptr, nullptr, nullptr, En, FFn);
  k_layernorm<<<NT, 256, 0, stream>>>(t3, ln_g[2], ln_b[2], out, nullptr);
}

// Round 11
// 970.017 us; speedup vs baseline: 1.3193x; 1.0235x over previous
//
#include <hip/hip_runtime.h>
#include <hip/hip_bf16.h>
#include <math.h>

#define DEVFN __device__ __forceinline__

typedef __attribute__((ext_vector_type(8))) short bf16x8;
typedef __attribute__((ext_vector_type(8))) unsigned short u16x8;
typedef __attribute__((ext_vector_type(4))) unsigned short u16x4;
typedef __attribute__((ext_vector_type(4))) float f32x4;

static constexpr int Bn = 4, Sn = 256, En = 1024, Hn = 16;
static constexpr int Mn = 65536, Kt = 32, FFn = 4096;
static constexpr int NT = Bn * Sn;           // 1024 tokens

DEVFN unsigned short f2b(float f) {          // f32 -> bf16 RNE
  unsigned int u = __float_as_uint(f);
  unsigned int r = (u + 0x7FFFu + ((u >> 16) & 1u)) >> 16;
  return (unsigned short)r;
}

DEVFN unsigned okey16(unsigned short u) {    // order-preserving bf16 -> u16
  return (unsigned)(u ^ ((u >> 15) ? 0xFFFFu : 0x8000u)) & 0xFFFFu;
}

typedef const __attribute__((address_space(1))) void* as1cv_t;
typedef __attribute__((address_space(3))) void* as3v_t;
DEVFN void gload16(const void* g, void* l) {   // async global->LDS, 16B/lane
  __builtin_amdgcn_global_load_lds((as1cv_t)g, (as3v_t)l, 16, 0, 0);
}
#define MEMFENCE asm volatile("" ::: "memory")

struct P8 { const float* s[8]; };

// ---------------- batched transpose W[1024][1024] f32 -> out[C][R] bf16 ----------------
__global__ __launch_bounds__(256) void k_transpose8(
    P8 ps, unsigned short* __restrict__ outbase) {
  const float* in = ps.s[blockIdx.z];
  unsigned short* out = outbase + (size_t)blockIdx.z * En * En;
  __shared__ float tile[64][65];
  int tx = threadIdx.x & 63, ty = threadIdx.x >> 6;
  int c0 = blockIdx.x * 64, r0 = blockIdx.y * 64;
  #pragma unroll
  for (int i = 0; i < 16; i++) {
    int r = ty + i * 4;
    tile[tx][r] = in[(size_t)(r0 + r) * En + (c0 + tx)];
  }
  __syncthreads();
  #pragma unroll
  for (int i = 0; i < 16; i++) {
    int c = ty + i * 4;
    out[(size_t)(c0 + c) * En + (r0 + tx)] = f2b(tile[c][tx]);
  }
}

// ---------------- transpose W[R][C] f32 -> out[C][R] bf16 ----------------
__global__ __launch_bounds__(256) void k_transpose_bf16(
    const float* __restrict__ in, unsigned short* __restrict__ out, int R, int C) {
  __shared__ float tile[64][65];
  int tx = threadIdx.x & 63, ty = threadIdx.x >> 6;
  int c0 = blockIdx.x * 64, r0 = blockIdx.y * 64;
  #pragma unroll
  for (int i = 0; i < 16; i++) {
    int r = ty + i * 4;
    tile[tx][r] = in[(size_t)(r0 + r) * C + (c0 + tx)];
  }
  __syncthreads();
  #pragma unroll
  for (int i = 0; i < 16; i++) {
    int c = ty + i * 4;
    out[(size_t)(c0 + c) * R + (r0 + tx)] = f2b(tile[c][tx]);
  }
}

// ---------------- f32 -> bf16 elementwise (x4) ----------------
__global__ __launch_bounds__(256) void k_cvt_bf16(
    const float* __restrict__ in, unsigned short* __restrict__ out, int n4) {
  int i = blockIdx.x * 256 + threadIdx.x;
  if (i >= n4) return;
  float4 v = ((const float4*)in)[i];
  uint2 o;
  o.x = (unsigned int)f2b(v.x) | ((unsigned int)f2b(v.y) << 16);
  o.y = (unsigned int)f2b(v.z) | ((unsigned int)f2b(v.w) << 16);
  ((uint2*)out)[i] = o;
}

// ---------------- concat up to 3 x 1024-f32 vectors ----------------
__global__ __launch_bounds__(256) void k_concat3(
    const float* __restrict__ a, const float* __restrict__ b,
    const float* __restrict__ c, float* __restrict__ o) {
  int i = blockIdx.x * 256 + threadIdx.x;
  float v = (i < 1024) ? a[i] : (i < 2048) ? b[i - 1024] : c[i - 2048];
  o[i] = v;
}

// ---- mem_keys row-normalize + cvt to bf16 (folds cosine norm into B) ----
__global__ __launch_bounds__(256) void k_normcvt(
    const float* __restrict__ mk, unsigned short* __restrict__ out) {
  int m = blockIdx.x, t = threadIdx.x;
  float4 v = ((const float4*)(mk + (size_t)m * En))[t];
  float ss = v.x*v.x + v.y*v.y + v.z*v.z + v.w*v.w;
  #pragma unroll
  for (int d = 32; d; d >>= 1) ss += __shfl_down(ss, d);
  __shared__ float red[4];
  int lane = t & 63, w = t >> 6;
  if (lane == 0) red[w] = ss;
  __syncthreads();
  float rs = 1.0f / fmaxf(sqrtf(red[0] + red[1] + red[2] + red[3]), 1e-12f);
  uint2 o;
  o.x = (unsigned int)f2b(v.x * rs) | ((unsigned int)f2b(v.y * rs) << 16);
  o.y = (unsigned int)f2b(v.z * rs) | ((unsigned int)f2b(v.w * rs) << 16);
  ((uint2*)(out + (size_t)m * En))[t] = o;
}

// ---------------- LayerNorm over rows of [NT][En] ----------------
__global__ __launch_bounds__(256) void k_layernorm(
    const float* __restrict__ in, const float* __restrict__ g, const float* __restrict__ bb,
    float* __restrict__ outf, unsigned short* __restrict__ outb) {
  int n = blockIdx.x, t = threadIdx.x;
  float4 v = ((const float4*)(in + (size_t)n * En))[t];
  float s  = v.x + v.y + v.z + v.w;
  float s2 = v.x*v.x + v.y*v.y + v.z*v.z + v.w*v.w;
  #pragma unroll
  for (int d = 32; d; d >>= 1) { s += __shfl_down(s, d); s2 += __shfl_down(s2, d); }
  __shared__ float rs[4], rq[4];
  int lane = t & 63, w = t >> 6;
  if (lane == 0) { rs[w] = s; rq[w] = s2; }
  __syncthreads();
  float mean = (rs[0]+rs[1]+rs[2]+rs[3]) * (1.0f/En);
  float var  = (rq[0]+rq[1]+rq[2]+rq[3]) * (1.0f/En) - mean*mean;
  float rstd = rsqrtf(var + 1e-5f);
  float4 gg = ((const float4*)g)[t];
  float4 bv = ((const float4*)bb)[t];
  float o0 = (v.x-mean)*rstd*gg.x + bv.x;
  float o1 = (v.y-mean)*rstd*gg.y + bv.y;
  float o2 = (v.z-mean)*rstd*gg.z + bv.z;
  float o3 = (v.w-mean)*rstd*gg.w + bv.w;
  if (outf) { float4 ov = {o0,o1,o2,o3}; ((float4*)(outf + (size_t)n*En))[t] = ov; }
  if (outb) {
    uint2 o;
    o.x = (unsigned int)f2b(o0) | ((unsigned int)f2b(o1) << 16);
    o.y = (unsigned int)f2b(o2) | ((unsigned int)f2b(o3) << 16);
    ((uint2*)(outb + (size_t)n*En))[t] = o;
  }
}

// ======== 256x256 GEMM, 4 half-tile ring buffers + counted vmcnt (T1..T5) ========
// EPI 4: f32 out | EPI 5: bf16 no-bias | EPI 0 + NOUT2: bf16 (+bias), split N
// EPI 6: split N=2048 -> cb0 row-major (+bias), cb1 TRANSPOSED [B][1024][8192] (+bias)
template<int EPI, bool AGATHER, int NOUT, int LSWZ>
__global__ __launch_bounds__(512) void k_gemm256(
    const unsigned short* __restrict__ Ab, const unsigned short* __restrict__ Bb,
    const int* __restrict__ gidx, const float* __restrict__ bias,
    float* __restrict__ Cf, unsigned short* __restrict__ cb0, unsigned short* __restrict__ cb1,
    int Ndim, int Kdim, int nRT, int nCT) {
  extern __shared__ unsigned short lds[];
  const int t = threadIdx.x, lane = t & 63, w = t >> 6;
  const int wr = w >> 2, wc = w & 3, l15 = lane & 15, l4 = lane >> 4;
  const int lr2 = lane >> 2;
  const int cg  = (lane & 3) ^ (((lane >> 5) & 1) << 1);   // source pre-swizzle (involution)

  const int nwg = nRT * nCT;
  int lb = ((int)blockIdx.x % 8) * (nwg >> 3) + ((int)blockIdx.x >> 3);
  int rowT, colT;
  if (LSWZ == 0) { rowT = lb % nRT; colT = lb / nRT; }
  else           { colT = lb % nCT; rowT = lb / nCT; }
  const int row0 = rowT * 256, col0 = colT * 256;

  auto pa = [&](int h) -> unsigned short* { return lds + h * 16384; };
  auto pb = [&](int h) -> unsigned short* { return lds + h * 16384 + 8192; };

  const unsigned short *aSrc0, *aSrc1;
  if constexpr (AGATHER) {
    aSrc0 = Ab + (size_t)gidx[row0 + w * 32 + lr2] * Kdim + cg * 8;
    aSrc1 = Ab + (size_t)gidx[row0 + w * 32 + 16 + lr2] * Kdim + cg * 8;
  } else {
    aSrc0 = Ab + (size_t)(row0 + w * 32 + lr2) * Kdim + cg * 8;
    aSrc1 = aSrc0 + (size_t)16 * Kdim;
  }
  const unsigned short* bSrc0 = Bb + (size_t)(col0 + w * 32 + lr2) * Kdim + cg * 8;
  const unsigned short* bSrc1 = bSrc0 + (size_t)16 * Kdim;

  f32x4 acc[8][4];
  #pragma unroll
  for (int i = 0; i < 8; i++)
    #pragma unroll
    for (int j = 0; j < 4; j++) acc[i][j] = (f32x4){0.f, 0.f, 0.f, 0.f};

  const int NH = Kdim >> 5;                 // K half-tiles of 32
  #pragma unroll
  for (int h = 0; h < 3; ++h) {
    const int ko = h * 32;
    gload16(aSrc0 + ko, pa(h) + w*32*32);
    gload16(aSrc1 + ko, pa(h) + (w*32+16)*32);
    gload16(bSrc0 + ko, pb(h) + w*32*32);
    gload16(bSrc1 + ko, pb(h) + (w*32+16)*32);
  }
  asm volatile("s_waitcnt vmcnt(8)" ::: "memory");   // half 0 landed
  __builtin_amdgcn_s_barrier();
  MEMFENCE;

  for (int hs = 0; hs < NH; ++hs) {
    const int cur = hs & 3;
    const unsigned short* Ap = pa(cur);
    const unsigned short* Bp = pb(cur);
    const int h3 = (hs + 3) & 3, ko3 = (hs + 3) * 32;
    const bool pf = (hs + 3) < NH;
    bf16x8 bfr[4], af[4];

    // ---- phase 0: B frags + A rows 0..63 ----
    #pragma unroll
    for (int ni = 0; ni < 4; ni++) {
      int row = wc * 64 + ni * 16 + l15;
      int c8 = l4 ^ (((row >> 3) & 1) << 1);
      bfr[ni] = *(const bf16x8*)&Bp[row * 32 + c8 * 8];
    }
    #pragma unroll
    for (int m = 0; m < 4; m++) {
      int row = wr * 128 + m * 16 + l15;
      int c8 = l4 ^ (((row >> 3) & 1) << 1);
      af[m] = *(const bf16x8*)&Ap[row * 32 + c8 * 8];
    }
    if (pf) {
      gload16(aSrc0 + ko3, pa(h3) + w*32*32);
      gload16(aSrc1 + ko3, pa(h3) + (w*32+16)*32);
    }
    MEMFENCE; __builtin_amdgcn_s_barrier(); MEMFENCE;
    __builtin_amdgcn_s_setprio(1);
    #pragma unroll
    for (int m = 0; m < 4; m++)
      #pragma unroll
      for (int ni = 0; ni < 4; ni++)
        acc[m][ni] = __builtin_amdgcn_mfma_f32_16x16x32_bf16(af[m], bfr[ni], acc[m][ni], 0, 0, 0);
    __builtin_amdgcn_s_setprio(0);
    MEMFENCE; __builtin_amdgcn_s_barrier(); MEMFENCE;

    // ---- phase 1: A rows 64..127 ----
    #pragma unroll
    for (int m = 0; m < 4; m++) {
      int row = wr * 128 + (4 + m) * 16 + l15;
      int c8 = l4 ^ (((row >> 3) & 1) << 1);
      af[m] = *(const bf16x8*)&Ap[row * 32 + c8 * 8];
    }
    if (pf) {
      gload16(bSrc0 + ko3, pb(h3) + w*32*32);
      gload16(bSrc1 + ko3, pb(h3) + (w*32+16)*32);
    }
    MEMFENCE; __builtin_amdgcn_s_barrier(); MEMFENCE;
    __builtin_amdgcn_s_setprio(1);
    #pragma unroll
    for (int m = 0; m < 4; m++)
      #pragma unroll
      for (int ni = 0; ni < 4; ni++)
        acc[4 + m][ni] = __builtin_amdgcn_mfma_f32_16x16x32_bf16(af[m], bfr[ni], acc[4 + m][ni], 0, 0, 0);
    __builtin_amdgcn_s_setprio(0);

    if (hs + 1 < NH) {
      const int rem = NH - 2 - hs;
      if (rem >= 2)      asm volatile("s_waitcnt vmcnt(8)" ::: "memory");
      else if (rem == 1) asm volatile("s_waitcnt vmcnt(4)" ::: "memory");
      else               asm volatile("s_waitcnt vmcnt(0)" ::: "memory");
      __builtin_amdgcn_s_barrier();
      MEMFENCE;
    }
  }

  #pragma unroll
  for (int m = 0; m < 8; m++) {
    #pragma unroll
    for (int ni = 0; ni < 4; ni++) {
      int col  = col0 + wc * 64 + ni * 16 + l15;
      int rowb = row0 + wr * 128 + m * 16 + l4 * 4;
      if constexpr (EPI == 6) {
        if (col < 1024) {
          #pragma unroll
          for (int r = 0; r < 4; r++)
            cb0[(size_t)(rowb + r) * 1024 + col] = f2b(acc[m][ni][r] + bias[col]);
        } else {
          int c = col - 1024;
          int bi = rowb >> 13, k0 = rowb & 8191;
          u16x4 o;
          #pragma unroll
          for (int r = 0; r < 4; r++) o[r] = f2b(acc[m][ni][r] + bias[col]);
          *(u16x4*)&cb1[((size_t)bi * 1024 + c) * 8192 + k0] = o;
        }
      } else {
        #pragma unroll
        for (int r = 0; r < 4; r++) {
          float v = acc[m][ni][r];
          if constexpr (EPI == 4) {
            Cf[(size_t)(rowb + r) * Ndim + col] = v;
          } else if constexpr (EPI == 5) {
            cb0[(size_t)(rowb + r) * Ndim + col] = f2b(v);
          } else {
            unsigned short* cb = (col >> 10) ? cb1 : cb0;
            cb[(size_t)(rowb + r) * 1024 + (col & 1023)] = f2b(v + bias[col]);
          }
        }
      }
    }
  }
}

// ---------------- GEMM 128x128 (2-phase) for the small GEMMs ----------------
template<int EPI, bool AGATHER, bool SWAPG, int NOUT>
__global__ __launch_bounds__(256) void k_gemm(
    const unsigned short* __restrict__ Ab, const unsigned short* __restrict__ Bb,
    const int* __restrict__ gidx,
    const float* __restrict__ bias, const float* __restrict__ resid,
    float* __restrict__ Cf, unsigned short* __restrict__ cb0,
    unsigned short* __restrict__ cb1, unsigned short* __restrict__ cb2,
    int Ndim, int Kdim) {
  __shared__ unsigned short As[128][32];
  __shared__ unsigned short Bs[128][32];
  const int t = threadIdx.x, lane = t & 63, w = t >> 6;
  const int wr = w >> 1, wc = w & 1, l15 = lane & 15, l4 = lane >> 4;
  const int row0 = (SWAPG ? blockIdx.x : blockIdx.y) * 128;
  const int col0 = (SWAPG ? blockIdx.y : blockIdx.x) * 128;
  const int c8  = (lane & 3) * 8;
  const int r16 = lane >> 2;
  const int rA0 = w * 32 + r16, rA1 = rA0 + 16;

  size_t raA0, raA1, raB0, raB1;
  if constexpr (AGATHER) {
    raA0 = (size_t)gidx[row0 + rA0] * Kdim;
    raA1 = (size_t)gidx[row0 + rA1] * Kdim;
  } else {
    raA0 = (size_t)(row0 + rA0) * Kdim;
    raA1 = (size_t)(row0 + rA1) * Kdim;
  }
  raB0 = (size_t)(col0 + rA0) * Kdim;
  raB1 = (size_t)(col0 + rA1) * Kdim;

  f32x4 acc[4][4];
  #pragma unroll
  for (int i = 0; i < 4; i++)
    #pragma unroll
    for (int j = 0; j < 4; j++) acc[i][j] = (f32x4){0.f,0.f,0.f,0.f};

  for (int kt0 = 0; kt0 < Kdim; kt0 += 32) {
    __syncthreads();
    gload16(Ab + raA0 + kt0 + c8, &As[w * 32][0]);
    gload16(Ab + raA1 + kt0 + c8, &As[w * 32 + 16][0]);
    gload16(Bb + raB0 + kt0 + c8, &Bs[w * 32][0]);
    gload16(Bb + raB1 + kt0 + c8, &Bs[w * 32 + 16][0]);
    __syncthreads();
    bf16x8 af[4], bfr[4];
    #pragma unroll
    for (int mi = 0; mi < 4; mi++) af[mi]  = *(const bf16x8*)&As[wr*64 + mi*16 + l15][l4*8];
    #pragma unroll
    for (int ni = 0; ni < 4; ni++) bfr[ni] = *(const bf16x8*)&Bs[wc*64 + ni*16 + l15][l4*8];
    #pragma unroll
    for (int mi = 0; mi < 4; mi++)
      #pragma unroll
      for (int ni = 0; ni < 4; ni++)
        acc[mi][ni] = __builtin_amdgcn_mfma_f32_16x16x32_bf16(af[mi], bfr[ni], acc[mi][ni], 0, 0, 0);
  }

  unsigned short* cbase = cb0;
  int colsub = 0;
  if constexpr (NOUT > 1) {
    int which = col0 >> 10;
    cbase = (which == 0) ? cb0 : (which == 1) ? cb1 : cb2;
    colsub = col0 & 1023;
  }

  #pragma unroll
  for (int mi = 0; mi < 4; mi++) {
    #pragma unroll
    for (int ni = 0; ni < 4; ni++) {
      int col  = col0 + wc*64 + ni*16 + l15;
      int rowb = row0 + wr*64 + mi*16 + l4*4;
      #pragma unroll
      for (int r = 0; r < 4; r++) {
        float v = acc[mi][ni][r];
        size_t off = (size_t)(rowb + r) * Ndim + col;
        if constexpr (EPI == 0) {
          if constexpr (NOUT > 1) {
            int c2 = colsub + wc*64 + ni*16 + l15;
            cbase[(size_t)(rowb + r) * 1024 + c2] = f2b(v + bias[col]);
          } else {
            cb0[off] = f2b(v + bias[col]);
          }
        } else if constexpr (EPI == 1) {
          Cf[off] = v + bias[col] + resid[off];
        } else if constexpr (EPI == 2) {
          float u = v + bias[col];
          u = 0.5f * u * (1.0f + erff(u * 0.70710678118654752f));
          cb0[off] = f2b(u);
        } else {
          Cf[off] = v;
        }
      }
    }
  }
}

// ---------------- SA fused attention (flash-style, Lk=256) ----------------
__global__ __launch_bounds__(256) void k_attn_sa(
    const unsigned short* __restrict__ Qp, const unsigned short* __restrict__ Kp,
    const unsigned short* __restrict__ Vp, unsigned short* __restrict__ Op, int Lk) {
  __shared__ unsigned short Ks[64][72];
  __shared__ unsigned short Vt[64][72];
  __shared__ float Ps[4][16][68];
  const int b = blockIdx.z;
  const int h = blockIdx.y, q0 = blockIdx.x * 64;
  const int t = threadIdx.x, lane = t & 63, w = t >> 6;
  const int l15 = lane & 15, l4 = lane >> 4;

  const int qrow = q0 + w * 16 + l15;
  const unsigned short* qptr = Qp + (size_t)(b * Sn + qrow) * En + h * 64 + l4 * 8;
  bf16x8 qf0 = *(const bf16x8*)qptr;
  bf16x8 qf1 = *(const bf16x8*)(qptr + 32);

  f32x4 oacc[4];
  #pragma unroll
  for (int i = 0; i < 4; i++) oacc[i] = (f32x4){0.f,0.f,0.f,0.f};
  float m_[4] = {-INFINITY, -INFINITY, -INFINITY, -INFINITY};
  float l_[4] = {0.f, 0.f, 0.f, 0.f};

  const int nkt = Lk / 64;
  for (int kt = 0; kt < nkt; ++kt) {
    __syncthreads();
    #pragma unroll
    for (int i = 0; i < 2; i++) {
      int ld = t + i * 256;
      int kr = ld >> 3, d8 = (ld & 7) * 8;
      size_t base = (size_t)(b * Lk + kt * 64 + kr) * En + h * 64 + d8;
      *(uint4*)&Ks[kr][d8] = *(const uint4*)(Kp + base);
      bf16x8 vv = *(const bf16x8*)(Vp + base);
      int colswz = kr ^ ((t & 7) << 3);
      #pragma unroll
      for (int j = 0; j < 8; j++) Vt[d8 + j][colswz] = ((unsigned short*)&vv)[j];
    }
    __syncthreads();

    f32x4 s[4];
    #pragma unroll
    for (int ni = 0; ni < 4; ni++) {
      s[ni] = (f32x4){0.f,0.f,0.f,0.f};
      bf16x8 kb0 = *(const bf16x8*)&Ks[ni*16 + l15][l4*8];
      bf16x8 kb1 = *(const bf16x8*)&Ks[ni*16 + l15][l4*8 + 32];
      s[ni] = __builtin_amdgcn_mfma_f32_16x16x32_bf16(qf0, kb0, s[ni], 0, 0, 0);
      s[ni] = __builtin_amdgcn_mfma_f32_16x16x32_bf16(qf1, kb1, s[ni], 0, 0, 0);
    }

    #pragma unroll
    for (int r = 0; r < 4; r++) {
      float mx = fmaxf(fmaxf(s[0][r], s[1][r]), fmaxf(s[2][r], s[3][r]));
      #pragma unroll
      for (int d2 = 1; d2 < 16; d2 <<= 1) mx = fmaxf(mx, __shfl_xor(mx, d2));
      if (mx > m_[r]) {
        float alpha = __expf((m_[r] - mx) * 0.125f);
        l_[r] *= alpha;
        #pragma unroll
        for (int nd = 0; nd < 4; nd++) oacc[nd][r] *= alpha;
        m_[r] = mx;
      }
      float rsum = 0.f;
      #pragma unroll
      for (int ni = 0; ni < 4; ni++) {
        float p = __expf((s[ni][r] - m_[r]) * 0.125f);
        s[ni][r] = p; rsum += p;
      }
      #pragma unroll
      for (int d2 = 1; d2 < 16; d2 <<= 1) rsum += __shfl_xor(rsum, d2);
      l_[r] += rsum;
    }

    #pragma unroll
    for (int ni = 0; ni < 4; ni++)
      #pragma unroll
      for (int r = 0; r < 4; r++)
        Ps[w][l4*4 + r][ni*16 + l15] = s[ni][r];
    asm volatile("s_waitcnt lgkmcnt(0)" ::: "memory");

    #pragma unroll
    for (int half = 0; half < 2; half++) {
      float4 pv0 = *(const float4*)&Ps[w][l15][half*32 + l4*8];
      float4 pv1 = *(const float4*)&Ps[w][l15][half*32 + l4*8 + 4];
      bf16x8 pa;
      pa[0]=(short)f2b(pv0.x); pa[1]=(short)f2b(pv0.y); pa[2]=(short)f2b(pv0.z); pa[3]=(short)f2b(pv0.w);
      pa[4]=(short)f2b(pv1.x); pa[5]=(short)f2b(pv1.y); pa[6]=(short)f2b(pv1.z); pa[7]=(short)f2b(pv1.w);
      #pragma unroll
      for (int nd = 0; nd < 4; nd++) {
        int dd = nd*16 + l15;
        bf16x8 vb = *(const bf16x8*)&Vt[dd][(half*32 + l4*8) ^ (((dd >> 3) & 7) << 3)];
        oacc[nd] = __builtin_amdgcn_mfma_f32_16x16x32_bf16(pa, vb, oacc[nd], 0, 0, 0);
      }
    }
  }

  #pragma unroll
  for (int nd = 0; nd < 4; nd++)
    #pragma unroll
    for (int r = 0; r < 4; r++) {
      int q = q0 + w*16 + l4*4 + r;
      Op[(size_t)(b * Sn + q) * En + h * 64 + nd*16 + l15] = f2b(oacc[nd][r] / l_[r]);
    }
}

// ------- MA attention: 4 q-tiles folded, SPLIT=16, double-buffered VT staging -------
// Q: [B*Sn][En]; K: [B*8192][En]; V TRANSPOSED: [B][1024][8192]. Partials PO/PM/PL.
__global__ __launch_bounds__(256, 2) void k_attn_ma(
    const unsigned short* __restrict__ Qp, const unsigned short* __restrict__ Kp,
    const unsigned short* __restrict__ Vp,
    float* __restrict__ PO, float* __restrict__ PM, float* __restrict__ PL) {
  constexpr int Lk = Sn * Kt;            // 8192
  constexpr int NTI = 8;                 // k-tiles per block (8192/64/16)
  __shared__ unsigned short Ks[2][64 * 64];
  __shared__ unsigned short Vt[2][64 * 64];
  __shared__ float Ps[4][16][68];
  const int sp = blockIdx.x, h = blockIdx.y, b = blockIdx.z;
  const int t = threadIdx.x, lane = t & 63, w = t >> 6;
  const int l15 = lane & 15, l4 = lane >> 4;
  const int l8 = lane >> 3, l7 = lane & 7;
  const int kswz = (l7 ^ l8) * 8;        // source pre-swizzle (row&7)
  const int rbase = w * 16;

  bf16x8 qf[4][2];
  #pragma unroll
  for (int qt = 0; qt < 4; qt++) {
    const unsigned short* qptr = Qp + (size_t)(b * Sn + w * 64 + qt * 16 + l15) * En + h * 64 + l4 * 8;
    qf[qt][0] = *(const bf16x8*)qptr;
    qf[qt][1] = *(const bf16x8*)(qptr + 32);
  }

  f32x4 oacc[4][4];
  #pragma unroll
  for (int i = 0; i < 4; i++)
    #pragma unroll
    for (int j = 0; j < 4; j++) oacc[i][j] = (f32x4){0.f,0.f,0.f,0.f};
  float m_[4][4], l_[4][4];
  #pragma unroll
  for (int i = 0; i < 4; i++)
    #pragma unroll
    for (int j = 0; j < 4; j++) { m_[i][j] = -INFINITY; l_[i][j] = 0.f; }

  const int kt0 = sp * NTI;
  auto stage = [&](int kt, int buf) {
    #pragma unroll
    for (int i = 0; i < 2; i++) {
      int row = rbase + i * 8 + l8;
      gload16(Kp + (size_t)(b * Lk + kt * 64 + row) * En + h * 64 + kswz,
              &Ks[buf][(rbase + i * 8) * 64]);
      gload16(Vp + ((size_t)b * 1024 + h * 64 + row) * (size_t)Lk + kt * 64 + kswz,
              &Vt[buf][(rbase + i * 8) * 64]);
    }
  };

  stage(kt0, 0);
  stage(kt0 + 1, 1);
  asm volatile("s_waitcnt vmcnt(4)" ::: "memory");   // tile0 landed (Q drained too)
  __builtin_amdgcn_s_barrier();
  MEMFENCE;

  for (int j = 0; j < NTI; ++j) {
    const int cur = j & 1;
    #pragma unroll
    for (int qt = 0; qt < 4; qt++) {
      f32x4 s[4];
      #pragma unroll
      for (int ni = 0; ni < 4; ni++) {
        s[ni] = (f32x4){0.f,0.f,0.f,0.f};
        int rowK = ni * 16 + l15, sw = (rowK & 7) * 8;
        bf16x8 kb0 = *(const bf16x8*)&Ks[cur][rowK * 64 + ((l4 * 8) ^ sw)];
        bf16x8 kb1 = *(const bf16x8*)&Ks[cur][rowK * 64 + ((l4 * 8 + 32) ^ sw)];
        s[ni] = __builtin_amdgcn_mfma_f32_16x16x32_bf16(qf[qt][0], kb0, s[ni], 0, 0, 0);
        s[ni] = __builtin_amdgcn_mfma_f32_16x16x32_bf16(qf[qt][1], kb1, s[ni], 0, 0, 0);
      }
      #pragma unroll
      for (int r = 0; r < 4; r++) {
        float mx = fmaxf(fmaxf(s[0][r], s[1][r]), fmaxf(s[2][r], s[3][r]));
        #pragma unroll
        for (int d2 = 1; d2 < 16; d2 <<= 1) mx = fmaxf(mx, __shfl_xor(mx, d2));
        if (mx > m_[qt][r]) {
          float alpha = __expf((m_[qt][r] - mx) * 0.125f);
          l_[qt][r] *= alpha;
          #pragma unroll
          for (int nd = 0; nd < 4; nd++) oacc[qt][nd][r] *= alpha;
          m_[qt][r] = mx;
        }
        float rsum = 0.f;
        #pragma unroll
        for (int ni = 0; ni < 4; ni++) {
          float p = __expf((s[ni][r] - m_[qt][r]) * 0.125f);
          s[ni][r] = p; rsum += p;
        }
        #pragma unroll
        for (int d2 = 1; d2 < 16; d2 <<= 1) rsum += __shfl_xor(rsum, d2);
        l_[qt][r] += rsum;
      }
      #pragma unroll
      for (int ni = 0; ni < 4; ni++)
        #pragma unroll
        for (int r = 0; r < 4; r++)
          Ps[w][l4*4 + r][ni*16 + l15] = s[ni][r];
      asm volatile("s_waitcnt lgkmcnt(0)" ::: "memory");
      #pragma unroll
      for (int half = 0; half < 2; half++) {
        float4 pv0 = *(const float4*)&Ps[w][l15][half*32 + l4*8];
        float4 pv1 = *(const float4*)&Ps[w][l15][half*32 + l4*8 + 4];
        bf16x8 pa;
        pa[0]=(short)f2b(pv0.x); pa[1]=(short)f2b(pv0.y); pa[2]=(short)f2b(pv0.z); pa[3]=(short)f2b(pv0.w);
        pa[4]=(short)f2b(pv1.x); pa[5]=(short)f2b(pv1.y); pa[6]=(short)f2b(pv1.z); pa[7]=(short)f2b(pv1.w);
        #pragma unroll
        for (int nd = 0; nd < 4; nd++) {
          int dd = nd*16 + l15;
          bf16x8 vb = *(const bf16x8*)&Vt[cur][dd * 64 + ((half*32 + l4*8) ^ ((dd & 7) * 8))];
          oacc[qt][nd] = __builtin_amdgcn_mfma_f32_16x16x32_bf16(pa, vb, oacc[qt][nd], 0, 0, 0);
        }
      }
    }
    // all reads of buf cur complete (waited before their MFMA uses)
    MEMFENCE; __builtin_amdgcn_s_barrier(); MEMFENCE;
    if (j + 2 < NTI) stage(kt0 + j + 2, cur);
    if (j + 1 < NTI) {
      if (j + 2 < NTI) asm volatile("s_waitcnt vmcnt(4)" ::: "memory");
      else             asm volatile("s_waitcnt vmcnt(0)" ::: "memory");
      __builtin_amdgcn_s_barrier();
      MEMFENCE;
    }
  }

  const int slot = (b * Hn + h) * 16 + sp;
  #pragma unroll
  for (int qt = 0; qt < 4; qt++)
    #pragma unroll
    for (int nd = 0; nd < 4; nd++)
      #pragma unroll
      for (int r = 0; r < 4; r++)
        PO[(size_t)slot * 16384 + (w*64 + qt*16 + l4*4 + r) * 64 + nd*16 + l15] = oacc[qt][nd][r];
  if (l15 == 0) {
    #pragma unroll
    for (int qt = 0; qt < 4; qt++)
      #pragma unroll
      for (int r = 0; r < 4; r++) {
        PM[slot * 256 + w*64 + qt*16 + l4*4 + r] = m_[qt][r];
        PL[slot * 256 + w*64 + qt*16 + l4*4 + r] = l_[qt][r];
      }
  }
}

// ---------------- combine 16 split partials ----------------
__global__ __launch_bounds__(256) void k_attn_comb16(
    const float* __restrict__ PO, const float* __restrict__ PM,
    const float* __restrict__ PL, unsigned short* __restrict__ Op) {
  const int W = blockIdx.x * 4 + (threadIdx.x >> 6);  // (bh, q) row
  const int lane = threadIdx.x & 63;
  const int bh = W >> 8, q = W & 255;
  const int slotBase = bh * 16;
  float ms[16];
  float M = -INFINITY;
  #pragma unroll
  for (int s = 0; s < 16; s++) { ms[s] = PM[(slotBase + s) * 256 + q]; M = fmaxf(M, ms[s]); }
  float L = 0.f, acc = 0.f;
  #pragma unroll
  for (int s = 0; s < 16; s++) {
    float wgt = __expf((ms[s] - M) * 0.125f);
    L += PL[(slotBase + s) * 256 + q] * wgt;
    acc += wgt * PO[(size_t)(slotBase + s) * 16384 + q * 64 + lane];
  }
  const int b = bh >> 4, h = bh & 15;
  Op[(size_t)(b * Sn + q) * En + h * 64 + lane] = f2b(acc / L);
}

// ------------- helpers for radix top-k (1024-thread blocks) -------------
DEVFN unsigned blk_exscan16(unsigned part, volatile unsigned* wsum, int lane, int wid) {
  unsigned v = part;
  #pragma unroll
  for (int d = 1; d < 64; d <<= 1) { unsigned o = __shfl_up(v, d); if (lane >= d) v += o; }
  if (lane == 63) wsum[wid] = v;
  __syncthreads();
  unsigned woff = 0;
  for (int i = 0; i < wid; i++) woff += wsum[i];
  unsigned r = woff + v - part;
  __syncthreads();
  return r;
}

DEVFN void find_thr16(const unsigned* hist, int NB, unsigned need,
                      int t, int lane, int wid, volatile unsigned* wsum,
                      volatile int* s_thr, volatile unsigned* s_above) {
  int per = NB >> 10;
  int lo = NB - per * (t + 1);
  unsigned part = 0;
  for (int j = 0; j < per; j++) part += hist[lo + j];
  unsigned ex = blk_exscan16(part, wsum, lane, wid);
  if (ex < need && ex + part >= need) {
    unsigned c = ex;
    for (int j = per - 1; j >= 0; j--) {
      unsigned h = hist[lo + j];
      if (c + h >= need) { *s_thr = lo + j; *s_above = c; break; }
      c += h;
    }
  }
  __syncthreads();
}

// ------- exact top-32 per row on bf16 keys: 2 global passes + in-LDS select -------
__global__ __launch_bounds__(1024) void k_topk16(
    const unsigned short* __restrict__ simsb, int* __restrict__ oidx) {
  const int n = blockIdx.x, t = threadIdx.x;
  const int lane = t & 63, wid = t >> 6;
  const u16x8* row8 = (const u16x8*)(simsb + (size_t)n * Mn);
  constexpr unsigned CAP = 2048;
  __shared__ unsigned hist[2048];
  __shared__ unsigned wsum[16];
  __shared__ int s_thr;
  __shared__ unsigned s_above;
  __shared__ unsigned h2[32];
  __shared__ unsigned s_cnt, s_na;
  __shared__ unsigned short ckey[CAP];
  __shared__ unsigned cidx[CAP];
  __shared__ int slist[32];
  __shared__ unsigned sL, sneedEq, scntEq, s_imin;

  for (int i = t; i < 2048; i += 1024) hist[i] = 0;
  if (t < 32) h2[t] = 0;
  if (t == 0) { s_cnt = 0; s_na = 0; }
  __syncthreads();

  #pragma unroll
  for (int p = 0; p < 8; p++) {
    u16x8 v = row8[p * 1024 + t];
    #pragma unroll
    for (int j = 0; j < 8; j++) atomicAdd(&hist[okey16(v[j]) >> 5], 1u);
  }
  __syncthreads();
  find_thr16(hist, 2048, 32, t, lane, wid, wsum, &s_thr, &s_above);
  const unsigned T1 = (unsigned)s_thr;
  const unsigned need2 = 32 - s_above;
  const unsigned cnt1 = hist[T1];
  const unsigned base = T1 << 5;

  #pragma unroll
  for (int p = 0; p < 8; p++) {
    u16x8 v = row8[p * 1024 + t];
    unsigned i0 = (unsigned)(p * 1024 + t) * 8;
    #pragma unroll
    for (int j = 0; j < 8; j++) {
      unsigned k = okey16(v[j]);
      if (k >= base) {
        unsigned slot = atomicAdd(&s_cnt, 1u);
        if (slot < CAP) { ckey[slot] = (unsigned short)k; cidx[slot] = i0 + j; }
        if ((k >> 5) == T1) atomicAdd(&h2[k & 31], 1u);
      }
    }
  }
  __syncthreads();
  const unsigned total = s_cnt;

  unsigned L, istar = 0xFFFFFFFFu;
  if (cnt1 == need2) {
    L = base;
  } else {
    if (t == 0) {
      unsigned cum = 0; int T3 = 0; unsigned above = 0;
      for (int j = 31; j >= 0; j--) {
        if (cum + h2[j] >= need2) { T3 = j; above = cum; break; }
        cum += h2[j];
      }
      sL = base | (unsigned)T3;
      sneedEq = need2 - above;
      scntEq = h2[T3];
    }
    __syncthreads();
    L = sL;
    if (scntEq != sneedEq) {
      if (total <= CAP) {
        int prev = -1;
        for (unsigned j = 0; j < sneedEq; j++) {
          if (t == 0) s_imin = 0xFFFFFFFFu;
          __syncthreads();
          for (unsigned i = t; i < total; i += 1024)
            if ((unsigned)ckey[i] == L && (int)cidx[i] > prev) atomicMin(&s_imin, cidx[i]);
          __syncthreads();
          prev = (int)s_imin;
          __syncthreads();
        }
        istar = (unsigned)prev;
      } else {
        const unsigned short* rowp = simsb + (size_t)n * Mn;
        unsigned cntLoc = 0;
        for (int j = 0; j < 64; j++)
          if (okey16(rowp[t * 64 + j]) == L) cntLoc++;
        unsigned pre = blk_exscan16(cntLoc, wsum, lane, wid);
        unsigned c = 0;
        for (int j = 0; j < 64; j++)
          if (okey16(rowp[t * 64 + j]) == L) { if (pre + c < 32) slist[pre + c] = t * 64 + j; c++; }
        __syncthreads();
        istar = (unsigned)slist[sneedEq - 1];
        __syncthreads();
        if (t == 0) s_na = 0;
        __syncthreads();
      }
    }
  }
  __syncthreads();

  if (total <= CAP) {
    for (unsigned i = t; i < total; i += 1024) {
      unsigned k = (unsigned)ckey[i];
      if (k > L || (k == L && cidx[i] <= istar)) {
        unsigned s = atomicAdd(&s_na, 1u);
        slist[s] = (int)cidx[i];
      }
    }
    __syncthreads();
    if (t < 32) {
      int my = slist[t];
      int rank = 0;
      #pragma unroll
      for (int j = 0; j < 32; j++) rank += (slist[j] < my);
      oidx[n * Kt + rank] = my;
    }
  } else {
    unsigned cnt = 0;
    for (int p = 0; p < 8; p++) {
      u16x8 v = row8[p * 1024 + t];
      unsigned i0 = (unsigned)(p * 1024 + t) * 8;
      #pragma unroll
      for (int j = 0; j < 8; j++) {
        unsigned k = okey16(v[j]);
        cnt += (k > L || (k == L && i0 + j <= istar));
      }
    }
    unsigned pos = blk_exscan16(cnt, wsum, lane, wid);
    for (int p = 0; p < 8; p++) {
      u16x8 v = row8[p * 1024 + t];
      unsigned i0 = (unsigned)(p * 1024 + t) * 8;
      #pragma unroll
      for (int j = 0; j < 8; j++) {
        unsigned k = okey16(v[j]);
        if (k > L || (k == L && i0 + j <= istar)) oidx[n * Kt + pos++] = (int)(i0 + j);
      }
    }
  }
}

// =============================== host ===============================
extern "C" void kernel_launch(void* const* d_in, const int* in_sizes, int n_in,
                              void* d_out, int out_size, void* d_ws, size_t ws_size,
                              hipStream_t stream) {
  (void)in_sizes; (void)n_in; (void)out_size;
  const float* x      = (const float*)d_in[0];
  const float* mem_k  = (const float*)d_in[1];
  const float* mem_v  = (const float*)d_in[2];
  const float* sa_w[4] = {(const float*)d_in[3], (const float*)d_in[4], (const float*)d_in[5], (const float*)d_in[6]};
  const float* sa_b[4] = {(const float*)d_in[7], (const float*)d_in[8], (const float*)d_in[9], (const float*)d_in[10]};
  const float* ma_w[4] = {(const float*)d_in[11], (const float*)d_in[12], (const float*)d_in[13], (const float*)d_in[14]};
  const float* ma_b[4] = {(const float*)d_in[15], (const float*)d_in[16], (const float*)d_in[17], (const float*)d_in[18]};
  const float* ln_g[3] = {(const float*)d_in[19], (const float*)d_in[21], (const float*)d_in[23]};
  const float* ln_b[3] = {(const float*)d_in[20], (const float*)d_in[22], (const float*)d_in[24]};
  const float* fc1_w = (const float*)d_in[25];
  const float* fc1_b = (const float*)d_in[26];
  const float* fc2_w = (const float*)d_in[27];
  const float* fc2_b = (const float*)d_in[28];
  float* out = (float*)d_out;

  char* ws = (char*)d_ws;
  size_t off = 0;
  auto alloc = [&](size_t bytes) -> char* {
    char* p = ws + off;
    off = (off + bytes + 255) & ~(size_t)255;
    return p;
  };

  unsigned short* wt[8];
  for (int i = 0; i < 8; i++) wt[i] = (unsigned short*)alloc((size_t)En * En * 2);  // contiguous
  unsigned short* fc1t  = (unsigned short*)alloc((size_t)FFn * En * 2);
  unsigned short* fc2t  = (unsigned short*)alloc((size_t)En * FFn * 2);
  unsigned short* xb    = (unsigned short*)alloc((size_t)NT * En * 2);
  unsigned short* Qb    = (unsigned short*)alloc((size_t)NT * En * 2);
  unsigned short* Kb    = (unsigned short*)alloc((size_t)NT * En * 2);
  unsigned short* Vb    = (unsigned short*)alloc((size_t)NT * En * 2);
  unsigned short* at1b  = (unsigned short*)alloc((size_t)NT * En * 2);
  float*          t1    = (float*)alloc((size_t)NT * En * 4);
  float*          x1f   = (float*)alloc((size_t)NT * En * 4);
  unsigned short* x1b   = (unsigned short*)alloc((size_t)NT * En * 2);
  char*           simsRaw = alloc((size_t)NT * Mn * 4);                // 256 MiB region
  int*            idx   = (int*)alloc((size_t)NT * Kt * 4);
  unsigned short* K2b   = (unsigned short*)alloc((size_t)NT * Kt * En * 2);  // 64 MiB
  unsigned short* V2b   = (unsigned short*)alloc((size_t)NT * Kt * En * 2);  // V2t: [B][1024][8192]
  unsigned short* Q2b   = (unsigned short*)alloc((size_t)NT * En * 2);
  unsigned short* at2b  = (unsigned short*)alloc((size_t)NT * En * 2);
  float*          t2    = (float*)alloc((size_t)NT * En * 4);
  float*          x2f   = (float*)alloc((size_t)NT * En * 4);
  unsigned short* x2b   = (unsigned short*)alloc((size_t)NT * En * 2);
  unsigned short* hb    = (unsigned short*)alloc((size_t)NT * FFn * 2);
  float*          t3    = (float*)alloc((size_t)NT * En * 4);
  float*          bcat_sa = (float*)alloc(3072 * 4);
  float*          bcat_ma = (float*)alloc(2048 * 4);

  if (off > ws_size) return;   // insufficient workspace: leave output poisoned (fail loudly)

  // Overlays (dead-region reuse):
  unsigned short* simsb = (unsigned short*)simsRaw;   // bf16 sims: 128 MiB of the region
  unsigned short* mkb = (unsigned short*)K2b;         // until sims GEMM done
  unsigned short* mvb = (unsigned short*)simsRaw;     // after topk
  float* PO = (float*)(simsRaw + (size_t)128 * 1024 * 1024);  // 64 MiB (1024 slots x 256 x 64)
  float* PM = PO + (size_t)1024 * 16384;
  float* PL = PM + (size_t)1024 * 256;

  (void)hipFuncSetAttribute((const void*)&k_gemm256<5,false,1,0>,
                            hipFuncAttributeMaxDynamicSharedMemorySize, 131072);
  (void)hipFuncSetAttribute((const void*)&k_gemm256<6,true,2,1>,
                            hipFuncAttributeMaxDynamicSharedMemorySize, 131072);

  // ---- prep: weight transposes to bf16 [N][K], bias concats ----
  P8 p8;
  for (int i = 0; i < 4; i++) { p8.s[i] = sa_w[i]; p8.s[4 + i] = ma_w[i]; }
  k_transpose8<<<dim3(16, 16, 8), 256, 0, stream>>>(p8, wt[0]);
  k_transpose_bf16<<<dim3(64, 16), 256, 0, stream>>>(fc1_w, fc1t, En, FFn);
  k_transpose_bf16<<<dim3(16, 64), 256, 0, stream>>>(fc2_w, fc2t, FFn, En);
  k_concat3<<<dim3(12), 256, 0, stream>>>(sa_b[0], sa_b[1], sa_b[2], bcat_sa);
  k_concat3<<<dim3(8),  256, 0, stream>>>(ma_b[1], ma_b[2], ma_b[2], bcat_ma);

  k_cvt_bf16<<<dim3(NT * En / 4 / 256), 256, 0, stream>>>(x, xb, NT * En / 4);
  k_normcvt<<<dim3(Mn), 256, 0, stream>>>(mem_k, mkb);

  const dim3 g1(En / 128, NT / 128);   // (8,8)

  // ---- self-attention (QKV fused: N=3072 over contiguous wt[0..2]) ----
  k_gemm<0,false,false,3><<<dim3(24, 8), 256, 0, stream>>>(xb, wt[0], nullptr, bcat_sa, nullptr, nullptr, Qb, Kb, Vb, 3072, En);
  k_attn_sa<<<dim3(Sn / 64, Hn, Bn), 256, 0, stream>>>(Qb, Kb, Vb, at1b, Sn);
  k_gemm<1,false,false,1><<<g1, 256, 0, stream>>>(at1b, wt[3], nullptr, sa_b[3], x, t1, nullptr, nullptr, nullptr, En, En);
  k_layernorm<<<NT, 256, 0, stream>>>(t1, ln_g[0], ln_b[0], x1f, x1b);

  // ---- retrieval: sims in bf16 + 2-pass candidate top-k ----
  k_gemm256<5,false,1,0><<<dim3(1024), 512, 131072, stream>>>(
      x1b, mkb, nullptr, nullptr, nullptr, simsb, nullptr, Mn, En, NT / 256, Mn / 256);
  k_topk16<<<NT, 1024, 0, stream>>>(simsb, idx);

  // ---- memory cross-attention (K2 row-major + V2 transposed, fused gather GEMM) ----
  k_cvt_bf16<<<dim3(Mn * En / 4 / 256), 256, 0, stream>>>(mem_v, mvb, Mn * En / 4);
  k_gemm256<6,true,2,1><<<dim3(1024), 512, 131072, stream>>>(
      mvb, wt[5], idx, bcat_ma, nullptr, K2b, V2b, 2048, En, NT * Kt / 256, 2048 / 256);
  k_gemm<0,false,false,1><<<g1, 256, 0, stream>>>(x1b, wt[4], nullptr, ma_b[0], nullptr, nullptr, Q2b, nullptr, nullptr, En, En);
  k_attn_ma<<<dim3(16, Hn, Bn), 256, 0, stream>>>(Q2b, K2b, V2b, PO, PM, PL);
  k_attn_comb16<<<dim3(Bn * Hn * Sn / 4), 256, 0, stream>>>(PO, PM, PL, at2b);
  k_gemm<1,false,false,1><<<g1, 256, 0, stream>>>(at2b, wt[7], nullptr, ma_b[3], x1f, t2, nullptr, nullptr, nullptr, En, En);
  k_layernorm<<<NT, 256, 0, stream>>>(t2, ln_g[1], ln_b[1], x2f, x2b);

  // ---- FFN ----
  k_gemm<2,false,false,1><<<dim3(FFn / 128, NT / 128), 256, 0, stream>>>(x2b, fc1t, nullptr, fc1_b, nullptr, nullptr, hb, nullptr, nullptr, FFn, En);
  k_gemm<1,false,false,1><<<g1, 256, 0, stream>>>(hb, fc2t, nullptr, fc2_b, x2f, t3, nullptr, nullptr, nullptr, En, FFn);
  k_layernorm<<<NT, 256, 0, stream>>>(t3, ln_g[2], ln_b[2], out, nullptr);
}

// Round 12
// 926.262 us; speedup vs baseline: 1.3817x; 1.0472x over previous
//
#include <hip/hip_runtime.h>
#include <hip/hip_bf16.h>
#include <math.h>

#define DEVFN __device__ __forceinline__

typedef __attribute__((ext_vector_type(8))) short bf16x8;
typedef __attribute__((ext_vector_type(8))) unsigned short u16x8;
typedef __attribute__((ext_vector_type(4))) unsigned short u16x4;
typedef __attribute__((ext_vector_type(4))) float f32x4;

static constexpr int Bn = 4, Sn = 256, En = 1024, Hn = 16;
static constexpr int Mn = 65536, Kt = 32, FFn = 4096;
static constexpr int NT = Bn * Sn;           // 1024 tokens

DEVFN unsigned short f2b(float f) {          // f32 -> bf16 RNE
  unsigned int u = __float_as_uint(f);
  unsigned int r = (u + 0x7FFFu + ((u >> 16) & 1u)) >> 16;
  return (unsigned short)r;
}
DEVFN float b2f(unsigned short u) { return __uint_as_float((unsigned)u << 16); }

DEVFN unsigned okey16(unsigned short u) {    // order-preserving bf16 -> u16
  return (unsigned)(u ^ ((u >> 15) ? 0xFFFFu : 0x8000u)) & 0xFFFFu;
}

typedef const __attribute__((address_space(1))) void* as1cv_t;
typedef __attribute__((address_space(3))) void* as3v_t;
DEVFN void gload16(const void* g, void* l) {   // async global->LDS, 16B/lane
  __builtin_amdgcn_global_load_lds((as1cv_t)g, (as3v_t)l, 16, 0, 0);
}
#define MEMFENCE asm volatile("" ::: "memory")

struct P8 { const float* s[8]; };

// ---------------- batched transpose W[1024][1024] f32 -> out[C][R] bf16 ----------------
__global__ __launch_bounds__(256) void k_transpose8(
    P8 ps, unsigned short* __restrict__ outbase) {
  const float* in = ps.s[blockIdx.z];
  unsigned short* out = outbase + (size_t)blockIdx.z * En * En;
  __shared__ float tile[64][65];
  int tx = threadIdx.x & 63, ty = threadIdx.x >> 6;
  int c0 = blockIdx.x * 64, r0 = blockIdx.y * 64;
  #pragma unroll
  for (int i = 0; i < 16; i++) {
    int r = ty + i * 4;
    tile[tx][r] = in[(size_t)(r0 + r) * En + (c0 + tx)];
  }
  __syncthreads();
  #pragma unroll
  for (int i = 0; i < 16; i++) {
    int c = ty + i * 4;
    out[(size_t)(c0 + c) * En + (r0 + tx)] = f2b(tile[c][tx]);
  }
}

// ---------------- transpose W[R][C] f32 -> out[C][R] bf16 ----------------
__global__ __launch_bounds__(256) void k_transpose_bf16(
    const float* __restrict__ in, unsigned short* __restrict__ out, int R, int C) {
  __shared__ float tile[64][65];
  int tx = threadIdx.x & 63, ty = threadIdx.x >> 6;
  int c0 = blockIdx.x * 64, r0 = blockIdx.y * 64;
  #pragma unroll
  for (int i = 0; i < 16; i++) {
    int r = ty + i * 4;
    tile[tx][r] = in[(size_t)(r0 + r) * C + (c0 + tx)];
  }
  __syncthreads();
  #pragma unroll
  for (int i = 0; i < 16; i++) {
    int c = ty + i * 4;
    out[(size_t)(c0 + c) * R + (r0 + tx)] = f2b(tile[c][tx]);
  }
}

// ---------------- f32 -> bf16 elementwise (x4) ----------------
__global__ __launch_bounds__(256) void k_cvt_bf16(
    const float* __restrict__ in, unsigned short* __restrict__ out, int n4) {
  int i = blockIdx.x * 256 + threadIdx.x;
  if (i >= n4) return;
  float4 v = ((const float4*)in)[i];
  uint2 o;
  o.x = (unsigned int)f2b(v.x) | ((unsigned int)f2b(v.y) << 16);
  o.y = (unsigned int)f2b(v.z) | ((unsigned int)f2b(v.w) << 16);
  ((uint2*)out)[i] = o;
}

// ---- gather + cvt: out[r] = bf16(mem_v[idx[r]]), one 4KB row per block ----
__global__ __launch_bounds__(256) void k_gathercvt(
    const float* __restrict__ mv, const int* __restrict__ idx,
    unsigned short* __restrict__ out) {
  int r = blockIdx.x;
  int src = idx[r];
  float4 v = ((const float4*)(mv + (size_t)src * En))[threadIdx.x];
  uint2 o;
  o.x = (unsigned int)f2b(v.x) | ((unsigned int)f2b(v.y) << 16);
  o.y = (unsigned int)f2b(v.z) | ((unsigned int)f2b(v.w) << 16);
  ((uint2*)(out + (size_t)r * En))[threadIdx.x] = o;
}

// ---------------- concat up to 3 x 1024-f32 vectors ----------------
__global__ __launch_bounds__(256) void k_concat3(
    const float* __restrict__ a, const float* __restrict__ b,
    const float* __restrict__ c, float* __restrict__ o) {
  int i = blockIdx.x * 256 + threadIdx.x;
  float v = (i < 1024) ? a[i] : (i < 2048) ? b[i - 1024] : c[i - 2048];
  o[i] = v;
}

// ---- mem_keys row-normalize + cvt to bf16 (folds cosine norm into B) ----
__global__ __launch_bounds__(256) void k_normcvt(
    const float* __restrict__ mk, unsigned short* __restrict__ out) {
  int m = blockIdx.x, t = threadIdx.x;
  float4 v = ((const float4*)(mk + (size_t)m * En))[t];
  float ss = v.x*v.x + v.y*v.y + v.z*v.z + v.w*v.w;
  #pragma unroll
  for (int d = 32; d; d >>= 1) ss += __shfl_down(ss, d);
  __shared__ float red[4];
  int lane = t & 63, w = t >> 6;
  if (lane == 0) red[w] = ss;
  __syncthreads();
  float rs = 1.0f / fmaxf(sqrtf(red[0] + red[1] + red[2] + red[3]), 1e-12f);
  uint2 o;
  o.x = (unsigned int)f2b(v.x * rs) | ((unsigned int)f2b(v.y * rs) << 16);
  o.y = (unsigned int)f2b(v.z * rs) | ((unsigned int)f2b(v.w * rs) << 16);
  ((uint2*)(out + (size_t)m * En))[t] = o;
}

// ---------------- LayerNorm over rows of [NT][En] ----------------
__global__ __launch_bounds__(256) void k_layernorm(
    const float* __restrict__ in, const float* __restrict__ g, const float* __restrict__ bb,
    float* __restrict__ outf, unsigned short* __restrict__ outb) {
  int n = blockIdx.x, t = threadIdx.x;
  float4 v = ((const float4*)(in + (size_t)n * En))[t];
  float s  = v.x + v.y + v.z + v.w;
  float s2 = v.x*v.x + v.y*v.y + v.z*v.z + v.w*v.w;
  #pragma unroll
  for (int d = 32; d; d >>= 1) { s += __shfl_down(s, d); s2 += __shfl_down(s2, d); }
  __shared__ float rs[4], rq[4];
  int lane = t & 63, w = t >> 6;
  if (lane == 0) { rs[w] = s; rq[w] = s2; }
  __syncthreads();
  float mean = (rs[0]+rs[1]+rs[2]+rs[3]) * (1.0f/En);
  float var  = (rq[0]+rq[1]+rq[2]+rq[3]) * (1.0f/En) - mean*mean;
  float rstd = rsqrtf(var + 1e-5f);
  float4 gg = ((const float4*)g)[t];
  float4 bv = ((const float4*)bb)[t];
  float o0 = (v.x-mean)*rstd*gg.x + bv.x;
  float o1 = (v.y-mean)*rstd*gg.y + bv.y;
  float o2 = (v.z-mean)*rstd*gg.z + bv.z;
  float o3 = (v.w-mean)*rstd*gg.w + bv.w;
  if (outf) { float4 ov = {o0,o1,o2,o3}; ((float4*)(outf + (size_t)n*En))[t] = ov; }
  if (outb) {
    uint2 o;
    o.x = (unsigned int)f2b(o0) | ((unsigned int)f2b(o1) << 16);
    o.y = (unsigned int)f2b(o2) | ((unsigned int)f2b(o3) << 16);
    ((uint2*)(outb + (size_t)n*En))[t] = o;
  }
}

// ======== 256x256 GEMM, 4 half-tile ring buffers + counted vmcnt (T1..T5) ========
// EPI 4: f32 out | EPI 5: bf16 no-bias | EPI 0 + NOUT2: bf16 (+bias), split N
// EPI 6: split N=2048 -> cb0 row-major (+bias), cb1 TRANSPOSED [B][1024][8192] (+bias)
template<int EPI, bool AGATHER, int NOUT, int LSWZ>
__global__ __launch_bounds__(512) void k_gemm256(
    const unsigned short* __restrict__ Ab, const unsigned short* __restrict__ Bb,
    const int* __restrict__ gidx, const float* __restrict__ bias,
    float* __restrict__ Cf, unsigned short* __restrict__ cb0, unsigned short* __restrict__ cb1,
    int Ndim, int Kdim, int nRT, int nCT) {
  extern __shared__ unsigned short lds[];
  const int t = threadIdx.x, lane = t & 63, w = t >> 6;
  const int wr = w >> 2, wc = w & 3, l15 = lane & 15, l4 = lane >> 4;
  const int lr2 = lane >> 2;
  const int cg  = (lane & 3) ^ (((lane >> 5) & 1) << 1);   // source pre-swizzle (involution)

  const int nwg = nRT * nCT;
  int lb = ((int)blockIdx.x % 8) * (nwg >> 3) + ((int)blockIdx.x >> 3);
  int rowT, colT;
  if (LSWZ == 0) { rowT = lb % nRT; colT = lb / nRT; }
  else           { colT = lb % nCT; rowT = lb / nCT; }
  const int row0 = rowT * 256, col0 = colT * 256;

  auto pa = [&](int h) -> unsigned short* { return lds + h * 16384; };
  auto pb = [&](int h) -> unsigned short* { return lds + h * 16384 + 8192; };

  const unsigned short *aSrc0, *aSrc1;
  if constexpr (AGATHER) {
    aSrc0 = Ab + (size_t)gidx[row0 + w * 32 + lr2] * Kdim + cg * 8;
    aSrc1 = Ab + (size_t)gidx[row0 + w * 32 + 16 + lr2] * Kdim + cg * 8;
  } else {
    aSrc0 = Ab + (size_t)(row0 + w * 32 + lr2) * Kdim + cg * 8;
    aSrc1 = aSrc0 + (size_t)16 * Kdim;
  }
  const unsigned short* bSrc0 = Bb + (size_t)(col0 + w * 32 + lr2) * Kdim + cg * 8;
  const unsigned short* bSrc1 = bSrc0 + (size_t)16 * Kdim;

  f32x4 acc[8][4];
  #pragma unroll
  for (int i = 0; i < 8; i++)
    #pragma unroll
    for (int j = 0; j < 4; j++) acc[i][j] = (f32x4){0.f, 0.f, 0.f, 0.f};

  const int NH = Kdim >> 5;                 // K half-tiles of 32
  #pragma unroll
  for (int h = 0; h < 3; ++h) {
    const int ko = h * 32;
    gload16(aSrc0 + ko, pa(h) + w*32*32);
    gload16(aSrc1 + ko, pa(h) + (w*32+16)*32);
    gload16(bSrc0 + ko, pb(h) + w*32*32);
    gload16(bSrc1 + ko, pb(h) + (w*32+16)*32);
  }
  asm volatile("s_waitcnt vmcnt(8)" ::: "memory");   // half 0 landed
  __builtin_amdgcn_s_barrier();
  MEMFENCE;

  for (int hs = 0; hs < NH; ++hs) {
    const int cur = hs & 3;
    const unsigned short* Ap = pa(cur);
    const unsigned short* Bp = pb(cur);
    const int h3 = (hs + 3) & 3, ko3 = (hs + 3) * 32;
    const bool pf = (hs + 3) < NH;
    bf16x8 bfr[4], af[4];

    // ---- phase 0: B frags + A rows 0..63 ----
    #pragma unroll
    for (int ni = 0; ni < 4; ni++) {
      int row = wc * 64 + ni * 16 + l15;
      int c8 = l4 ^ (((row >> 3) & 1) << 1);
      bfr[ni] = *(const bf16x8*)&Bp[row * 32 + c8 * 8];
    }
    #pragma unroll
    for (int m = 0; m < 4; m++) {
      int row = wr * 128 + m * 16 + l15;
      int c8 = l4 ^ (((row >> 3) & 1) << 1);
      af[m] = *(const bf16x8*)&Ap[row * 32 + c8 * 8];
    }
    if (pf) {
      gload16(aSrc0 + ko3, pa(h3) + w*32*32);
      gload16(aSrc1 + ko3, pa(h3) + (w*32+16)*32);
    }
    MEMFENCE; __builtin_amdgcn_s_barrier(); MEMFENCE;
    __builtin_amdgcn_s_setprio(1);
    #pragma unroll
    for (int m = 0; m < 4; m++)
      #pragma unroll
      for (int ni = 0; ni < 4; ni++)
        acc[m][ni] = __builtin_amdgcn_mfma_f32_16x16x32_bf16(af[m], bfr[ni], acc[m][ni], 0, 0, 0);
    __builtin_amdgcn_s_setprio(0);
    MEMFENCE; __builtin_amdgcn_s_barrier(); MEMFENCE;

    // ---- phase 1: A rows 64..127 ----
    #pragma unroll
    for (int m = 0; m < 4; m++) {
      int row = wr * 128 + (4 + m) * 16 + l15;
      int c8 = l4 ^ (((row >> 3) & 1) << 1);
      af[m] = *(const bf16x8*)&Ap[row * 32 + c8 * 8];
    }
    if (pf) {
      gload16(bSrc0 + ko3, pb(h3) + w*32*32);
      gload16(bSrc1 + ko3, pb(h3) + (w*32+16)*32);
    }
    MEMFENCE; __builtin_amdgcn_s_barrier(); MEMFENCE;
    __builtin_amdgcn_s_setprio(1);
    #pragma unroll
    for (int m = 0; m < 4; m++)
      #pragma unroll
      for (int ni = 0; ni < 4; ni++)
        acc[4 + m][ni] = __builtin_amdgcn_mfma_f32_16x16x32_bf16(af[m], bfr[ni], acc[4 + m][ni], 0, 0, 0);
    __builtin_amdgcn_s_setprio(0);

    if (hs + 1 < NH) {
      const int rem = NH - 2 - hs;
      if (rem >= 2)      asm volatile("s_waitcnt vmcnt(8)" ::: "memory");
      else if (rem == 1) asm volatile("s_waitcnt vmcnt(4)" ::: "memory");
      else               asm volatile("s_waitcnt vmcnt(0)" ::: "memory");
      __builtin_amdgcn_s_barrier();
      MEMFENCE;
    }
  }

  #pragma unroll
  for (int m = 0; m < 8; m++) {
    #pragma unroll
    for (int ni = 0; ni < 4; ni++) {
      int col  = col0 + wc * 64 + ni * 16 + l15;
      int rowb = row0 + wr * 128 + m * 16 + l4 * 4;
      if constexpr (EPI == 6) {
        if (col < 1024) {
          #pragma unroll
          for (int r = 0; r < 4; r++)
            cb0[(size_t)(rowb + r) * 1024 + col] = f2b(acc[m][ni][r] + bias[col]);
        } else {
          int c = col - 1024;
          int bi = rowb >> 13, k0 = rowb & 8191;
          u16x4 o;
          #pragma unroll
          for (int r = 0; r < 4; r++) o[r] = f2b(acc[m][ni][r] + bias[col]);
          *(u16x4*)&cb1[((size_t)bi * 1024 + c) * 8192 + k0] = o;
        }
      } else {
        #pragma unroll
        for (int r = 0; r < 4; r++) {
          float v = acc[m][ni][r];
          if constexpr (EPI == 4) {
            Cf[(size_t)(rowb + r) * Ndim + col] = v;
          } else if constexpr (EPI == 5) {
            cb0[(size_t)(rowb + r) * Ndim + col] = f2b(v);
          } else {
            unsigned short* cb = (col >> 10) ? cb1 : cb0;
            cb[(size_t)(rowb + r) * 1024 + (col & 1023)] = f2b(v + bias[col]);
          }
        }
      }
    }
  }
}

// ---------------- GEMM 128x128 (2-phase) for the small GEMMs ----------------
template<int EPI, bool AGATHER, bool SWAPG, int NOUT>
__global__ __launch_bounds__(256) void k_gemm(
    const unsigned short* __restrict__ Ab, const unsigned short* __restrict__ Bb,
    const int* __restrict__ gidx,
    const float* __restrict__ bias, const float* __restrict__ resid,
    float* __restrict__ Cf, unsigned short* __restrict__ cb0,
    unsigned short* __restrict__ cb1, unsigned short* __restrict__ cb2,
    int Ndim, int Kdim) {
  __shared__ unsigned short As[128][32];
  __shared__ unsigned short Bs[128][32];
  const int t = threadIdx.x, lane = t & 63, w = t >> 6;
  const int wr = w >> 1, wc = w & 1, l15 = lane & 15, l4 = lane >> 4;
  const int row0 = (SWAPG ? blockIdx.x : blockIdx.y) * 128;
  const int col0 = (SWAPG ? blockIdx.y : blockIdx.x) * 128;
  const int c8  = (lane & 3) * 8;
  const int r16 = lane >> 2;
  const int rA0 = w * 32 + r16, rA1 = rA0 + 16;

  size_t raA0, raA1, raB0, raB1;
  if constexpr (AGATHER) {
    raA0 = (size_t)gidx[row0 + rA0] * Kdim;
    raA1 = (size_t)gidx[row0 + rA1] * Kdim;
  } else {
    raA0 = (size_t)(row0 + rA0) * Kdim;
    raA1 = (size_t)(row0 + rA1) * Kdim;
  }
  raB0 = (size_t)(col0 + rA0) * Kdim;
  raB1 = (size_t)(col0 + rA1) * Kdim;

  f32x4 acc[4][4];
  #pragma unroll
  for (int i = 0; i < 4; i++)
    #pragma unroll
    for (int j = 0; j < 4; j++) acc[i][j] = (f32x4){0.f,0.f,0.f,0.f};

  for (int kt0 = 0; kt0 < Kdim; kt0 += 32) {
    __syncthreads();
    gload16(Ab + raA0 + kt0 + c8, &As[w * 32][0]);
    gload16(Ab + raA1 + kt0 + c8, &As[w * 32 + 16][0]);
    gload16(Bb + raB0 + kt0 + c8, &Bs[w * 32][0]);
    gload16(Bb + raB1 + kt0 + c8, &Bs[w * 32 + 16][0]);
    __syncthreads();
    bf16x8 af[4], bfr[4];
    #pragma unroll
    for (int mi = 0; mi < 4; mi++) af[mi]  = *(const bf16x8*)&As[wr*64 + mi*16 + l15][l4*8];
    #pragma unroll
    for (int ni = 0; ni < 4; ni++) bfr[ni] = *(const bf16x8*)&Bs[wc*64 + ni*16 + l15][l4*8];
    #pragma unroll
    for (int mi = 0; mi < 4; mi++)
      #pragma unroll
      for (int ni = 0; ni < 4; ni++)
        acc[mi][ni] = __builtin_amdgcn_mfma_f32_16x16x32_bf16(af[mi], bfr[ni], acc[mi][ni], 0, 0, 0);
  }

  unsigned short* cbase = cb0;
  int colsub = 0;
  if constexpr (NOUT > 1) {
    int which = col0 >> 10;
    cbase = (which == 0) ? cb0 : (which == 1) ? cb1 : cb2;
    colsub = col0 & 1023;
  }

  #pragma unroll
  for (int mi = 0; mi < 4; mi++) {
    #pragma unroll
    for (int ni = 0; ni < 4; ni++) {
      int col  = col0 + wc*64 + ni*16 + l15;
      int rowb = row0 + wr*64 + mi*16 + l4*4;
      #pragma unroll
      for (int r = 0; r < 4; r++) {
        float v = acc[mi][ni][r];
        size_t off = (size_t)(rowb + r) * Ndim + col;
        if constexpr (EPI == 0) {
          if constexpr (NOUT > 1) {
            int c2 = colsub + wc*64 + ni*16 + l15;
            cbase[(size_t)(rowb + r) * 1024 + c2] = f2b(v + bias[col]);
          } else {
            cb0[off] = f2b(v + bias[col]);
          }
        } else if constexpr (EPI == 1) {
          Cf[off] = v + bias[col] + resid[off];
        } else if constexpr (EPI == 2) {
          float u = v + bias[col];
          u = 0.5f * u * (1.0f + erff(u * 0.70710678118654752f));
          cb0[off] = f2b(u);
        } else {
          Cf[off] = v;
        }
      }
    }
  }
}

// ---------------- SA fused attention (flash-style, Lk=256) ----------------
__global__ __launch_bounds__(256) void k_attn_sa(
    const unsigned short* __restrict__ Qp, const unsigned short* __restrict__ Kp,
    const unsigned short* __restrict__ Vp, unsigned short* __restrict__ Op, int Lk) {
  __shared__ unsigned short Ks[64][72];
  __shared__ unsigned short Vt[64][72];
  __shared__ float Ps[4][16][68];
  const int b = blockIdx.z;
  const int h = blockIdx.y, q0 = blockIdx.x * 64;
  const int t = threadIdx.x, lane = t & 63, w = t >> 6;
  const int l15 = lane & 15, l4 = lane >> 4;

  const int qrow = q0 + w * 16 + l15;
  const unsigned short* qptr = Qp + (size_t)(b * Sn + qrow) * En + h * 64 + l4 * 8;
  bf16x8 qf0 = *(const bf16x8*)qptr;
  bf16x8 qf1 = *(const bf16x8*)(qptr + 32);

  f32x4 oacc[4];
  #pragma unroll
  for (int i = 0; i < 4; i++) oacc[i] = (f32x4){0.f,0.f,0.f,0.f};
  float m_[4] = {-INFINITY, -INFINITY, -INFINITY, -INFINITY};
  float l_[4] = {0.f, 0.f, 0.f, 0.f};

  const int nkt = Lk / 64;
  for (int kt = 0; kt < nkt; ++kt) {
    __syncthreads();
    #pragma unroll
    for (int i = 0; i < 2; i++) {
      int ld = t + i * 256;
      int kr = ld >> 3, d8 = (ld & 7) * 8;
      size_t base = (size_t)(b * Lk + kt * 64 + kr) * En + h * 64 + d8;
      *(uint4*)&Ks[kr][d8] = *(const uint4*)(Kp + base);
      bf16x8 vv = *(const bf16x8*)(Vp + base);
      int colswz = kr ^ ((t & 7) << 3);
      #pragma unroll
      for (int j = 0; j < 8; j++) Vt[d8 + j][colswz] = ((unsigned short*)&vv)[j];
    }
    __syncthreads();

    f32x4 s[4];
    #pragma unroll
    for (int ni = 0; ni < 4; ni++) {
      s[ni] = (f32x4){0.f,0.f,0.f,0.f};
      bf16x8 kb0 = *(const bf16x8*)&Ks[ni*16 + l15][l4*8];
      bf16x8 kb1 = *(const bf16x8*)&Ks[ni*16 + l15][l4*8 + 32];
      s[ni] = __builtin_amdgcn_mfma_f32_16x16x32_bf16(qf0, kb0, s[ni], 0, 0, 0);
      s[ni] = __builtin_amdgcn_mfma_f32_16x16x32_bf16(qf1, kb1, s[ni], 0, 0, 0);
    }

    #pragma unroll
    for (int r = 0; r < 4; r++) {
      float mx = fmaxf(fmaxf(s[0][r], s[1][r]), fmaxf(s[2][r], s[3][r]));
      #pragma unroll
      for (int d2 = 1; d2 < 16; d2 <<= 1) mx = fmaxf(mx, __shfl_xor(mx, d2));
      if (mx > m_[r]) {
        float alpha = __expf((m_[r] - mx) * 0.125f);
        l_[r] *= alpha;
        #pragma unroll
        for (int nd = 0; nd < 4; nd++) oacc[nd][r] *= alpha;
        m_[r] = mx;
      }
      float rsum = 0.f;
      #pragma unroll
      for (int ni = 0; ni < 4; ni++) {
        float p = __expf((s[ni][r] - m_[r]) * 0.125f);
        s[ni][r] = p; rsum += p;
      }
      #pragma unroll
      for (int d2 = 1; d2 < 16; d2 <<= 1) rsum += __shfl_xor(rsum, d2);
      l_[r] += rsum;
    }

    #pragma unroll
    for (int ni = 0; ni < 4; ni++)
      #pragma unroll
      for (int r = 0; r < 4; r++)
        Ps[w][l4*4 + r][ni*16 + l15] = s[ni][r];
    asm volatile("s_waitcnt lgkmcnt(0)" ::: "memory");

    #pragma unroll
    for (int half = 0; half < 2; half++) {
      float4 pv0 = *(const float4*)&Ps[w][l15][half*32 + l4*8];
      float4 pv1 = *(const float4*)&Ps[w][l15][half*32 + l4*8 + 4];
      bf16x8 pa;
      pa[0]=(short)f2b(pv0.x); pa[1]=(short)f2b(pv0.y); pa[2]=(short)f2b(pv0.z); pa[3]=(short)f2b(pv0.w);
      pa[4]=(short)f2b(pv1.x); pa[5]=(short)f2b(pv1.y); pa[6]=(short)f2b(pv1.z); pa[7]=(short)f2b(pv1.w);
      #pragma unroll
      for (int nd = 0; nd < 4; nd++) {
        int dd = nd*16 + l15;
        bf16x8 vb = *(const bf16x8*)&Vt[dd][(half*32 + l4*8) ^ (((dd >> 3) & 7) << 3)];
        oacc[nd] = __builtin_amdgcn_mfma_f32_16x16x32_bf16(pa, vb, oacc[nd], 0, 0, 0);
      }
    }
  }

  #pragma unroll
  for (int nd = 0; nd < 4; nd++)
    #pragma unroll
    for (int r = 0; r < 4; r++) {
      int q = q0 + w*16 + l4*4 + r;
      Op[(size_t)(b * Sn + q) * En + h * 64 + nd*16 + l15] = f2b(oacc[nd][r] / l_[r]);
    }
}

// ------- MA attention: 4 q-tiles folded, SPLIT=16, double-buffered VT staging -------
// PO partials in bf16 (precision headroom is 3x).
__global__ __launch_bounds__(256, 2) void k_attn_ma(
    const unsigned short* __restrict__ Qp, const unsigned short* __restrict__ Kp,
    const unsigned short* __restrict__ Vp,
    unsigned short* __restrict__ PO, float* __restrict__ PM, float* __restrict__ PL) {
  constexpr int Lk = Sn * Kt;            // 8192
  constexpr int NTI = 8;                 // k-tiles per block (8192/64/16)
  __shared__ unsigned short Ks[2][64 * 64];
  __shared__ unsigned short Vt[2][64 * 64];
  __shared__ float Ps[4][16][68];
  const int sp = blockIdx.x, h = blockIdx.y, b = blockIdx.z;
  const int t = threadIdx.x, lane = t & 63, w = t >> 6;
  const int l15 = lane & 15, l4 = lane >> 4;
  const int l8 = lane >> 3, l7 = lane & 7;
  const int kswz = (l7 ^ l8) * 8;        // source pre-swizzle (row&7)
  const int rbase = w * 16;

  bf16x8 qf[4][2];
  #pragma unroll
  for (int qt = 0; qt < 4; qt++) {
    const unsigned short* qptr = Qp + (size_t)(b * Sn + w * 64 + qt * 16 + l15) * En + h * 64 + l4 * 8;
    qf[qt][0] = *(const bf16x8*)qptr;
    qf[qt][1] = *(const bf16x8*)(qptr + 32);
  }

  f32x4 oacc[4][4];
  #pragma unroll
  for (int i = 0; i < 4; i++)
    #pragma unroll
    for (int j = 0; j < 4; j++) oacc[i][j] = (f32x4){0.f,0.f,0.f,0.f};
  float m_[4][4], l_[4][4];
  #pragma unroll
  for (int i = 0; i < 4; i++)
    #pragma unroll
    for (int j = 0; j < 4; j++) { m_[i][j] = -INFINITY; l_[i][j] = 0.f; }

  const int kt0 = sp * NTI;
  auto stage = [&](int kt, int buf) {
    #pragma unroll
    for (int i = 0; i < 2; i++) {
      int row = rbase + i * 8 + l8;
      gload16(Kp + (size_t)(b * Lk + kt * 64 + row) * En + h * 64 + kswz,
              &Ks[buf][(rbase + i * 8) * 64]);
      gload16(Vp + ((size_t)b * 1024 + h * 64 + row) * (size_t)Lk + kt * 64 + kswz,
              &Vt[buf][(rbase + i * 8) * 64]);
    }
  };

  stage(kt0, 0);
  stage(kt0 + 1, 1);
  asm volatile("s_waitcnt vmcnt(4)" ::: "memory");   // tile0 landed (Q drained too)
  __builtin_amdgcn_s_barrier();
  MEMFENCE;

  for (int j = 0; j < NTI; ++j) {
    const int cur = j & 1;
    #pragma unroll
    for (int qt = 0; qt < 4; qt++) {
      f32x4 s[4];
      #pragma unroll
      for (int ni = 0; ni < 4; ni++) {
        s[ni] = (f32x4){0.f,0.f,0.f,0.f};
        int rowK = ni * 16 + l15, sw = (rowK & 7) * 8;
        bf16x8 kb0 = *(const bf16x8*)&Ks[cur][rowK * 64 + ((l4 * 8) ^ sw)];
        bf16x8 kb1 = *(const bf16x8*)&Ks[cur][rowK * 64 + ((l4 * 8 + 32) ^ sw)];
        s[ni] = __builtin_amdgcn_mfma_f32_16x16x32_bf16(qf[qt][0], kb0, s[ni], 0, 0, 0);
        s[ni] = __builtin_amdgcn_mfma_f32_16x16x32_bf16(qf[qt][1], kb1, s[ni], 0, 0, 0);
      }
      #pragma unroll
      for (int r = 0; r < 4; r++) {
        float mx = fmaxf(fmaxf(s[0][r], s[1][r]), fmaxf(s[2][r], s[3][r]));
        #pragma unroll
        for (int d2 = 1; d2 < 16; d2 <<= 1) mx = fmaxf(mx, __shfl_xor(mx, d2));
        if (mx > m_[qt][r]) {
          float alpha = __expf((m_[qt][r] - mx) * 0.125f);
          l_[qt][r] *= alpha;
          #pragma unroll
          for (int nd = 0; nd < 4; nd++) oacc[qt][nd][r] *= alpha;
          m_[qt][r] = mx;
        }
        float rsum = 0.f;
        #pragma unroll
        for (int ni = 0; ni < 4; ni++) {
          float p = __expf((s[ni][r] - m_[qt][r]) * 0.125f);
          s[ni][r] = p; rsum += p;
        }
        #pragma unroll
        for (int d2 = 1; d2 < 16; d2 <<= 1) rsum += __shfl_xor(rsum, d2);
        l_[qt][r] += rsum;
      }
      #pragma unroll
      for (int ni = 0; ni < 4; ni++)
        #pragma unroll
        for (int r = 0; r < 4; r++)
          Ps[w][l4*4 + r][ni*16 + l15] = s[ni][r];
      asm volatile("s_waitcnt lgkmcnt(0)" ::: "memory");
      #pragma unroll
      for (int half = 0; half < 2; half++) {
        float4 pv0 = *(const float4*)&Ps[w][l15][half*32 + l4*8];
        float4 pv1 = *(const float4*)&Ps[w][l15][half*32 + l4*8 + 4];
        bf16x8 pa;
        pa[0]=(short)f2b(pv0.x); pa[1]=(short)f2b(pv0.y); pa[2]=(short)f2b(pv0.z); pa[3]=(short)f2b(pv0.w);
        pa[4]=(short)f2b(pv1.x); pa[5]=(short)f2b(pv1.y); pa[6]=(short)f2b(pv1.z); pa[7]=(short)f2b(pv1.w);
        #pragma unroll
        for (int nd = 0; nd < 4; nd++) {
          int dd = nd*16 + l15;
          bf16x8 vb = *(const bf16x8*)&Vt[cur][dd * 64 + ((half*32 + l4*8) ^ ((dd & 7) * 8))];
          oacc[qt][nd] = __builtin_amdgcn_mfma_f32_16x16x32_bf16(pa, vb, oacc[qt][nd], 0, 0, 0);
        }
      }
    }
    MEMFENCE; __builtin_amdgcn_s_barrier(); MEMFENCE;
    if (j + 2 < NTI) stage(kt0 + j + 2, cur);
    if (j + 1 < NTI) {
      if (j + 2 < NTI) asm volatile("s_waitcnt vmcnt(4)" ::: "memory");
      else             asm volatile("s_waitcnt vmcnt(0)" ::: "memory");
      __builtin_amdgcn_s_barrier();
      MEMFENCE;
    }
  }

  const int slot = (b * Hn + h) * 16 + sp;
  #pragma unroll
  for (int qt = 0; qt < 4; qt++)
    #pragma unroll
    for (int nd = 0; nd < 4; nd++)
      #pragma unroll
      for (int r = 0; r < 4; r++)
        PO[(size_t)slot * 16384 + (w*64 + qt*16 + l4*4 + r) * 64 + nd*16 + l15] = f2b(oacc[qt][nd][r]);
  if (l15 == 0) {
    #pragma unroll
    for (int qt = 0; qt < 4; qt++)
      #pragma unroll
      for (int r = 0; r < 4; r++) {
        PM[slot * 256 + w*64 + qt*16 + l4*4 + r] = m_[qt][r];
        PL[slot * 256 + w*64 + qt*16 + l4*4 + r] = l_[qt][r];
      }
  }
}

// ---------------- combine 16 split partials (bf16 PO) ----------------
__global__ __launch_bounds__(256) void k_attn_comb16(
    const unsigned short* __restrict__ PO, const float* __restrict__ PM,
    const float* __restrict__ PL, unsigned short* __restrict__ Op) {
  const int W = blockIdx.x * 4 + (threadIdx.x >> 6);  // (bh, q) row
  const int lane = threadIdx.x & 63;
  const int bh = W >> 8, q = W & 255;
  const int slotBase = bh * 16;
  float ms[16];
  float M = -INFINITY;
  #pragma unroll
  for (int s = 0; s < 16; s++) { ms[s] = PM[(slotBase + s) * 256 + q]; M = fmaxf(M, ms[s]); }
  float L = 0.f, acc = 0.f;
  #pragma unroll
  for (int s = 0; s < 16; s++) {
    float wgt = __expf((ms[s] - M) * 0.125f);
    L += PL[(slotBase + s) * 256 + q] * wgt;
    acc += wgt * b2f(PO[(size_t)(slotBase + s) * 16384 + q * 64 + lane]);
  }
  const int b = bh >> 4, h = bh & 15;
  Op[(size_t)(b * Sn + q) * En + h * 64 + lane] = f2b(acc / L);
}

// ------------- helpers for radix top-k (1024-thread blocks) -------------
DEVFN unsigned blk_exscan16(unsigned part, volatile unsigned* wsum, int lane, int wid) {
  unsigned v = part;
  #pragma unroll
  for (int d = 1; d < 64; d <<= 1) { unsigned o = __shfl_up(v, d); if (lane >= d) v += o; }
  if (lane == 63) wsum[wid] = v;
  __syncthreads();
  unsigned woff = 0;
  for (int i = 0; i < wid; i++) woff += wsum[i];
  unsigned r = woff + v - part;
  __syncthreads();
  return r;
}

DEVFN void find_thr16(const unsigned* hist, int NB, unsigned need,
                      int t, int lane, int wid, volatile unsigned* wsum,
                      volatile int* s_thr, volatile unsigned* s_above) {
  int per = NB >> 10;
  int lo = NB - per * (t + 1);
  unsigned part = 0;
  for (int j = 0; j < per; j++) part += hist[lo + j];
  unsigned ex = blk_exscan16(part, wsum, lane, wid);
  if (ex < need && ex + part >= need) {
    unsigned c = ex;
    for (int j = per - 1; j >= 0; j--) {
      unsigned h = hist[lo + j];
      if (c + h >= need) { *s_thr = lo + j; *s_above = c; break; }
      c += h;
    }
  }
  __syncthreads();
}

// ------- exact top-32: sampled threshold -> 1 compact pass -> in-LDS select -------
// Sample guarantees count_full(>=base) >= 32 (sampled keys are a subset of the row).
// Candidate multiset == exact multiset of all keys in bins >= base-bin, so the
// in-LDS selection is exactly equivalent to the full global algorithm.
__global__ __launch_bounds__(1024) void k_topk16(
    const unsigned short* __restrict__ simsb, int* __restrict__ oidx) {
  const int n = blockIdx.x, t = threadIdx.x;
  const int lane = t & 63, wid = t >> 6;
  const u16x8* row8 = (const u16x8*)(simsb + (size_t)n * Mn);
  constexpr unsigned CAP = 2048;
  __shared__ unsigned hist[2048];
  __shared__ unsigned wsum[16];
  __shared__ int s_thr;
  __shared__ unsigned s_above;
  __shared__ unsigned h2[32];
  __shared__ unsigned s_cnt, s_na;
  __shared__ unsigned short ckey[CAP];
  __shared__ unsigned cidx[CAP];
  __shared__ int slist[32];
  __shared__ unsigned sL, sneedEq, scntEq, s_imin;

  for (int i = t; i < 2048; i += 1024) hist[i] = 0;
  if (t < 32) h2[t] = 0;
  if (t == 0) { s_cnt = 0; s_na = 0; }
  __syncthreads();

  // ---- sample pass: 1024 contiguous groups (16 KiB, middle of row) ----
  {
    u16x8 v = row8[3584 + t];
    #pragma unroll
    for (int j = 0; j < 8; j++) atomicAdd(&hist[okey16(v[j]) >> 5], 1u);
  }
  __syncthreads();
  find_thr16(hist, 2048, 32, t, lane, wid, wsum, &s_thr, &s_above);
  const unsigned base = ((unsigned)s_thr) << 5;

  // ---- full pass: compact keys >= base ----
  #pragma unroll
  for (int p = 0; p < 8; p++) {
    u16x8 v = row8[p * 1024 + t];
    unsigned i0 = (unsigned)(p * 1024 + t) * 8;
    #pragma unroll
    for (int j = 0; j < 8; j++) {
      unsigned k = okey16(v[j]);
      if (k >= base) {
        unsigned slot = atomicAdd(&s_cnt, 1u);
        if (slot < CAP) { ckey[slot] = (unsigned short)k; cidx[slot] = i0 + j; }
      }
    }
  }
  __syncthreads();
  const unsigned total = s_cnt;        // >= 32 guaranteed

  unsigned L, istar = 0xFFFFFFFFu;
  if (total <= CAP) {
    // ---- exact select over candidates, all in LDS ----
    for (int i = t; i < 2048; i += 1024) hist[i] = 0;
    __syncthreads();
    for (unsigned i = t; i < total; i += 1024)
      atomicAdd(&hist[(unsigned)ckey[i] >> 5], 1u);
    __syncthreads();
    find_thr16(hist, 2048, 32, t, lane, wid, wsum, &s_thr, &s_above);
    const unsigned T1 = (unsigned)s_thr;
    const unsigned need2 = 32 - s_above;
    const unsigned cnt1 = hist[T1];
    if (cnt1 == need2) {
      L = T1 << 5;
    } else {
      for (unsigned i = t; i < total; i += 1024) {
        unsigned k = (unsigned)ckey[i];
        if ((k >> 5) == T1) atomicAdd(&h2[k & 31], 1u);
      }
      __syncthreads();
      if (t == 0) {
        unsigned cum = 0; int T3 = 0; unsigned above = 0;
        for (int j = 31; j >= 0; j--) {
          if (cum + h2[j] >= need2) { T3 = j; above = cum; break; }
          cum += h2[j];
        }
        sL = (T1 << 5) | (unsigned)T3;
        sneedEq = need2 - above;
        scntEq = h2[T3];
      }
      __syncthreads();
      L = sL;
      if (scntEq != sneedEq) {           // exact ties: smallest-index subset
        int prev = -1;
        for (unsigned j = 0; j < sneedEq; j++) {
          if (t == 0) s_imin = 0xFFFFFFFFu;
          __syncthreads();
          for (unsigned i = t; i < total; i += 1024)
            if ((unsigned)ckey[i] == L && (int)cidx[i] > prev) atomicMin(&s_imin, cidx[i]);
          __syncthreads();
          prev = (int)s_imin;
          __syncthreads();
        }
        istar = (unsigned)prev;
      }
    }
    __syncthreads();
    for (unsigned i = t; i < total; i += 1024) {
      unsigned k = (unsigned)ckey[i];
      if (k > L || (k == L && cidx[i] <= istar)) {
        unsigned s = atomicAdd(&s_na, 1u);
        slist[s] = (int)cidx[i];
      }
    }
    __syncthreads();
    if (t < 32) {
      int my = slist[t];
      int rank = 0;
      #pragma unroll
      for (int j = 0; j < 32; j++) rank += (slist[j] < my);
      oidx[n * Kt + rank] = my;
    }
  } else {
    // ======= fallback: full exact global algorithm =======
    for (int i = t; i < 2048; i += 1024) hist[i] = 0;
    __syncthreads();
    #pragma unroll
    for (int p = 0; p < 8; p++) {
      u16x8 v = row8[p * 1024 + t];
      #pragma unroll
      for (int j = 0; j < 8; j++) atomicAdd(&hist[okey16(v[j]) >> 5], 1u);
    }
    __syncthreads();
    find_thr16(hist, 2048, 32, t, lane, wid, wsum, &s_thr, &s_above);
    const unsigned T1 = (unsigned)s_thr;
    const unsigned need2 = 32 - s_above;
    const unsigned cnt1 = hist[T1];
    if (cnt1 == need2) {
      L = T1 << 5;
    } else {
      for (int p = 0; p < 8; p++) {
        u16x8 v = row8[p * 1024 + t];
        #pragma unroll
        for (int j = 0; j < 8; j++) {
          unsigned k = okey16(v[j]);
          if ((k >> 5) == T1) atomicAdd(&h2[k & 31], 1u);
        }
      }
      __syncthreads();
      if (t == 0) {
        unsigned cum = 0; int T3 = 0; unsigned above = 0;
        for (int j = 31; j >= 0; j--) {
          if (cum + h2[j] >= need2) { T3 = j; above = cum; break; }
          cum += h2[j];
        }
        sL = (T1 << 5) | (unsigned)T3;
        sneedEq = need2 - above;
        scntEq = h2[T3];
      }
      __syncthreads();
      L = sL;
      if (scntEq != sneedEq) {
        const unsigned short* rowp = simsb + (size_t)n * Mn;
        unsigned cntLoc = 0;
        for (int j = 0; j < 64; j++)
          if (okey16(rowp[t * 64 + j]) == L) cntLoc++;
        unsigned pre = blk_exscan16(cntLoc, wsum, lane, wid);
        unsigned c = 0;
        for (int j = 0; j < 64; j++)
          if (okey16(rowp[t * 64 + j]) == L) { if (pre + c < 32) slist[pre + c] = t * 64 + j; c++; }
        __syncthreads();
        istar = (unsigned)slist[sneedEq - 1];
        __syncthreads();
      }
    }
    __syncthreads();
    unsigned cnt = 0;
    for (int p = 0; p < 8; p++) {
      u16x8 v = row8[p * 1024 + t];
      unsigned i0 = (unsigned)(p * 1024 + t) * 8;
      #pragma unroll
      for (int j = 0; j < 8; j++) {
        unsigned k = okey16(v[j]);
        cnt += (k > L || (k == L && i0 + j <= istar));
      }
    }
    unsigned pos = blk_exscan16(cnt, wsum, lane, wid);
    for (int p = 0; p < 8; p++) {
      u16x8 v = row8[p * 1024 + t];
      unsigned i0 = (unsigned)(p * 1024 + t) * 8;
      #pragma unroll
      for (int j = 0; j < 8; j++) {
        unsigned k = okey16(v[j]);
        if (k > L || (k == L && i0 + j <= istar)) oidx[n * Kt + pos++] = (int)(i0 + j);
      }
    }
  }
}

// =============================== host ===============================
extern "C" void kernel_launch(void* const* d_in, const int* in_sizes, int n_in,
                              void* d_out, int out_size, void* d_ws, size_t ws_size,
                              hipStream_t stream) {
  (void)in_sizes; (void)n_in; (void)out_size;
  const float* x      = (const float*)d_in[0];
  const float* mem_k  = (const float*)d_in[1];
  const float* mem_v  = (const float*)d_in[2];
  const float* sa_w[4] = {(const float*)d_in[3], (const float*)d_in[4], (const float*)d_in[5], (const float*)d_in[6]};
  const float* sa_b[4] = {(const float*)d_in[7], (const float*)d_in[8], (const float*)d_in[9], (const float*)d_in[10]};
  const float* ma_w[4] = {(const float*)d_in[11], (const float*)d_in[12], (const float*)d_in[13], (const float*)d_in[14]};
  const float* ma_b[4] = {(const float*)d_in[15], (const float*)d_in[16], (const float*)d_in[17], (const float*)d_in[18]};
  const float* ln_g[3] = {(const float*)d_in[19], (const float*)d_in[21], (const float*)d_in[23]};
  const float* ln_b[3] = {(const float*)d_in[20], (const float*)d_in[22], (const float*)d_in[24]};
  const float* fc1_w = (const float*)d_in[25];
  const float* fc1_b = (const float*)d_in[26];
  const float* fc2_w = (const float*)d_in[27];
  const float* fc2_b = (const float*)d_in[28];
  float* out = (float*)d_out;

  char* ws = (char*)d_ws;
  size_t off = 0;
  auto alloc = [&](size_t bytes) -> char* {
    char* p = ws + off;
    off = (off + bytes + 255) & ~(size_t)255;
    return p;
  };

  unsigned short* wt[8];
  for (int i = 0; i < 8; i++) wt[i] = (unsigned short*)alloc((size_t)En * En * 2);  // contiguous
  unsigned short* fc1t  = (unsigned short*)alloc((size_t)FFn * En * 2);
  unsigned short* fc2t  = (unsigned short*)alloc((size_t)En * FFn * 2);
  unsigned short* xb    = (unsigned short*)alloc((size_t)NT * En * 2);
  unsigned short* Qb    = (unsigned short*)alloc((size_t)NT * En * 2);
  unsigned short* Kb    = (unsigned short*)alloc((size_t)NT * En * 2);
  unsigned short* Vb    = (unsigned short*)alloc((size_t)NT * En * 2);
  unsigned short* at1b  = (unsigned short*)alloc((size_t)NT * En * 2);
  float*          t1    = (float*)alloc((size_t)NT * En * 4);
  float*          x1f   = (float*)alloc((size_t)NT * En * 4);
  unsigned short* x1b   = (unsigned short*)alloc((size_t)NT * En * 2);
  char*           simsRaw = alloc((size_t)NT * Mn * 4);                // 256 MiB region
  int*            idx   = (int*)alloc((size_t)NT * Kt * 4);
  unsigned short* K2b   = (unsigned short*)alloc((size_t)NT * Kt * En * 2);  // 64 MiB
  unsigned short* V2b   = (unsigned short*)alloc((size_t)NT * Kt * En * 2);  // V2t: [B][1024][8192]
  unsigned short* Q2b   = (unsigned short*)alloc((size_t)NT * En * 2);
  unsigned short* at2b  = (unsigned short*)alloc((size_t)NT * En * 2);
  float*          t2    = (float*)alloc((size_t)NT * En * 4);
  float*          x2f   = (float*)alloc((size_t)NT * En * 4);
  unsigned short* x2b   = (unsigned short*)alloc((size_t)NT * En * 2);
  unsigned short* hb    = (unsigned short*)alloc((size_t)NT * FFn * 2);
  float*          t3    = (float*)alloc((size_t)NT * En * 4);
  float*          bcat_sa = (float*)alloc(3072 * 4);
  float*          bcat_ma = (float*)alloc(2048 * 4);

  if (off > ws_size) return;   // insufficient workspace: leave output poisoned (fail loudly)

  // Overlays within the 256 MiB sims region (all uses strictly sequential):
  //  [0,128M)   simsb  (bf16 sims; dead after topk)
  //  [128,192M) Ab2    (pre-gathered bf16 mem_v rows; dead after gather GEMM)
  //  [192,224M) PO     (bf16 attn partials)
  //  [224,225M) PM, [225,226M) PL
  unsigned short* simsb = (unsigned short*)simsRaw;
  unsigned short* mkb = (unsigned short*)K2b;         // until sims GEMM done
  unsigned short* Ab2 = (unsigned short*)(simsRaw + (size_t)128 * 1024 * 1024);
  unsigned short* PO  = (unsigned short*)(simsRaw + (size_t)192 * 1024 * 1024);
  float* PM = (float*)(simsRaw + (size_t)224 * 1024 * 1024);
  float* PL = (float*)(simsRaw + (size_t)225 * 1024 * 1024);

  (void)hipFuncSetAttribute((const void*)&k_gemm256<5,false,1,0>,
                            hipFuncAttributeMaxDynamicSharedMemorySize, 131072);
  (void)hipFuncSetAttribute((const void*)&k_gemm256<6,false,2,1>,
                            hipFuncAttributeMaxDynamicSharedMemorySize, 131072);

  // ---- prep: weight transposes to bf16 [N][K], bias concats ----
  P8 p8;
  for (int i = 0; i < 4; i++) { p8.s[i] = sa_w[i]; p8.s[4 + i] = ma_w[i]; }
  k_transpose8<<<dim3(16, 16, 8), 256, 0, stream>>>(p8, wt[0]);
  k_transpose_bf16<<<dim3(64, 16), 256, 0, stream>>>(fc1_w, fc1t, En, FFn);
  k_transpose_bf16<<<dim3(16, 64), 256, 0, stream>>>(fc2_w, fc2t, FFn, En);
  k_concat3<<<dim3(12), 256, 0, stream>>>(sa_b[0], sa_b[1], sa_b[2], bcat_sa);
  k_concat3<<<dim3(8),  256, 0, stream>>>(ma_b[1], ma_b[2], ma_b[2], bcat_ma);

  k_cvt_bf16<<<dim3(NT * En / 4 / 256), 256, 0, stream>>>(x, xb, NT * En / 4);
  k_normcvt<<<dim3(Mn), 256, 0, stream>>>(mem_k, mkb);

  const dim3 g1(En / 128, NT / 128);   // (8,8)

  // ---- self-attention (QKV fused: N=3072 over contiguous wt[0..2]) ----
  k_gemm<0,false,false,3><<<dim3(24, 8), 256, 0, stream>>>(xb, wt[0], nullptr, bcat_sa, nullptr, nullptr, Qb, Kb, Vb, 3072, En);
  k_attn_sa<<<dim3(Sn / 64, Hn, Bn), 256, 0, stream>>>(Qb, Kb, Vb, at1b, Sn);
  k_gemm<1,false,false,1><<<g1, 256, 0, stream>>>(at1b, wt[3], nullptr, sa_b[3], x, t1, nullptr, nullptr, nullptr, En, En);
  k_layernorm<<<NT, 256, 0, stream>>>(t1, ln_g[0], ln_b[0], x1f, x1b);

  // ---- retrieval: sims in bf16 + sampled-threshold top-k ----
  k_gemm256<5,false,1,0><<<dim3(1024), 512, 131072, stream>>>(
      x1b, mkb, nullptr, nullptr, nullptr, simsb, nullptr, Mn, En, NT / 256, Mn / 256);
  k_topk16<<<NT, 1024, 0, stream>>>(simsb, idx);

  // ---- memory cross-attention ----
  k_gathercvt<<<dim3(NT * Kt), 256, 0, stream>>>(mem_v, idx, Ab2);
  k_gemm256<6,false,2,1><<<dim3(1024), 512, 131072, stream>>>(
      Ab2, wt[5], nullptr, bcat_ma, nullptr, K2b, V2b, 2048, En, NT * Kt / 256, 2048 / 256);
  k_gemm<0,false,false,1><<<g1, 256, 0, stream>>>(x1b, wt[4], nullptr, ma_b[0], nullptr, nullptr, Q2b, nullptr, nullptr, En, En);
  k_attn_ma<<<dim3(16, Hn, Bn), 256, 0, stream>>>(Q2b, K2b, V2b, PO, PM, PL);
  k_attn_comb16<<<dim3(Bn * Hn * Sn / 4), 256, 0, stream>>>(PO, PM, PL, at2b);
  k_gemm<1,false,false,1><<<g1, 256, 0, stream>>>(at2b, wt[7], nullptr, ma_b[3], x1f, t2, nullptr, nullptr, nullptr, En, En);
  k_layernorm<<<NT, 256, 0, stream>>>(t2, ln_g[1], ln_b[1], x2f, x2b);

  // ---- FFN ----
  k_gemm<2,false,false,1><<<dim3(FFn / 128, NT / 128), 256, 0, stream>>>(x2b, fc1t, nullptr, fc1_b, nullptr, nullptr, hb, nullptr, nullptr, FFn, En);
  k_gemm<1,false,false,1><<<g1, 256, 0, stream>>>(hb, fc2t, nullptr, fc2_b, x2f, t3, nullptr, nullptr, nullptr, En, FFn);
  k_layernorm<<<NT, 256, 0, stream>>>(t3, ln_g[2], ln_b[2], out, nullptr);
}

// Round 13
// 908.806 us; speedup vs baseline: 1.4082x; 1.0192x over previous
//
#include <hip/hip_runtime.h>
#include <hip/hip_bf16.h>
#include <math.h>

#define DEVFN __device__ __forceinline__

typedef __attribute__((ext_vector_type(8))) short bf16x8;
typedef __attribute__((ext_vector_type(8))) unsigned short u16x8;
typedef __attribute__((ext_vector_type(4))) unsigned short u16x4;
typedef __attribute__((ext_vector_type(4))) float f32x4;

static constexpr int Bn = 4, Sn = 256, En = 1024, Hn = 16;
static constexpr int Mn = 65536, Kt = 32, FFn = 4096;
static constexpr int NT = Bn * Sn;           // 1024 tokens

DEVFN unsigned short f2b(float f) {          // f32 -> bf16 RNE
  unsigned int u = __float_as_uint(f);
  unsigned int r = (u + 0x7FFFu + ((u >> 16) & 1u)) >> 16;
  return (unsigned short)r;
}
DEVFN float b2f(unsigned short u) { return __uint_as_float((unsigned)u << 16); }

DEVFN unsigned okey16(unsigned short u) {    // order-preserving bf16 -> u16
  return (unsigned)(u ^ ((u >> 15) ? 0xFFFFu : 0x8000u)) & 0xFFFFu;
}

typedef const __attribute__((address_space(1))) void* as1cv_t;
typedef __attribute__((address_space(3))) void* as3v_t;
DEVFN void gload16(const void* g, void* l) {   // async global->LDS, 16B/lane
  __builtin_amdgcn_global_load_lds((as1cv_t)g, (as3v_t)l, 16, 0, 0);
}
#define MEMFENCE asm volatile("" ::: "memory")

struct P8 { const float* s[8]; };

// ---------------- batched transpose W[1024][1024] f32 -> out[C][R] bf16 ----------------
__global__ __launch_bounds__(256) void k_transpose8(
    P8 ps, unsigned short* __restrict__ outbase) {
  const float* in = ps.s[blockIdx.z];
  unsigned short* out = outbase + (size_t)blockIdx.z * En * En;
  __shared__ float tile[64][65];
  int tx = threadIdx.x & 63, ty = threadIdx.x >> 6;
  int c0 = blockIdx.x * 64, r0 = blockIdx.y * 64;
  #pragma unroll
  for (int i = 0; i < 16; i++) {
    int r = ty + i * 4;
    tile[tx][r] = in[(size_t)(r0 + r) * En + (c0 + tx)];
  }
  __syncthreads();
  #pragma unroll
  for (int i = 0; i < 16; i++) {
    int c = ty + i * 4;
    out[(size_t)(c0 + c) * En + (r0 + tx)] = f2b(tile[c][tx]);
  }
}

// ---------------- transpose W[R][C] f32 -> out[C][R] bf16 ----------------
__global__ __launch_bounds__(256) void k_transpose_bf16(
    const float* __restrict__ in, unsigned short* __restrict__ out, int R, int C) {
  __shared__ float tile[64][65];
  int tx = threadIdx.x & 63, ty = threadIdx.x >> 6;
  int c0 = blockIdx.x * 64, r0 = blockIdx.y * 64;
  #pragma unroll
  for (int i = 0; i < 16; i++) {
    int r = ty + i * 4;
    tile[tx][r] = in[(size_t)(r0 + r) * C + (c0 + tx)];
  }
  __syncthreads();
  #pragma unroll
  for (int i = 0; i < 16; i++) {
    int c = ty + i * 4;
    out[(size_t)(c0 + c) * R + (r0 + tx)] = f2b(tile[c][tx]);
  }
}

// ---------------- f32 -> bf16 elementwise (x4) ----------------
__global__ __launch_bounds__(256) void k_cvt_bf16(
    const float* __restrict__ in, unsigned short* __restrict__ out, int n4) {
  int i = blockIdx.x * 256 + threadIdx.x;
  if (i >= n4) return;
  float4 v = ((const float4*)in)[i];
  uint2 o;
  o.x = (unsigned int)f2b(v.x) | ((unsigned int)f2b(v.y) << 16);
  o.y = (unsigned int)f2b(v.z) | ((unsigned int)f2b(v.w) << 16);
  ((uint2*)out)[i] = o;
}

// ---- gather + cvt: out[r] = bf16(mem_v[idx[r]]), one 4KB row per block ----
__global__ __launch_bounds__(256) void k_gathercvt(
    const float* __restrict__ mv, const int* __restrict__ idx,
    unsigned short* __restrict__ out) {
  int r = blockIdx.x;
  int src = idx[r];
  float4 v = ((const float4*)(mv + (size_t)src * En))[threadIdx.x];
  uint2 o;
  o.x = (unsigned int)f2b(v.x) | ((unsigned int)f2b(v.y) << 16);
  o.y = (unsigned int)f2b(v.z) | ((unsigned int)f2b(v.w) << 16);
  ((uint2*)(out + (size_t)r * En))[threadIdx.x] = o;
}

// ---------------- concat up to 3 x 1024-f32 vectors ----------------
__global__ __launch_bounds__(256) void k_concat3(
    const float* __restrict__ a, const float* __restrict__ b,
    const float* __restrict__ c, float* __restrict__ o) {
  int i = blockIdx.x * 256 + threadIdx.x;
  float v = (i < 1024) ? a[i] : (i < 2048) ? b[i - 1024] : c[i - 2048];
  o[i] = v;
}

// ---- mem_keys row-normalize + cvt to bf16 (folds cosine norm into B) ----
__global__ __launch_bounds__(256) void k_normcvt(
    const float* __restrict__ mk, unsigned short* __restrict__ out) {
  int m = blockIdx.x, t = threadIdx.x;
  float4 v = ((const float4*)(mk + (size_t)m * En))[t];
  float ss = v.x*v.x + v.y*v.y + v.z*v.z + v.w*v.w;
  #pragma unroll
  for (int d = 32; d; d >>= 1) ss += __shfl_down(ss, d);
  __shared__ float red[4];
  int lane = t & 63, w = t >> 6;
  if (lane == 0) red[w] = ss;
  __syncthreads();
  float rs = 1.0f / fmaxf(sqrtf(red[0] + red[1] + red[2] + red[3]), 1e-12f);
  uint2 o;
  o.x = (unsigned int)f2b(v.x * rs) | ((unsigned int)f2b(v.y * rs) << 16);
  o.y = (unsigned int)f2b(v.z * rs) | ((unsigned int)f2b(v.w * rs) << 16);
  ((uint2*)(out + (size_t)m * En))[t] = o;
}

// ---------------- LayerNorm over rows of [NT][En] ----------------
__global__ __launch_bounds__(256) void k_layernorm(
    const float* __restrict__ in, const float* __restrict__ g, const float* __restrict__ bb,
    float* __restrict__ outf, unsigned short* __restrict__ outb) {
  int n = blockIdx.x, t = threadIdx.x;
  float4 v = ((const float4*)(in + (size_t)n * En))[t];
  float s  = v.x + v.y + v.z + v.w;
  float s2 = v.x*v.x + v.y*v.y + v.z*v.z + v.w*v.w;
  #pragma unroll
  for (int d = 32; d; d >>= 1) { s += __shfl_down(s, d); s2 += __shfl_down(s2, d); }
  __shared__ float rs[4], rq[4];
  int lane = t & 63, w = t >> 6;
  if (lane == 0) { rs[w] = s; rq[w] = s2; }
  __syncthreads();
  float mean = (rs[0]+rs[1]+rs[2]+rs[3]) * (1.0f/En);
  float var  = (rq[0]+rq[1]+rq[2]+rq[3]) * (1.0f/En) - mean*mean;
  float rstd = rsqrtf(var + 1e-5f);
  float4 gg = ((const float4*)g)[t];
  float4 bv = ((const float4*)bb)[t];
  float o0 = (v.x-mean)*rstd*gg.x + bv.x;
  float o1 = (v.y-mean)*rstd*gg.y + bv.y;
  float o2 = (v.z-mean)*rstd*gg.z + bv.z;
  float o3 = (v.w-mean)*rstd*gg.w + bv.w;
  if (outf) { float4 ov = {o0,o1,o2,o3}; ((float4*)(outf + (size_t)n*En))[t] = ov; }
  if (outb) {
    uint2 o;
    o.x = (unsigned int)f2b(o0) | ((unsigned int)f2b(o1) << 16);
    o.y = (unsigned int)f2b(o2) | ((unsigned int)f2b(o3) << 16);
    ((uint2*)(outb + (size_t)n*En))[t] = o;
  }
}

// ======== 256x256 GEMM, 4 half-tile ring buffers + counted vmcnt (T1..T5) ========
// EPI 4: f32 out | EPI 5: bf16 no-bias | EPI 0 + NOUT2: bf16 (+bias), split N
// EPI 6: split N=2048 -> cb0 row-major (+bias), cb1 TRANSPOSED [B][1024][8192] (+bias)
template<int EPI, bool AGATHER, int NOUT, int LSWZ>
__global__ __launch_bounds__(512) void k_gemm256(
    const unsigned short* __restrict__ Ab, const unsigned short* __restrict__ Bb,
    const int* __restrict__ gidx, const float* __restrict__ bias,
    float* __restrict__ Cf, unsigned short* __restrict__ cb0, unsigned short* __restrict__ cb1,
    int Ndim, int Kdim, int nRT, int nCT) {
  extern __shared__ unsigned short lds[];
  const int t = threadIdx.x, lane = t & 63, w = t >> 6;
  const int wr = w >> 2, wc = w & 3, l15 = lane & 15, l4 = lane >> 4;
  const int lr2 = lane >> 2;
  const int cg  = (lane & 3) ^ (((lane >> 5) & 1) << 1);   // source pre-swizzle (involution)

  const int nwg = nRT * nCT;
  int lb = ((int)blockIdx.x % 8) * (nwg >> 3) + ((int)blockIdx.x >> 3);
  int rowT, colT;
  if (LSWZ == 0) { rowT = lb % nRT; colT = lb / nRT; }
  else           { colT = lb % nCT; rowT = lb / nCT; }
  const int row0 = rowT * 256, col0 = colT * 256;

  auto pa = [&](int h) -> unsigned short* { return lds + h * 16384; };
  auto pb = [&](int h) -> unsigned short* { return lds + h * 16384 + 8192; };

  const unsigned short *aSrc0, *aSrc1;
  if constexpr (AGATHER) {
    aSrc0 = Ab + (size_t)gidx[row0 + w * 32 + lr2] * Kdim + cg * 8;
    aSrc1 = Ab + (size_t)gidx[row0 + w * 32 + 16 + lr2] * Kdim + cg * 8;
  } else {
    aSrc0 = Ab + (size_t)(row0 + w * 32 + lr2) * Kdim + cg * 8;
    aSrc1 = aSrc0 + (size_t)16 * Kdim;
  }
  const unsigned short* bSrc0 = Bb + (size_t)(col0 + w * 32 + lr2) * Kdim + cg * 8;
  const unsigned short* bSrc1 = bSrc0 + (size_t)16 * Kdim;

  f32x4 acc[8][4];
  #pragma unroll
  for (int i = 0; i < 8; i++)
    #pragma unroll
    for (int j = 0; j < 4; j++) acc[i][j] = (f32x4){0.f, 0.f, 0.f, 0.f};

  const int NH = Kdim >> 5;                 // K half-tiles of 32
  #pragma unroll
  for (int h = 0; h < 3; ++h) {
    const int ko = h * 32;
    gload16(aSrc0 + ko, pa(h) + w*32*32);
    gload16(aSrc1 + ko, pa(h) + (w*32+16)*32);
    gload16(bSrc0 + ko, pb(h) + w*32*32);
    gload16(bSrc1 + ko, pb(h) + (w*32+16)*32);
  }
  asm volatile("s_waitcnt vmcnt(8)" ::: "memory");   // half 0 landed
  __builtin_amdgcn_s_barrier();
  MEMFENCE;

  for (int hs = 0; hs < NH; ++hs) {
    const int cur = hs & 3;
    const unsigned short* Ap = pa(cur);
    const unsigned short* Bp = pb(cur);
    const int h3 = (hs + 3) & 3, ko3 = (hs + 3) * 32;
    const bool pf = (hs + 3) < NH;
    bf16x8 bfr[4], af[4];

    // ---- phase 0: B frags + A rows 0..63 ----
    #pragma unroll
    for (int ni = 0; ni < 4; ni++) {
      int row = wc * 64 + ni * 16 + l15;
      int c8 = l4 ^ (((row >> 3) & 1) << 1);
      bfr[ni] = *(const bf16x8*)&Bp[row * 32 + c8 * 8];
    }
    #pragma unroll
    for (int m = 0; m < 4; m++) {
      int row = wr * 128 + m * 16 + l15;
      int c8 = l4 ^ (((row >> 3) & 1) << 1);
      af[m] = *(const bf16x8*)&Ap[row * 32 + c8 * 8];
    }
    if (pf) {
      gload16(aSrc0 + ko3, pa(h3) + w*32*32);
      gload16(aSrc1 + ko3, pa(h3) + (w*32+16)*32);
    }
    MEMFENCE; __builtin_amdgcn_s_barrier(); MEMFENCE;
    __builtin_amdgcn_s_setprio(1);
    #pragma unroll
    for (int m = 0; m < 4; m++)
      #pragma unroll
      for (int ni = 0; ni < 4; ni++)
        acc[m][ni] = __builtin_amdgcn_mfma_f32_16x16x32_bf16(af[m], bfr[ni], acc[m][ni], 0, 0, 0);
    __builtin_amdgcn_s_setprio(0);
    MEMFENCE; __builtin_amdgcn_s_barrier(); MEMFENCE;

    // ---- phase 1: A rows 64..127 ----
    #pragma unroll
    for (int m = 0; m < 4; m++) {
      int row = wr * 128 + (4 + m) * 16 + l15;
      int c8 = l4 ^ (((row >> 3) & 1) << 1);
      af[m] = *(const bf16x8*)&Ap[row * 32 + c8 * 8];
    }
    if (pf) {
      gload16(bSrc0 + ko3, pb(h3) + w*32*32);
      gload16(bSrc1 + ko3, pb(h3) + (w*32+16)*32);
    }
    MEMFENCE; __builtin_amdgcn_s_barrier(); MEMFENCE;
    __builtin_amdgcn_s_setprio(1);
    #pragma unroll
    for (int m = 0; m < 4; m++)
      #pragma unroll
      for (int ni = 0; ni < 4; ni++)
        acc[4 + m][ni] = __builtin_amdgcn_mfma_f32_16x16x32_bf16(af[m], bfr[ni], acc[4 + m][ni], 0, 0, 0);
    __builtin_amdgcn_s_setprio(0);

    if (hs + 1 < NH) {
      const int rem = NH - 2 - hs;
      if (rem >= 2)      asm volatile("s_waitcnt vmcnt(8)" ::: "memory");
      else if (rem == 1) asm volatile("s_waitcnt vmcnt(4)" ::: "memory");
      else               asm volatile("s_waitcnt vmcnt(0)" ::: "memory");
      __builtin_amdgcn_s_barrier();
      MEMFENCE;
    }
  }

  #pragma unroll
  for (int m = 0; m < 8; m++) {
    #pragma unroll
    for (int ni = 0; ni < 4; ni++) {
      int col  = col0 + wc * 64 + ni * 16 + l15;
      int rowb = row0 + wr * 128 + m * 16 + l4 * 4;
      if constexpr (EPI == 6) {
        if (col < 1024) {
          #pragma unroll
          for (int r = 0; r < 4; r++)
            cb0[(size_t)(rowb + r) * 1024 + col] = f2b(acc[m][ni][r] + bias[col]);
        } else {
          int c = col - 1024;
          int bi = rowb >> 13, k0 = rowb & 8191;
          u16x4 o;
          #pragma unroll
          for (int r = 0; r < 4; r++) o[r] = f2b(acc[m][ni][r] + bias[col]);
          *(u16x4*)&cb1[((size_t)bi * 1024 + c) * 8192 + k0] = o;
        }
      } else {
        #pragma unroll
        for (int r = 0; r < 4; r++) {
          float v = acc[m][ni][r];
          if constexpr (EPI == 4) {
            Cf[(size_t)(rowb + r) * Ndim + col] = v;
          } else if constexpr (EPI == 5) {
            cb0[(size_t)(rowb + r) * Ndim + col] = f2b(v);
          } else {
            unsigned short* cb = (col >> 10) ? cb1 : cb0;
            cb[(size_t)(rowb + r) * 1024 + (col & 1023)] = f2b(v + bias[col]);
          }
        }
      }
    }
  }
}

// ---------------- GEMM 128x128 (2-phase) for the small GEMMs ----------------
// QSC: scale output by 0.125 (Q pre-scale; NOUT>1: only the first 1024 cols)
template<int EPI, bool AGATHER, bool SWAPG, int NOUT, bool QSC>
__global__ __launch_bounds__(256) void k_gemm(
    const unsigned short* __restrict__ Ab, const unsigned short* __restrict__ Bb,
    const int* __restrict__ gidx,
    const float* __restrict__ bias, const float* __restrict__ resid,
    float* __restrict__ Cf, unsigned short* __restrict__ cb0,
    unsigned short* __restrict__ cb1, unsigned short* __restrict__ cb2,
    int Ndim, int Kdim) {
  __shared__ unsigned short As[128][32];
  __shared__ unsigned short Bs[128][32];
  const int t = threadIdx.x, lane = t & 63, w = t >> 6;
  const int wr = w >> 1, wc = w & 1, l15 = lane & 15, l4 = lane >> 4;
  const int row0 = (SWAPG ? blockIdx.x : blockIdx.y) * 128;
  const int col0 = (SWAPG ? blockIdx.y : blockIdx.x) * 128;
  const int c8  = (lane & 3) * 8;
  const int r16 = lane >> 2;
  const int rA0 = w * 32 + r16, rA1 = rA0 + 16;

  size_t raA0, raA1, raB0, raB1;
  if constexpr (AGATHER) {
    raA0 = (size_t)gidx[row0 + rA0] * Kdim;
    raA1 = (size_t)gidx[row0 + rA1] * Kdim;
  } else {
    raA0 = (size_t)(row0 + rA0) * Kdim;
    raA1 = (size_t)(row0 + rA1) * Kdim;
  }
  raB0 = (size_t)(col0 + rA0) * Kdim;
  raB1 = (size_t)(col0 + rA1) * Kdim;

  f32x4 acc[4][4];
  #pragma unroll
  for (int i = 0; i < 4; i++)
    #pragma unroll
    for (int j = 0; j < 4; j++) acc[i][j] = (f32x4){0.f,0.f,0.f,0.f};

  for (int kt0 = 0; kt0 < Kdim; kt0 += 32) {
    __syncthreads();
    gload16(Ab + raA0 + kt0 + c8, &As[w * 32][0]);
    gload16(Ab + raA1 + kt0 + c8, &As[w * 32 + 16][0]);
    gload16(Bb + raB0 + kt0 + c8, &Bs[w * 32][0]);
    gload16(Bb + raB1 + kt0 + c8, &Bs[w * 32 + 16][0]);
    __syncthreads();
    bf16x8 af[4], bfr[4];
    #pragma unroll
    for (int mi = 0; mi < 4; mi++) af[mi]  = *(const bf16x8*)&As[wr*64 + mi*16 + l15][l4*8];
    #pragma unroll
    for (int ni = 0; ni < 4; ni++) bfr[ni] = *(const bf16x8*)&Bs[wc*64 + ni*16 + l15][l4*8];
    #pragma unroll
    for (int mi = 0; mi < 4; mi++)
      #pragma unroll
      for (int ni = 0; ni < 4; ni++)
        acc[mi][ni] = __builtin_amdgcn_mfma_f32_16x16x32_bf16(af[mi], bfr[ni], acc[mi][ni], 0, 0, 0);
  }

  unsigned short* cbase = cb0;
  int colsub = 0;
  float qsc = 1.0f;
  if constexpr (NOUT > 1) {
    int which = col0 >> 10;
    cbase = (which == 0) ? cb0 : (which == 1) ? cb1 : cb2;
    colsub = col0 & 1023;
    if (QSC && which == 0) qsc = 0.125f;
  } else if constexpr (QSC) {
    qsc = 0.125f;
  }

  #pragma unroll
  for (int mi = 0; mi < 4; mi++) {
    #pragma unroll
    for (int ni = 0; ni < 4; ni++) {
      int col  = col0 + wc*64 + ni*16 + l15;
      int rowb = row0 + wr*64 + mi*16 + l4*4;
      #pragma unroll
      for (int r = 0; r < 4; r++) {
        float v = acc[mi][ni][r];
        size_t off = (size_t)(rowb + r) * Ndim + col;
        if constexpr (EPI == 0) {
          if constexpr (NOUT > 1) {
            int c2 = colsub + wc*64 + ni*16 + l15;
            cbase[(size_t)(rowb + r) * 1024 + c2] = f2b((v + bias[col]) * qsc);
          } else {
            cb0[off] = f2b((v + bias[col]) * qsc);
          }
        } else if constexpr (EPI == 1) {
          Cf[off] = v + bias[col] + resid[off];
        } else if constexpr (EPI == 2) {
          float u = v + bias[col];
          u = 0.5f * u * (1.0f + erff(u * 0.70710678118654752f));
          cb0[off] = f2b(u);
        } else {
          Cf[off] = v;
        }
      }
    }
  }
}

// ---------------- SA fused attention (Q pre-scaled, T13 defer-max, deferred l) --------
__global__ __launch_bounds__(256) void k_attn_sa(
    const unsigned short* __restrict__ Qp, const unsigned short* __restrict__ Kp,
    const unsigned short* __restrict__ Vp, unsigned short* __restrict__ Op, int Lk) {
  __shared__ unsigned short Ks[64][72];
  __shared__ unsigned short Vt[64][72];
  __shared__ float Ps[4][16][68];
  const int b = blockIdx.z;
  const int h = blockIdx.y, q0 = blockIdx.x * 64;
  const int t = threadIdx.x, lane = t & 63, w = t >> 6;
  const int l15 = lane & 15, l4 = lane >> 4;

  const int qrow = q0 + w * 16 + l15;
  const unsigned short* qptr = Qp + (size_t)(b * Sn + qrow) * En + h * 64 + l4 * 8;
  bf16x8 qf0 = *(const bf16x8*)qptr;
  bf16x8 qf1 = *(const bf16x8*)(qptr + 32);

  f32x4 oacc[4];
  #pragma unroll
  for (int i = 0; i < 4; i++) oacc[i] = (f32x4){0.f,0.f,0.f,0.f};
  float m_[4] = {-INFINITY, -INFINITY, -INFINITY, -INFINITY};
  float l_[4] = {0.f, 0.f, 0.f, 0.f};

  const int nkt = Lk / 64;
  for (int kt = 0; kt < nkt; ++kt) {
    __syncthreads();
    #pragma unroll
    for (int i = 0; i < 2; i++) {
      int ld = t + i * 256;
      int kr = ld >> 3, d8 = (ld & 7) * 8;
      size_t base = (size_t)(b * Lk + kt * 64 + kr) * En + h * 64 + d8;
      *(uint4*)&Ks[kr][d8] = *(const uint4*)(Kp + base);
      bf16x8 vv = *(const bf16x8*)(Vp + base);
      int colswz = kr ^ ((t & 7) << 3);
      #pragma unroll
      for (int j = 0; j < 8; j++) Vt[d8 + j][colswz] = ((unsigned short*)&vv)[j];
    }
    __syncthreads();

    f32x4 s[4];
    #pragma unroll
    for (int ni = 0; ni < 4; ni++) {
      s[ni] = (f32x4){0.f,0.f,0.f,0.f};
      bf16x8 kb0 = *(const bf16x8*)&Ks[ni*16 + l15][l4*8];
      bf16x8 kb1 = *(const bf16x8*)&Ks[ni*16 + l15][l4*8 + 32];
      s[ni] = __builtin_amdgcn_mfma_f32_16x16x32_bf16(qf0, kb0, s[ni], 0, 0, 0);
      s[ni] = __builtin_amdgcn_mfma_f32_16x16x32_bf16(qf1, kb1, s[ni], 0, 0, 0);
    }

    #pragma unroll
    for (int r = 0; r < 4; r++) {
      float mx = fmaxf(fmaxf(s[0][r], s[1][r]), fmaxf(s[2][r], s[3][r]));
      #pragma unroll
      for (int d2 = 1; d2 < 16; d2 <<= 1) mx = fmaxf(mx, __shfl_xor(mx, d2));
      float m = m_[r];
      if (mx > m + 8.f) {                    // T13: rescale only on large jump
        float alpha = __expf(m - mx);
        l_[r] *= alpha;
        #pragma unroll
        for (int nd = 0; nd < 4; nd++) oacc[nd][r] *= alpha;
        m = mx; m_[r] = mx;
      }
      float p0 = __expf(s[0][r] - m), p1 = __expf(s[1][r] - m);
      float p2 = __expf(s[2][r] - m), p3 = __expf(s[3][r] - m);
      s[0][r] = p0; s[1][r] = p1; s[2][r] = p2; s[3][r] = p3;
      l_[r] += (p0 + p1) + (p2 + p3);        // per-lane partial; reduce at end
    }

    #pragma unroll
    for (int ni = 0; ni < 4; ni++)
      #pragma unroll
      for (int r = 0; r < 4; r++)
        Ps[w][l4*4 + r][ni*16 + l15] = s[ni][r];
    asm volatile("s_waitcnt lgkmcnt(0)" ::: "memory");

    #pragma unroll
    for (int half = 0; half < 2; half++) {
      float4 pv0 = *(const float4*)&Ps[w][l15][half*32 + l4*8];
      float4 pv1 = *(const float4*)&Ps[w][l15][half*32 + l4*8 + 4];
      bf16x8 pa;
      pa[0]=(short)f2b(pv0.x); pa[1]=(short)f2b(pv0.y); pa[2]=(short)f2b(pv0.z); pa[3]=(short)f2b(pv0.w);
      pa[4]=(short)f2b(pv1.x); pa[5]=(short)f2b(pv1.y); pa[6]=(short)f2b(pv1.z); pa[7]=(short)f2b(pv1.w);
      #pragma unroll
      for (int nd = 0; nd < 4; nd++) {
        int dd = nd*16 + l15;
        bf16x8 vb = *(const bf16x8*)&Vt[dd][(half*32 + l4*8) ^ (((dd >> 3) & 7) << 3)];
        oacc[nd] = __builtin_amdgcn_mfma_f32_16x16x32_bf16(pa, vb, oacc[nd], 0, 0, 0);
      }
    }
  }

  #pragma unroll
  for (int r = 0; r < 4; r++) {              // final 16-lane l reduce
    float lv = l_[r];
    #pragma unroll
    for (int d2 = 1; d2 < 16; d2 <<= 1) lv += __shfl_xor(lv, d2);
    l_[r] = lv;
  }
  #pragma unroll
  for (int nd = 0; nd < 4; nd++)
    #pragma unroll
    for (int r = 0; r < 4; r++) {
      int q = q0 + w*16 + l4*4 + r;
      Op[(size_t)(b * Sn + q) * En + h * 64 + nd*16 + l15] = f2b(oacc[nd][r] / l_[r]);
    }
}

// ------- MA attention: 4 q-tiles folded, SPLIT=16, dbuf VT staging, lean softmax -------
__global__ __launch_bounds__(256, 2) void k_attn_ma(
    const unsigned short* __restrict__ Qp, const unsigned short* __restrict__ Kp,
    const unsigned short* __restrict__ Vp,
    unsigned short* __restrict__ PO, float* __restrict__ PM, float* __restrict__ PL) {
  constexpr int Lk = Sn * Kt;            // 8192
  constexpr int NTI = 8;                 // k-tiles per block (8192/64/16)
  __shared__ unsigned short Ks[2][64 * 64];
  __shared__ unsigned short Vt[2][64 * 64];
  __shared__ float Ps[4][16][68];
  const int sp = blockIdx.x, h = blockIdx.y, b = blockIdx.z;
  const int t = threadIdx.x, lane = t & 63, w = t >> 6;
  const int l15 = lane & 15, l4 = lane >> 4;
  const int l8 = lane >> 3, l7 = lane & 7;
  const int kswz = (l7 ^ l8) * 8;        // source pre-swizzle (row&7)
  const int rbase = w * 16;

  bf16x8 qf[4][2];
  #pragma unroll
  for (int qt = 0; qt < 4; qt++) {
    const unsigned short* qptr = Qp + (size_t)(b * Sn + w * 64 + qt * 16 + l15) * En + h * 64 + l4 * 8;
    qf[qt][0] = *(const bf16x8*)qptr;
    qf[qt][1] = *(const bf16x8*)(qptr + 32);
  }

  f32x4 oacc[4][4];
  #pragma unroll
  for (int i = 0; i < 4; i++)
    #pragma unroll
    for (int j = 0; j < 4; j++) oacc[i][j] = (f32x4){0.f,0.f,0.f,0.f};
  float m_[4][4], l_[4][4];
  #pragma unroll
  for (int i = 0; i < 4; i++)
    #pragma unroll
    for (int j = 0; j < 4; j++) { m_[i][j] = -INFINITY; l_[i][j] = 0.f; }

  const int kt0 = sp * NTI;
  auto stage = [&](int kt, int buf) {
    #pragma unroll
    for (int i = 0; i < 2; i++) {
      int row = rbase + i * 8 + l8;
      gload16(Kp + (size_t)(b * Lk + kt * 64 + row) * En + h * 64 + kswz,
              &Ks[buf][(rbase + i * 8) * 64]);
      gload16(Vp + ((size_t)b * 1024 + h * 64 + row) * (size_t)Lk + kt * 64 + kswz,
              &Vt[buf][(rbase + i * 8) * 64]);
    }
  };

  stage(kt0, 0);
  stage(kt0 + 1, 1);
  asm volatile("s_waitcnt vmcnt(4)" ::: "memory");   // tile0 landed (Q drained too)
  __builtin_amdgcn_s_barrier();
  MEMFENCE;

  for (int j = 0; j < NTI; ++j) {
    const int cur = j & 1;
    #pragma unroll
    for (int qt = 0; qt < 4; qt++) {
      f32x4 s[4];
      #pragma unroll
      for (int ni = 0; ni < 4; ni++) {
        s[ni] = (f32x4){0.f,0.f,0.f,0.f};
        int rowK = ni * 16 + l15, sw = (rowK & 7) * 8;
        bf16x8 kb0 = *(const bf16x8*)&Ks[cur][rowK * 64 + ((l4 * 8) ^ sw)];
        bf16x8 kb1 = *(const bf16x8*)&Ks[cur][rowK * 64 + ((l4 * 8 + 32) ^ sw)];
        s[ni] = __builtin_amdgcn_mfma_f32_16x16x32_bf16(qf[qt][0], kb0, s[ni], 0, 0, 0);
        s[ni] = __builtin_amdgcn_mfma_f32_16x16x32_bf16(qf[qt][1], kb1, s[ni], 0, 0, 0);
      }
      #pragma unroll
      for (int r = 0; r < 4; r++) {
        float mx = fmaxf(fmaxf(s[0][r], s[1][r]), fmaxf(s[2][r], s[3][r]));
        #pragma unroll
        for (int d2 = 1; d2 < 16; d2 <<= 1) mx = fmaxf(mx, __shfl_xor(mx, d2));
        float m = m_[qt][r];
        if (mx > m + 8.f) {                  // T13 defer-max
          float alpha = __expf(m - mx);
          l_[qt][r] *= alpha;
          #pragma unroll
          for (int nd = 0; nd < 4; nd++) oacc[qt][nd][r] *= alpha;
          m = mx; m_[qt][r] = mx;
        }
        float p0 = __expf(s[0][r] - m), p1 = __expf(s[1][r] - m);
        float p2 = __expf(s[2][r] - m), p3 = __expf(s[3][r] - m);
        s[0][r] = p0; s[1][r] = p1; s[2][r] = p2; s[3][r] = p3;
        l_[qt][r] += (p0 + p1) + (p2 + p3);  // per-lane partial
      }
      #pragma unroll
      for (int ni = 0; ni < 4; ni++)
        #pragma unroll
        for (int r = 0; r < 4; r++)
          Ps[w][l4*4 + r][ni*16 + l15] = s[ni][r];
      asm volatile("s_waitcnt lgkmcnt(0)" ::: "memory");
      #pragma unroll
      for (int half = 0; half < 2; half++) {
        float4 pv0 = *(const float4*)&Ps[w][l15][half*32 + l4*8];
        float4 pv1 = *(const float4*)&Ps[w][l15][half*32 + l4*8 + 4];
        bf16x8 pa;
        pa[0]=(short)f2b(pv0.x); pa[1]=(short)f2b(pv0.y); pa[2]=(short)f2b(pv0.z); pa[3]=(short)f2b(pv0.w);
        pa[4]=(short)f2b(pv1.x); pa[5]=(short)f2b(pv1.y); pa[6]=(short)f2b(pv1.z); pa[7]=(short)f2b(pv1.w);
        #pragma unroll
        for (int nd = 0; nd < 4; nd++) {
          int dd = nd*16 + l15;
          bf16x8 vb = *(const bf16x8*)&Vt[cur][dd * 64 + ((half*32 + l4*8) ^ ((dd & 7) * 8))];
          oacc[qt][nd] = __builtin_amdgcn_mfma_f32_16x16x32_bf16(pa, vb, oacc[qt][nd], 0, 0, 0);
        }
      }
    }
    MEMFENCE; __builtin_amdgcn_s_barrier(); MEMFENCE;
    if (j + 2 < NTI) stage(kt0 + j + 2, cur);
    if (j + 1 < NTI) {
      if (j + 2 < NTI) asm volatile("s_waitcnt vmcnt(4)" ::: "memory");
      else             asm volatile("s_waitcnt vmcnt(0)" ::: "memory");
      __builtin_amdgcn_s_barrier();
      MEMFENCE;
    }
  }

  #pragma unroll
  for (int qt = 0; qt < 4; qt++)             // final 16-lane l reduce
    #pragma unroll
    for (int r = 0; r < 4; r++) {
      float lv = l_[qt][r];
      #pragma unroll
      for (int d2 = 1; d2 < 16; d2 <<= 1) lv += __shfl_xor(lv, d2);
      l_[qt][r] = lv;
    }

  const int slot = (b * Hn + h) * 16 + sp;
  #pragma unroll
  for (int qt = 0; qt < 4; qt++)
    #pragma unroll
    for (int nd = 0; nd < 4; nd++)
      #pragma unroll
      for (int r = 0; r < 4; r++)
        PO[(size_t)slot * 16384 + (w*64 + qt*16 + l4*4 + r) * 64 + nd*16 + l15] = f2b(oacc[qt][nd][r]);
  if (l15 == 0) {
    #pragma unroll
    for (int qt = 0; qt < 4; qt++)
      #pragma unroll
      for (int r = 0; r < 4; r++) {
        PM[slot * 256 + w*64 + qt*16 + l4*4 + r] = m_[qt][r];
        PL[slot * 256 + w*64 + qt*16 + l4*4 + r] = l_[qt][r];
      }
  }
}

// ---------------- combine 16 split partials (bf16 PO, Q pre-scaled) ----------------
__global__ __launch_bounds__(256) void k_attn_comb16(
    const unsigned short* __restrict__ PO, const float* __restrict__ PM,
    const float* __restrict__ PL, unsigned short* __restrict__ Op) {
  const int W = blockIdx.x * 4 + (threadIdx.x >> 6);  // (bh, q) row
  const int lane = threadIdx.x & 63;
  const int bh = W >> 8, q = W & 255;
  const int slotBase = bh * 16;
  float ms[16];
  float M = -INFINITY;
  #pragma unroll
  for (int s = 0; s < 16; s++) { ms[s] = PM[(slotBase + s) * 256 + q]; M = fmaxf(M, ms[s]); }
  float L = 0.f, acc = 0.f;
  #pragma unroll
  for (int s = 0; s < 16; s++) {
    float wgt = __expf(ms[s] - M);
    L += PL[(slotBase + s) * 256 + q] * wgt;
    acc += wgt * b2f(PO[(size_t)(slotBase + s) * 16384 + q * 64 + lane]);
  }
  const int b = bh >> 4, h = bh & 15;
  Op[(size_t)(b * Sn + q) * En + h * 64 + lane] = f2b(acc / L);
}

// ------------- helpers for radix top-k (1024-thread blocks) -------------
DEVFN unsigned blk_exscan16(unsigned part, volatile unsigned* wsum, int lane, int wid) {
  unsigned v = part;
  #pragma unroll
  for (int d = 1; d < 64; d <<= 1) { unsigned o = __shfl_up(v, d); if (lane >= d) v += o; }
  if (lane == 63) wsum[wid] = v;
  __syncthreads();
  unsigned woff = 0;
  for (int i = 0; i < wid; i++) woff += wsum[i];
  unsigned r = woff + v - part;
  __syncthreads();
  return r;
}

DEVFN void find_thr16(const unsigned* hist, int NB, unsigned need,
                      int t, int lane, int wid, volatile unsigned* wsum,
                      volatile int* s_thr, volatile unsigned* s_above) {
  int per = NB >> 10;
  int lo = NB - per * (t + 1);
  unsigned part = 0;
  for (int j = 0; j < per; j++) part += hist[lo + j];
  unsigned ex = blk_exscan16(part, wsum, lane, wid);
  if (ex < need && ex + part >= need) {
    unsigned c = ex;
    for (int j = per - 1; j >= 0; j--) {
      unsigned h = hist[lo + j];
      if (c + h >= need) { *s_thr = lo + j; *s_above = c; break; }
      c += h;
    }
  }
  __syncthreads();
}

// ------- exact top-32: sampled threshold -> 1 compact pass -> in-LDS select -------
__global__ __launch_bounds__(1024) void k_topk16(
    const unsigned short* __restrict__ simsb, int* __restrict__ oidx) {
  const int n = blockIdx.x, t = threadIdx.x;
  const int lane = t & 63, wid = t >> 6;
  const u16x8* row8 = (const u16x8*)(simsb + (size_t)n * Mn);
  constexpr unsigned CAP = 2048;
  __shared__ unsigned hist[2048];
  __shared__ unsigned wsum[16];
  __shared__ int s_thr;
  __shared__ unsigned s_above;
  __shared__ unsigned h2[32];
  __shared__ unsigned s_cnt, s_na;
  __shared__ unsigned short ckey[CAP];
  __shared__ unsigned cidx[CAP];
  __shared__ int slist[32];
  __shared__ unsigned sL, sneedEq, scntEq, s_imin;

  for (int i = t; i < 2048; i += 1024) hist[i] = 0;
  if (t < 32) h2[t] = 0;
  if (t == 0) { s_cnt = 0; s_na = 0; }
  __syncthreads();

  // ---- sample pass: 1024 contiguous groups (16 KiB, middle of row) ----
  {
    u16x8 v = row8[3584 + t];
    #pragma unroll
    for (int j = 0; j < 8; j++) atomicAdd(&hist[okey16(v[j]) >> 5], 1u);
  }
  __syncthreads();
  find_thr16(hist, 2048, 32, t, lane, wid, wsum, &s_thr, &s_above);
  const unsigned base = ((unsigned)s_thr) << 5;

  // ---- full pass: compact keys >= base ----
  #pragma unroll
  for (int p = 0; p < 8; p++) {
    u16x8 v = row8[p * 1024 + t];
    unsigned i0 = (unsigned)(p * 1024 + t) * 8;
    #pragma unroll
    for (int j = 0; j < 8; j++) {
      unsigned k = okey16(v[j]);
      if (k >= base) {
        unsigned slot = atomicAdd(&s_cnt, 1u);
        if (slot < CAP) { ckey[slot] = (unsigned short)k; cidx[slot] = i0 + j; }
      }
    }
  }
  __syncthreads();
  const unsigned total = s_cnt;        // >= 32 guaranteed

  unsigned L, istar = 0xFFFFFFFFu;
  if (total <= CAP) {
    for (int i = t; i < 2048; i += 1024) hist[i] = 0;
    __syncthreads();
    for (unsigned i = t; i < total; i += 1024)
      atomicAdd(&hist[(unsigned)ckey[i] >> 5], 1u);
    __syncthreads();
    find_thr16(hist, 2048, 32, t, lane, wid, wsum, &s_thr, &s_above);
    const unsigned T1 = (unsigned)s_thr;
    const unsigned need2 = 32 - s_above;
    const unsigned cnt1 = hist[T1];
    if (cnt1 == need2) {
      L = T1 << 5;
    } else {
      for (unsigned i = t; i < total; i += 1024) {
        unsigned k = (unsigned)ckey[i];
        if ((k >> 5) == T1) atomicAdd(&h2[k & 31], 1u);
      }
      __syncthreads();
      if (t == 0) {
        unsigned cum = 0; int T3 = 0; unsigned above = 0;
        for (int j = 31; j >= 0; j--) {
          if (cum + h2[j] >= need2) { T3 = j; above = cum; break; }
          cum += h2[j];
        }
        sL = (T1 << 5) | (unsigned)T3;
        sneedEq = need2 - above;
        scntEq = h2[T3];
      }
      __syncthreads();
      L = sL;
      if (scntEq != sneedEq) {
        int prev = -1;
        for (unsigned j = 0; j < sneedEq; j++) {
          if (t == 0) s_imin = 0xFFFFFFFFu;
          __syncthreads();
          for (unsigned i = t; i < total; i += 1024)
            if ((unsigned)ckey[i] == L && (int)cidx[i] > prev) atomicMin(&s_imin, cidx[i]);
          __syncthreads();
          prev = (int)s_imin;
          __syncthreads();
        }
        istar = (unsigned)prev;
      }
    }
    __syncthreads();
    for (unsigned i = t; i < total; i += 1024) {
      unsigned k = (unsigned)ckey[i];
      if (k > L || (k == L && cidx[i] <= istar)) {
        unsigned s = atomicAdd(&s_na, 1u);
        slist[s] = (int)cidx[i];
      }
    }
    __syncthreads();
    if (t < 32) {
      int my = slist[t];
      int rank = 0;
      #pragma unroll
      for (int j = 0; j < 32; j++) rank += (slist[j] < my);
      oidx[n * Kt + rank] = my;
    }
  } else {
    // ======= fallback: full exact global algorithm =======
    for (int i = t; i < 2048; i += 1024) hist[i] = 0;
    __syncthreads();
    #pragma unroll
    for (int p = 0; p < 8; p++) {
      u16x8 v = row8[p * 1024 + t];
      #pragma unroll
      for (int j = 0; j < 8; j++) atomicAdd(&hist[okey16(v[j]) >> 5], 1u);
    }
    __syncthreads();
    find_thr16(hist, 2048, 32, t, lane, wid, wsum, &s_thr, &s_above);
    const unsigned T1 = (unsigned)s_thr;
    const unsigned need2 = 32 - s_above;
    const unsigned cnt1 = hist[T1];
    if (cnt1 == need2) {
      L = T1 << 5;
    } else {
      for (int p = 0; p < 8; p++) {
        u16x8 v = row8[p * 1024 + t];
        #pragma unroll
        for (int j = 0; j < 8; j++) {
          unsigned k = okey16(v[j]);
          if ((k >> 5) == T1) atomicAdd(&h2[k & 31], 1u);
        }
      }
      __syncthreads();
      if (t == 0) {
        unsigned cum = 0; int T3 = 0; unsigned above = 0;
        for (int j = 31; j >= 0; j--) {
          if (cum + h2[j] >= need2) { T3 = j; above = cum; break; }
          cum += h2[j];
        }
        sL = (T1 << 5) | (unsigned)T3;
        sneedEq = need2 - above;
        scntEq = h2[T3];
      }
      __syncthreads();
      L = sL;
      if (scntEq != sneedEq) {
        const unsigned short* rowp = simsb + (size_t)n * Mn;
        unsigned cntLoc = 0;
        for (int j = 0; j < 64; j++)
          if (okey16(rowp[t * 64 + j]) == L) cntLoc++;
        unsigned pre = blk_exscan16(cntLoc, wsum, lane, wid);
        unsigned c = 0;
        for (int j = 0; j < 64; j++)
          if (okey16(rowp[t * 64 + j]) == L) { if (pre + c < 32) slist[pre + c] = t * 64 + j; c++; }
        __syncthreads();
        istar = (unsigned)slist[sneedEq - 1];
        __syncthreads();
      }
    }
    __syncthreads();
    unsigned cnt = 0;
    for (int p = 0; p < 8; p++) {
      u16x8 v = row8[p * 1024 + t];
      unsigned i0 = (unsigned)(p * 1024 + t) * 8;
      #pragma unroll
      for (int j = 0; j < 8; j++) {
        unsigned k = okey16(v[j]);
        cnt += (k > L || (k == L && i0 + j <= istar));
      }
    }
    unsigned pos = blk_exscan16(cnt, wsum, lane, wid);
    for (int p = 0; p < 8; p++) {
      u16x8 v = row8[p * 1024 + t];
      unsigned i0 = (unsigned)(p * 1024 + t) * 8;
      #pragma unroll
      for (int j = 0; j < 8; j++) {
        unsigned k = okey16(v[j]);
        if (k > L || (k == L && i0 + j <= istar)) oidx[n * Kt + pos++] = (int)(i0 + j);
      }
    }
  }
}

// =============================== host ===============================
extern "C" void kernel_launch(void* const* d_in, const int* in_sizes, int n_in,
                              void* d_out, int out_size, void* d_ws, size_t ws_size,
                              hipStream_t stream) {
  (void)in_sizes; (void)n_in; (void)out_size;
  const float* x      = (const float*)d_in[0];
  const float* mem_k  = (const float*)d_in[1];
  const float* mem_v  = (const float*)d_in[2];
  const float* sa_w[4] = {(const float*)d_in[3], (const float*)d_in[4], (const float*)d_in[5], (const float*)d_in[6]};
  const float* sa_b[4] = {(const float*)d_in[7], (const float*)d_in[8], (const float*)d_in[9], (const float*)d_in[10]};
  const float* ma_w[4] = {(const float*)d_in[11], (const float*)d_in[12], (const float*)d_in[13], (const float*)d_in[14]};
  const float* ma_b[4] = {(const float*)d_in[15], (const float*)d_in[16], (const float*)d_in[17], (const float*)d_in[18]};
  const float* ln_g[3] = {(const float*)d_in[19], (const float*)d_in[21], (const float*)d_in[23]};
  const float* ln_b[3] = {(const float*)d_in[20], (const float*)d_in[22], (const float*)d_in[24]};
  const float* fc1_w = (const float*)d_in[25];
  const float* fc1_b = (const float*)d_in[26];
  const float* fc2_w = (const float*)d_in[27];
  const float* fc2_b = (const float*)d_in[28];
  float* out = (float*)d_out;

  char* ws = (char*)d_ws;
  size_t off = 0;
  auto alloc = [&](size_t bytes) -> char* {
    char* p = ws + off;
    off = (off + bytes + 255) & ~(size_t)255;
    return p;
  };

  unsigned short* wt[8];
  for (int i = 0; i < 8; i++) wt[i] = (unsigned short*)alloc((size_t)En * En * 2);  // contiguous
  unsigned short* fc1t  = (unsigned short*)alloc((size_t)FFn * En * 2);
  unsigned short* fc2t  = (unsigned short*)alloc((size_t)En * FFn * 2);
  unsigned short* xb    = (unsigned short*)alloc((size_t)NT * En * 2);
  unsigned short* Qb    = (unsigned short*)alloc((size_t)NT * En * 2);
  unsigned short* Kb    = (unsigned short*)alloc((size_t)NT * En * 2);
  unsigned short* Vb    = (unsigned short*)alloc((size_t)NT * En * 2);
  unsigned short* at1b  = (unsigned short*)alloc((size_t)NT * En * 2);
  float*          t1    = (float*)alloc((size_t)NT * En * 4);
  float*          x1f   = (float*)alloc((size_t)NT * En * 4);
  unsigned short* x1b   = (unsigned short*)alloc((size_t)NT * En * 2);
  char*           simsRaw = alloc((size_t)NT * Mn * 4);                // 256 MiB region
  int*            idx   = (int*)alloc((size_t)NT * Kt * 4);
  unsigned short* K2b   = (unsigned short*)alloc((size_t)NT * Kt * En * 2);  // 64 MiB
  unsigned short* V2b   = (unsigned short*)alloc((size_t)NT * Kt * En * 2);  // V2t: [B][1024][8192]
  unsigned short* Q2b   = (unsigned short*)alloc((size_t)NT * En * 2);
  unsigned short* at2b  = (unsigned short*)alloc((size_t)NT * En * 2);
  float*          t2    = (float*)alloc((size_t)NT * En * 4);
  float*          x2f   = (float*)alloc((size_t)NT * En * 4);
  unsigned short* x2b   = (unsigned short*)alloc((size_t)NT * En * 2);
  unsigned short* hb    = (unsigned short*)alloc((size_t)NT * FFn * 2);
  float*          t3    = (float*)alloc((size_t)NT * En * 4);
  float*          bcat_sa = (float*)alloc(3072 * 4);
  float*          bcat_ma = (float*)alloc(2048 * 4);

  if (off > ws_size) return;   // insufficient workspace: leave output poisoned (fail loudly)

  // Overlays within the 256 MiB sims region (uses strictly sequential):
  unsigned short* simsb = (unsigned short*)simsRaw;
  unsigned short* mkb = (unsigned short*)K2b;         // until sims GEMM done
  unsigned short* Ab2 = (unsigned short*)(simsRaw + (size_t)128 * 1024 * 1024);
  unsigned short* PO  = (unsigned short*)(simsRaw + (size_t)192 * 1024 * 1024);
  float* PM = (float*)(simsRaw + (size_t)224 * 1024 * 1024);
  float* PL = (float*)(simsRaw + (size_t)225 * 1024 * 1024);

  (void)hipFuncSetAttribute((const void*)&k_gemm256<5,false,1,0>,
                            hipFuncAttributeMaxDynamicSharedMemorySize, 131072);
  (void)hipFuncSetAttribute((const void*)&k_gemm256<6,false,2,1>,
                            hipFuncAttributeMaxDynamicSharedMemorySize, 131072);

  // ---- prep: weight transposes to bf16 [N][K], bias concats ----
  P8 p8;
  for (int i = 0; i < 4; i++) { p8.s[i] = sa_w[i]; p8.s[4 + i] = ma_w[i]; }
  k_transpose8<<<dim3(16, 16, 8), 256, 0, stream>>>(p8, wt[0]);
  k_transpose_bf16<<<dim3(64, 16), 256, 0, stream>>>(fc1_w, fc1t, En, FFn);
  k_transpose_bf16<<<dim3(16, 64), 256, 0, stream>>>(fc2_w, fc2t, FFn, En);
  k_concat3<<<dim3(12), 256, 0, stream>>>(sa_b[0], sa_b[1], sa_b[2], bcat_sa);
  k_concat3<<<dim3(8),  256, 0, stream>>>(ma_b[1], ma_b[2], ma_b[2], bcat_ma);

  k_cvt_bf16<<<dim3(NT * En / 4 / 256), 256, 0, stream>>>(x, xb, NT * En / 4);
  k_normcvt<<<dim3(Mn), 256, 0, stream>>>(mem_k, mkb);

  const dim3 g1(En / 128, NT / 128);   // (8,8)

  // ---- self-attention (QKV fused, Q pre-scaled by 1/8) ----
  k_gemm<0,false,false,3,true><<<dim3(24, 8), 256, 0, stream>>>(xb, wt[0], nullptr, bcat_sa, nullptr, nullptr, Qb, Kb, Vb, 3072, En);
  k_attn_sa<<<dim3(Sn / 64, Hn, Bn), 256, 0, stream>>>(Qb, Kb, Vb, at1b, Sn);
  k_gemm<1,false,false,1,false><<<g1, 256, 0, stream>>>(at1b, wt[3], nullptr, sa_b[3], x, t1, nullptr, nullptr, nullptr, En, En);
  k_layernorm<<<NT, 256, 0, stream>>>(t1, ln_g[0], ln_b[0], x1f, x1b);

  // ---- retrieval: sims in bf16 + sampled-threshold top-k ----
  k_gemm256<5,false,1,0><<<dim3(1024), 512, 131072, stream>>>(
      x1b, mkb, nullptr, nullptr, nullptr, simsb, nullptr, Mn, En, NT / 256, Mn / 256);
  k_topk16<<<NT, 1024, 0, stream>>>(simsb, idx);

  // ---- memory cross-attention ----
  k_gathercvt<<<dim3(NT * Kt), 256, 0, stream>>>(mem_v, idx, Ab2);
  k_gemm256<6,false,2,1><<<dim3(1024), 512, 131072, stream>>>(
      Ab2, wt[5], nullptr, bcat_ma, nullptr, K2b, V2b, 2048, En, NT * Kt / 256, 2048 / 256);
  k_gemm<0,false,false,1,true><<<g1, 256, 0, stream>>>(x1b, wt[4], nullptr, ma_b[0], nullptr, nullptr, Q2b, nullptr, nullptr, En, En);
  k_attn_ma<<<dim3(16, Hn, Bn), 256, 0, stream>>>(Q2b, K2b, V2b, PO, PM, PL);
  k_attn_comb16<<<dim3(Bn * Hn * Sn / 4), 256, 0, stream>>>(PO, PM, PL, at2b);
  k_gemm<1,false,false,1,false><<<g1, 256, 0, stream>>>(at2b, wt[7], nullptr, ma_b[3], x1f, t2, nullptr, nullptr, nullptr, En, En);
  k_layernorm<<<NT, 256, 0, stream>>>(t2, ln_g[1], ln_b[1], x2f, x2b);

  // ---- FFN ----
  k_gemm<2,false,false,1,false><<<dim3(FFn / 128, NT / 128), 256, 0, stream>>>(x2b, fc1t, nullptr, fc1_b, nullptr, nullptr, hb, nullptr, nullptr, FFn, En);
  k_gemm<1,false,false,1,false><<<g1, 256, 0, stream>>>(hb, fc2t, nullptr, fc2_b, x2f, t3, nullptr, nullptr, nullptr, En, FFn);
  k_layernorm<<<NT, 256, 0, stream>>>(t3, ln_g[2], ln_b[2], out, nullptr);
}

// Round 14
// 885.382 us; speedup vs baseline: 1.4455x; 1.0265x over previous
//
#include <hip/hip_runtime.h>
#include <hip/hip_bf16.h>
#include <math.h>

#define DEVFN __device__ __forceinline__

typedef __attribute__((ext_vector_type(8))) short bf16x8;
typedef __attribute__((ext_vector_type(8))) unsigned short u16x8;
typedef __attribute__((ext_vector_type(4))) unsigned short u16x4;
typedef __attribute__((ext_vector_type(4))) float f32x4;

static constexpr int Bn = 4, Sn = 256, En = 1024, Hn = 16;
static constexpr int Mn = 65536, Kt = 32, FFn = 4096;
static constexpr int NT = Bn * Sn;           // 1024 tokens

DEVFN unsigned short f2b(float f) {          // f32 -> bf16 RNE
  unsigned int u = __float_as_uint(f);
  unsigned int r = (u + 0x7FFFu + ((u >> 16) & 1u)) >> 16;
  return (unsigned short)r;
}
DEVFN float b2f(unsigned short u) { return __uint_as_float((unsigned)u << 16); }

DEVFN unsigned okey16(unsigned short u) {    // order-preserving bf16 -> u16
  return (unsigned)(u ^ ((u >> 15) ? 0xFFFFu : 0x8000u)) & 0xFFFFu;
}

typedef const __attribute__((address_space(1))) void* as1cv_t;
typedef __attribute__((address_space(3))) void* as3v_t;
DEVFN void gload16(const void* g, void* l) {   // async global->LDS, 16B/lane
  __builtin_amdgcn_global_load_lds((as1cv_t)g, (as3v_t)l, 16, 0, 0);
}
#define MEMFENCE asm volatile("" ::: "memory")

struct P8 { const float* s[8]; };

// ---------------- batched transpose W[1024][1024] f32 -> out[C][R] bf16 ----------------
__global__ __launch_bounds__(256) void k_transpose8(
    P8 ps, unsigned short* __restrict__ outbase) {
  const float* in = ps.s[blockIdx.z];
  unsigned short* out = outbase + (size_t)blockIdx.z * En * En;
  __shared__ float tile[64][65];
  int tx = threadIdx.x & 63, ty = threadIdx.x >> 6;
  int c0 = blockIdx.x * 64, r0 = blockIdx.y * 64;
  #pragma unroll
  for (int i = 0; i < 16; i++) {
    int r = ty + i * 4;
    tile[tx][r] = in[(size_t)(r0 + r) * En + (c0 + tx)];
  }
  __syncthreads();
  #pragma unroll
  for (int i = 0; i < 16; i++) {
    int c = ty + i * 4;
    out[(size_t)(c0 + c) * En + (r0 + tx)] = f2b(tile[c][tx]);
  }
}

// ---------------- transpose W[R][C] f32 -> out[C][R] bf16 ----------------
__global__ __launch_bounds__(256) void k_transpose_bf16(
    const float* __restrict__ in, unsigned short* __restrict__ out, int R, int C) {
  __shared__ float tile[64][65];
  int tx = threadIdx.x & 63, ty = threadIdx.x >> 6;
  int c0 = blockIdx.x * 64, r0 = blockIdx.y * 64;
  #pragma unroll
  for (int i = 0; i < 16; i++) {
    int r = ty + i * 4;
    tile[tx][r] = in[(size_t)(r0 + r) * C + (c0 + tx)];
  }
  __syncthreads();
  #pragma unroll
  for (int i = 0; i < 16; i++) {
    int c = ty + i * 4;
    out[(size_t)(c0 + c) * R + (r0 + tx)] = f2b(tile[c][tx]);
  }
}

// ---------------- f32 -> bf16 elementwise (x4) ----------------
__global__ __launch_bounds__(256) void k_cvt_bf16(
    const float* __restrict__ in, unsigned short* __restrict__ out, int n4) {
  int i = blockIdx.x * 256 + threadIdx.x;
  if (i >= n4) return;
  float4 v = ((const float4*)in)[i];
  uint2 o;
  o.x = (unsigned int)f2b(v.x) | ((unsigned int)f2b(v.y) << 16);
  o.y = (unsigned int)f2b(v.z) | ((unsigned int)f2b(v.w) << 16);
  ((uint2*)out)[i] = o;
}

// ---- gather + cvt: out[r] = bf16(mem_v[idx[r]]), one 4KB row per block ----
__global__ __launch_bounds__(256) void k_gathercvt(
    const float* __restrict__ mv, const int* __restrict__ idx,
    unsigned short* __restrict__ out) {
  int r = blockIdx.x;
  int src = idx[r];
  float4 v = ((const float4*)(mv + (size_t)src * En))[threadIdx.x];
  uint2 o;
  o.x = (unsigned int)f2b(v.x) | ((unsigned int)f2b(v.y) << 16);
  o.y = (unsigned int)f2b(v.z) | ((unsigned int)f2b(v.w) << 16);
  ((uint2*)(out + (size_t)r * En))[threadIdx.x] = o;
}

// ---------------- concat up to 3 x 1024-f32 vectors ----------------
__global__ __launch_bounds__(256) void k_concat3(
    const float* __restrict__ a, const float* __restrict__ b,
    const float* __restrict__ c, float* __restrict__ o) {
  int i = blockIdx.x * 256 + threadIdx.x;
  float v = (i < 1024) ? a[i] : (i < 2048) ? b[i - 1024] : c[i - 2048];
  o[i] = v;
}

// ---- mem_keys row-normalize + cvt to bf16 (folds cosine norm into B) ----
__global__ __launch_bounds__(256) void k_normcvt(
    const float* __restrict__ mk, unsigned short* __restrict__ out) {
  int m = blockIdx.x, t = threadIdx.x;
  float4 v = ((const float4*)(mk + (size_t)m * En))[t];
  float ss = v.x*v.x + v.y*v.y + v.z*v.z + v.w*v.w;
  #pragma unroll
  for (int d = 32; d; d >>= 1) ss += __shfl_down(ss, d);
  __shared__ float red[4];
  int lane = t & 63, w = t >> 6;
  if (lane == 0) red[w] = ss;
  __syncthreads();
  float rs = 1.0f / fmaxf(sqrtf(red[0] + red[1] + red[2] + red[3]), 1e-12f);
  uint2 o;
  o.x = (unsigned int)f2b(v.x * rs) | ((unsigned int)f2b(v.y * rs) << 16);
  o.y = (unsigned int)f2b(v.z * rs) | ((unsigned int)f2b(v.w * rs) << 16);
  ((uint2*)(out + (size_t)m * En))[t] = o;
}

// ---------------- LayerNorm over rows of [NT][En] ----------------
__global__ __launch_bounds__(256) void k_layernorm(
    const float* __restrict__ in, const float* __restrict__ g, const float* __restrict__ bb,
    float* __restrict__ outf, unsigned short* __restrict__ outb) {
  int n = blockIdx.x, t = threadIdx.x;
  float4 v = ((const float4*)(in + (size_t)n * En))[t];
  float s  = v.x + v.y + v.z + v.w;
  float s2 = v.x*v.x + v.y*v.y + v.z*v.z + v.w*v.w;
  #pragma unroll
  for (int d = 32; d; d >>= 1) { s += __shfl_down(s, d); s2 += __shfl_down(s2, d); }
  __shared__ float rs[4], rq[4];
  int lane = t & 63, w = t >> 6;
  if (lane == 0) { rs[w] = s; rq[w] = s2; }
  __syncthreads();
  float mean = (rs[0]+rs[1]+rs[2]+rs[3]) * (1.0f/En);
  float var  = (rq[0]+rq[1]+rq[2]+rq[3]) * (1.0f/En) - mean*mean;
  float rstd = rsqrtf(var + 1e-5f);
  float4 gg = ((const float4*)g)[t];
  float4 bv = ((const float4*)bb)[t];
  float o0 = (v.x-mean)*rstd*gg.x + bv.x;
  float o1 = (v.y-mean)*rstd*gg.y + bv.y;
  float o2 = (v.z-mean)*rstd*gg.z + bv.z;
  float o3 = (v.w-mean)*rstd*gg.w + bv.w;
  if (outf) { float4 ov = {o0,o1,o2,o3}; ((float4*)(outf + (size_t)n*En))[t] = ov; }
  if (outb) {
    uint2 o;
    o.x = (unsigned int)f2b(o0) | ((unsigned int)f2b(o1) << 16);
    o.y = (unsigned int)f2b(o2) | ((unsigned int)f2b(o3) << 16);
    ((uint2*)(outb + (size_t)n*En))[t] = o;
  }
}

// ======== 256x256 GEMM, ring-4 half-tile buffers + counted vmcnt ========
// Minimal-barrier schedule: ONE boundary barrier per half-tile (correctness-audited:
// staging target buf[(hs+3)%4]=buf[hs-1] whose reads completed before boundary hs-1).
// EPI 4: f32 out | EPI 5: bf16 no-bias | EPI 0 + NOUT2: bf16 (+bias), split N
// EPI 6: split N=2048 -> cb0 row-major (+bias), cb1 TRANSPOSED [B][1024][8192] (+bias)
template<int EPI, bool AGATHER, int NOUT, int LSWZ>
__global__ __launch_bounds__(512) void k_gemm256(
    const unsigned short* __restrict__ Ab, const unsigned short* __restrict__ Bb,
    const int* __restrict__ gidx, const float* __restrict__ bias,
    float* __restrict__ Cf, unsigned short* __restrict__ cb0, unsigned short* __restrict__ cb1,
    int Ndim, int Kdim, int nRT, int nCT) {
  extern __shared__ unsigned short lds[];
  const int t = threadIdx.x, lane = t & 63, w = t >> 6;
  const int wr = w >> 2, wc = w & 3, l15 = lane & 15, l4 = lane >> 4;
  const int lr2 = lane >> 2;
  const int cg  = (lane & 3) ^ (((lane >> 5) & 1) << 1);   // source pre-swizzle (involution)

  const int nwg = nRT * nCT;
  int lb = ((int)blockIdx.x % 8) * (nwg >> 3) + ((int)blockIdx.x >> 3);
  int rowT, colT;
  if (LSWZ == 0) { rowT = lb % nRT; colT = lb / nRT; }
  else           { colT = lb % nCT; rowT = lb / nCT; }
  const int row0 = rowT * 256, col0 = colT * 256;

  auto pa = [&](int h) -> unsigned short* { return lds + h * 16384; };
  auto pb = [&](int h) -> unsigned short* { return lds + h * 16384 + 8192; };

  const unsigned short *aSrc0, *aSrc1;
  if constexpr (AGATHER) {
    aSrc0 = Ab + (size_t)gidx[row0 + w * 32 + lr2] * Kdim + cg * 8;
    aSrc1 = Ab + (size_t)gidx[row0 + w * 32 + 16 + lr2] * Kdim + cg * 8;
  } else {
    aSrc0 = Ab + (size_t)(row0 + w * 32 + lr2) * Kdim + cg * 8;
    aSrc1 = aSrc0 + (size_t)16 * Kdim;
  }
  const unsigned short* bSrc0 = Bb + (size_t)(col0 + w * 32 + lr2) * Kdim + cg * 8;
  const unsigned short* bSrc1 = bSrc0 + (size_t)16 * Kdim;

  f32x4 acc[8][4];
  #pragma unroll
  for (int i = 0; i < 8; i++)
    #pragma unroll
    for (int j = 0; j < 4; j++) acc[i][j] = (f32x4){0.f, 0.f, 0.f, 0.f};

  const int NH = Kdim >> 5;                 // K half-tiles of 32
  #pragma unroll
  for (int h = 0; h < 3; ++h) {
    const int ko = h * 32;
    gload16(aSrc0 + ko, pa(h) + w*32*32);
    gload16(aSrc1 + ko, pa(h) + (w*32+16)*32);
    gload16(bSrc0 + ko, pb(h) + w*32*32);
    gload16(bSrc1 + ko, pb(h) + (w*32+16)*32);
  }
  asm volatile("s_waitcnt vmcnt(8)" ::: "memory");   // half 0 landed
  __builtin_amdgcn_s_barrier();
  MEMFENCE;

  for (int hs = 0; hs < NH; ++hs) {
    const int cur = hs & 3;
    const unsigned short* Ap = pa(cur);
    const unsigned short* Bp = pb(cur);
    const int h3 = (hs + 3) & 3, ko3 = (hs + 3) * 32;
    const bool pf = (hs + 3) < NH;
    bf16x8 bfr[4], af[4];

    // ---- cluster 0: B frags + A rows 0..63, stage A pair ----
    #pragma unroll
    for (int ni = 0; ni < 4; ni++) {
      int row = wc * 64 + ni * 16 + l15;
      int c8 = l4 ^ (((row >> 3) & 1) << 1);
      bfr[ni] = *(const bf16x8*)&Bp[row * 32 + c8 * 8];
    }
    #pragma unroll
    for (int m = 0; m < 4; m++) {
      int row = wr * 128 + m * 16 + l15;
      int c8 = l4 ^ (((row >> 3) & 1) << 1);
      af[m] = *(const bf16x8*)&Ap[row * 32 + c8 * 8];
    }
    if (pf) {
      gload16(aSrc0 + ko3, pa(h3) + w*32*32);
      gload16(aSrc1 + ko3, pa(h3) + (w*32+16)*32);
    }
    __builtin_amdgcn_s_setprio(1);
    #pragma unroll
    for (int m = 0; m < 4; m++)
      #pragma unroll
      for (int ni = 0; ni < 4; ni++)
        acc[m][ni] = __builtin_amdgcn_mfma_f32_16x16x32_bf16(af[m], bfr[ni], acc[m][ni], 0, 0, 0);
    __builtin_amdgcn_s_setprio(0);

    // ---- cluster 1: A rows 64..127, stage B pair ----
    #pragma unroll
    for (int m = 0; m < 4; m++) {
      int row = wr * 128 + (4 + m) * 16 + l15;
      int c8 = l4 ^ (((row >> 3) & 1) << 1);
      af[m] = *(const bf16x8*)&Ap[row * 32 + c8 * 8];
    }
    if (pf) {
      gload16(bSrc0 + ko3, pb(h3) + w*32*32);
      gload16(bSrc1 + ko3, pb(h3) + (w*32+16)*32);
    }
    __builtin_amdgcn_s_setprio(1);
    #pragma unroll
    for (int m = 0; m < 4; m++)
      #pragma unroll
      for (int ni = 0; ni < 4; ni++)
        acc[4 + m][ni] = __builtin_amdgcn_mfma_f32_16x16x32_bf16(af[m], bfr[ni], acc[4 + m][ni], 0, 0, 0);
    __builtin_amdgcn_s_setprio(0);

    // ---- boundary: counted wait for half hs+1, single barrier per half-tile ----
    if (hs + 1 < NH) {
      const int rem = NH - 2 - hs;
      if (rem >= 2)      asm volatile("s_waitcnt vmcnt(8)" ::: "memory");
      else if (rem == 1) asm volatile("s_waitcnt vmcnt(4)" ::: "memory");
      else               asm volatile("s_waitcnt vmcnt(0)" ::: "memory");
      __builtin_amdgcn_s_barrier();
      MEMFENCE;
    }
  }

  #pragma unroll
  for (int m = 0; m < 8; m++) {
    #pragma unroll
    for (int ni = 0; ni < 4; ni++) {
      int col  = col0 + wc * 64 + ni * 16 + l15;
      int rowb = row0 + wr * 128 + m * 16 + l4 * 4;
      if constexpr (EPI == 6) {
        if (col < 1024) {
          #pragma unroll
          for (int r = 0; r < 4; r++)
            cb0[(size_t)(rowb + r) * 1024 + col] = f2b(acc[m][ni][r] + bias[col]);
        } else {
          int c = col - 1024;
          int bi = rowb >> 13, k0 = rowb & 8191;
          u16x4 o;
          #pragma unroll
          for (int r = 0; r < 4; r++) o[r] = f2b(acc[m][ni][r] + bias[col]);
          *(u16x4*)&cb1[((size_t)bi * 1024 + c) * 8192 + k0] = o;
        }
      } else {
        #pragma unroll
        for (int r = 0; r < 4; r++) {
          float v = acc[m][ni][r];
          if constexpr (EPI == 4) {
            Cf[(size_t)(rowb + r) * Ndim + col] = v;
          } else if constexpr (EPI == 5) {
            cb0[(size_t)(rowb + r) * Ndim + col] = f2b(v);
          } else {
            unsigned short* cb = (col >> 10) ? cb1 : cb0;
            cb[(size_t)(rowb + r) * 1024 + (col & 1023)] = f2b(v + bias[col]);
          }
        }
      }
    }
  }
}

// ---------------- GEMM 128x128 (2-phase) for the small GEMMs ----------------
// QSC: scale output by 0.125 (Q pre-scale; NOUT>1: only the first 1024 cols)
template<int EPI, bool AGATHER, bool SWAPG, int NOUT, bool QSC>
__global__ __launch_bounds__(256) void k_gemm(
    const unsigned short* __restrict__ Ab, const unsigned short* __restrict__ Bb,
    const int* __restrict__ gidx,
    const float* __restrict__ bias, const float* __restrict__ resid,
    float* __restrict__ Cf, unsigned short* __restrict__ cb0,
    unsigned short* __restrict__ cb1, unsigned short* __restrict__ cb2,
    int Ndim, int Kdim) {
  __shared__ unsigned short As[128][32];
  __shared__ unsigned short Bs[128][32];
  const int t = threadIdx.x, lane = t & 63, w = t >> 6;
  const int wr = w >> 1, wc = w & 1, l15 = lane & 15, l4 = lane >> 4;
  const int row0 = (SWAPG ? blockIdx.x : blockIdx.y) * 128;
  const int col0 = (SWAPG ? blockIdx.y : blockIdx.x) * 128;
  const int c8  = (lane & 3) * 8;
  const int r16 = lane >> 2;
  const int rA0 = w * 32 + r16, rA1 = rA0 + 16;

  size_t raA0, raA1, raB0, raB1;
  if constexpr (AGATHER) {
    raA0 = (size_t)gidx[row0 + rA0] * Kdim;
    raA1 = (size_t)gidx[row0 + rA1] * Kdim;
  } else {
    raA0 = (size_t)(row0 + rA0) * Kdim;
    raA1 = (size_t)(row0 + rA1) * Kdim;
  }
  raB0 = (size_t)(col0 + rA0) * Kdim;
  raB1 = (size_t)(col0 + rA1) * Kdim;

  f32x4 acc[4][4];
  #pragma unroll
  for (int i = 0; i < 4; i++)
    #pragma unroll
    for (int j = 0; j < 4; j++) acc[i][j] = (f32x4){0.f,0.f,0.f,0.f};

  for (int kt0 = 0; kt0 < Kdim; kt0 += 32) {
    __syncthreads();
    gload16(Ab + raA0 + kt0 + c8, &As[w * 32][0]);
    gload16(Ab + raA1 + kt0 + c8, &As[w * 32 + 16][0]);
    gload16(Bb + raB0 + kt0 + c8, &Bs[w * 32][0]);
    gload16(Bb + raB1 + kt0 + c8, &Bs[w * 32 + 16][0]);
    __syncthreads();
    bf16x8 af[4], bfr[4];
    #pragma unroll
    for (int mi = 0; mi < 4; mi++) af[mi]  = *(const bf16x8*)&As[wr*64 + mi*16 + l15][l4*8];
    #pragma unroll
    for (int ni = 0; ni < 4; ni++) bfr[ni] = *(const bf16x8*)&Bs[wc*64 + ni*16 + l15][l4*8];
    #pragma unroll
    for (int mi = 0; mi < 4; mi++)
      #pragma unroll
      for (int ni = 0; ni < 4; ni++)
        acc[mi][ni] = __builtin_amdgcn_mfma_f32_16x16x32_bf16(af[mi], bfr[ni], acc[mi][ni], 0, 0, 0);
  }

  unsigned short* cbase = cb0;
  int colsub = 0;
  float qsc = 1.0f;
  if constexpr (NOUT > 1) {
    int which = col0 >> 10;
    cbase = (which == 0) ? cb0 : (which == 1) ? cb1 : cb2;
    colsub = col0 & 1023;
    if (QSC && which == 0) qsc = 0.125f;
  } else if constexpr (QSC) {
    qsc = 0.125f;
  }

  #pragma unroll
  for (int mi = 0; mi < 4; mi++) {
    #pragma unroll
    for (int ni = 0; ni < 4; ni++) {
      int col  = col0 + wc*64 + ni*16 + l15;
      int rowb = row0 + wr*64 + mi*16 + l4*4;
      #pragma unroll
      for (int r = 0; r < 4; r++) {
        float v = acc[mi][ni][r];
        size_t off = (size_t)(rowb + r) * Ndim + col;
        if constexpr (EPI == 0) {
          if constexpr (NOUT > 1) {
            int c2 = colsub + wc*64 + ni*16 + l15;
            cbase[(size_t)(rowb + r) * 1024 + c2] = f2b((v + bias[col]) * qsc);
          } else {
            cb0[off] = f2b((v + bias[col]) * qsc);
          }
        } else if constexpr (EPI == 1) {
          Cf[off] = v + bias[col] + resid[off];
        } else if constexpr (EPI == 2) {
          float u = v + bias[col];
          u = 0.5f * u * (1.0f + erff(u * 0.70710678118654752f));
          cb0[off] = f2b(u);
        } else {
          Cf[off] = v;
        }
      }
    }
  }
}

// ---------------- SA fused attention (Q pre-scaled, T13 defer-max, deferred l) --------
__global__ __launch_bounds__(256) void k_attn_sa(
    const unsigned short* __restrict__ Qp, const unsigned short* __restrict__ Kp,
    const unsigned short* __restrict__ Vp, unsigned short* __restrict__ Op, int Lk) {
  __shared__ unsigned short Ks[64][72];
  __shared__ unsigned short Vt[64][72];
  __shared__ float Ps[4][16][68];
  const int b = blockIdx.z;
  const int h = blockIdx.y, q0 = blockIdx.x * 64;
  const int t = threadIdx.x, lane = t & 63, w = t >> 6;
  const int l15 = lane & 15, l4 = lane >> 4;

  const int qrow = q0 + w * 16 + l15;
  const unsigned short* qptr = Qp + (size_t)(b * Sn + qrow) * En + h * 64 + l4 * 8;
  bf16x8 qf0 = *(const bf16x8*)qptr;
  bf16x8 qf1 = *(const bf16x8*)(qptr + 32);

  f32x4 oacc[4];
  #pragma unroll
  for (int i = 0; i < 4; i++) oacc[i] = (f32x4){0.f,0.f,0.f,0.f};
  float m_[4] = {-INFINITY, -INFINITY, -INFINITY, -INFINITY};
  float l_[4] = {0.f, 0.f, 0.f, 0.f};

  const int nkt = Lk / 64;
  for (int kt = 0; kt < nkt; ++kt) {
    __syncthreads();
    #pragma unroll
    for (int i = 0; i < 2; i++) {
      int ld = t + i * 256;
      int kr = ld >> 3, d8 = (ld & 7) * 8;
      size_t base = (size_t)(b * Lk + kt * 64 + kr) * En + h * 64 + d8;
      *(uint4*)&Ks[kr][d8] = *(const uint4*)(Kp + base);
      bf16x8 vv = *(const bf16x8*)(Vp + base);
      int colswz = kr ^ ((t & 7) << 3);
      #pragma unroll
      for (int j = 0; j < 8; j++) Vt[d8 + j][colswz] = ((unsigned short*)&vv)[j];
    }
    __syncthreads();

    f32x4 s[4];
    #pragma unroll
    for (int ni = 0; ni < 4; ni++) {
      s[ni] = (f32x4){0.f,0.f,0.f,0.f};
      bf16x8 kb0 = *(const bf16x8*)&Ks[ni*16 + l15][l4*8];
      bf16x8 kb1 = *(const bf16x8*)&Ks[ni*16 + l15][l4*8 + 32];
      s[ni] = __builtin_amdgcn_mfma_f32_16x16x32_bf16(qf0, kb0, s[ni], 0, 0, 0);
      s[ni] = __builtin_amdgcn_mfma_f32_16x16x32_bf16(qf1, kb1, s[ni], 0, 0, 0);
    }

    #pragma unroll
    for (int r = 0; r < 4; r++) {
      float mx = fmaxf(fmaxf(s[0][r], s[1][r]), fmaxf(s[2][r], s[3][r]));
      #pragma unroll
      for (int d2 = 1; d2 < 16; d2 <<= 1) mx = fmaxf(mx, __shfl_xor(mx, d2));
      float m = m_[r];
      if (mx > m + 8.f) {                    // T13: rescale only on large jump
        float alpha = __expf(m - mx);
        l_[r] *= alpha;
        #pragma unroll
        for (int nd = 0; nd < 4; nd++) oacc[nd][r] *= alpha;
        m = mx; m_[r] = mx;
      }
      float p0 = __expf(s[0][r] - m), p1 = __expf(s[1][r] - m);
      float p2 = __expf(s[2][r] - m), p3 = __expf(s[3][r] - m);
      s[0][r] = p0; s[1][r] = p1; s[2][r] = p2; s[3][r] = p3;
      l_[r] += (p0 + p1) + (p2 + p3);        // per-lane partial; reduce at end
    }

    #pragma unroll
    for (int ni = 0; ni < 4; ni++)
      #pragma unroll
      for (int r = 0; r < 4; r++)
        Ps[w][l4*4 + r][ni*16 + l15] = s[ni][r];
    asm volatile("s_waitcnt lgkmcnt(0)" ::: "memory");

    #pragma unroll
    for (int half = 0; half < 2; half++) {
      float4 pv0 = *(const float4*)&Ps[w][l15][half*32 + l4*8];
      float4 pv1 = *(const float4*)&Ps[w][l15][half*32 + l4*8 + 4];
      bf16x8 pa;
      pa[0]=(short)f2b(pv0.x); pa[1]=(short)f2b(pv0.y); pa[2]=(short)f2b(pv0.z); pa[3]=(short)f2b(pv0.w);
      pa[4]=(short)f2b(pv1.x); pa[5]=(short)f2b(pv1.y); pa[6]=(short)f2b(pv1.z); pa[7]=(short)f2b(pv1.w);
      #pragma unroll
      for (int nd = 0; nd < 4; nd++) {
        int dd = nd*16 + l15;
        bf16x8 vb = *(const bf16x8*)&Vt[dd][(half*32 + l4*8) ^ (((dd >> 3) & 7) << 3)];
        oacc[nd] = __builtin_amdgcn_mfma_f32_16x16x32_bf16(pa, vb, oacc[nd], 0, 0, 0);
      }
    }
  }

  #pragma unroll
  for (int r = 0; r < 4; r++) {              // final 16-lane l reduce
    float lv = l_[r];
    #pragma unroll
    for (int d2 = 1; d2 < 16; d2 <<= 1) lv += __shfl_xor(lv, d2);
    l_[r] = lv;
  }
  #pragma unroll
  for (int nd = 0; nd < 4; nd++)
    #pragma unroll
    for (int r = 0; r < 4; r++) {
      int q = q0 + w*16 + l4*4 + r;
      Op[(size_t)(b * Sn + q) * En + h * 64 + nd*16 + l15] = f2b(oacc[nd][r] / l_[r]);
    }
}

// ------- MA attention: 4 q-tiles folded, SPLIT=16, dbuf VT staging, lean softmax -------
__global__ __launch_bounds__(256, 2) void k_attn_ma(
    const unsigned short* __restrict__ Qp, const unsigned short* __restrict__ Kp,
    const unsigned short* __restrict__ Vp,
    unsigned short* __restrict__ PO, float* __restrict__ PM, float* __restrict__ PL) {
  constexpr int Lk = Sn * Kt;            // 8192
  constexpr int NTI = 8;                 // k-tiles per block (8192/64/16)
  __shared__ unsigned short Ks[2][64 * 64];
  __shared__ unsigned short Vt[2][64 * 64];
  __shared__ float Ps[4][16][68];
  const int sp = blockIdx.x, h = blockIdx.y, b = blockIdx.z;
  const int t = threadIdx.x, lane = t & 63, w = t >> 6;
  const int l15 = lane & 15, l4 = lane >> 4;
  const int l8 = lane >> 3, l7 = lane & 7;
  const int kswz = (l7 ^ l8) * 8;        // source pre-swizzle (row&7)
  const int rbase = w * 16;

  bf16x8 qf[4][2];
  #pragma unroll
  for (int qt = 0; qt < 4; qt++) {
    const unsigned short* qptr = Qp + (size_t)(b * Sn + w * 64 + qt * 16 + l15) * En + h * 64 + l4 * 8;
    qf[qt][0] = *(const bf16x8*)qptr;
    qf[qt][1] = *(const bf16x8*)(qptr + 32);
  }

  f32x4 oacc[4][4];
  #pragma unroll
  for (int i = 0; i < 4; i++)
    #pragma unroll
    for (int j = 0; j < 4; j++) oacc[i][j] = (f32x4){0.f,0.f,0.f,0.f};
  float m_[4][4], l_[4][4];
  #pragma unroll
  for (int i = 0; i < 4; i++)
    #pragma unroll
    for (int j = 0; j < 4; j++) { m_[i][j] = -INFINITY; l_[i][j] = 0.f; }

  const int kt0 = sp * NTI;
  auto stage = [&](int kt, int buf) {
    #pragma unroll
    for (int i = 0; i < 2; i++) {
      int row = rbase + i * 8 + l8;
      gload16(Kp + (size_t)(b * Lk + kt * 64 + row) * En + h * 64 + kswz,
              &Ks[buf][(rbase + i * 8) * 64]);
      gload16(Vp + ((size_t)b * 1024 + h * 64 + row) * (size_t)Lk + kt * 64 + kswz,
              &Vt[buf][(rbase + i * 8) * 64]);
    }
  };

  stage(kt0, 0);
  stage(kt0 + 1, 1);
  asm volatile("s_waitcnt vmcnt(4)" ::: "memory");   // tile0 landed (Q drained too)
  __builtin_amdgcn_s_barrier();
  MEMFENCE;

  for (int j = 0; j < NTI; ++j) {
    const int cur = j & 1;
    #pragma unroll
    for (int qt = 0; qt < 4; qt++) {
      f32x4 s[4];
      #pragma unroll
      for (int ni = 0; ni < 4; ni++) {
        s[ni] = (f32x4){0.f,0.f,0.f,0.f};
        int rowK = ni * 16 + l15, sw = (rowK & 7) * 8;
        bf16x8 kb0 = *(const bf16x8*)&Ks[cur][rowK * 64 + ((l4 * 8) ^ sw)];
        bf16x8 kb1 = *(const bf16x8*)&Ks[cur][rowK * 64 + ((l4 * 8 + 32) ^ sw)];
        s[ni] = __builtin_amdgcn_mfma_f32_16x16x32_bf16(qf[qt][0], kb0, s[ni], 0, 0, 0);
        s[ni] = __builtin_amdgcn_mfma_f32_16x16x32_bf16(qf[qt][1], kb1, s[ni], 0, 0, 0);
      }
      #pragma unroll
      for (int r = 0; r < 4; r++) {
        float mx = fmaxf(fmaxf(s[0][r], s[1][r]), fmaxf(s[2][r], s[3][r]));
        #pragma unroll
        for (int d2 = 1; d2 < 16; d2 <<= 1) mx = fmaxf(mx, __shfl_xor(mx, d2));
        float m = m_[qt][r];
        if (mx > m + 8.f) {                  // T13 defer-max
          float alpha = __expf(m - mx);
          l_[qt][r] *= alpha;
          #pragma unroll
          for (int nd = 0; nd < 4; nd++) oacc[qt][nd][r] *= alpha;
          m = mx; m_[qt][r] = mx;
        }
        float p0 = __expf(s[0][r] - m), p1 = __expf(s[1][r] - m);
        float p2 = __expf(s[2][r] - m), p3 = __expf(s[3][r] - m);
        s[0][r] = p0; s[1][r] = p1; s[2][r] = p2; s[3][r] = p3;
        l_[qt][r] += (p0 + p1) + (p2 + p3);  // per-lane partial
      }
      #pragma unroll
      for (int ni = 0; ni < 4; ni++)
        #pragma unroll
        for (int r = 0; r < 4; r++)
          Ps[w][l4*4 + r][ni*16 + l15] = s[ni][r];
      asm volatile("s_waitcnt lgkmcnt(0)" ::: "memory");
      #pragma unroll
      for (int half = 0; half < 2; half++) {
        float4 pv0 = *(const float4*)&Ps[w][l15][half*32 + l4*8];
        float4 pv1 = *(const float4*)&Ps[w][l15][half*32 + l4*8 + 4];
        bf16x8 pa;
        pa[0]=(short)f2b(pv0.x); pa[1]=(short)f2b(pv0.y); pa[2]=(short)f2b(pv0.z); pa[3]=(short)f2b(pv0.w);
        pa[4]=(short)f2b(pv1.x); pa[5]=(short)f2b(pv1.y); pa[6]=(short)f2b(pv1.z); pa[7]=(short)f2b(pv1.w);
        #pragma unroll
        for (int nd = 0; nd < 4; nd++) {
          int dd = nd*16 + l15;
          bf16x8 vb = *(const bf16x8*)&Vt[cur][dd * 64 + ((half*32 + l4*8) ^ ((dd & 7) * 8))];
          oacc[qt][nd] = __builtin_amdgcn_mfma_f32_16x16x32_bf16(pa, vb, oacc[qt][nd], 0, 0, 0);
        }
      }
    }
    MEMFENCE; __builtin_amdgcn_s_barrier(); MEMFENCE;
    if (j + 2 < NTI) stage(kt0 + j + 2, cur);
    if (j + 1 < NTI) {
      if (j + 2 < NTI) asm volatile("s_waitcnt vmcnt(4)" ::: "memory");
      else             asm volatile("s_waitcnt vmcnt(0)" ::: "memory");
      __builtin_amdgcn_s_barrier();
      MEMFENCE;
    }
  }

  #pragma unroll
  for (int qt = 0; qt < 4; qt++)             // final 16-lane l reduce
    #pragma unroll
    for (int r = 0; r < 4; r++) {
      float lv = l_[qt][r];
      #pragma unroll
      for (int d2 = 1; d2 < 16; d2 <<= 1) lv += __shfl_xor(lv, d2);
      l_[qt][r] = lv;
    }

  const int slot = (b * Hn + h) * 16 + sp;
  #pragma unroll
  for (int qt = 0; qt < 4; qt++)
    #pragma unroll
    for (int nd = 0; nd < 4; nd++)
      #pragma unroll
      for (int r = 0; r < 4; r++)
        PO[(size_t)slot * 16384 + (w*64 + qt*16 + l4*4 + r) * 64 + nd*16 + l15] = f2b(oacc[qt][nd][r]);
  if (l15 == 0) {
    #pragma unroll
    for (int qt = 0; qt < 4; qt++)
      #pragma unroll
      for (int r = 0; r < 4; r++) {
        PM[slot * 256 + w*64 + qt*16 + l4*4 + r] = m_[qt][r];
        PL[slot * 256 + w*64 + qt*16 + l4*4 + r] = l_[qt][r];
      }
  }
}

// ---------------- combine 16 split partials (bf16 PO, Q pre-scaled) ----------------
__global__ __launch_bounds__(256) void k_attn_comb16(
    const unsigned short* __restrict__ PO, const float* __restrict__ PM,
    const float* __restrict__ PL, unsigned short* __restrict__ Op) {
  const int W = blockIdx.x * 4 + (threadIdx.x >> 6);  // (bh, q) row
  const int lane = threadIdx.x & 63;
  const int bh = W >> 8, q = W & 255;
  const int slotBase = bh * 16;
  float ms[16];
  float M = -INFINITY;
  #pragma unroll
  for (int s = 0; s < 16; s++) { ms[s] = PM[(slotBase + s) * 256 + q]; M = fmaxf(M, ms[s]); }
  float L = 0.f, acc = 0.f;
  #pragma unroll
  for (int s = 0; s < 16; s++) {
    float wgt = __expf(ms[s] - M);
    L += PL[(slotBase + s) * 256 + q] * wgt;
    acc += wgt * b2f(PO[(size_t)(slotBase + s) * 16384 + q * 64 + lane]);
  }
  const int b = bh >> 4, h = bh & 15;
  Op[(size_t)(b * Sn + q) * En + h * 64 + lane] = f2b(acc / L);
}

// ------------- helpers for radix top-k (1024-thread blocks) -------------
DEVFN unsigned blk_exscan16(unsigned part, volatile unsigned* wsum, int lane, int wid) {
  unsigned v = part;
  #pragma unroll
  for (int d = 1; d < 64; d <<= 1) { unsigned o = __shfl_up(v, d); if (lane >= d) v += o; }
  if (lane == 63) wsum[wid] = v;
  __syncthreads();
  unsigned woff = 0;
  for (int i = 0; i < wid; i++) woff += wsum[i];
  unsigned r = woff + v - part;
  __syncthreads();
  return r;
}

DEVFN void find_thr16(const unsigned* hist, int NB, unsigned need,
                      int t, int lane, int wid, volatile unsigned* wsum,
                      volatile int* s_thr, volatile unsigned* s_above) {
  int per = NB >> 10;
  int lo = NB - per * (t + 1);
  unsigned part = 0;
  for (int j = 0; j < per; j++) part += hist[lo + j];
  unsigned ex = blk_exscan16(part, wsum, lane, wid);
  if (ex < need && ex + part >= need) {
    unsigned c = ex;
    for (int j = per - 1; j >= 0; j--) {
      unsigned h = hist[lo + j];
      if (c + h >= need) { *s_thr = lo + j; *s_above = c; break; }
      c += h;
    }
  }
  __syncthreads();
}

// ------- exact top-32: sampled threshold -> 1 compact pass -> in-LDS select -------
__global__ __launch_bounds__(1024) void k_topk16(
    const unsigned short* __restrict__ simsb, int* __restrict__ oidx) {
  const int n = blockIdx.x, t = threadIdx.x;
  const int lane = t & 63, wid = t >> 6;
  const u16x8* row8 = (const u16x8*)(simsb + (size_t)n * Mn);
  constexpr unsigned CAP = 2048;
  __shared__ unsigned hist[2048];
  __shared__ unsigned wsum[16];
  __shared__ int s_thr;
  __shared__ unsigned s_above;
  __shared__ unsigned h2[32];
  __shared__ unsigned s_cnt, s_na;
  __shared__ unsigned short ckey[CAP];
  __shared__ unsigned cidx[CAP];
  __shared__ int slist[32];
  __shared__ unsigned sL, sneedEq, scntEq, s_imin;

  for (int i = t; i < 2048; i += 1024) hist[i] = 0;
  if (t < 32) h2[t] = 0;
  if (t == 0) { s_cnt = 0; s_na = 0; }
  __syncthreads();

  // ---- sample pass: 1024 contiguous groups (16 KiB, middle of row) ----
  {
    u16x8 v = row8[3584 + t];
    #pragma unroll
    for (int j = 0; j < 8; j++) atomicAdd(&hist[okey16(v[j]) >> 5], 1u);
  }
  __syncthreads();
  find_thr16(hist, 2048, 32, t, lane, wid, wsum, &s_thr, &s_above);
  const unsigned base = ((unsigned)s_thr) << 5;

  // ---- full pass: compact keys >= base ----
  #pragma unroll
  for (int p = 0; p < 8; p++) {
    u16x8 v = row8[p * 1024 + t];
    unsigned i0 = (unsigned)(p * 1024 + t) * 8;
    #pragma unroll
    for (int j = 0; j < 8; j++) {
      unsigned k = okey16(v[j]);
      if (k >= base) {
        unsigned slot = atomicAdd(&s_cnt, 1u);
        if (slot < CAP) { ckey[slot] = (unsigned short)k; cidx[slot] = i0 + j; }
      }
    }
  }
  __syncthreads();
  const unsigned total = s_cnt;        // >= 32 guaranteed

  unsigned L, istar = 0xFFFFFFFFu;
  if (total <= CAP) {
    for (int i = t; i < 2048; i += 1024) hist[i] = 0;
    __syncthreads();
    for (unsigned i = t; i < total; i += 1024)
      atomicAdd(&hist[(unsigned)ckey[i] >> 5], 1u);
    __syncthreads();
    find_thr16(hist, 2048, 32, t, lane, wid, wsum, &s_thr, &s_above);
    const unsigned T1 = (unsigned)s_thr;
    const unsigned need2 = 32 - s_above;
    const unsigned cnt1 = hist[T1];
    if (cnt1 == need2) {
      L = T1 << 5;
    } else {
      for (unsigned i = t; i < total; i += 1024) {
        unsigned k = (unsigned)ckey[i];
        if ((k >> 5) == T1) atomicAdd(&h2[k & 31], 1u);
      }
      __syncthreads();
      if (t == 0) {
        unsigned cum = 0; int T3 = 0; unsigned above = 0;
        for (int j = 31; j >= 0; j--) {
          if (cum + h2[j] >= need2) { T3 = j; above = cum; break; }
          cum += h2[j];
        }
        sL = (T1 << 5) | (unsigned)T3;
        sneedEq = need2 - above;
        scntEq = h2[T3];
      }
      __syncthreads();
      L = sL;
      if (scntEq != sneedEq) {
        int prev = -1;
        for (unsigned j = 0; j < sneedEq; j++) {
          if (t == 0) s_imin = 0xFFFFFFFFu;
          __syncthreads();
          for (unsigned i = t; i < total; i += 1024)
            if ((unsigned)ckey[i] == L && (int)cidx[i] > prev) atomicMin(&s_imin, cidx[i]);
          __syncthreads();
          prev = (int)s_imin;
          __syncthreads();
        }
        istar = (unsigned)prev;
      }
    }
    __syncthreads();
    for (unsigned i = t; i < total; i += 1024) {
      unsigned k = (unsigned)ckey[i];
      if (k > L || (k == L && cidx[i] <= istar)) {
        unsigned s = atomicAdd(&s_na, 1u);
        slist[s] = (int)cidx[i];
      }
    }
    __syncthreads();
    if (t < 32) {
      int my = slist[t];
      int rank = 0;
      #pragma unroll
      for (int j = 0; j < 32; j++) rank += (slist[j] < my);
      oidx[n * Kt + rank] = my;
    }
  } else {
    // ======= fallback: full exact global algorithm =======
    for (int i = t; i < 2048; i += 1024) hist[i] = 0;
    __syncthreads();
    #pragma unroll
    for (int p = 0; p < 8; p++) {
      u16x8 v = row8[p * 1024 + t];
      #pragma unroll
      for (int j = 0; j < 8; j++) atomicAdd(&hist[okey16(v[j]) >> 5], 1u);
    }
    __syncthreads();
    find_thr16(hist, 2048, 32, t, lane, wid, wsum, &s_thr, &s_above);
    const unsigned T1 = (unsigned)s_thr;
    const unsigned need2 = 32 - s_above;
    const unsigned cnt1 = hist[T1];
    if (cnt1 == need2) {
      L = T1 << 5;
    } else {
      for (int p = 0; p < 8; p++) {
        u16x8 v = row8[p * 1024 + t];
        #pragma unroll
        for (int j = 0; j < 8; j++) {
          unsigned k = okey16(v[j]);
          if ((k >> 5) == T1) atomicAdd(&h2[k & 31], 1u);
        }
      }
      __syncthreads();
      if (t == 0) {
        unsigned cum = 0; int T3 = 0; unsigned above = 0;
        for (int j = 31; j >= 0; j--) {
          if (cum + h2[j] >= need2) { T3 = j; above = cum; break; }
          cum += h2[j];
        }
        sL = (T1 << 5) | (unsigned)T3;
        sneedEq = need2 - above;
        scntEq = h2[T3];
      }
      __syncthreads();
      L = sL;
      if (scntEq != sneedEq) {
        const unsigned short* rowp = simsb + (size_t)n * Mn;
        unsigned cntLoc = 0;
        for (int j = 0; j < 64; j++)
          if (okey16(rowp[t * 64 + j]) == L) cntLoc++;
        unsigned pre = blk_exscan16(cntLoc, wsum, lane, wid);
        unsigned c = 0;
        for (int j = 0; j < 64; j++)
          if (okey16(rowp[t * 64 + j]) == L) { if (pre + c < 32) slist[pre + c] = t * 64 + j; c++; }
        __syncthreads();
        istar = (unsigned)slist[sneedEq - 1];
        __syncthreads();
      }
    }
    __syncthreads();
    unsigned cnt = 0;
    for (int p = 0; p < 8; p++) {
      u16x8 v = row8[p * 1024 + t];
      unsigned i0 = (unsigned)(p * 1024 + t) * 8;
      #pragma unroll
      for (int j = 0; j < 8; j++) {
        unsigned k = okey16(v[j]);
        cnt += (k > L || (k == L && i0 + j <= istar));
      }
    }
    unsigned pos = blk_exscan16(cnt, wsum, lane, wid);
    for (int p = 0; p < 8; p++) {
      u16x8 v = row8[p * 1024 + t];
      unsigned i0 = (unsigned)(p * 1024 + t) * 8;
      #pragma unroll
      for (int j = 0; j < 8; j++) {
        unsigned k = okey16(v[j]);
        if (k > L || (k == L && i0 + j <= istar)) oidx[n * Kt + pos++] = (int)(i0 + j);
      }
    }
  }
}

// =============================== host ===============================
extern "C" void kernel_launch(void* const* d_in, const int* in_sizes, int n_in,
                              void* d_out, int out_size, void* d_ws, size_t ws_size,
                              hipStream_t stream) {
  (void)in_sizes; (void)n_in; (void)out_size;
  const float* x      = (const float*)d_in[0];
  const float* mem_k  = (const float*)d_in[1];
  const float* mem_v  = (const float*)d_in[2];
  const float* sa_w[4] = {(const float*)d_in[3], (const float*)d_in[4], (const float*)d_in[5], (const float*)d_in[6]};
  const float* sa_b[4] = {(const float*)d_in[7], (const float*)d_in[8], (const float*)d_in[9], (const float*)d_in[10]};
  const float* ma_w[4] = {(const float*)d_in[11], (const float*)d_in[12], (const float*)d_in[13], (const float*)d_in[14]};
  const float* ma_b[4] = {(const float*)d_in[15], (const float*)d_in[16], (const float*)d_in[17], (const float*)d_in[18]};
  const float* ln_g[3] = {(const float*)d_in[19], (const float*)d_in[21], (const float*)d_in[23]};
  const float* ln_b[3] = {(const float*)d_in[20], (const float*)d_in[22], (const float*)d_in[24]};
  const float* fc1_w = (const float*)d_in[25];
  const float* fc1_b = (const float*)d_in[26];
  const float* fc2_w = (const float*)d_in[27];
  const float* fc2_b = (const float*)d_in[28];
  float* out = (float*)d_out;

  char* ws = (char*)d_ws;
  size_t off = 0;
  auto alloc = [&](size_t bytes) -> char* {
    char* p = ws + off;
    off = (off + bytes + 255) & ~(size_t)255;
    return p;
  };

  unsigned short* wt[8];
  for (int i = 0; i < 8; i++) wt[i] = (unsigned short*)alloc((size_t)En * En * 2);  // contiguous
  unsigned short* fc1t  = (unsigned short*)alloc((size_t)FFn * En * 2);
  unsigned short* fc2t  = (unsigned short*)alloc((size_t)En * FFn * 2);
  unsigned short* xb    = (unsigned short*)alloc((size_t)NT * En * 2);
  unsigned short* Qb    = (unsigned short*)alloc((size_t)NT * En * 2);
  unsigned short* Kb    = (unsigned short*)alloc((size_t)NT * En * 2);
  unsigned short* Vb    = (unsigned short*)alloc((size_t)NT * En * 2);
  unsigned short* at1b  = (unsigned short*)alloc((size_t)NT * En * 2);
  float*          t1    = (float*)alloc((size_t)NT * En * 4);
  float*          x1f   = (float*)alloc((size_t)NT * En * 4);
  unsigned short* x1b   = (unsigned short*)alloc((size_t)NT * En * 2);
  char*           simsRaw = alloc((size_t)NT * Mn * 4);                // 256 MiB region
  int*            idx   = (int*)alloc((size_t)NT * Kt * 4);
  unsigned short* K2b   = (unsigned short*)alloc((size_t)NT * Kt * En * 2);  // 64 MiB
  unsigned short* V2b   = (unsigned short*)alloc((size_t)NT * Kt * En * 2);  // V2t: [B][1024][8192]
  unsigned short* Q2b   = (unsigned short*)alloc((size_t)NT * En * 2);
  unsigned short* at2b  = (unsigned short*)alloc((size_t)NT * En * 2);
  float*          t2    = (float*)alloc((size_t)NT * En * 4);
  float*          x2f   = (float*)alloc((size_t)NT * En * 4);
  unsigned short* x2b   = (unsigned short*)alloc((size_t)NT * En * 2);
  unsigned short* hb    = (unsigned short*)alloc((size_t)NT * FFn * 2);
  float*          t3    = (float*)alloc((size_t)NT * En * 4);
  float*          bcat_sa = (float*)alloc(3072 * 4);
  float*          bcat_ma = (float*)alloc(2048 * 4);

  if (off > ws_size) return;   // insufficient workspace: leave output poisoned (fail loudly)

  // Overlays within the 256 MiB sims region (uses strictly sequential):
  unsigned short* simsb = (unsigned short*)simsRaw;
  unsigned short* mkb = (unsigned short*)K2b;         // until sims GEMM done
  unsigned short* Ab2 = (unsigned short*)(simsRaw + (size_t)128 * 1024 * 1024);
  unsigned short* PO  = (unsigned short*)(simsRaw + (size_t)192 * 1024 * 1024);
  float* PM = (float*)(simsRaw + (size_t)224 * 1024 * 1024);
  float* PL = (float*)(simsRaw + (size_t)225 * 1024 * 1024);

  (void)hipFuncSetAttribute((const void*)&k_gemm256<5,false,1,0>,
                            hipFuncAttributeMaxDynamicSharedMemorySize, 131072);
  (void)hipFuncSetAttribute((const void*)&k_gemm256<6,false,2,1>,
                            hipFuncAttributeMaxDynamicSharedMemorySize, 131072);

  // ---- prep: weight transposes to bf16 [N][K], bias concats ----
  P8 p8;
  for (int i = 0; i < 4; i++) { p8.s[i] = sa_w[i]; p8.s[4 + i] = ma_w[i]; }
  k_transpose8<<<dim3(16, 16, 8), 256, 0, stream>>>(p8, wt[0]);
  k_transpose_bf16<<<dim3(64, 16), 256, 0, stream>>>(fc1_w, fc1t, En, FFn);
  k_transpose_bf16<<<dim3(16, 64), 256, 0, stream>>>(fc2_w, fc2t, FFn, En);
  k_concat3<<<dim3(12), 256, 0, stream>>>(sa_b[0], sa_b[1], sa_b[2], bcat_sa);
  k_concat3<<<dim3(8),  256, 0, stream>>>(ma_b[1], ma_b[2], ma_b[2], bcat_ma);

  k_cvt_bf16<<<dim3(NT * En / 4 / 256), 256, 0, stream>>>(x, xb, NT * En / 4);
  k_normcvt<<<dim3(Mn), 256, 0, stream>>>(mem_k, mkb);

  const dim3 g1(En / 128, NT / 128);   // (8,8)

  // ---- self-attention (QKV fused, Q pre-scaled by 1/8) ----
  k_gemm<0,false,false,3,true><<<dim3(24, 8), 256, 0, stream>>>(xb, wt[0], nullptr, bcat_sa, nullptr, nullptr, Qb, Kb, Vb, 3072, En);
  k_attn_sa<<<dim3(Sn / 64, Hn, Bn), 256, 0, stream>>>(Qb, Kb, Vb, at1b, Sn);
  k_gemm<1,false,false,1,false><<<g1, 256, 0, stream>>>(at1b, wt[3], nullptr, sa_b[3], x, t1, nullptr, nullptr, nullptr, En, En);
  k_layernorm<<<NT, 256, 0, stream>>>(t1, ln_g[0], ln_b[0], x1f, x1b);

  // ---- retrieval: sims in bf16 + sampled-threshold top-k ----
  k_gemm256<5,false,1,0><<<dim3(1024), 512, 131072, stream>>>(
      x1b, mkb, nullptr, nullptr, nullptr, simsb, nullptr, Mn, En, NT / 256, Mn / 256);
  k_topk16<<<NT, 1024, 0, stream>>>(simsb, idx);

  // ---- memory cross-attention ----
  k_gathercvt<<<dim3(NT * Kt), 256, 0, stream>>>(mem_v, idx, Ab2);
  k_gemm256<6,false,2,1><<<dim3(1024), 512, 131072, stream>>>(
      Ab2, wt[5], nullptr, bcat_ma, nullptr, K2b, V2b, 2048, En, NT * Kt / 256, 2048 / 256);
  k_gemm<0,false,false,1,true><<<g1, 256, 0, stream>>>(x1b, wt[4], nullptr, ma_b[0], nullptr, nullptr, Q2b, nullptr, nullptr, En, En);
  k_attn_ma<<<dim3(16, Hn, Bn), 256, 0, stream>>>(Q2b, K2b, V2b, PO, PM, PL);
  k_attn_comb16<<<dim3(Bn * Hn * Sn / 4), 256, 0, stream>>>(PO, PM, PL, at2b);
  k_gemm<1,false,false,1,false><<<g1, 256, 0, stream>>>(at2b, wt[7], nullptr, ma_b[3], x1f, t2, nullptr, nullptr, nullptr, En, En);
  k_layernorm<<<NT, 256, 0, stream>>>(t2, ln_g[1], ln_b[1], x2f, x2b);

  // ---- FFN ----
  k_gemm<2,false,false,1,false><<<dim3(FFn / 128, NT / 128), 256, 0, stream>>>(x2b, fc1t, nullptr, fc1_b, nullptr, nullptr, hb, nullptr, nullptr, FFn, En);
  k_gemm<1,false,false,1,false><<<g1, 256, 0, stream>>>(hb, fc2t, nullptr, fc2_b, x2f, t3, nullptr, nullptr, nullptr, En, FFn);
  k_layernorm<<<NT, 256, 0, stream>>>(t3, ln_g[2], ln_b[2], out, nullptr);
}

// Round 15
// 791.074 us; speedup vs baseline: 1.6178x; 1.1192x over previous
//
#include <hip/hip_runtime.h>
#include <hip/hip_bf16.h>
#include <math.h>

#define DEVFN __device__ __forceinline__

typedef __attribute__((ext_vector_type(8))) short bf16x8;
typedef __attribute__((ext_vector_type(8))) unsigned short u16x8;
typedef __attribute__((ext_vector_type(4))) unsigned short u16x4;
typedef __attribute__((ext_vector_type(4))) float f32x4;

static constexpr int Bn = 4, Sn = 256, En = 1024, Hn = 16;
static constexpr int Mn = 65536, Kt = 32, FFn = 4096;
static constexpr int NT = Bn * Sn;           // 1024 tokens

DEVFN unsigned short f2b(float f) {          // f32 -> bf16 RNE
  unsigned int u = __float_as_uint(f);
  unsigned int r = (u + 0x7FFFu + ((u >> 16) & 1u)) >> 16;
  return (unsigned short)r;
}
DEVFN float b2f(unsigned short u) { return __uint_as_float((unsigned)u << 16); }

DEVFN unsigned okey16(unsigned short u) {    // order-preserving bf16 -> u16
  return (unsigned)(u ^ ((u >> 15) ? 0xFFFFu : 0x8000u)) & 0xFFFFu;
}

typedef const __attribute__((address_space(1))) void* as1cv_t;
typedef __attribute__((address_space(3))) void* as3v_t;
DEVFN void gload16(const void* g, void* l) {   // async global->LDS, 16B/lane
  __builtin_amdgcn_global_load_lds((as1cv_t)g, (as3v_t)l, 16, 0, 0);
}
#define MEMFENCE asm volatile("" ::: "memory")

struct P8 { const float* s[8]; };

// ---------------- batched transpose W[1024][1024] f32 -> out[C][R] bf16 ----------------
__global__ __launch_bounds__(256) void k_transpose8(
    P8 ps, unsigned short* __restrict__ outbase) {
  const float* in = ps.s[blockIdx.z];
  unsigned short* out = outbase + (size_t)blockIdx.z * En * En;
  __shared__ float tile[64][65];
  int tx = threadIdx.x & 63, ty = threadIdx.x >> 6;
  int c0 = blockIdx.x * 64, r0 = blockIdx.y * 64;
  #pragma unroll
  for (int i = 0; i < 16; i++) {
    int r = ty + i * 4;
    tile[tx][r] = in[(size_t)(r0 + r) * En + (c0 + tx)];
  }
  __syncthreads();
  #pragma unroll
  for (int i = 0; i < 16; i++) {
    int c = ty + i * 4;
    out[(size_t)(c0 + c) * En + (r0 + tx)] = f2b(tile[c][tx]);
  }
}

// ---------------- transpose W[R][C] f32 -> out[C][R] bf16 ----------------
__global__ __launch_bounds__(256) void k_transpose_bf16(
    const float* __restrict__ in, unsigned short* __restrict__ out, int R, int C) {
  __shared__ float tile[64][65];
  int tx = threadIdx.x & 63, ty = threadIdx.x >> 6;
  int c0 = blockIdx.x * 64, r0 = blockIdx.y * 64;
  #pragma unroll
  for (int i = 0; i < 16; i++) {
    int r = ty + i * 4;
    tile[tx][r] = in[(size_t)(r0 + r) * C + (c0 + tx)];
  }
  __syncthreads();
  #pragma unroll
  for (int i = 0; i < 16; i++) {
    int c = ty + i * 4;
    out[(size_t)(c0 + c) * R + (r0 + tx)] = f2b(tile[c][tx]);
  }
}

// ---------------- f32 -> bf16 elementwise (x4) ----------------
__global__ __launch_bounds__(256) void k_cvt_bf16(
    const float* __restrict__ in, unsigned short* __restrict__ out, int n4) {
  int i = blockIdx.x * 256 + threadIdx.x;
  if (i >= n4) return;
  float4 v = ((const float4*)in)[i];
  uint2 o;
  o.x = (unsigned int)f2b(v.x) | ((unsigned int)f2b(v.y) << 16);
  o.y = (unsigned int)f2b(v.z) | ((unsigned int)f2b(v.w) << 16);
  ((uint2*)out)[i] = o;
}

// ---- gather + cvt: out[r] = bf16(mem_v[idx[r]]), one 4KB row per block ----
__global__ __launch_bounds__(256) void k_gathercvt(
    const float* __restrict__ mv, const int* __restrict__ idx,
    unsigned short* __restrict__ out) {
  int r = blockIdx.x;
  int src = idx[r];
  float4 v = ((const float4*)(mv + (size_t)src * En))[threadIdx.x];
  uint2 o;
  o.x = (unsigned int)f2b(v.x) | ((unsigned int)f2b(v.y) << 16);
  o.y = (unsigned int)f2b(v.z) | ((unsigned int)f2b(v.w) << 16);
  ((uint2*)(out + (size_t)r * En))[threadIdx.x] = o;
}

// ---------------- concat up to 3 x 1024-f32 vectors ----------------
__global__ __launch_bounds__(256) void k_concat3(
    const float* __restrict__ a, const float* __restrict__ b,
    const float* __restrict__ c, float* __restrict__ o) {
  int i = blockIdx.x * 256 + threadIdx.x;
  float v = (i < 1024) ? a[i] : (i < 2048) ? b[i - 1024] : c[i - 2048];
  o[i] = v;
}

// ---- mem_keys row-normalize + cvt to bf16 (folds cosine norm into B) ----
__global__ __launch_bounds__(256) void k_normcvt(
    const float* __restrict__ mk, unsigned short* __restrict__ out) {
  int m = blockIdx.x, t = threadIdx.x;
  float4 v = ((const float4*)(mk + (size_t)m * En))[t];
  float ss = v.x*v.x + v.y*v.y + v.z*v.z + v.w*v.w;
  #pragma unroll
  for (int d = 32; d; d >>= 1) ss += __shfl_down(ss, d);
  __shared__ float red[4];
  int lane = t & 63, w = t >> 6;
  if (lane == 0) red[w] = ss;
  __syncthreads();
  float rs = 1.0f / fmaxf(sqrtf(red[0] + red[1] + red[2] + red[3]), 1e-12f);
  uint2 o;
  o.x = (unsigned int)f2b(v.x * rs) | ((unsigned int)f2b(v.y * rs) << 16);
  o.y = (unsigned int)f2b(v.z * rs) | ((unsigned int)f2b(v.w * rs) << 16);
  ((uint2*)(out + (size_t)m * En))[t] = o;
}

// ---------------- LayerNorm over rows of [NT][En] ----------------
__global__ __launch_bounds__(256) void k_layernorm(
    const float* __restrict__ in, const float* __restrict__ g, const float* __restrict__ bb,
    float* __restrict__ outf, unsigned short* __restrict__ outb) {
  int n = blockIdx.x, t = threadIdx.x;
  float4 v = ((const float4*)(in + (size_t)n * En))[t];
  float s  = v.x + v.y + v.z + v.w;
  float s2 = v.x*v.x + v.y*v.y + v.z*v.z + v.w*v.w;
  #pragma unroll
  for (int d = 32; d; d >>= 1) { s += __shfl_down(s, d); s2 += __shfl_down(s2, d); }
  __shared__ float rs[4], rq[4];
  int lane = t & 63, w = t >> 6;
  if (lane == 0) { rs[w] = s; rq[w] = s2; }
  __syncthreads();
  float mean = (rs[0]+rs[1]+rs[2]+rs[3]) * (1.0f/En);
  float var  = (rq[0]+rq[1]+rq[2]+rq[3]) * (1.0f/En) - mean*mean;
  float rstd = rsqrtf(var + 1e-5f);
  float4 gg = ((const float4*)g)[t];
  float4 bv = ((const float4*)bb)[t];
  float o0 = (v.x-mean)*rstd*gg.x + bv.x;
  float o1 = (v.y-mean)*rstd*gg.y + bv.y;
  float o2 = (v.z-mean)*rstd*gg.z + bv.z;
  float o3 = (v.w-mean)*rstd*gg.w + bv.w;
  if (outf) { float4 ov = {o0,o1,o2,o3}; ((float4*)(outf + (size_t)n*En))[t] = ov; }
  if (outb) {
    uint2 o;
    o.x = (unsigned int)f2b(o0) | ((unsigned int)f2b(o1) << 16);
    o.y = (unsigned int)f2b(o2) | ((unsigned int)f2b(o3) << 16);
    ((uint2*)(outb + (size_t)n*En))[t] = o;
  }
}

// ---- LayerNorm over (sum of 4 split-K partials + bias + resid) rows ----
__global__ __launch_bounds__(256) void k_layernorm4(
    const float* __restrict__ pp, const float* __restrict__ pbias,
    const float* __restrict__ resid,
    const float* __restrict__ g, const float* __restrict__ bb,
    float* __restrict__ outf, unsigned short* __restrict__ outb) {
  int n = blockIdx.x, t = threadIdx.x;
  const size_t PS = (size_t)NT * En / 4;   // plane stride in float4
  size_t i = (size_t)n * 256 + t;
  float4 p0 = ((const float4*)pp)[i];
  float4 p1 = ((const float4*)pp)[i + PS];
  float4 p2 = ((const float4*)pp)[i + 2 * PS];
  float4 p3 = ((const float4*)pp)[i + 3 * PS];
  float4 rv = ((const float4*)(resid + (size_t)n * En))[t];
  float4 bi = ((const float4*)pbias)[t];
  float4 v;
  v.x = (p0.x + p1.x) + (p2.x + p3.x) + bi.x + rv.x;
  v.y = (p0.y + p1.y) + (p2.y + p3.y) + bi.y + rv.y;
  v.z = (p0.z + p1.z) + (p2.z + p3.z) + bi.z + rv.z;
  v.w = (p0.w + p1.w) + (p2.w + p3.w) + bi.w + rv.w;
  float s  = v.x + v.y + v.z + v.w;
  float s2 = v.x*v.x + v.y*v.y + v.z*v.z + v.w*v.w;
  #pragma unroll
  for (int d = 32; d; d >>= 1) { s += __shfl_down(s, d); s2 += __shfl_down(s2, d); }
  __shared__ float rs[4], rq[4];
  int lane = t & 63, w = t >> 6;
  if (lane == 0) { rs[w] = s; rq[w] = s2; }
  __syncthreads();
  float mean = (rs[0]+rs[1]+rs[2]+rs[3]) * (1.0f/En);
  float var  = (rq[0]+rq[1]+rq[2]+rq[3]) * (1.0f/En) - mean*mean;
  float rstd = rsqrtf(var + 1e-5f);
  float4 gg = ((const float4*)g)[t];
  float4 bv = ((const float4*)bb)[t];
  float o0 = (v.x-mean)*rstd*gg.x + bv.x;
  float o1 = (v.y-mean)*rstd*gg.y + bv.y;
  float o2 = (v.z-mean)*rstd*gg.z + bv.z;
  float o3 = (v.w-mean)*rstd*gg.w + bv.w;
  if (outf) { float4 ov = {o0,o1,o2,o3}; ((float4*)(outf + (size_t)n*En))[t] = ov; }
  if (outb) {
    uint2 o;
    o.x = (unsigned int)f2b(o0) | ((unsigned int)f2b(o1) << 16);
    o.y = (unsigned int)f2b(o2) | ((unsigned int)f2b(o3) << 16);
    ((uint2*)(outb + (size_t)n*En))[t] = o;
  }
}

// ======== 256x256 GEMM, ring-4 half-tile buffers + counted vmcnt (minimal barriers) ====
// EPI 4: f32 out | EPI 5: bf16 no-bias | EPI 0 + NOUT2: bf16 (+bias), split N
// EPI 6: split N=2048 -> cb0 row-major (+bias), cb1 TRANSPOSED [B][1024][8192] (+bias)
template<int EPI, bool AGATHER, int NOUT, int LSWZ>
__global__ __launch_bounds__(512) void k_gemm256(
    const unsigned short* __restrict__ Ab, const unsigned short* __restrict__ Bb,
    const int* __restrict__ gidx, const float* __restrict__ bias,
    float* __restrict__ Cf, unsigned short* __restrict__ cb0, unsigned short* __restrict__ cb1,
    int Ndim, int Kdim, int nRT, int nCT) {
  extern __shared__ unsigned short lds[];
  const int t = threadIdx.x, lane = t & 63, w = t >> 6;
  const int wr = w >> 2, wc = w & 3, l15 = lane & 15, l4 = lane >> 4;
  const int lr2 = lane >> 2;
  const int cg  = (lane & 3) ^ (((lane >> 5) & 1) << 1);   // source pre-swizzle (involution)

  const int nwg = nRT * nCT;
  int lb = ((int)blockIdx.x % 8) * (nwg >> 3) + ((int)blockIdx.x >> 3);
  int rowT, colT;
  if (LSWZ == 0) { rowT = lb % nRT; colT = lb / nRT; }
  else           { colT = lb % nCT; rowT = lb / nCT; }
  const int row0 = rowT * 256, col0 = colT * 256;

  auto pa = [&](int h) -> unsigned short* { return lds + h * 16384; };
  auto pb = [&](int h) -> unsigned short* { return lds + h * 16384 + 8192; };

  const unsigned short *aSrc0, *aSrc1;
  if constexpr (AGATHER) {
    aSrc0 = Ab + (size_t)gidx[row0 + w * 32 + lr2] * Kdim + cg * 8;
    aSrc1 = Ab + (size_t)gidx[row0 + w * 32 + 16 + lr2] * Kdim + cg * 8;
  } else {
    aSrc0 = Ab + (size_t)(row0 + w * 32 + lr2) * Kdim + cg * 8;
    aSrc1 = aSrc0 + (size_t)16 * Kdim;
  }
  const unsigned short* bSrc0 = Bb + (size_t)(col0 + w * 32 + lr2) * Kdim + cg * 8;
  const unsigned short* bSrc1 = bSrc0 + (size_t)16 * Kdim;

  f32x4 acc[8][4];
  #pragma unroll
  for (int i = 0; i < 8; i++)
    #pragma unroll
    for (int j = 0; j < 4; j++) acc[i][j] = (f32x4){0.f, 0.f, 0.f, 0.f};

  const int NH = Kdim >> 5;                 // K half-tiles of 32
  #pragma unroll
  for (int h = 0; h < 3; ++h) {
    const int ko = h * 32;
    gload16(aSrc0 + ko, pa(h) + w*32*32);
    gload16(aSrc1 + ko, pa(h) + (w*32+16)*32);
    gload16(bSrc0 + ko, pb(h) + w*32*32);
    gload16(bSrc1 + ko, pb(h) + (w*32+16)*32);
  }
  asm volatile("s_waitcnt vmcnt(8)" ::: "memory");   // half 0 landed
  __builtin_amdgcn_s_barrier();
  MEMFENCE;

  for (int hs = 0; hs < NH; ++hs) {
    const int cur = hs & 3;
    const unsigned short* Ap = pa(cur);
    const unsigned short* Bp = pb(cur);
    const int h3 = (hs + 3) & 3, ko3 = (hs + 3) * 32;
    const bool pf = (hs + 3) < NH;
    bf16x8 bfr[4], af[4];

    // ---- cluster 0: B frags + A rows 0..63, stage A pair ----
    #pragma unroll
    for (int ni = 0; ni < 4; ni++) {
      int row = wc * 64 + ni * 16 + l15;
      int c8 = l4 ^ (((row >> 3) & 1) << 1);
      bfr[ni] = *(const bf16x8*)&Bp[row * 32 + c8 * 8];
    }
    #pragma unroll
    for (int m = 0; m < 4; m++) {
      int row = wr * 128 + m * 16 + l15;
      int c8 = l4 ^ (((row >> 3) & 1) << 1);
      af[m] = *(const bf16x8*)&Ap[row * 32 + c8 * 8];
    }
    if (pf) {
      gload16(aSrc0 + ko3, pa(h3) + w*32*32);
      gload16(aSrc1 + ko3, pa(h3) + (w*32+16)*32);
    }
    __builtin_amdgcn_s_setprio(1);
    #pragma unroll
    for (int m = 0; m < 4; m++)
      #pragma unroll
      for (int ni = 0; ni < 4; ni++)
        acc[m][ni] = __builtin_amdgcn_mfma_f32_16x16x32_bf16(af[m], bfr[ni], acc[m][ni], 0, 0, 0);
    __builtin_amdgcn_s_setprio(0);

    // ---- cluster 1: A rows 64..127, stage B pair ----
    #pragma unroll
    for (int m = 0; m < 4; m++) {
      int row = wr * 128 + (4 + m) * 16 + l15;
      int c8 = l4 ^ (((row >> 3) & 1) << 1);
      af[m] = *(const bf16x8*)&Ap[row * 32 + c8 * 8];
    }
    if (pf) {
      gload16(bSrc0 + ko3, pb(h3) + w*32*32);
      gload16(bSrc1 + ko3, pb(h3) + (w*32+16)*32);
    }
    __builtin_amdgcn_s_setprio(1);
    #pragma unroll
    for (int m = 0; m < 4; m++)
      #pragma unroll
      for (int ni = 0; ni < 4; ni++)
        acc[4 + m][ni] = __builtin_amdgcn_mfma_f32_16x16x32_bf16(af[m], bfr[ni], acc[4 + m][ni], 0, 0, 0);
    __builtin_amdgcn_s_setprio(0);

    // ---- boundary: counted wait for half hs+1, single barrier per half-tile ----
    if (hs + 1 < NH) {
      const int rem = NH - 2 - hs;
      if (rem >= 2)      asm volatile("s_waitcnt vmcnt(8)" ::: "memory");
      else if (rem == 1) asm volatile("s_waitcnt vmcnt(4)" ::: "memory");
      else               asm volatile("s_waitcnt vmcnt(0)" ::: "memory");
      __builtin_amdgcn_s_barrier();
      MEMFENCE;
    }
  }

  #pragma unroll
  for (int m = 0; m < 8; m++) {
    #pragma unroll
    for (int ni = 0; ni < 4; ni++) {
      int col  = col0 + wc * 64 + ni * 16 + l15;
      int rowb = row0 + wr * 128 + m * 16 + l4 * 4;
      if constexpr (EPI == 6) {
        if (col < 1024) {
          #pragma unroll
          for (int r = 0; r < 4; r++)
            cb0[(size_t)(rowb + r) * 1024 + col] = f2b(acc[m][ni][r] + bias[col]);
        } else {
          int c = col - 1024;
          int bi = rowb >> 13, k0 = rowb & 8191;
          u16x4 o;
          #pragma unroll
          for (int r = 0; r < 4; r++) o[r] = f2b(acc[m][ni][r] + bias[col]);
          *(u16x4*)&cb1[((size_t)bi * 1024 + c) * 8192 + k0] = o;
        }
      } else {
        #pragma unroll
        for (int r = 0; r < 4; r++) {
          float v = acc[m][ni][r];
          if constexpr (EPI == 4) {
            Cf[(size_t)(rowb + r) * Ndim + col] = v;
          } else if constexpr (EPI == 5) {
            cb0[(size_t)(rowb + r) * Ndim + col] = f2b(v);
          } else {
            unsigned short* cb = (col >> 10) ? cb1 : cb0;
            cb[(size_t)(rowb + r) * 1024 + (col & 1023)] = f2b(v + bias[col]);
          }
        }
      }
    }
  }
}

// ---------------- GEMM 128x128 (2-phase) for the small GEMMs ----------------
// QSC: scale output by 0.125 (Q pre-scale; NOUT>1: only the first 1024 cols)
// SK>1: split-K via blockIdx.z; EPI 7: write f32 partial plane (no bias/resid)
template<int EPI, bool AGATHER, bool SWAPG, int NOUT, bool QSC, int SK>
__global__ __launch_bounds__(256) void k_gemm(
    const unsigned short* __restrict__ Ab, const unsigned short* __restrict__ Bb,
    const int* __restrict__ gidx,
    const float* __restrict__ bias, const float* __restrict__ resid,
    float* __restrict__ Cf, unsigned short* __restrict__ cb0,
    unsigned short* __restrict__ cb1, unsigned short* __restrict__ cb2,
    int Ndim, int Kdim) {
  __shared__ unsigned short As[128][32];
  __shared__ unsigned short Bs[128][32];
  const int t = threadIdx.x, lane = t & 63, w = t >> 6;
  const int wr = w >> 1, wc = w & 1, l15 = lane & 15, l4 = lane >> 4;
  const int row0 = (SWAPG ? blockIdx.x : blockIdx.y) * 128;
  const int col0 = (SWAPG ? blockIdx.y : blockIdx.x) * 128;
  const int c8  = (lane & 3) * 8;
  const int r16 = lane >> 2;
  const int rA0 = w * 32 + r16, rA1 = rA0 + 16;
  const int koff = (SK > 1) ? (int)blockIdx.z * (Kdim / SK) : 0;
  const int kend = (SK > 1) ? koff + Kdim / SK : Kdim;

  size_t raA0, raA1, raB0, raB1;
  if constexpr (AGATHER) {
    raA0 = (size_t)gidx[row0 + rA0] * Kdim;
    raA1 = (size_t)gidx[row0 + rA1] * Kdim;
  } else {
    raA0 = (size_t)(row0 + rA0) * Kdim;
    raA1 = (size_t)(row0 + rA1) * Kdim;
  }
  raB0 = (size_t)(col0 + rA0) * Kdim;
  raB1 = (size_t)(col0 + rA1) * Kdim;

  f32x4 acc[4][4];
  #pragma unroll
  for (int i = 0; i < 4; i++)
    #pragma unroll
    for (int j = 0; j < 4; j++) acc[i][j] = (f32x4){0.f,0.f,0.f,0.f};

  for (int kt0 = koff; kt0 < kend; kt0 += 32) {
    __syncthreads();
    gload16(Ab + raA0 + kt0 + c8, &As[w * 32][0]);
    gload16(Ab + raA1 + kt0 + c8, &As[w * 32 + 16][0]);
    gload16(Bb + raB0 + kt0 + c8, &Bs[w * 32][0]);
    gload16(Bb + raB1 + kt0 + c8, &Bs[w * 32 + 16][0]);
    __syncthreads();
    bf16x8 af[4], bfr[4];
    #pragma unroll
    for (int mi = 0; mi < 4; mi++) af[mi]  = *(const bf16x8*)&As[wr*64 + mi*16 + l15][l4*8];
    #pragma unroll
    for (int ni = 0; ni < 4; ni++) bfr[ni] = *(const bf16x8*)&Bs[wc*64 + ni*16 + l15][l4*8];
    #pragma unroll
    for (int mi = 0; mi < 4; mi++)
      #pragma unroll
      for (int ni = 0; ni < 4; ni++)
        acc[mi][ni] = __builtin_amdgcn_mfma_f32_16x16x32_bf16(af[mi], bfr[ni], acc[mi][ni], 0, 0, 0);
  }

  unsigned short* cbase = cb0;
  int colsub = 0;
  float qsc = 1.0f;
  if constexpr (NOUT > 1) {
    int which = col0 >> 10;
    cbase = (which == 0) ? cb0 : (which == 1) ? cb1 : cb2;
    colsub = col0 & 1023;
    if (QSC && which == 0) qsc = 0.125f;
  } else if constexpr (QSC) {
    qsc = 0.125f;
  }
  float* Cfp = Cf;
  if constexpr (EPI == 7) Cfp = Cf + (size_t)blockIdx.z * NT * En;

  #pragma unroll
  for (int mi = 0; mi < 4; mi++) {
    #pragma unroll
    for (int ni = 0; ni < 4; ni++) {
      int col  = col0 + wc*64 + ni*16 + l15;
      int rowb = row0 + wr*64 + mi*16 + l4*4;
      #pragma unroll
      for (int r = 0; r < 4; r++) {
        float v = acc[mi][ni][r];
        size_t off = (size_t)(rowb + r) * Ndim + col;
        if constexpr (EPI == 0) {
          if constexpr (NOUT > 1) {
            int c2 = colsub + wc*64 + ni*16 + l15;
            cbase[(size_t)(rowb + r) * 1024 + c2] = f2b((v + bias[col]) * qsc);
          } else {
            cb0[off] = f2b((v + bias[col]) * qsc);
          }
        } else if constexpr (EPI == 1) {
          Cf[off] = v + bias[col] + resid[off];
        } else if constexpr (EPI == 2) {
          float u = v + bias[col];
          u = 0.5f * u * (1.0f + erff(u * 0.70710678118654752f));
          cb0[off] = f2b(u);
        } else if constexpr (EPI == 7) {
          Cfp[off] = v;
        } else {
          Cf[off] = v;
        }
      }
    }
  }
}

// ---------------- SA fused attention (Q pre-scaled, T13 defer-max, deferred l) --------
__global__ __launch_bounds__(256) void k_attn_sa(
    const unsigned short* __restrict__ Qp, const unsigned short* __restrict__ Kp,
    const unsigned short* __restrict__ Vp, unsigned short* __restrict__ Op, int Lk) {
  __shared__ unsigned short Ks[64][72];
  __shared__ unsigned short Vt[64][72];
  __shared__ float Ps[4][16][68];
  const int b = blockIdx.z;
  const int h = blockIdx.y, q0 = blockIdx.x * 64;
  const int t = threadIdx.x, lane = t & 63, w = t >> 6;
  const int l15 = lane & 15, l4 = lane >> 4;

  const int qrow = q0 + w * 16 + l15;
  const unsigned short* qptr = Qp + (size_t)(b * Sn + qrow) * En + h * 64 + l4 * 8;
  bf16x8 qf0 = *(const bf16x8*)qptr;
  bf16x8 qf1 = *(const bf16x8*)(qptr + 32);

  f32x4 oacc[4];
  #pragma unroll
  for (int i = 0; i < 4; i++) oacc[i] = (f32x4){0.f,0.f,0.f,0.f};
  float m_[4] = {-INFINITY, -INFINITY, -INFINITY, -INFINITY};
  float l_[4] = {0.f, 0.f, 0.f, 0.f};

  const int nkt = Lk / 64;
  for (int kt = 0; kt < nkt; ++kt) {
    __syncthreads();
    #pragma unroll
    for (int i = 0; i < 2; i++) {
      int ld = t + i * 256;
      int kr = ld >> 3, d8 = (ld & 7) * 8;
      size_t base = (size_t)(b * Lk + kt * 64 + kr) * En + h * 64 + d8;
      *(uint4*)&Ks[kr][d8] = *(const uint4*)(Kp + base);
      bf16x8 vv = *(const bf16x8*)(Vp + base);
      int colswz = kr ^ ((t & 7) << 3);
      #pragma unroll
      for (int j = 0; j < 8; j++) Vt[d8 + j][colswz] = ((unsigned short*)&vv)[j];
    }
    __syncthreads();

    f32x4 s[4];
    #pragma unroll
    for (int ni = 0; ni < 4; ni++) {
      s[ni] = (f32x4){0.f,0.f,0.f,0.f};
      bf16x8 kb0 = *(const bf16x8*)&Ks[ni*16 + l15][l4*8];
      bf16x8 kb1 = *(const bf16x8*)&Ks[ni*16 + l15][l4*8 + 32];
      s[ni] = __builtin_amdgcn_mfma_f32_16x16x32_bf16(qf0, kb0, s[ni], 0, 0, 0);
      s[ni] = __builtin_amdgcn_mfma_f32_16x16x32_bf16(qf1, kb1, s[ni], 0, 0, 0);
    }

    #pragma unroll
    for (int r = 0; r < 4; r++) {
      float mx = fmaxf(fmaxf(s[0][r], s[1][r]), fmaxf(s[2][r], s[3][r]));
      #pragma unroll
      for (int d2 = 1; d2 < 16; d2 <<= 1) mx = fmaxf(mx, __shfl_xor(mx, d2));
      float m = m_[r];
      if (mx > m + 8.f) {                    // T13: rescale only on large jump
        float alpha = __expf(m - mx);
        l_[r] *= alpha;
        #pragma unroll
        for (int nd = 0; nd < 4; nd++) oacc[nd][r] *= alpha;
        m = mx; m_[r] = mx;
      }
      float p0 = __expf(s[0][r] - m), p1 = __expf(s[1][r] - m);
      float p2 = __expf(s[2][r] - m), p3 = __expf(s[3][r] - m);
      s[0][r] = p0; s[1][r] = p1; s[2][r] = p2; s[3][r] = p3;
      l_[r] += (p0 + p1) + (p2 + p3);        // per-lane partial; reduce at end
    }

    #pragma unroll
    for (int ni = 0; ni < 4; ni++)
      #pragma unroll
      for (int r = 0; r < 4; r++)
        Ps[w][l4*4 + r][ni*16 + l15] = s[ni][r];
    asm volatile("s_waitcnt lgkmcnt(0)" ::: "memory");

    #pragma unroll
    for (int half = 0; half < 2; half++) {
      float4 pv0 = *(const float4*)&Ps[w][l15][half*32 + l4*8];
      float4 pv1 = *(const float4*)&Ps[w][l15][half*32 + l4*8 + 4];
      bf16x8 pa;
      pa[0]=(short)f2b(pv0.x); pa[1]=(short)f2b(pv0.y); pa[2]=(short)f2b(pv0.z); pa[3]=(short)f2b(pv0.w);
      pa[4]=(short)f2b(pv1.x); pa[5]=(short)f2b(pv1.y); pa[6]=(short)f2b(pv1.z); pa[7]=(short)f2b(pv1.w);
      #pragma unroll
      for (int nd = 0; nd < 4; nd++) {
        int dd = nd*16 + l15;
        bf16x8 vb = *(const bf16x8*)&Vt[dd][(half*32 + l4*8) ^ (((dd >> 3) & 7) << 3)];
        oacc[nd] = __builtin_amdgcn_mfma_f32_16x16x32_bf16(pa, vb, oacc[nd], 0, 0, 0);
      }
    }
  }

  #pragma unroll
  for (int r = 0; r < 4; r++) {              // final 16-lane l reduce
    float lv = l_[r];
    #pragma unroll
    for (int d2 = 1; d2 < 16; d2 <<= 1) lv += __shfl_xor(lv, d2);
    l_[r] = lv;
  }
  #pragma unroll
  for (int nd = 0; nd < 4; nd++)
    #pragma unroll
    for (int r = 0; r < 4; r++) {
      int q = q0 + w*16 + l4*4 + r;
      Op[(size_t)(b * Sn + q) * En + h * 64 + nd*16 + l15] = f2b(oacc[nd][r] / l_[r]);
    }
}

// ------- MA attention: 4 q-tiles folded, SPLIT=16, dbuf VT staging, lean softmax -------
__global__ __launch_bounds__(256, 2) void k_attn_ma(
    const unsigned short* __restrict__ Qp, const unsigned short* __restrict__ Kp,
    const unsigned short* __restrict__ Vp,
    unsigned short* __restrict__ PO, float* __restrict__ PM, float* __restrict__ PL) {
  constexpr int Lk = Sn * Kt;            // 8192
  constexpr int NTI = 8;                 // k-tiles per block (8192/64/16)
  __shared__ unsigned short Ks[2][64 * 64];
  __shared__ unsigned short Vt[2][64 * 64];
  __shared__ float Ps[4][16][68];
  const int sp = blockIdx.x, h = blockIdx.y, b = blockIdx.z;
  const int t = threadIdx.x, lane = t & 63, w = t >> 6;
  const int l15 = lane & 15, l4 = lane >> 4;
  const int l8 = lane >> 3, l7 = lane & 7;
  const int kswz = (l7 ^ l8) * 8;        // source pre-swizzle (row&7)
  const int rbase = w * 16;

  bf16x8 qf[4][2];
  #pragma unroll
  for (int qt = 0; qt < 4; qt++) {
    const unsigned short* qptr = Qp + (size_t)(b * Sn + w * 64 + qt * 16 + l15) * En + h * 64 + l4 * 8;
    qf[qt][0] = *(const bf16x8*)qptr;
    qf[qt][1] = *(const bf16x8*)(qptr + 32);
  }

  f32x4 oacc[4][4];
  #pragma unroll
  for (int i = 0; i < 4; i++)
    #pragma unroll
    for (int j = 0; j < 4; j++) oacc[i][j] = (f32x4){0.f,0.f,0.f,0.f};
  float m_[4][4], l_[4][4];
  #pragma unroll
  for (int i = 0; i < 4; i++)
    #pragma unroll
    for (int j = 0; j < 4; j++) { m_[i][j] = -INFINITY; l_[i][j] = 0.f; }

  const int kt0 = sp * NTI;
  auto stage = [&](int kt, int buf) {
    #pragma unroll
    for (int i = 0; i < 2; i++) {
      int row = rbase + i * 8 + l8;
      gload16(Kp + (size_t)(b * Lk + kt * 64 + row) * En + h * 64 + kswz,
              &Ks[buf][(rbase + i * 8) * 64]);
      gload16(Vp + ((size_t)b * 1024 + h * 64 + row) * (size_t)Lk + kt * 64 + kswz,
              &Vt[buf][(rbase + i * 8) * 64]);
    }
  };

  stage(kt0, 0);
  stage(kt0 + 1, 1);
  asm volatile("s_waitcnt vmcnt(4)" ::: "memory");   // tile0 landed (Q drained too)
  __builtin_amdgcn_s_barrier();
  MEMFENCE;

  for (int j = 0; j < NTI; ++j) {
    const int cur = j & 1;
    #pragma unroll
    for (int qt = 0; qt < 4; qt++) {
      f32x4 s[4];
      #pragma unroll
      for (int ni = 0; ni < 4; ni++) {
        s[ni] = (f32x4){0.f,0.f,0.f,0.f};
        int rowK = ni * 16 + l15, sw = (rowK & 7) * 8;
        bf16x8 kb0 = *(const bf16x8*)&Ks[cur][rowK * 64 + ((l4 * 8) ^ sw)];
        bf16x8 kb1 = *(const bf16x8*)&Ks[cur][rowK * 64 + ((l4 * 8 + 32) ^ sw)];
        s[ni] = __builtin_amdgcn_mfma_f32_16x16x32_bf16(qf[qt][0], kb0, s[ni], 0, 0, 0);
        s[ni] = __builtin_amdgcn_mfma_f32_16x16x32_bf16(qf[qt][1], kb1, s[ni], 0, 0, 0);
      }
      #pragma unroll
      for (int r = 0; r < 4; r++) {
        float mx = fmaxf(fmaxf(s[0][r], s[1][r]), fmaxf(s[2][r], s[3][r]));
        #pragma unroll
        for (int d2 = 1; d2 < 16; d2 <<= 1) mx = fmaxf(mx, __shfl_xor(mx, d2));
        float m = m_[qt][r];
        if (mx > m + 8.f) {                  // T13 defer-max
          float alpha = __expf(m - mx);
          l_[qt][r] *= alpha;
          #pragma unroll
          for (int nd = 0; nd < 4; nd++) oacc[qt][nd][r] *= alpha;
          m = mx; m_[qt][r] = mx;
        }
        float p0 = __expf(s[0][r] - m), p1 = __expf(s[1][r] - m);
        float p2 = __expf(s[2][r] - m), p3 = __expf(s[3][r] - m);
        s[0][r] = p0; s[1][r] = p1; s[2][r] = p2; s[3][r] = p3;
        l_[qt][r] += (p0 + p1) + (p2 + p3);  // per-lane partial
      }
      #pragma unroll
      for (int ni = 0; ni < 4; ni++)
        #pragma unroll
        for (int r = 0; r < 4; r++)
          Ps[w][l4*4 + r][ni*16 + l15] = s[ni][r];
      asm volatile("s_waitcnt lgkmcnt(0)" ::: "memory");
      #pragma unroll
      for (int half = 0; half < 2; half++) {
        float4 pv0 = *(const float4*)&Ps[w][l15][half*32 + l4*8];
        float4 pv1 = *(const float4*)&Ps[w][l15][half*32 + l4*8 + 4];
        bf16x8 pa;
        pa[0]=(short)f2b(pv0.x); pa[1]=(short)f2b(pv0.y); pa[2]=(short)f2b(pv0.z); pa[3]=(short)f2b(pv0.w);
        pa[4]=(short)f2b(pv1.x); pa[5]=(short)f2b(pv1.y); pa[6]=(short)f2b(pv1.z); pa[7]=(short)f2b(pv1.w);
        #pragma unroll
        for (int nd = 0; nd < 4; nd++) {
          int dd = nd*16 + l15;
          bf16x8 vb = *(const bf16x8*)&Vt[cur][dd * 64 + ((half*32 + l4*8) ^ ((dd & 7) * 8))];
          oacc[qt][nd] = __builtin_amdgcn_mfma_f32_16x16x32_bf16(pa, vb, oacc[qt][nd], 0, 0, 0);
        }
      }
    }
    MEMFENCE; __builtin_amdgcn_s_barrier(); MEMFENCE;
    if (j + 2 < NTI) stage(kt0 + j + 2, cur);
    if (j + 1 < NTI) {
      if (j + 2 < NTI) asm volatile("s_waitcnt vmcnt(4)" ::: "memory");
      else             asm volatile("s_waitcnt vmcnt(0)" ::: "memory");
      __builtin_amdgcn_s_barrier();
      MEMFENCE;
    }
  }

  #pragma unroll
  for (int qt = 0; qt < 4; qt++)             // final 16-lane l reduce
    #pragma unroll
    for (int r = 0; r < 4; r++) {
      float lv = l_[qt][r];
      #pragma unroll
      for (int d2 = 1; d2 < 16; d2 <<= 1) lv += __shfl_xor(lv, d2);
      l_[qt][r] = lv;
    }

  const int slot = (b * Hn + h) * 16 + sp;
  #pragma unroll
  for (int qt = 0; qt < 4; qt++)
    #pragma unroll
    for (int nd = 0; nd < 4; nd++)
      #pragma unroll
      for (int r = 0; r < 4; r++)
        PO[(size_t)slot * 16384 + (w*64 + qt*16 + l4*4 + r) * 64 + nd*16 + l15] = f2b(oacc[qt][nd][r]);
  if (l15 == 0) {
    #pragma unroll
    for (int qt = 0; qt < 4; qt++)
      #pragma unroll
      for (int r = 0; r < 4; r++) {
        PM[slot * 256 + w*64 + qt*16 + l4*4 + r] = m_[qt][r];
        PL[slot * 256 + w*64 + qt*16 + l4*4 + r] = l_[qt][r];
      }
  }
}

// ---------------- combine 16 split partials (bf16 PO, Q pre-scaled) ----------------
__global__ __launch_bounds__(256) void k_attn_comb16(
    const unsigned short* __restrict__ PO, const float* __restrict__ PM,
    const float* __restrict__ PL, unsigned short* __restrict__ Op) {
  const int W = blockIdx.x * 4 + (threadIdx.x >> 6);  // (bh, q) row
  const int lane = threadIdx.x & 63;
  const int bh = W >> 8, q = W & 255;
  const int slotBase = bh * 16;
  float ms[16];
  float M = -INFINITY;
  #pragma unroll
  for (int s = 0; s < 16; s++) { ms[s] = PM[(slotBase + s) * 256 + q]; M = fmaxf(M, ms[s]); }
  float L = 0.f, acc = 0.f;
  #pragma unroll
  for (int s = 0; s < 16; s++) {
    float wgt = __expf(ms[s] - M);
    L += PL[(slotBase + s) * 256 + q] * wgt;
    acc += wgt * b2f(PO[(size_t)(slotBase + s) * 16384 + q * 64 + lane]);
  }
  const int b = bh >> 4, h = bh & 15;
  Op[(size_t)(b * Sn + q) * En + h * 64 + lane] = f2b(acc / L);
}

// ------------- helpers for radix top-k (1024-thread blocks) -------------
DEVFN unsigned blk_exscan16(unsigned part, volatile unsigned* wsum, int lane, int wid) {
  unsigned v = part;
  #pragma unroll
  for (int d = 1; d < 64; d <<= 1) { unsigned o = __shfl_up(v, d); if (lane >= d) v += o; }
  if (lane == 63) wsum[wid] = v;
  __syncthreads();
  unsigned woff = 0;
  for (int i = 0; i < wid; i++) woff += wsum[i];
  unsigned r = woff + v - part;
  __syncthreads();
  return r;
}

DEVFN void find_thr16(const unsigned* hist, int NB, unsigned need,
                      int t, int lane, int wid, volatile unsigned* wsum,
                      volatile int* s_thr, volatile unsigned* s_above) {
  int per = NB >> 10;
  int lo = NB - per * (t + 1);
  unsigned part = 0;
  for (int j = 0; j < per; j++) part += hist[lo + j];
  unsigned ex = blk_exscan16(part, wsum, lane, wid);
  if (ex < need && ex + part >= need) {
    unsigned c = ex;
    for (int j = per - 1; j >= 0; j--) {
      unsigned h = hist[lo + j];
      if (c + h >= need) { *s_thr = lo + j; *s_above = c; break; }
      c += h;
    }
  }
  __syncthreads();
}

// ------- exact top-32: sampled threshold -> 1 compact pass -> in-LDS select -------
__global__ __launch_bounds__(1024) void k_topk16(
    const unsigned short* __restrict__ simsb, int* __restrict__ oidx) {
  const int n = blockIdx.x, t = threadIdx.x;
  const int lane = t & 63, wid = t >> 6;
  const u16x8* row8 = (const u16x8*)(simsb + (size_t)n * Mn);
  constexpr unsigned CAP = 2048;
  __shared__ unsigned hist[2048];
  __shared__ unsigned wsum[16];
  __shared__ int s_thr;
  __shared__ unsigned s_above;
  __shared__ unsigned h2[32];
  __shared__ unsigned s_cnt, s_na;
  __shared__ unsigned short ckey[CAP];
  __shared__ unsigned cidx[CAP];
  __shared__ int slist[32];
  __shared__ unsigned sL, sneedEq, scntEq, s_imin;

  for (int i = t; i < 2048; i += 1024) hist[i] = 0;
  if (t < 32) h2[t] = 0;
  if (t == 0) { s_cnt = 0; s_na = 0; }
  __syncthreads();

  // ---- sample pass: 1024 contiguous groups (16 KiB, middle of row) ----
  {
    u16x8 v = row8[3584 + t];
    #pragma unroll
    for (int j = 0; j < 8; j++) atomicAdd(&hist[okey16(v[j]) >> 5], 1u);
  }
  __syncthreads();
  find_thr16(hist, 2048, 32, t, lane, wid, wsum, &s_thr, &s_above);
  const unsigned base = ((unsigned)s_thr) << 5;

  // ---- full pass: compact keys >= base ----
  #pragma unroll
  for (int p = 0; p < 8; p++) {
    u16x8 v = row8[p * 1024 + t];
    unsigned i0 = (unsigned)(p * 1024 + t) * 8;
    #pragma unroll
    for (int j = 0; j < 8; j++) {
      unsigned k = okey16(v[j]);
      if (k >= base) {
        unsigned slot = atomicAdd(&s_cnt, 1u);
        if (slot < CAP) { ckey[slot] = (unsigned short)k; cidx[slot] = i0 + j; }
      }
    }
  }
  __syncthreads();
  const unsigned total = s_cnt;        // >= 32 guaranteed

  unsigned L, istar = 0xFFFFFFFFu;
  if (total <= CAP) {
    for (int i = t; i < 2048; i += 1024) hist[i] = 0;
    __syncthreads();
    for (unsigned i = t; i < total; i += 1024)
      atomicAdd(&hist[(unsigned)ckey[i] >> 5], 1u);
    __syncthreads();
    find_thr16(hist, 2048, 32, t, lane, wid, wsum, &s_thr, &s_above);
    const unsigned T1 = (unsigned)s_thr;
    const unsigned need2 = 32 - s_above;
    const unsigned cnt1 = hist[T1];
    if (cnt1 == need2) {
      L = T1 << 5;
    } else {
      for (unsigned i = t; i < total; i += 1024) {
        unsigned k = (unsigned)ckey[i];
        if ((k >> 5) == T1) atomicAdd(&h2[k & 31], 1u);
      }
      __syncthreads();
      if (t == 0) {
        unsigned cum = 0; int T3 = 0; unsigned above = 0;
        for (int j = 31; j >= 0; j--) {
          if (cum + h2[j] >= need2) { T3 = j; above = cum; break; }
          cum += h2[j];
        }
        sL = (T1 << 5) | (unsigned)T3;
        sneedEq = need2 - above;
        scntEq = h2[T3];
      }
      __syncthreads();
      L = sL;
      if (scntEq != sneedEq) {
        int prev = -1;
        for (unsigned j = 0; j < sneedEq; j++) {
          if (t == 0) s_imin = 0xFFFFFFFFu;
          __syncthreads();
          for (unsigned i = t; i < total; i += 1024)
            if ((unsigned)ckey[i] == L && (int)cidx[i] > prev) atomicMin(&s_imin, cidx[i]);
          __syncthreads();
          prev = (int)s_imin;
          __syncthreads();
        }
        istar = (unsigned)prev;
      }
    }
    __syncthreads();
    for (unsigned i = t; i < total; i += 1024) {
      unsigned k = (unsigned)ckey[i];
      if (k > L || (k == L && cidx[i] <= istar)) {
        unsigned s = atomicAdd(&s_na, 1u);
        slist[s] = (int)cidx[i];
      }
    }
    __syncthreads();
    if (t < 32) {
      int my = slist[t];
      int rank = 0;
      #pragma unroll
      for (int j = 0; j < 32; j++) rank += (slist[j] < my);
      oidx[n * Kt + rank] = my;
    }
  } else {
    // ======= fallback: full exact global algorithm =======
    for (int i = t; i < 2048; i += 1024) hist[i] = 0;
    __syncthreads();
    #pragma unroll
    for (int p = 0; p < 8; p++) {
      u16x8 v = row8[p * 1024 + t];
      #pragma unroll
      for (int j = 0; j < 8; j++) atomicAdd(&hist[okey16(v[j]) >> 5], 1u);
    }
    __syncthreads();
    find_thr16(hist, 2048, 32, t, lane, wid, wsum, &s_thr, &s_above);
    const unsigned T1 = (unsigned)s_thr;
    const unsigned need2 = 32 - s_above;
    const unsigned cnt1 = hist[T1];
    if (cnt1 == need2) {
      L = T1 << 5;
    } else {
      for (int p = 0; p < 8; p++) {
        u16x8 v = row8[p * 1024 + t];
        #pragma unroll
        for (int j = 0; j < 8; j++) {
          unsigned k = okey16(v[j]);
          if ((k >> 5) == T1) atomicAdd(&h2[k & 31], 1u);
        }
      }
      __syncthreads();
      if (t == 0) {
        unsigned cum = 0; int T3 = 0; unsigned above = 0;
        for (int j = 31; j >= 0; j--) {
          if (cum + h2[j] >= need2) { T3 = j; above = cum; break; }
          cum += h2[j];
        }
        sL = (T1 << 5) | (unsigned)T3;
        sneedEq = need2 - above;
        scntEq = h2[T3];
      }
      __syncthreads();
      L = sL;
      if (scntEq != sneedEq) {
        const unsigned short* rowp = simsb + (size_t)n * Mn;
        unsigned cntLoc = 0;
        for (int j = 0; j < 64; j++)
          if (okey16(rowp[t * 64 + j]) == L) cntLoc++;
        unsigned pre = blk_exscan16(cntLoc, wsum, lane, wid);
        unsigned c = 0;
        for (int j = 0; j < 64; j++)
          if (okey16(rowp[t * 64 + j]) == L) { if (pre + c < 32) slist[pre + c] = t * 64 + j; c++; }
        __syncthreads();
        istar = (unsigned)slist[sneedEq - 1];
        __syncthreads();
      }
    }
    __syncthreads();
    unsigned cnt = 0;
    for (int p = 0; p < 8; p++) {
      u16x8 v = row8[p * 1024 + t];
      unsigned i0 = (unsigned)(p * 1024 + t) * 8;
      #pragma unroll
      for (int j = 0; j < 8; j++) {
        unsigned k = okey16(v[j]);
        cnt += (k > L || (k == L && i0 + j <= istar));
      }
    }
    unsigned pos = blk_exscan16(cnt, wsum, lane, wid);
    for (int p = 0; p < 8; p++) {
      u16x8 v = row8[p * 1024 + t];
      unsigned i0 = (unsigned)(p * 1024 + t) * 8;
      #pragma unroll
      for (int j = 0; j < 8; j++) {
        unsigned k = okey16(v[j]);
        if (k > L || (k == L && i0 + j <= istar)) oidx[n * Kt + pos++] = (int)(i0 + j);
      }
    }
  }
}

// =============================== host ===============================
extern "C" void kernel_launch(void* const* d_in, const int* in_sizes, int n_in,
                              void* d_out, int out_size, void* d_ws, size_t ws_size,
                              hipStream_t stream) {
  (void)in_sizes; (void)n_in; (void)out_size;
  const float* x      = (const float*)d_in[0];
  const float* mem_k  = (const float*)d_in[1];
  const float* mem_v  = (const float*)d_in[2];
  const float* sa_w[4] = {(const float*)d_in[3], (const float*)d_in[4], (const float*)d_in[5], (const float*)d_in[6]};
  const float* sa_b[4] = {(const float*)d_in[7], (const float*)d_in[8], (const float*)d_in[9], (const float*)d_in[10]};
  const float* ma_w[4] = {(const float*)d_in[11], (const float*)d_in[12], (const float*)d_in[13], (const float*)d_in[14]};
  const float* ma_b[4] = {(const float*)d_in[15], (const float*)d_in[16], (const float*)d_in[17], (const float*)d_in[18]};
  const float* ln_g[3] = {(const float*)d_in[19], (const float*)d_in[21], (const float*)d_in[23]};
  const float* ln_b[3] = {(const float*)d_in[20], (const float*)d_in[22], (const float*)d_in[24]};
  const float* fc1_w = (const float*)d_in[25];
  const float* fc1_b = (const float*)d_in[26];
  const float* fc2_w = (const float*)d_in[27];
  const float* fc2_b = (const float*)d_in[28];
  float* out = (float*)d_out;

  char* ws = (char*)d_ws;
  size_t off = 0;
  auto alloc = [&](size_t bytes) -> char* {
    char* p = ws + off;
    off = (off + bytes + 255) & ~(size_t)255;
    return p;
  };

  unsigned short* wt[8];
  for (int i = 0; i < 8; i++) wt[i] = (unsigned short*)alloc((size_t)En * En * 2);  // contiguous
  unsigned short* fc1t  = (unsigned short*)alloc((size_t)FFn * En * 2);
  unsigned short* fc2t  = (unsigned short*)alloc((size_t)En * FFn * 2);
  unsigned short* xb    = (unsigned short*)alloc((size_t)NT * En * 2);
  unsigned short* Qb    = (unsigned short*)alloc((size_t)NT * En * 2);
  unsigned short* Kb    = (unsigned short*)alloc((size_t)NT * En * 2);
  unsigned short* Vb    = (unsigned short*)alloc((size_t)NT * En * 2);
  unsigned short* at1b  = (unsigned short*)alloc((size_t)NT * En * 2);
  float*          x1f   = (float*)alloc((size_t)NT * En * 4);
  unsigned short* x1b   = (unsigned short*)alloc((size_t)NT * En * 2);
  char*           simsRaw = alloc((size_t)NT * Mn * 4);                // 256 MiB region
  int*            idx   = (int*)alloc((size_t)NT * Kt * 4);
  unsigned short* K2b   = (unsigned short*)alloc((size_t)NT * Kt * En * 2);  // 64 MiB
  unsigned short* V2b   = (unsigned short*)alloc((size_t)NT * Kt * En * 2);  // V2t: [B][1024][8192]
  unsigned short* Q2b   = (unsigned short*)alloc((size_t)NT * En * 2);
  unsigned short* at2b  = (unsigned short*)alloc((size_t)NT * En * 2);
  float*          x2f   = (float*)alloc((size_t)NT * En * 4);
  unsigned short* x2b   = (unsigned short*)alloc((size_t)NT * En * 2);
  unsigned short* hb    = (unsigned short*)alloc((size_t)NT * FFn * 2);
  float*          pp    = (float*)alloc((size_t)4 * NT * En * 4);      // 16 MiB split-K partials
  float*          bcat_sa = (float*)alloc(3072 * 4);
  float*          bcat_ma = (float*)alloc(2048 * 4);

  if (off > ws_size) return;   // insufficient workspace: leave output poisoned (fail loudly)

  // Overlays within the 256 MiB sims region (uses strictly sequential):
  unsigned short* simsb = (unsigned short*)simsRaw;
  unsigned short* mkb = (unsigned short*)K2b;         // until sims GEMM done
  unsigned short* Ab2 = (unsigned short*)(simsRaw + (size_t)128 * 1024 * 1024);
  unsigned short* PO  = (unsigned short*)(simsRaw + (size_t)192 * 1024 * 1024);
  float* PM = (float*)(simsRaw + (size_t)224 * 1024 * 1024);
  float* PL = (float*)(simsRaw + (size_t)225 * 1024 * 1024);

  (void)hipFuncSetAttribute((const void*)&k_gemm256<5,false,1,0>,
                            hipFuncAttributeMaxDynamicSharedMemorySize, 131072);
  (void)hipFuncSetAttribute((const void*)&k_gemm256<6,false,2,1>,
                            hipFuncAttributeMaxDynamicSharedMemorySize, 131072);

  // ---- prep: weight transposes to bf16 [N][K], bias concats ----
  P8 p8;
  for (int i = 0; i < 4; i++) { p8.s[i] = sa_w[i]; p8.s[4 + i] = ma_w[i]; }
  k_transpose8<<<dim3(16, 16, 8), 256, 0, stream>>>(p8, wt[0]);
  k_transpose_bf16<<<dim3(64, 16), 256, 0, stream>>>(fc1_w, fc1t, En, FFn);
  k_transpose_bf16<<<dim3(16, 64), 256, 0, stream>>>(fc2_w, fc2t, FFn, En);
  k_concat3<<<dim3(12), 256, 0, stream>>>(sa_b[0], sa_b[1], sa_b[2], bcat_sa);
  k_concat3<<<dim3(8),  256, 0, stream>>>(ma_b[1], ma_b[2], ma_b[2], bcat_ma);

  k_cvt_bf16<<<dim3(NT * En / 4 / 256), 256, 0, stream>>>(x, xb, NT * En / 4);
  k_normcvt<<<dim3(Mn), 256, 0, stream>>>(mem_k, mkb);

  const dim3 g1(En / 128, NT / 128);        // (8,8)
  const dim3 g1s(En / 128, NT / 128, 4);    // split-K=4 -> 256 blocks

  // ---- self-attention (QKV fused, Q pre-scaled by 1/8) ----
  k_gemm<0,false,false,3,true,1><<<dim3(24, 8), 256, 0, stream>>>(xb, wt[0], nullptr, bcat_sa, nullptr, nullptr, Qb, Kb, Vb, 3072, En);
  k_attn_sa<<<dim3(Sn / 64, Hn, Bn), 256, 0, stream>>>(Qb, Kb, Vb, at1b, Sn);
  k_gemm<7,false,false,1,false,4><<<g1s, 256, 0, stream>>>(at1b, wt[3], nullptr, nullptr, nullptr, pp, nullptr, nullptr, nullptr, En, En);
  k_layernorm4<<<NT, 256, 0, stream>>>(pp, sa_b[3], x, ln_g[0], ln_b[0], x1f, x1b);

  // ---- retrieval: sims in bf16 + sampled-threshold top-k ----
  k_gemm256<5,false,1,0><<<dim3(1024), 512, 131072, stream>>>(
      x1b, mkb, nullptr, nullptr, nullptr, simsb, nullptr, Mn, En, NT / 256, Mn / 256);
  k_topk16<<<NT, 1024, 0, stream>>>(simsb, idx);

  // ---- memory cross-attention ----
  k_gathercvt<<<dim3(NT * Kt), 256, 0, stream>>>(mem_v, idx, Ab2);
  k_gemm256<6,false,2,1><<<dim3(1024), 512, 131072, stream>>>(
      Ab2, wt[5], nullptr, bcat_ma, nullptr, K2b, V2b, 2048, En, NT * Kt / 256, 2048 / 256);
  k_gemm<0,false,false,1,true,1><<<g1, 256, 0, stream>>>(x1b, wt[4], nullptr, ma_b[0], nullptr, nullptr, Q2b, nullptr, nullptr, En, En);
  k_attn_ma<<<dim3(16, Hn, Bn), 256, 0, stream>>>(Q2b, K2b, V2b, PO, PM, PL);
  k_attn_comb16<<<dim3(Bn * Hn * Sn / 4), 256, 0, stream>>>(PO, PM, PL, at2b);
  k_gemm<7,false,false,1,false,4><<<g1s, 256, 0, stream>>>(at2b, wt[7], nullptr, nullptr, nullptr, pp, nullptr, nullptr, nullptr, En, En);
  k_layernorm4<<<NT, 256, 0, stream>>>(pp, ma_b[3], x1f, ln_g[1], ln_b[1], x2f, x2b);

  // ---- FFN ----
  k_gemm<2,false,false,1,false,1><<<dim3(FFn / 128, NT / 128), 256, 0, stream>>>(x2b, fc1t, nullptr, fc1_b, nullptr, nullptr, hb, nullptr, nullptr, FFn, En);
  k_gemm<7,false,false,1,false,4><<<g1s, 256, 0, stream>>>(hb, fc2t, nullptr, nullptr, nullptr, pp, nullptr, nullptr, nullptr, En, FFn);
  k_layernorm4<<<NT, 256, 0, stream>>>(pp, fc2_b, x2f, ln_g[2], ln_b[2], out, nullptr);
}

// Round 16
// 749.549 us; speedup vs baseline: 1.7074x; 1.0554x over previous
//
#include <hip/hip_runtime.h>
#include <hip/hip_bf16.h>
#include <math.h>

#define DEVFN __device__ __forceinline__

typedef __attribute__((ext_vector_type(8))) short bf16x8;
typedef __attribute__((ext_vector_type(8))) unsigned short u16x8;
typedef __attribute__((ext_vector_type(4))) unsigned short u16x4;
typedef __attribute__((ext_vector_type(4))) float f32x4;

static constexpr int Bn = 4, Sn = 256, En = 1024, Hn = 16;
static constexpr int Mn = 65536, Kt = 32, FFn = 4096;
static constexpr int NT = Bn * Sn;           // 1024 tokens
static constexpr float QS = 0.18033688011112042f;   // 0.125 * log2(e): Q pre-scale (exp2 units)

DEVFN unsigned short f2b(float f) {          // f32 -> bf16 RNE
  unsigned int u = __float_as_uint(f);
  unsigned int r = (u + 0x7FFFu + ((u >> 16) & 1u)) >> 16;
  return (unsigned short)r;
}
DEVFN float b2f(unsigned short u) { return __uint_as_float((unsigned)u << 16); }

DEVFN unsigned okey16(unsigned short u) {    // order-preserving bf16 -> u16
  return (unsigned)(u ^ ((u >> 15) ? 0xFFFFu : 0x8000u)) & 0xFFFFu;
}

typedef const __attribute__((address_space(1))) void* as1cv_t;
typedef __attribute__((address_space(3))) void* as3v_t;
DEVFN void gload16(const void* g, void* l) {   // async global->LDS, 16B/lane
  __builtin_amdgcn_global_load_lds((as1cv_t)g, (as3v_t)l, 16, 0, 0);
}
#define MEMFENCE asm volatile("" ::: "memory")

struct P8 { const float* s[8]; };

// ---------------- batched transpose W[1024][1024] f32 -> out[C][R] bf16 ----------------
__global__ __launch_bounds__(256) void k_transpose8(
    P8 ps, unsigned short* __restrict__ outbase) {
  const float* in = ps.s[blockIdx.z];
  unsigned short* out = outbase + (size_t)blockIdx.z * En * En;
  __shared__ float tile[64][65];
  int tx = threadIdx.x & 63, ty = threadIdx.x >> 6;
  int c0 = blockIdx.x * 64, r0 = blockIdx.y * 64;
  #pragma unroll
  for (int i = 0; i < 16; i++) {
    int r = ty + i * 4;
    tile[tx][r] = in[(size_t)(r0 + r) * En + (c0 + tx)];
  }
  __syncthreads();
  #pragma unroll
  for (int i = 0; i < 16; i++) {
    int c = ty + i * 4;
    out[(size_t)(c0 + c) * En + (r0 + tx)] = f2b(tile[c][tx]);
  }
}

// ---------------- transpose W[R][C] f32 -> out[C][R] bf16 ----------------
__global__ __launch_bounds__(256) void k_transpose_bf16(
    const float* __restrict__ in, unsigned short* __restrict__ out, int R, int C) {
  __shared__ float tile[64][65];
  int tx = threadIdx.x & 63, ty = threadIdx.x >> 6;
  int c0 = blockIdx.x * 64, r0 = blockIdx.y * 64;
  #pragma unroll
  for (int i = 0; i < 16; i++) {
    int r = ty + i * 4;
    tile[tx][r] = in[(size_t)(r0 + r) * C + (c0 + tx)];
  }
  __syncthreads();
  #pragma unroll
  for (int i = 0; i < 16; i++) {
    int c = ty + i * 4;
    out[(size_t)(c0 + c) * R + (r0 + tx)] = f2b(tile[c][tx]);
  }
}

// ---------------- f32 -> bf16 elementwise (x4) ----------------
__global__ __launch_bounds__(256) void k_cvt_bf16(
    const float* __restrict__ in, unsigned short* __restrict__ out, int n4) {
  int i = blockIdx.x * 256 + threadIdx.x;
  if (i >= n4) return;
  float4 v = ((const float4*)in)[i];
  uint2 o;
  o.x = (unsigned int)f2b(v.x) | ((unsigned int)f2b(v.y) << 16);
  o.y = (unsigned int)f2b(v.z) | ((unsigned int)f2b(v.w) << 16);
  ((uint2*)out)[i] = o;
}

// ---- gather + cvt: out[r] = bf16(mem_v[idx[r]]), one 4KB row per block ----
__global__ __launch_bounds__(256) void k_gathercvt(
    const float* __restrict__ mv, const int* __restrict__ idx,
    unsigned short* __restrict__ out) {
  int r = blockIdx.x;
  int src = idx[r];
  float4 v = ((const float4*)(mv + (size_t)src * En))[threadIdx.x];
  uint2 o;
  o.x = (unsigned int)f2b(v.x) | ((unsigned int)f2b(v.y) << 16);
  o.y = (unsigned int)f2b(v.z) | ((unsigned int)f2b(v.w) << 16);
  ((uint2*)(out + (size_t)r * En))[threadIdx.x] = o;
}

// ---------------- concat up to 3 x 1024-f32 vectors ----------------
__global__ __launch_bounds__(256) void k_concat3(
    const float* __restrict__ a, const float* __restrict__ b,
    const float* __restrict__ c, float* __restrict__ o) {
  int i = blockIdx.x * 256 + threadIdx.x;
  float v = (i < 1024) ? a[i] : (i < 2048) ? b[i - 1024] : c[i - 2048];
  o[i] = v;
}

// ---- mem_keys row-normalize + cvt to bf16 (folds cosine norm into B) ----
__global__ __launch_bounds__(256) void k_normcvt(
    const float* __restrict__ mk, unsigned short* __restrict__ out) {
  int m = blockIdx.x, t = threadIdx.x;
  float4 v = ((const float4*)(mk + (size_t)m * En))[t];
  float ss = v.x*v.x + v.y*v.y + v.z*v.z + v.w*v.w;
  #pragma unroll
  for (int d = 32; d; d >>= 1) ss += __shfl_down(ss, d);
  __shared__ float red[4];
  int lane = t & 63, w = t >> 6;
  if (lane == 0) red[w] = ss;
  __syncthreads();
  float rs = 1.0f / fmaxf(sqrtf(red[0] + red[1] + red[2] + red[3]), 1e-12f);
  uint2 o;
  o.x = (unsigned int)f2b(v.x * rs) | ((unsigned int)f2b(v.y * rs) << 16);
  o.y = (unsigned int)f2b(v.z * rs) | ((unsigned int)f2b(v.w * rs) << 16);
  ((uint2*)(out + (size_t)m * En))[t] = o;
}

// ---- LayerNorm over (sum of 4 split-K partials + bias + resid) rows ----
__global__ __launch_bounds__(256) void k_layernorm4(
    const float* __restrict__ pp, const float* __restrict__ pbias,
    const float* __restrict__ resid,
    const float* __restrict__ g, const float* __restrict__ bb,
    float* __restrict__ outf, unsigned short* __restrict__ outb) {
  int n = blockIdx.x, t = threadIdx.x;
  const size_t PS = (size_t)NT * En / 4;   // plane stride in float4
  size_t i = (size_t)n * 256 + t;
  float4 p0 = ((const float4*)pp)[i];
  float4 p1 = ((const float4*)pp)[i + PS];
  float4 p2 = ((const float4*)pp)[i + 2 * PS];
  float4 p3 = ((const float4*)pp)[i + 3 * PS];
  float4 rv = ((const float4*)(resid + (size_t)n * En))[t];
  float4 bi = ((const float4*)pbias)[t];
  float4 v;
  v.x = (p0.x + p1.x) + (p2.x + p3.x) + bi.x + rv.x;
  v.y = (p0.y + p1.y) + (p2.y + p3.y) + bi.y + rv.y;
  v.z = (p0.z + p1.z) + (p2.z + p3.z) + bi.z + rv.z;
  v.w = (p0.w + p1.w) + (p2.w + p3.w) + bi.w + rv.w;
  float s  = v.x + v.y + v.z + v.w;
  float s2 = v.x*v.x + v.y*v.y + v.z*v.z + v.w*v.w;
  #pragma unroll
  for (int d = 32; d; d >>= 1) { s += __shfl_down(s, d); s2 += __shfl_down(s2, d); }
  __shared__ float rs[4], rq[4];
  int lane = t & 63, w = t >> 6;
  if (lane == 0) { rs[w] = s; rq[w] = s2; }
  __syncthreads();
  float mean = (rs[0]+rs[1]+rs[2]+rs[3]) * (1.0f/En);
  float var  = (rq[0]+rq[1]+rq[2]+rq[3]) * (1.0f/En) - mean*mean;
  float rstd = rsqrtf(var + 1e-5f);
  float4 gg = ((const float4*)g)[t];
  float4 bv = ((const float4*)bb)[t];
  float o0 = (v.x-mean)*rstd*gg.x + bv.x;
  float o1 = (v.y-mean)*rstd*gg.y + bv.y;
  float o2 = (v.z-mean)*rstd*gg.z + bv.z;
  float o3 = (v.w-mean)*rstd*gg.w + bv.w;
  if (outf) { float4 ov = {o0,o1,o2,o3}; ((float4*)(outf + (size_t)n*En))[t] = ov; }
  if (outb) {
    uint2 o;
    o.x = (unsigned int)f2b(o0) | ((unsigned int)f2b(o1) << 16);
    o.y = (unsigned int)f2b(o2) | ((unsigned int)f2b(o3) << 16);
    ((uint2*)(outb + (size_t)n*En))[t] = o;
  }
}

// ======== 256x256 GEMM, ring-4 half-tile buffers + counted vmcnt (minimal barriers) ====
// EPI 5: bf16 no-bias | EPI 6: split N=2048 -> cb0 row-major (+bias), cb1 TRANSPOSED
template<int EPI, int NOUT, int LSWZ>
__global__ __launch_bounds__(512) void k_gemm256(
    const unsigned short* __restrict__ Ab, const unsigned short* __restrict__ Bb,
    const float* __restrict__ bias,
    float* __restrict__ Cf, unsigned short* __restrict__ cb0, unsigned short* __restrict__ cb1,
    int Ndim, int Kdim, int nRT, int nCT) {
  extern __shared__ unsigned short lds[];
  const int t = threadIdx.x, lane = t & 63, w = t >> 6;
  const int wr = w >> 2, wc = w & 3, l15 = lane & 15, l4 = lane >> 4;
  const int lr2 = lane >> 2;
  const int cg  = (lane & 3) ^ (((lane >> 5) & 1) << 1);   // source pre-swizzle (involution)

  const int nwg = nRT * nCT;
  int lb = ((int)blockIdx.x % 8) * (nwg >> 3) + ((int)blockIdx.x >> 3);
  int rowT, colT;
  if (LSWZ == 0) { rowT = lb % nRT; colT = lb / nRT; }
  else           { colT = lb % nCT; rowT = lb / nCT; }
  const int row0 = rowT * 256, col0 = colT * 256;

  auto pa = [&](int h) -> unsigned short* { return lds + h * 16384; };
  auto pb = [&](int h) -> unsigned short* { return lds + h * 16384 + 8192; };

  const unsigned short* aSrc0 = Ab + (size_t)(row0 + w * 32 + lr2) * Kdim + cg * 8;
  const unsigned short* aSrc1 = aSrc0 + (size_t)16 * Kdim;
  const unsigned short* bSrc0 = Bb + (size_t)(col0 + w * 32 + lr2) * Kdim + cg * 8;
  const unsigned short* bSrc1 = bSrc0 + (size_t)16 * Kdim;

  f32x4 acc[8][4];
  #pragma unroll
  for (int i = 0; i < 8; i++)
    #pragma unroll
    for (int j = 0; j < 4; j++) acc[i][j] = (f32x4){0.f, 0.f, 0.f, 0.f};

  const int NH = Kdim >> 5;                 // K half-tiles of 32
  #pragma unroll
  for (int h = 0; h < 3; ++h) {
    const int ko = h * 32;
    gload16(aSrc0 + ko, pa(h) + w*32*32);
    gload16(aSrc1 + ko, pa(h) + (w*32+16)*32);
    gload16(bSrc0 + ko, pb(h) + w*32*32);
    gload16(bSrc1 + ko, pb(h) + (w*32+16)*32);
  }
  asm volatile("s_waitcnt vmcnt(8)" ::: "memory");   // half 0 landed
  __builtin_amdgcn_s_barrier();
  MEMFENCE;

  for (int hs = 0; hs < NH; ++hs) {
    const int cur = hs & 3;
    const unsigned short* Ap = pa(cur);
    const unsigned short* Bp = pb(cur);
    const int h3 = (hs + 3) & 3, ko3 = (hs + 3) * 32;
    const bool pf = (hs + 3) < NH;
    bf16x8 bfr[4], af[4];

    // ---- cluster 0: B frags + A rows 0..63, stage A pair ----
    #pragma unroll
    for (int ni = 0; ni < 4; ni++) {
      int row = wc * 64 + ni * 16 + l15;
      int c8 = l4 ^ (((row >> 3) & 1) << 1);
      bfr[ni] = *(const bf16x8*)&Bp[row * 32 + c8 * 8];
    }
    #pragma unroll
    for (int m = 0; m < 4; m++) {
      int row = wr * 128 + m * 16 + l15;
      int c8 = l4 ^ (((row >> 3) & 1) << 1);
      af[m] = *(const bf16x8*)&Ap[row * 32 + c8 * 8];
    }
    if (pf) {
      gload16(aSrc0 + ko3, pa(h3) + w*32*32);
      gload16(aSrc1 + ko3, pa(h3) + (w*32+16)*32);
    }
    __builtin_amdgcn_s_setprio(1);
    #pragma unroll
    for (int m = 0; m < 4; m++)
      #pragma unroll
      for (int ni = 0; ni < 4; ni++)
        acc[m][ni] = __builtin_amdgcn_mfma_f32_16x16x32_bf16(af[m], bfr[ni], acc[m][ni], 0, 0, 0);
    __builtin_amdgcn_s_setprio(0);

    // ---- cluster 1: A rows 64..127, stage B pair ----
    #pragma unroll
    for (int m = 0; m < 4; m++) {
      int row = wr * 128 + (4 + m) * 16 + l15;
      int c8 = l4 ^ (((row >> 3) & 1) << 1);
      af[m] = *(const bf16x8*)&Ap[row * 32 + c8 * 8];
    }
    if (pf) {
      gload16(bSrc0 + ko3, pb(h3) + w*32*32);
      gload16(bSrc1 + ko3, pb(h3) + (w*32+16)*32);
    }
    __builtin_amdgcn_s_setprio(1);
    #pragma unroll
    for (int m = 0; m < 4; m++)
      #pragma unroll
      for (int ni = 0; ni < 4; ni++)
        acc[4 + m][ni] = __builtin_amdgcn_mfma_f32_16x16x32_bf16(af[m], bfr[ni], acc[4 + m][ni], 0, 0, 0);
    __builtin_amdgcn_s_setprio(0);

    // ---- boundary: counted wait for half hs+1, single barrier per half-tile ----
    if (hs + 1 < NH) {
      const int rem = NH - 2 - hs;
      if (rem >= 2)      asm volatile("s_waitcnt vmcnt(8)" ::: "memory");
      else if (rem == 1) asm volatile("s_waitcnt vmcnt(4)" ::: "memory");
      else               asm volatile("s_waitcnt vmcnt(0)" ::: "memory");
      __builtin_amdgcn_s_barrier();
      MEMFENCE;
    }
  }

  #pragma unroll
  for (int m = 0; m < 8; m++) {
    #pragma unroll
    for (int ni = 0; ni < 4; ni++) {
      int col  = col0 + wc * 64 + ni * 16 + l15;
      int rowb = row0 + wr * 128 + m * 16 + l4 * 4;
      if constexpr (EPI == 6) {
        if (col < 1024) {
          #pragma unroll
          for (int r = 0; r < 4; r++)
            cb0[(size_t)(rowb + r) * 1024 + col] = f2b(acc[m][ni][r] + bias[col]);
        } else {
          int c = col - 1024;
          int bi = rowb >> 13, k0 = rowb & 8191;
          u16x4 o;
          #pragma unroll
          for (int r = 0; r < 4; r++) o[r] = f2b(acc[m][ni][r] + bias[col]);
          *(u16x4*)&cb1[((size_t)bi * 1024 + c) * 8192 + k0] = o;
        }
      } else {
        #pragma unroll
        for (int r = 0; r < 4; r++)
          cb0[(size_t)(rowb + r) * Ndim + col] = f2b(acc[m][ni][r]);
      }
    }
  }
}

// ---- GEMM 128x128, ring-3 half-tile buffers + counted vmcnt (minimal barriers) ----
// EPI 0: bf16 (+bias) [NOUT>1: split into cb0/1/2] | EPI 2: GELU->bf16 | EPI 7: f32 partial
// QSC: scale output by QS (Q pre-scale, exp2 units). SK>1: split-K via blockIdx.z.
template<int EPI, int NOUT, bool QSC, int SK>
__global__ __launch_bounds__(256) void k_gemm(
    const unsigned short* __restrict__ Ab, const unsigned short* __restrict__ Bb,
    const float* __restrict__ bias,
    float* __restrict__ Cf, unsigned short* __restrict__ cb0,
    unsigned short* __restrict__ cb1, unsigned short* __restrict__ cb2,
    int Ndim, int Kdim) {
  __shared__ unsigned short ring[3][2][128 * 32];   // 48 KiB: [buf][A|B][row*32]
  const int t = threadIdx.x, lane = t & 63, w = t >> 6;
  const int wr = w >> 1, wc = w & 1, l15 = lane & 15, l4 = lane >> 4;
  const int lr2 = lane >> 2;
  const int cg  = (lane & 3) ^ (((lane >> 5) & 1) << 1);   // source pre-swizzle
  const int row0 = blockIdx.y * 128;
  const int col0 = blockIdx.x * 128;
  const int koff = (SK > 1) ? (int)blockIdx.z * (Kdim / SK) : 0;
  const int NH = ((SK > 1) ? (Kdim / SK) : Kdim) >> 5;

  const unsigned short* aSrc0 = Ab + (size_t)(row0 + w * 32 + lr2) * Kdim + koff + cg * 8;
  const unsigned short* aSrc1 = aSrc0 + (size_t)16 * Kdim;
  const unsigned short* bSrc0 = Bb + (size_t)(col0 + w * 32 + lr2) * Kdim + koff + cg * 8;
  const unsigned short* bSrc1 = bSrc0 + (size_t)16 * Kdim;

  f32x4 acc[4][4];
  #pragma unroll
  for (int i = 0; i < 4; i++)
    #pragma unroll
    for (int j = 0; j < 4; j++) acc[i][j] = (f32x4){0.f,0.f,0.f,0.f};

  auto stage = [&](int h, int buf) {
    const int ko = h * 32;
    gload16(aSrc0 + ko, &ring[buf][0][w * 32 * 32]);
    gload16(aSrc1 + ko, &ring[buf][0][(w * 32 + 16) * 32]);
    gload16(bSrc0 + ko, &ring[buf][1][w * 32 * 32]);
    gload16(bSrc1 + ko, &ring[buf][1][(w * 32 + 16) * 32]);
  };

  stage(0, 0);
  stage(1, 1);
  asm volatile("s_waitcnt vmcnt(4)" ::: "memory");   // half 0 landed
  __builtin_amdgcn_s_barrier();
  MEMFENCE;

  int cur = 0;
  for (int hs = 0; hs < NH; ++hs) {
    const unsigned short* Ap = &ring[cur][0][0];
    const unsigned short* Bp = &ring[cur][1][0];
    bf16x8 af[4], bfr[4];
    #pragma unroll
    for (int ni = 0; ni < 4; ni++) {
      int row = wc * 64 + ni * 16 + l15;
      int c8 = l4 ^ (((row >> 3) & 1) << 1);
      bfr[ni] = *(const bf16x8*)&Bp[row * 32 + c8 * 8];
    }
    #pragma unroll
    for (int m = 0; m < 4; m++) {
      int row = wr * 64 + m * 16 + l15;
      int c8 = l4 ^ (((row >> 3) & 1) << 1);
      af[m] = *(const bf16x8*)&Ap[row * 32 + c8 * 8];
    }
    if (hs + 2 < NH) {
      int nb = cur + 2; if (nb >= 3) nb -= 3;
      stage(hs + 2, nb);
    }
    __builtin_amdgcn_s_setprio(1);
    #pragma unroll
    for (int mi = 0; mi < 4; mi++)
      #pragma unroll
      for (int ni = 0; ni < 4; ni++)
        acc[mi][ni] = __builtin_amdgcn_mfma_f32_16x16x32_bf16(af[mi], bfr[ni], acc[mi][ni], 0, 0, 0);
    __builtin_amdgcn_s_setprio(0);
    if (hs + 1 < NH) {
      if (hs + 2 < NH) asm volatile("s_waitcnt vmcnt(4)" ::: "memory");
      else             asm volatile("s_waitcnt vmcnt(0)" ::: "memory");
      __builtin_amdgcn_s_barrier();
      MEMFENCE;
    }
    cur = cur + 1; if (cur >= 3) cur -= 3;
  }

  unsigned short* cbase = cb0;
  int colsub = 0;
  float qsc = 1.0f;
  if constexpr (NOUT > 1) {
    int which = col0 >> 10;
    cbase = (which == 0) ? cb0 : (which == 1) ? cb1 : cb2;
    colsub = col0 & 1023;
    if (QSC && which == 0) qsc = QS;
  } else if constexpr (QSC) {
    qsc = QS;
  }
  float* Cfp = Cf;
  if constexpr (EPI == 7) Cfp = Cf + (size_t)blockIdx.z * NT * En;

  #pragma unroll
  for (int mi = 0; mi < 4; mi++) {
    #pragma unroll
    for (int ni = 0; ni < 4; ni++) {
      int col  = col0 + wc*64 + ni*16 + l15;
      int rowb = row0 + wr*64 + mi*16 + l4*4;
      #pragma unroll
      for (int r = 0; r < 4; r++) {
        float v = acc[mi][ni][r];
        size_t off = (size_t)(rowb + r) * Ndim + col;
        if constexpr (EPI == 0) {
          if constexpr (NOUT > 1) {
            int c2 = colsub + wc*64 + ni*16 + l15;
            cbase[(size_t)(rowb + r) * 1024 + c2] = f2b((v + bias[col]) * qsc);
          } else {
            cb0[off] = f2b((v + bias[col]) * qsc);
          }
        } else if constexpr (EPI == 2) {
          float u = v + bias[col];
          u = 0.5f * u * (1.0f + erff(u * 0.70710678118654752f));
          cb0[off] = f2b(u);
        } else if constexpr (EPI == 7) {
          Cfp[off] = v;
        } else {
          Cf[off] = v;
        }
      }
    }
  }
}

// ---------------- SA fused attention (Q in exp2 units, T13 defer-max, deferred l) ------
__global__ __launch_bounds__(256) void k_attn_sa(
    const unsigned short* __restrict__ Qp, const unsigned short* __restrict__ Kp,
    const unsigned short* __restrict__ Vp, unsigned short* __restrict__ Op, int Lk) {
  __shared__ unsigned short Ks[64][72];
  __shared__ unsigned short Vt[64][72];
  __shared__ float Ps[4][16][68];
  const int b = blockIdx.z;
  const int h = blockIdx.y, q0 = blockIdx.x * 64;
  const int t = threadIdx.x, lane = t & 63, w = t >> 6;
  const int l15 = lane & 15, l4 = lane >> 4;

  const int qrow = q0 + w * 16 + l15;
  const unsigned short* qptr = Qp + (size_t)(b * Sn + qrow) * En + h * 64 + l4 * 8;
  bf16x8 qf0 = *(const bf16x8*)qptr;
  bf16x8 qf1 = *(const bf16x8*)(qptr + 32);

  f32x4 oacc[4];
  #pragma unroll
  for (int i = 0; i < 4; i++) oacc[i] = (f32x4){0.f,0.f,0.f,0.f};
  float m_[4] = {-INFINITY, -INFINITY, -INFINITY, -INFINITY};
  float l_[4] = {0.f, 0.f, 0.f, 0.f};

  const int nkt = Lk / 64;
  for (int kt = 0; kt < nkt; ++kt) {
    __syncthreads();
    #pragma unroll
    for (int i = 0; i < 2; i++) {
      int ld = t + i * 256;
      int kr = ld >> 3, d8 = (ld & 7) * 8;
      size_t base = (size_t)(b * Lk + kt * 64 + kr) * En + h * 64 + d8;
      *(uint4*)&Ks[kr][d8] = *(const uint4*)(Kp + base);
      bf16x8 vv = *(const bf16x8*)(Vp + base);
      int colswz = kr ^ ((t & 7) << 3);
      #pragma unroll
      for (int j = 0; j < 8; j++) Vt[d8 + j][colswz] = ((unsigned short*)&vv)[j];
    }
    __syncthreads();

    f32x4 s[4];
    #pragma unroll
    for (int ni = 0; ni < 4; ni++) {
      s[ni] = (f32x4){0.f,0.f,0.f,0.f};
      bf16x8 kb0 = *(const bf16x8*)&Ks[ni*16 + l15][l4*8];
      bf16x8 kb1 = *(const bf16x8*)&Ks[ni*16 + l15][l4*8 + 32];
      s[ni] = __builtin_amdgcn_mfma_f32_16x16x32_bf16(qf0, kb0, s[ni], 0, 0, 0);
      s[ni] = __builtin_amdgcn_mfma_f32_16x16x32_bf16(qf1, kb1, s[ni], 0, 0, 0);
    }

    #pragma unroll
    for (int r = 0; r < 4; r++) {
      float mx = fmaxf(fmaxf(s[0][r], s[1][r]), fmaxf(s[2][r], s[3][r]));
      #pragma unroll
      for (int d2 = 1; d2 < 16; d2 <<= 1) mx = fmaxf(mx, __shfl_xor(mx, d2));
      float m = m_[r];
      if (mx > m + 8.f) {                    // T13: rescale only on large jump
        float alpha = exp2f(m - mx);
        l_[r] *= alpha;
        #pragma unroll
        for (int nd = 0; nd < 4; nd++) oacc[nd][r] *= alpha;
        m = mx; m_[r] = mx;
      }
      float p0 = exp2f(s[0][r] - m), p1 = exp2f(s[1][r] - m);
      float p2 = exp2f(s[2][r] - m), p3 = exp2f(s[3][r] - m);
      s[0][r] = p0; s[1][r] = p1; s[2][r] = p2; s[3][r] = p3;
      l_[r] += (p0 + p1) + (p2 + p3);        // per-lane partial; reduce at end
    }

    #pragma unroll
    for (int ni = 0; ni < 4; ni++)
      #pragma unroll
      for (int r = 0; r < 4; r++)
        Ps[w][l4*4 + r][ni*16 + l15] = s[ni][r];
    asm volatile("s_waitcnt lgkmcnt(0)" ::: "memory");

    #pragma unroll
    for (int half = 0; half < 2; half++) {
      float4 pv0 = *(const float4*)&Ps[w][l15][half*32 + l4*8];
      float4 pv1 = *(const float4*)&Ps[w][l15][half*32 + l4*8 + 4];
      bf16x8 pa;
      pa[0]=(short)f2b(pv0.x); pa[1]=(short)f2b(pv0.y); pa[2]=(short)f2b(pv0.z); pa[3]=(short)f2b(pv0.w);
      pa[4]=(short)f2b(pv1.x); pa[5]=(short)f2b(pv1.y); pa[6]=(short)f2b(pv1.z); pa[7]=(short)f2b(pv1.w);
      #pragma unroll
      for (int nd = 0; nd < 4; nd++) {
        int dd = nd*16 + l15;
        bf16x8 vb = *(const bf16x8*)&Vt[dd][(half*32 + l4*8) ^ (((dd >> 3) & 7) << 3)];
        oacc[nd] = __builtin_amdgcn_mfma_f32_16x16x32_bf16(pa, vb, oacc[nd], 0, 0, 0);
      }
    }
  }

  #pragma unroll
  for (int r = 0; r < 4; r++) {              // final 16-lane l reduce
    float lv = l_[r];
    #pragma unroll
    for (int d2 = 1; d2 < 16; d2 <<= 1) lv += __shfl_xor(lv, d2);
    l_[r] = lv;
  }
  #pragma unroll
  for (int nd = 0; nd < 4; nd++)
    #pragma unroll
    for (int r = 0; r < 4; r++) {
      int q = q0 + w*16 + l4*4 + r;
      Op[(size_t)(b * Sn + q) * En + h * 64 + nd*16 + l15] = f2b(oacc[nd][r] / l_[r]);
    }
}

// ------- MA attention: 4 q-tiles folded, SPLIT=16, dbuf VT staging, lean softmax -------
__global__ __launch_bounds__(256, 2) void k_attn_ma(
    const unsigned short* __restrict__ Qp, const unsigned short* __restrict__ Kp,
    const unsigned short* __restrict__ Vp,
    unsigned short* __restrict__ PO, float* __restrict__ PM, float* __restrict__ PL) {
  constexpr int Lk = Sn * Kt;            // 8192
  constexpr int NTI = 8;                 // k-tiles per block (8192/64/16)
  __shared__ unsigned short Ks[2][64 * 64];
  __shared__ unsigned short Vt[2][64 * 64];
  __shared__ float Ps[4][16][68];
  const int sp = blockIdx.x, h = blockIdx.y, b = blockIdx.z;
  const int t = threadIdx.x, lane = t & 63, w = t >> 6;
  const int l15 = lane & 15, l4 = lane >> 4;
  const int l8 = lane >> 3, l7 = lane & 7;
  const int kswz = (l7 ^ l8) * 8;        // source pre-swizzle (row&7)
  const int rbase = w * 16;

  bf16x8 qf[4][2];
  #pragma unroll
  for (int qt = 0; qt < 4; qt++) {
    const unsigned short* qptr = Qp + (size_t)(b * Sn + w * 64 + qt * 16 + l15) * En + h * 64 + l4 * 8;
    qf[qt][0] = *(const bf16x8*)qptr;
    qf[qt][1] = *(const bf16x8*)(qptr + 32);
  }

  f32x4 oacc[4][4];
  #pragma unroll
  for (int i = 0; i < 4; i++)
    #pragma unroll
    for (int j = 0; j < 4; j++) oacc[i][j] = (f32x4){0.f,0.f,0.f,0.f};
  float m_[4][4], l_[4][4];
  #pragma unroll
  for (int i = 0; i < 4; i++)
    #pragma unroll
    for (int j = 0; j < 4; j++) { m_[i][j] = -INFINITY; l_[i][j] = 0.f; }

  const int kt0 = sp * NTI;
  auto stage = [&](int kt, int buf) {
    #pragma unroll
    for (int i = 0; i < 2; i++) {
      int row = rbase + i * 8 + l8;
      gload16(Kp + (size_t)(b * Lk + kt * 64 + row) * En + h * 64 + kswz,
              &Ks[buf][(rbase + i * 8) * 64]);
      gload16(Vp + ((size_t)b * 1024 + h * 64 + row) * (size_t)Lk + kt * 64 + kswz,
              &Vt[buf][(rbase + i * 8) * 64]);
    }
  };

  stage(kt0, 0);
  stage(kt0 + 1, 1);
  asm volatile("s_waitcnt vmcnt(4)" ::: "memory");   // tile0 landed (Q drained too)
  __builtin_amdgcn_s_barrier();
  MEMFENCE;

  for (int j = 0; j < NTI; ++j) {
    const int cur = j & 1;
    #pragma unroll
    for (int qt = 0; qt < 4; qt++) {
      f32x4 s[4];
      #pragma unroll
      for (int ni = 0; ni < 4; ni++) {
        s[ni] = (f32x4){0.f,0.f,0.f,0.f};
        int rowK = ni * 16 + l15, sw = (rowK & 7) * 8;
        bf16x8 kb0 = *(const bf16x8*)&Ks[cur][rowK * 64 + ((l4 * 8) ^ sw)];
        bf16x8 kb1 = *(const bf16x8*)&Ks[cur][rowK * 64 + ((l4 * 8 + 32) ^ sw)];
        s[ni] = __builtin_amdgcn_mfma_f32_16x16x32_bf16(qf[qt][0], kb0, s[ni], 0, 0, 0);
        s[ni] = __builtin_amdgcn_mfma_f32_16x16x32_bf16(qf[qt][1], kb1, s[ni], 0, 0, 0);
      }
      #pragma unroll
      for (int r = 0; r < 4; r++) {
        float mx = fmaxf(fmaxf(s[0][r], s[1][r]), fmaxf(s[2][r], s[3][r]));
        #pragma unroll
        for (int d2 = 1; d2 < 16; d2 <<= 1) mx = fmaxf(mx, __shfl_xor(mx, d2));
        float m = m_[qt][r];
        if (mx > m + 8.f) {                  // T13 defer-max (exp2 units)
          float alpha = exp2f(m - mx);
          l_[qt][r] *= alpha;
          #pragma unroll
          for (int nd = 0; nd < 4; nd++) oacc[qt][nd][r] *= alpha;
          m = mx; m_[qt][r] = mx;
        }
        float p0 = exp2f(s[0][r] - m), p1 = exp2f(s[1][r] - m);
        float p2 = exp2f(s[2][r] - m), p3 = exp2f(s[3][r] - m);
        s[0][r] = p0; s[1][r] = p1; s[2][r] = p2; s[3][r] = p3;
        l_[qt][r] += (p0 + p1) + (p2 + p3);  // per-lane partial
      }
      #pragma unroll
      for (int ni = 0; ni < 4; ni++)
        #pragma unroll
        for (int r = 0; r < 4; r++)
          Ps[w][l4*4 + r][ni*16 + l15] = s[ni][r];
      asm volatile("s_waitcnt lgkmcnt(0)" ::: "memory");
      #pragma unroll
      for (int half = 0; half < 2; half++) {
        float4 pv0 = *(const float4*)&Ps[w][l15][half*32 + l4*8];
        float4 pv1 = *(const float4*)&Ps[w][l15][half*32 + l4*8 + 4];
        bf16x8 pa;
        pa[0]=(short)f2b(pv0.x); pa[1]=(short)f2b(pv0.y); pa[2]=(short)f2b(pv0.z); pa[3]=(short)f2b(pv0.w);
        pa[4]=(short)f2b(pv1.x); pa[5]=(short)f2b(pv1.y); pa[6]=(short)f2b(pv1.z); pa[7]=(short)f2b(pv1.w);
        #pragma unroll
        for (int nd = 0; nd < 4; nd++) {
          int dd = nd*16 + l15;
          bf16x8 vb = *(const bf16x8*)&Vt[cur][dd * 64 + ((half*32 + l4*8) ^ ((dd & 7) * 8))];
          oacc[qt][nd] = __builtin_amdgcn_mfma_f32_16x16x32_bf16(pa, vb, oacc[qt][nd], 0, 0, 0);
        }
      }
    }
    MEMFENCE; __builtin_amdgcn_s_barrier(); MEMFENCE;
    if (j + 2 < NTI) stage(kt0 + j + 2, cur);
    if (j + 1 < NTI) {
      if (j + 2 < NTI) asm volatile("s_waitcnt vmcnt(4)" ::: "memory");
      else             asm volatile("s_waitcnt vmcnt(0)" ::: "memory");
      __builtin_amdgcn_s_barrier();
      MEMFENCE;
    }
  }

  #pragma unroll
  for (int qt = 0; qt < 4; qt++)             // final 16-lane l reduce
    #pragma unroll
    for (int r = 0; r < 4; r++) {
      float lv = l_[qt][r];
      #pragma unroll
      for (int d2 = 1; d2 < 16; d2 <<= 1) lv += __shfl_xor(lv, d2);
      l_[qt][r] = lv;
    }

  const int slot = (b * Hn + h) * 16 + sp;
  #pragma unroll
  for (int qt = 0; qt < 4; qt++)
    #pragma unroll
    for (int nd = 0; nd < 4; nd++)
      #pragma unroll
      for (int r = 0; r < 4; r++)
        PO[(size_t)slot * 16384 + (w*64 + qt*16 + l4*4 + r) * 64 + nd*16 + l15] = f2b(oacc[qt][nd][r]);
  if (l15 == 0) {
    #pragma unroll
    for (int qt = 0; qt < 4; qt++)
      #pragma unroll
      for (int r = 0; r < 4; r++) {
        PM[slot * 256 + w*64 + qt*16 + l4*4 + r] = m_[qt][r];
        PL[slot * 256 + w*64 + qt*16 + l4*4 + r] = l_[qt][r];
      }
  }
}

// ---------------- combine 16 split partials (bf16 PO, exp2 units) ----------------
__global__ __launch_bounds__(256) void k_attn_comb16(
    const unsigned short* __restrict__ PO, const float* __restrict__ PM,
    const float* __restrict__ PL, unsigned short* __restrict__ Op) {
  const int W = blockIdx.x * 4 + (threadIdx.x >> 6);  // (bh, q) row
  const int lane = threadIdx.x & 63;
  const int bh = W >> 8, q = W & 255;
  const int slotBase = bh * 16;
  float ms[16];
  float M = -INFINITY;
  #pragma unroll
  for (int s = 0; s < 16; s++) { ms[s] = PM[(slotBase + s) * 256 + q]; M = fmaxf(M, ms[s]); }
  float L = 0.f, acc = 0.f;
  #pragma unroll
  for (int s = 0; s < 16; s++) {
    float wgt = exp2f(ms[s] - M);
    L += PL[(slotBase + s) * 256 + q] * wgt;
    acc += wgt * b2f(PO[(size_t)(slotBase + s) * 16384 + q * 64 + lane]);
  }
  const int b = bh >> 4, h = bh & 15;
  Op[(size_t)(b * Sn + q) * En + h * 64 + lane] = f2b(acc / L);
}

// ------------- helpers for radix top-k (1024-thread blocks) -------------
DEVFN unsigned blk_exscan16(unsigned part, volatile unsigned* wsum, int lane, int wid) {
  unsigned v = part;
  #pragma unroll
  for (int d = 1; d < 64; d <<= 1) { unsigned o = __shfl_up(v, d); if (lane >= d) v += o; }
  if (lane == 63) wsum[wid] = v;
  __syncthreads();
  unsigned woff = 0;
  for (int i = 0; i < wid; i++) woff += wsum[i];
  unsigned r = woff + v - part;
  __syncthreads();
  return r;
}

DEVFN void find_thr16(const unsigned* hist, int NB, unsigned need,
                      int t, int lane, int wid, volatile unsigned* wsum,
                      volatile int* s_thr, volatile unsigned* s_above) {
  int per = NB >> 10;
  int lo = NB - per * (t + 1);
  unsigned part = 0;
  for (int j = 0; j < per; j++) part += hist[lo + j];
  unsigned ex = blk_exscan16(part, wsum, lane, wid);
  if (ex < need && ex + part >= need) {
    unsigned c = ex;
    for (int j = per - 1; j >= 0; j--) {
      unsigned h = hist[lo + j];
      if (c + h >= need) { *s_thr = lo + j; *s_above = c; break; }
      c += h;
    }
  }
  __syncthreads();
}

// ------- exact top-32: sampled threshold -> 1 compact pass -> in-LDS select -------
__global__ __launch_bounds__(1024) void k_topk16(
    const unsigned short* __restrict__ simsb, int* __restrict__ oidx) {
  const int n = blockIdx.x, t = threadIdx.x;
  const int lane = t & 63, wid = t >> 6;
  const u16x8* row8 = (const u16x8*)(simsb + (size_t)n * Mn);
  constexpr unsigned CAP = 2048;
  __shared__ unsigned hist[2048];
  __shared__ unsigned wsum[16];
  __shared__ int s_thr;
  __shared__ unsigned s_above;
  __shared__ unsigned h2[32];
  __shared__ unsigned s_cnt, s_na;
  __shared__ unsigned short ckey[CAP];
  __shared__ unsigned cidx[CAP];
  __shared__ int slist[32];
  __shared__ unsigned sL, sneedEq, scntEq, s_imin;

  for (int i = t; i < 2048; i += 1024) hist[i] = 0;
  if (t < 32) h2[t] = 0;
  if (t == 0) { s_cnt = 0; s_na = 0; }
  __syncthreads();

  // ---- sample pass: 1024 contiguous groups (16 KiB, middle of row) ----
  {
    u16x8 v = row8[3584 + t];
    #pragma unroll
    for (int j = 0; j < 8; j++) atomicAdd(&hist[okey16(v[j]) >> 5], 1u);
  }
  __syncthreads();
  find_thr16(hist, 2048, 32, t, lane, wid, wsum, &s_thr, &s_above);
  const unsigned base = ((unsigned)s_thr) << 5;

  // ---- full pass: compact keys >= base ----
  #pragma unroll
  for (int p = 0; p < 8; p++) {
    u16x8 v = row8[p * 1024 + t];
    unsigned i0 = (unsigned)(p * 1024 + t) * 8;
    #pragma unroll
    for (int j = 0; j < 8; j++) {
      unsigned k = okey16(v[j]);
      if (k >= base) {
        unsigned slot = atomicAdd(&s_cnt, 1u);
        if (slot < CAP) { ckey[slot] = (unsigned short)k; cidx[slot] = i0 + j; }
      }
    }
  }
  __syncthreads();
  const unsigned total = s_cnt;        // >= 32 guaranteed

  unsigned L, istar = 0xFFFFFFFFu;
  if (total <= CAP) {
    for (int i = t; i < 2048; i += 1024) hist[i] = 0;
    __syncthreads();
    for (unsigned i = t; i < total; i += 1024)
      atomicAdd(&hist[(unsigned)ckey[i] >> 5], 1u);
    __syncthreads();
    find_thr16(hist, 2048, 32, t, lane, wid, wsum, &s_thr, &s_above);
    const unsigned T1 = (unsigned)s_thr;
    const unsigned need2 = 32 - s_above;
    const unsigned cnt1 = hist[T1];
    if (cnt1 == need2) {
      L = T1 << 5;
    } else {
      for (unsigned i = t; i < total; i += 1024) {
        unsigned k = (unsigned)ckey[i];
        if ((k >> 5) == T1) atomicAdd(&h2[k & 31], 1u);
      }
      __syncthreads();
      if (t == 0) {
        unsigned cum = 0; int T3 = 0; unsigned above = 0;
        for (int j = 31; j >= 0; j--) {
          if (cum + h2[j] >= need2) { T3 = j; above = cum; break; }
          cum += h2[j];
        }
        sL = (T1 << 5) | (unsigned)T3;
        sneedEq = need2 - above;
        scntEq = h2[T3];
      }
      __syncthreads();
      L = sL;
      if (scntEq != sneedEq) {
        int prev = -1;
        for (unsigned j = 0; j < sneedEq; j++) {
          if (t == 0) s_imin = 0xFFFFFFFFu;
          __syncthreads();
          for (unsigned i = t; i < total; i += 1024)
            if ((unsigned)ckey[i] == L && (int)cidx[i] > prev) atomicMin(&s_imin, cidx[i]);
          __syncthreads();
          prev = (int)s_imin;
          __syncthreads();
        }
        istar = (unsigned)prev;
      }
    }
    __syncthreads();
    for (unsigned i = t; i < total; i += 1024) {
      unsigned k = (unsigned)ckey[i];
      if (k > L || (k == L && cidx[i] <= istar)) {
        unsigned s = atomicAdd(&s_na, 1u);
        slist[s] = (int)cidx[i];
      }
    }
    __syncthreads();
    if (t < 32) {
      int my = slist[t];
      int rank = 0;
      #pragma unroll
      for (int j = 0; j < 32; j++) rank += (slist[j] < my);
      oidx[n * Kt + rank] = my;
    }
  } else {
    // ======= fallback: full exact global algorithm =======
    for (int i = t; i < 2048; i += 1024) hist[i] = 0;
    __syncthreads();
    #pragma unroll
    for (int p = 0; p < 8; p++) {
      u16x8 v = row8[p * 1024 + t];
      #pragma unroll
      for (int j = 0; j < 8; j++) atomicAdd(&hist[okey16(v[j]) >> 5], 1u);
    }
    __syncthreads();
    find_thr16(hist, 2048, 32, t, lane, wid, wsum, &s_thr, &s_above);
    const unsigned T1 = (unsigned)s_thr;
    const unsigned need2 = 32 - s_above;
    const unsigned cnt1 = hist[T1];
    if (cnt1 == need2) {
      L = T1 << 5;
    } else {
      for (int p = 0; p < 8; p++) {
        u16x8 v = row8[p * 1024 + t];
        #pragma unroll
        for (int j = 0; j < 8; j++) {
          unsigned k = okey16(v[j]);
          if ((k >> 5) == T1) atomicAdd(&h2[k & 31], 1u);
        }
      }
      __syncthreads();
      if (t == 0) {
        unsigned cum = 0; int T3 = 0; unsigned above = 0;
        for (int j = 31; j >= 0; j--) {
          if (cum + h2[j] >= need2) { T3 = j; above = cum; break; }
          cum += h2[j];
        }
        sL = (T1 << 5) | (unsigned)T3;
        sneedEq = need2 - above;
        scntEq = h2[T3];
      }
      __syncthreads();
      L = sL;
      if (scntEq != sneedEq) {
        const unsigned short* rowp = simsb + (size_t)n * Mn;
        unsigned cntLoc = 0;
        for (int j = 0; j < 64; j++)
          if (okey16(rowp[t * 64 + j]) == L) cntLoc++;
        unsigned pre = blk_exscan16(cntLoc, wsum, lane, wid);
        unsigned c = 0;
        for (int j = 0; j < 64; j++)
          if (okey16(rowp[t * 64 + j]) == L) { if (pre + c < 32) slist[pre + c] = t * 64 + j; c++; }
        __syncthreads();
        istar = (unsigned)slist[sneedEq - 1];
        __syncthreads();
      }
    }
    __syncthreads();
    unsigned cnt = 0;
    for (int p = 0; p < 8; p++) {
      u16x8 v = row8[p * 1024 + t];
      unsigned i0 = (unsigned)(p * 1024 + t) * 8;
      #pragma unroll
      for (int j = 0; j < 8; j++) {
        unsigned k = okey16(v[j]);
        cnt += (k > L || (k == L && i0 + j <= istar));
      }
    }
    unsigned pos = blk_exscan16(cnt, wsum, lane, wid);
    for (int p = 0; p < 8; p++) {
      u16x8 v = row8[p * 1024 + t];
      unsigned i0 = (unsigned)(p * 1024 + t) * 8;
      #pragma unroll
      for (int j = 0; j < 8; j++) {
        unsigned k = okey16(v[j]);
        if (k > L || (k == L && i0 + j <= istar)) oidx[n * Kt + pos++] = (int)(i0 + j);
      }
    }
  }
}

// =============================== host ===============================
extern "C" void kernel_launch(void* const* d_in, const int* in_sizes, int n_in,
                              void* d_out, int out_size, void* d_ws, size_t ws_size,
                              hipStream_t stream) {
  (void)in_sizes; (void)n_in; (void)out_size;
  const float* x      = (const float*)d_in[0];
  const float* mem_k  = (const float*)d_in[1];
  const float* mem_v  = (const float*)d_in[2];
  const float* sa_w[4] = {(const float*)d_in[3], (const float*)d_in[4], (const float*)d_in[5], (const float*)d_in[6]};
  const float* sa_b[4] = {(const float*)d_in[7], (const float*)d_in[8], (const float*)d_in[9], (const float*)d_in[10]};
  const float* ma_w[4] = {(const float*)d_in[11], (const float*)d_in[12], (const float*)d_in[13], (const float*)d_in[14]};
  const float* ma_b[4] = {(const float*)d_in[15], (const float*)d_in[16], (const float*)d_in[17], (const float*)d_in[18]};
  const float* ln_g[3] = {(const float*)d_in[19], (const float*)d_in[21], (const float*)d_in[23]};
  const float* ln_b[3] = {(const float*)d_in[20], (const float*)d_in[22], (const float*)d_in[24]};
  const float* fc1_w = (const float*)d_in[25];
  const float* fc1_b = (const float*)d_in[26];
  const float* fc2_w = (const float*)d_in[27];
  const float* fc2_b = (const float*)d_in[28];
  float* out = (float*)d_out;

  char* ws = (char*)d_ws;
  size_t off = 0;
  auto alloc = [&](size_t bytes) -> char* {
    char* p = ws + off;
    off = (off + bytes + 255) & ~(size_t)255;
    return p;
  };

  unsigned short* wt[8];
  for (int i = 0; i < 8; i++) wt[i] = (unsigned short*)alloc((size_t)En * En * 2);  // contiguous
  unsigned short* fc1t  = (unsigned short*)alloc((size_t)FFn * En * 2);
  unsigned short* fc2t  = (unsigned short*)alloc((size_t)En * FFn * 2);
  unsigned short* xb    = (unsigned short*)alloc((size_t)NT * En * 2);
  unsigned short* Qb    = (unsigned short*)alloc((size_t)NT * En * 2);
  unsigned short* Kb    = (unsigned short*)alloc((size_t)NT * En * 2);
  unsigned short* Vb    = (unsigned short*)alloc((size_t)NT * En * 2);
  unsigned short* at1b  = (unsigned short*)alloc((size_t)NT * En * 2);
  float*          x1f   = (float*)alloc((size_t)NT * En * 4);
  unsigned short* x1b   = (unsigned short*)alloc((size_t)NT * En * 2);
  char*           simsRaw = alloc((size_t)NT * Mn * 4);                // 256 MiB region
  int*            idx   = (int*)alloc((size_t)NT * Kt * 4);
  unsigned short* K2b   = (unsigned short*)alloc((size_t)NT * Kt * En * 2);  // 64 MiB
  unsigned short* V2b   = (unsigned short*)alloc((size_t)NT * Kt * En * 2);  // V2t: [B][1024][8192]
  unsigned short* Q2b   = (unsigned short*)alloc((size_t)NT * En * 2);
  unsigned short* at2b  = (unsigned short*)alloc((size_t)NT * En * 2);
  float*          x2f   = (float*)alloc((size_t)NT * En * 4);
  unsigned short* x2b   = (unsigned short*)alloc((size_t)NT * En * 2);
  unsigned short* hb    = (unsigned short*)alloc((size_t)NT * FFn * 2);
  float*          pp    = (float*)alloc((size_t)4 * NT * En * 4);      // 16 MiB split-K partials
  float*          bcat_sa = (float*)alloc(3072 * 4);
  float*          bcat_ma = (float*)alloc(2048 * 4);

  if (off > ws_size) return;   // insufficient workspace: leave output poisoned (fail loudly)

  // Overlays within the 256 MiB sims region (uses strictly sequential):
  unsigned short* simsb = (unsigned short*)simsRaw;
  unsigned short* mkb = (unsigned short*)K2b;         // until sims GEMM done
  unsigned short* Ab2 = (unsigned short*)(simsRaw + (size_t)128 * 1024 * 1024);
  unsigned short* PO  = (unsigned short*)(simsRaw + (size_t)192 * 1024 * 1024);
  float* PM = (float*)(simsRaw + (size_t)224 * 1024 * 1024);
  float* PL = (float*)(simsRaw + (size_t)225 * 1024 * 1024);

  (void)hipFuncSetAttribute((const void*)&k_gemm256<5,1,0>,
                            hipFuncAttributeMaxDynamicSharedMemorySize, 131072);
  (void)hipFuncSetAttribute((const void*)&k_gemm256<6,2,1>,
                            hipFuncAttributeMaxDynamicSharedMemorySize, 131072);

  // ---- prep: weight transposes to bf16 [N][K], bias concats ----
  P8 p8;
  for (int i = 0; i < 4; i++) { p8.s[i] = sa_w[i]; p8.s[4 + i] = ma_w[i]; }
  k_transpose8<<<dim3(16, 16, 8), 256, 0, stream>>>(p8, wt[0]);
  k_transpose_bf16<<<dim3(64, 16), 256, 0, stream>>>(fc1_w, fc1t, En, FFn);
  k_transpose_bf16<<<dim3(16, 64), 256, 0, stream>>>(fc2_w, fc2t, FFn, En);
  k_concat3<<<dim3(12), 256, 0, stream>>>(sa_b[0], sa_b[1], sa_b[2], bcat_sa);
  k_concat3<<<dim3(8),  256, 0, stream>>>(ma_b[1], ma_b[2], ma_b[2], bcat_ma);

  k_cvt_bf16<<<dim3(NT * En / 4 / 256), 256, 0, stream>>>(x, xb, NT * En / 4);
  k_normcvt<<<dim3(Mn), 256, 0, stream>>>(mem_k, mkb);

  const dim3 g1(En / 128, NT / 128);        // (8,8)
  const dim3 g1s(En / 128, NT / 128, 4);    // split-K=4 -> 256 blocks

  // ---- self-attention (QKV fused, Q pre-scaled into exp2 units) ----
  k_gemm<0,3,true,1><<<dim3(24, 8), 256, 0, stream>>>(xb, wt[0], bcat_sa, nullptr, Qb, Kb, Vb, 3072, En);
  k_attn_sa<<<dim3(Sn / 64, Hn, Bn), 256, 0, stream>>>(Qb, Kb, Vb, at1b, Sn);
  k_gemm<7,1,false,4><<<g1s, 256, 0, stream>>>(at1b, wt[3], nullptr, pp, nullptr, nullptr, nullptr, En, En);
  k_layernorm4<<<NT, 256, 0, stream>>>(pp, sa_b[3], x, ln_g[0], ln_b[0], x1f, x1b);

  // ---- retrieval: sims in bf16 + sampled-threshold top-k ----
  k_gemm256<5,1,0><<<dim3(1024), 512, 131072, stream>>>(
      x1b, mkb, nullptr, nullptr, simsb, nullptr, Mn, En, NT / 256, Mn / 256);
  k_topk16<<<NT, 1024, 0, stream>>>(simsb, idx);

  // ---- memory cross-attention ----
  k_gathercvt<<<dim3(NT * Kt), 256, 0, stream>>>(mem_v, idx, Ab2);
  k_gemm256<6,2,1><<<dim3(1024), 512, 131072, stream>>>(
      Ab2, wt[5], bcat_ma, nullptr, K2b, V2b, 2048, En, NT * Kt / 256, 2048 / 256);
  k_gemm<0,1,true,1><<<g1, 256, 0, stream>>>(x1b, wt[4], ma_b[0], nullptr, Q2b, nullptr, nullptr, En, En);
  k_attn_ma<<<dim3(16, Hn, Bn), 256, 0, stream>>>(Q2b, K2b, V2b, PO, PM, PL);
  k_attn_comb16<<<dim3(Bn * Hn * Sn / 4), 256, 0, stream>>>(PO, PM, PL, at2b);
  k_gemm<7,1,false,4><<<g1s, 256, 0, stream>>>(at2b, wt[7], nullptr, pp, nullptr, nullptr, nullptr, En, En);
  k_layernorm4<<<NT, 256, 0, stream>>>(pp, ma_b[3], x1f, ln_g[1], ln_b[1], x2f, x2b);

  // ---- FFN ----
  k_gemm<2,1,false,1><<<dim3(FFn / 128, NT / 128), 256, 0, stream>>>(x2b, fc1t, fc1_b, nullptr, hb, nullptr, nullptr, FFn, En);
  k_gemm<7,1,false,4><<<g1s, 256, 0, stream>>>(hb, fc2t, nullptr, pp, nullptr, nullptr, nullptr, En, FFn);
  k_layernorm4<<<NT, 256, 0, stream>>>(pp, fc2_b, x2f, ln_g[2], ln_b[2], out, nullptr);
}

// Round 17
// 712.563 us; speedup vs baseline: 1.7960x; 1.0519x over previous
//
#include <hip/hip_runtime.h>
#include <hip/hip_bf16.h>
#include <math.h>

#define DEVFN __device__ __forceinline__

typedef __attribute__((ext_vector_type(8))) short bf16x8;
typedef __attribute__((ext_vector_type(8))) unsigned short u16x8;
typedef __attribute__((ext_vector_type(4))) unsigned short u16x4;
typedef __attribute__((ext_vector_type(4))) float f32x4;

static constexpr int Bn = 4, Sn = 256, En = 1024, Hn = 16;
static constexpr int Mn = 65536, Kt = 32, FFn = 4096;
static constexpr int NT = Bn * Sn;           // 1024 tokens
static constexpr float QS = 0.18033688011112042f;   // 0.125 * log2(e): Q pre-scale (exp2 units)

DEVFN unsigned short f2b(float f) {          // f32 -> bf16 RNE
  unsigned int u = __float_as_uint(f);
  unsigned int r = (u + 0x7FFFu + ((u >> 16) & 1u)) >> 16;
  return (unsigned short)r;
}
DEVFN float b2f(unsigned short u) { return __uint_as_float((unsigned)u << 16); }

DEVFN unsigned cvtpk(float lo, float hi) {   // pack 2 f32 -> 2 bf16 (lo in bits 0..15)
  unsigned r;
  asm volatile("v_cvt_pk_bf16_f32 %0, %1, %2" : "=v"(r) : "v"(lo), "v"(hi));
  return r;
}

DEVFN unsigned okey16(unsigned short u) {    // order-preserving bf16 -> u16
  return (unsigned)(u ^ ((u >> 15) ? 0xFFFFu : 0x8000u)) & 0xFFFFu;
}

typedef const __attribute__((address_space(1))) void* as1cv_t;
typedef __attribute__((address_space(3))) void* as3v_t;
DEVFN void gload16(const void* g, void* l) {   // async global->LDS, 16B/lane
  __builtin_amdgcn_global_load_lds((as1cv_t)g, (as3v_t)l, 16, 0, 0);
}
#define MEMFENCE asm volatile("" ::: "memory")

struct P8 { const float* s[8]; };

// ---------------- batched transpose W[1024][1024] f32 -> out[C][R] bf16 ----------------
__global__ __launch_bounds__(256) void k_transpose8(
    P8 ps, unsigned short* __restrict__ outbase) {
  const float* in = ps.s[blockIdx.z];
  unsigned short* out = outbase + (size_t)blockIdx.z * En * En;
  __shared__ float tile[64][65];
  int tx = threadIdx.x & 63, ty = threadIdx.x >> 6;
  int c0 = blockIdx.x * 64, r0 = blockIdx.y * 64;
  #pragma unroll
  for (int i = 0; i < 16; i++) {
    int r = ty + i * 4;
    tile[tx][r] = in[(size_t)(r0 + r) * En + (c0 + tx)];
  }
  __syncthreads();
  #pragma unroll
  for (int i = 0; i < 16; i++) {
    int c = ty + i * 4;
    out[(size_t)(c0 + c) * En + (r0 + tx)] = f2b(tile[c][tx]);
  }
}

// ---------------- transpose W[R][C] f32 -> out[C][R] bf16 ----------------
__global__ __launch_bounds__(256) void k_transpose_bf16(
    const float* __restrict__ in, unsigned short* __restrict__ out, int R, int C) {
  __shared__ float tile[64][65];
  int tx = threadIdx.x & 63, ty = threadIdx.x >> 6;
  int c0 = blockIdx.x * 64, r0 = blockIdx.y * 64;
  #pragma unroll
  for (int i = 0; i < 16; i++) {
    int r = ty + i * 4;
    tile[tx][r] = in[(size_t)(r0 + r) * C + (c0 + tx)];
  }
  __syncthreads();
  #pragma unroll
  for (int i = 0; i < 16; i++) {
    int c = ty + i * 4;
    out[(size_t)(c0 + c) * R + (r0 + tx)] = f2b(tile[c][tx]);
  }
}

// ---------------- f32 -> bf16 elementwise (x4) ----------------
__global__ __launch_bounds__(256) void k_cvt_bf16(
    const float* __restrict__ in, unsigned short* __restrict__ out, int n4) {
  int i = blockIdx.x * 256 + threadIdx.x;
  if (i >= n4) return;
  float4 v = ((const float4*)in)[i];
  uint2 o;
  o.x = (unsigned int)f2b(v.x) | ((unsigned int)f2b(v.y) << 16);
  o.y = (unsigned int)f2b(v.z) | ((unsigned int)f2b(v.w) << 16);
  ((uint2*)out)[i] = o;
}

// ---- gather + cvt: out[r] = bf16(mem_v[idx[r]]), one 4KB row per block ----
__global__ __launch_bounds__(256) void k_gathercvt(
    const float* __restrict__ mv, const int* __restrict__ idx,
    unsigned short* __restrict__ out) {
  int r = blockIdx.x;
  int src = idx[r];
  float4 v = ((const float4*)(mv + (size_t)src * En))[threadIdx.x];
  uint2 o;
  o.x = (unsigned int)f2b(v.x) | ((unsigned int)f2b(v.y) << 16);
  o.y = (unsigned int)f2b(v.z) | ((unsigned int)f2b(v.w) << 16);
  ((uint2*)(out + (size_t)r * En))[threadIdx.x] = o;
}

// ---------------- concat up to 3 x 1024-f32 vectors ----------------
__global__ __launch_bounds__(256) void k_concat3(
    const float* __restrict__ a, const float* __restrict__ b,
    const float* __restrict__ c, float* __restrict__ o) {
  int i = blockIdx.x * 256 + threadIdx.x;
  float v = (i < 1024) ? a[i] : (i < 2048) ? b[i - 1024] : c[i - 2048];
  o[i] = v;
}

// ---- mem_keys row-normalize + cvt to bf16 (folds cosine norm into B) ----
__global__ __launch_bounds__(256) void k_normcvt(
    const float* __restrict__ mk, unsigned short* __restrict__ out) {
  int m = blockIdx.x, t = threadIdx.x;
  float4 v = ((const float4*)(mk + (size_t)m * En))[t];
  float ss = v.x*v.x + v.y*v.y + v.z*v.z + v.w*v.w;
  #pragma unroll
  for (int d = 32; d; d >>= 1) ss += __shfl_down(ss, d);
  __shared__ float red[4];
  int lane = t & 63, w = t >> 6;
  if (lane == 0) red[w] = ss;
  __syncthreads();
  float rs = 1.0f / fmaxf(sqrtf(red[0] + red[1] + red[2] + red[3]), 1e-12f);
  uint2 o;
  o.x = (unsigned int)f2b(v.x * rs) | ((unsigned int)f2b(v.y * rs) << 16);
  o.y = (unsigned int)f2b(v.z * rs) | ((unsigned int)f2b(v.w * rs) << 16);
  ((uint2*)(out + (size_t)m * En))[t] = o;
}

// ---- LayerNorm over (sum of 4 split-K partials + bias + resid) rows ----
__global__ __launch_bounds__(256) void k_layernorm4(
    const float* __restrict__ pp, const float* __restrict__ pbias,
    const float* __restrict__ resid,
    const float* __restrict__ g, const float* __restrict__ bb,
    float* __restrict__ outf, unsigned short* __restrict__ outb) {
  int n = blockIdx.x, t = threadIdx.x;
  const size_t PS = (size_t)NT * En / 4;   // plane stride in float4
  size_t i = (size_t)n * 256 + t;
  float4 p0 = ((const float4*)pp)[i];
  float4 p1 = ((const float4*)pp)[i + PS];
  float4 p2 = ((const float4*)pp)[i + 2 * PS];
  float4 p3 = ((const float4*)pp)[i + 3 * PS];
  float4 rv = ((const float4*)(resid + (size_t)n * En))[t];
  float4 bi = ((const float4*)pbias)[t];
  float4 v;
  v.x = (p0.x + p1.x) + (p2.x + p3.x) + bi.x + rv.x;
  v.y = (p0.y + p1.y) + (p2.y + p3.y) + bi.y + rv.y;
  v.z = (p0.z + p1.z) + (p2.z + p3.z) + bi.z + rv.z;
  v.w = (p0.w + p1.w) + (p2.w + p3.w) + bi.w + rv.w;
  float s  = v.x + v.y + v.z + v.w;
  float s2 = v.x*v.x + v.y*v.y + v.z*v.z + v.w*v.w;
  #pragma unroll
  for (int d = 32; d; d >>= 1) { s += __shfl_down(s, d); s2 += __shfl_down(s2, d); }
  __shared__ float rs[4], rq[4];
  int lane = t & 63, w = t >> 6;
  if (lane == 0) { rs[w] = s; rq[w] = s2; }
  __syncthreads();
  float mean = (rs[0]+rs[1]+rs[2]+rs[3]) * (1.0f/En);
  float var  = (rq[0]+rq[1]+rq[2]+rq[3]) * (1.0f/En) - mean*mean;
  float rstd = rsqrtf(var + 1e-5f);
  float4 gg = ((const float4*)g)[t];
  float4 bv = ((const float4*)bb)[t];
  float o0 = (v.x-mean)*rstd*gg.x + bv.x;
  float o1 = (v.y-mean)*rstd*gg.y + bv.y;
  float o2 = (v.z-mean)*rstd*gg.z + bv.z;
  float o3 = (v.w-mean)*rstd*gg.w + bv.w;
  if (outf) { float4 ov = {o0,o1,o2,o3}; ((float4*)(outf + (size_t)n*En))[t] = ov; }
  if (outb) {
    uint2 o;
    o.x = (unsigned int)f2b(o0) | ((unsigned int)f2b(o1) << 16);
    o.y = (unsigned int)f2b(o2) | ((unsigned int)f2b(o3) << 16);
    ((uint2*)(outb + (size_t)n*En))[t] = o;
  }
}

// ======== 256x256 GEMM, ring-4 half-tile buffers + counted vmcnt (minimal barriers) ====
// EPI 5: bf16 no-bias | EPI 6: split N=2048 -> cb0 row-major (+bias), cb1 TRANSPOSED
template<int EPI, int NOUT, int LSWZ>
__global__ __launch_bounds__(512) void k_gemm256(
    const unsigned short* __restrict__ Ab, const unsigned short* __restrict__ Bb,
    const float* __restrict__ bias,
    float* __restrict__ Cf, unsigned short* __restrict__ cb0, unsigned short* __restrict__ cb1,
    int Ndim, int Kdim, int nRT, int nCT) {
  extern __shared__ unsigned short lds[];
  const int t = threadIdx.x, lane = t & 63, w = t >> 6;
  const int wr = w >> 2, wc = w & 3, l15 = lane & 15, l4 = lane >> 4;
  const int lr2 = lane >> 2;
  const int cg  = (lane & 3) ^ (((lane >> 5) & 1) << 1);   // source pre-swizzle (involution)

  const int nwg = nRT * nCT;
  int lb = ((int)blockIdx.x % 8) * (nwg >> 3) + ((int)blockIdx.x >> 3);
  int rowT, colT;
  if (LSWZ == 0) { rowT = lb % nRT; colT = lb / nRT; }
  else           { colT = lb % nCT; rowT = lb / nCT; }
  const int row0 = rowT * 256, col0 = colT * 256;

  auto pa = [&](int h) -> unsigned short* { return lds + h * 16384; };
  auto pb = [&](int h) -> unsigned short* { return lds + h * 16384 + 8192; };

  const unsigned short* aSrc0 = Ab + (size_t)(row0 + w * 32 + lr2) * Kdim + cg * 8;
  const unsigned short* aSrc1 = aSrc0 + (size_t)16 * Kdim;
  const unsigned short* bSrc0 = Bb + (size_t)(col0 + w * 32 + lr2) * Kdim + cg * 8;
  const unsigned short* bSrc1 = bSrc0 + (size_t)16 * Kdim;

  f32x4 acc[8][4];
  #pragma unroll
  for (int i = 0; i < 8; i++)
    #pragma unroll
    for (int j = 0; j < 4; j++) acc[i][j] = (f32x4){0.f, 0.f, 0.f, 0.f};

  const int NH = Kdim >> 5;                 // K half-tiles of 32
  #pragma unroll
  for (int h = 0; h < 3; ++h) {
    const int ko = h * 32;
    gload16(aSrc0 + ko, pa(h) + w*32*32);
    gload16(aSrc1 + ko, pa(h) + (w*32+16)*32);
    gload16(bSrc0 + ko, pb(h) + w*32*32);
    gload16(bSrc1 + ko, pb(h) + (w*32+16)*32);
  }
  asm volatile("s_waitcnt vmcnt(8)" ::: "memory");   // half 0 landed
  __builtin_amdgcn_s_barrier();
  MEMFENCE;

  for (int hs = 0; hs < NH; ++hs) {
    const int cur = hs & 3;
    const unsigned short* Ap = pa(cur);
    const unsigned short* Bp = pb(cur);
    const int h3 = (hs + 3) & 3, ko3 = (hs + 3) * 32;
    const bool pf = (hs + 3) < NH;
    bf16x8 bfr[4], af[4];

    // ---- cluster 0: B frags + A rows 0..63, stage A pair ----
    #pragma unroll
    for (int ni = 0; ni < 4; ni++) {
      int row = wc * 64 + ni * 16 + l15;
      int c8 = l4 ^ (((row >> 3) & 1) << 1);
      bfr[ni] = *(const bf16x8*)&Bp[row * 32 + c8 * 8];
    }
    #pragma unroll
    for (int m = 0; m < 4; m++) {
      int row = wr * 128 + m * 16 + l15;
      int c8 = l4 ^ (((row >> 3) & 1) << 1);
      af[m] = *(const bf16x8*)&Ap[row * 32 + c8 * 8];
    }
    if (pf) {
      gload16(aSrc0 + ko3, pa(h3) + w*32*32);
      gload16(aSrc1 + ko3, pa(h3) + (w*32+16)*32);
    }
    __builtin_amdgcn_s_setprio(1);
    #pragma unroll
    for (int m = 0; m < 4; m++)
      #pragma unroll
      for (int ni = 0; ni < 4; ni++)
        acc[m][ni] = __builtin_amdgcn_mfma_f32_16x16x32_bf16(af[m], bfr[ni], acc[m][ni], 0, 0, 0);
    __builtin_amdgcn_s_setprio(0);

    // ---- cluster 1: A rows 64..127, stage B pair ----
    #pragma unroll
    for (int m = 0; m < 4; m++) {
      int row = wr * 128 + (4 + m) * 16 + l15;
      int c8 = l4 ^ (((row >> 3) & 1) << 1);
      af[m] = *(const bf16x8*)&Ap[row * 32 + c8 * 8];
    }
    if (pf) {
      gload16(bSrc0 + ko3, pb(h3) + w*32*32);
      gload16(bSrc1 + ko3, pb(h3) + (w*32+16)*32);
    }
    __builtin_amdgcn_s_setprio(1);
    #pragma unroll
    for (int m = 0; m < 4; m++)
      #pragma unroll
      for (int ni = 0; ni < 4; ni++)
        acc[4 + m][ni] = __builtin_amdgcn_mfma_f32_16x16x32_bf16(af[m], bfr[ni], acc[4 + m][ni], 0, 0, 0);
    __builtin_amdgcn_s_setprio(0);

    // ---- boundary: counted wait for half hs+1, single barrier per half-tile ----
    if (hs + 1 < NH) {
      const int rem = NH - 2 - hs;
      if (rem >= 2)      asm volatile("s_waitcnt vmcnt(8)" ::: "memory");
      else if (rem == 1) asm volatile("s_waitcnt vmcnt(4)" ::: "memory");
      else               asm volatile("s_waitcnt vmcnt(0)" ::: "memory");
      __builtin_amdgcn_s_barrier();
      MEMFENCE;
    }
  }

  #pragma unroll
  for (int m = 0; m < 8; m++) {
    #pragma unroll
    for (int ni = 0; ni < 4; ni++) {
      int col  = col0 + wc * 64 + ni * 16 + l15;
      int rowb = row0 + wr * 128 + m * 16 + l4 * 4;
      if constexpr (EPI == 6) {
        if (col < 1024) {
          #pragma unroll
          for (int r = 0; r < 4; r++)
            cb0[(size_t)(rowb + r) * 1024 + col] = f2b(acc[m][ni][r] + bias[col]);
        } else {
          int c = col - 1024;
          int bi = rowb >> 13, k0 = rowb & 8191;
          u16x4 o;
          #pragma unroll
          for (int r = 0; r < 4; r++) o[r] = f2b(acc[m][ni][r] + bias[col]);
          *(u16x4*)&cb1[((size_t)bi * 1024 + c) * 8192 + k0] = o;
        }
      } else {
        #pragma unroll
        for (int r = 0; r < 4; r++)
          cb0[(size_t)(rowb + r) * Ndim + col] = f2b(acc[m][ni][r]);
      }
    }
  }
}

// ---- GEMM 128x128, ring-3 half-tile buffers + counted vmcnt (minimal barriers) ----
// EPI 0: bf16 (+bias) [NOUT>1: split into cb0/1/2] | EPI 2: GELU->bf16 | EPI 7: f32 partial
// QSC: scale output by QS (Q pre-scale, exp2 units). SK>1: split-K via blockIdx.z.
template<int EPI, int NOUT, bool QSC, int SK>
__global__ __launch_bounds__(256) void k_gemm(
    const unsigned short* __restrict__ Ab, const unsigned short* __restrict__ Bb,
    const float* __restrict__ bias,
    float* __restrict__ Cf, unsigned short* __restrict__ cb0,
    unsigned short* __restrict__ cb1, unsigned short* __restrict__ cb2,
    int Ndim, int Kdim) {
  __shared__ unsigned short ring[3][2][128 * 32];   // 48 KiB: [buf][A|B][row*32]
  const int t = threadIdx.x, lane = t & 63, w = t >> 6;
  const int wr = w >> 1, wc = w & 1, l15 = lane & 15, l4 = lane >> 4;
  const int lr2 = lane >> 2;
  const int cg  = (lane & 3) ^ (((lane >> 5) & 1) << 1);   // source pre-swizzle
  const int row0 = blockIdx.y * 128;
  const int col0 = blockIdx.x * 128;
  const int koff = (SK > 1) ? (int)blockIdx.z * (Kdim / SK) : 0;
  const int NH = ((SK > 1) ? (Kdim / SK) : Kdim) >> 5;

  const unsigned short* aSrc0 = Ab + (size_t)(row0 + w * 32 + lr2) * Kdim + koff + cg * 8;
  const unsigned short* aSrc1 = aSrc0 + (size_t)16 * Kdim;
  const unsigned short* bSrc0 = Bb + (size_t)(col0 + w * 32 + lr2) * Kdim + koff + cg * 8;
  const unsigned short* bSrc1 = bSrc0 + (size_t)16 * Kdim;

  f32x4 acc[4][4];
  #pragma unroll
  for (int i = 0; i < 4; i++)
    #pragma unroll
    for (int j = 0; j < 4; j++) acc[i][j] = (f32x4){0.f,0.f,0.f,0.f};

  auto stage = [&](int h, int buf) {
    const int ko = h * 32;
    gload16(aSrc0 + ko, &ring[buf][0][w * 32 * 32]);
    gload16(aSrc1 + ko, &ring[buf][0][(w * 32 + 16) * 32]);
    gload16(bSrc0 + ko, &ring[buf][1][w * 32 * 32]);
    gload16(bSrc1 + ko, &ring[buf][1][(w * 32 + 16) * 32]);
  };

  stage(0, 0);
  stage(1, 1);
  asm volatile("s_waitcnt vmcnt(4)" ::: "memory");   // half 0 landed
  __builtin_amdgcn_s_barrier();
  MEMFENCE;

  int cur = 0;
  for (int hs = 0; hs < NH; ++hs) {
    const unsigned short* Ap = &ring[cur][0][0];
    const unsigned short* Bp = &ring[cur][1][0];
    bf16x8 af[4], bfr[4];
    #pragma unroll
    for (int ni = 0; ni < 4; ni++) {
      int row = wc * 64 + ni * 16 + l15;
      int c8 = l4 ^ (((row >> 3) & 1) << 1);
      bfr[ni] = *(const bf16x8*)&Bp[row * 32 + c8 * 8];
    }
    #pragma unroll
    for (int m = 0; m < 4; m++) {
      int row = wr * 64 + m * 16 + l15;
      int c8 = l4 ^ (((row >> 3) & 1) << 1);
      af[m] = *(const bf16x8*)&Ap[row * 32 + c8 * 8];
    }
    if (hs + 2 < NH) {
      int nb = cur + 2; if (nb >= 3) nb -= 3;
      stage(hs + 2, nb);
    }
    __builtin_amdgcn_s_setprio(1);
    #pragma unroll
    for (int mi = 0; mi < 4; mi++)
      #pragma unroll
      for (int ni = 0; ni < 4; ni++)
        acc[mi][ni] = __builtin_amdgcn_mfma_f32_16x16x32_bf16(af[mi], bfr[ni], acc[mi][ni], 0, 0, 0);
    __builtin_amdgcn_s_setprio(0);
    if (hs + 1 < NH) {
      if (hs + 2 < NH) asm volatile("s_waitcnt vmcnt(4)" ::: "memory");
      else             asm volatile("s_waitcnt vmcnt(0)" ::: "memory");
      __builtin_amdgcn_s_barrier();
      MEMFENCE;
    }
    cur = cur + 1; if (cur >= 3) cur -= 3;
  }

  unsigned short* cbase = cb0;
  int colsub = 0;
  float qsc = 1.0f;
  if constexpr (NOUT > 1) {
    int which = col0 >> 10;
    cbase = (which == 0) ? cb0 : (which == 1) ? cb1 : cb2;
    colsub = col0 & 1023;
    if (QSC && which == 0) qsc = QS;
  } else if constexpr (QSC) {
    qsc = QS;
  }
  float* Cfp = Cf;
  if constexpr (EPI == 7) Cfp = Cf + (size_t)blockIdx.z * NT * En;

  #pragma unroll
  for (int mi = 0; mi < 4; mi++) {
    #pragma unroll
    for (int ni = 0; ni < 4; ni++) {
      int col  = col0 + wc*64 + ni*16 + l15;
      int rowb = row0 + wr*64 + mi*16 + l4*4;
      #pragma unroll
      for (int r = 0; r < 4; r++) {
        float v = acc[mi][ni][r];
        size_t off = (size_t)(rowb + r) * Ndim + col;
        if constexpr (EPI == 0) {
          if constexpr (NOUT > 1) {
            int c2 = colsub + wc*64 + ni*16 + l15;
            cbase[(size_t)(rowb + r) * 1024 + c2] = f2b((v + bias[col]) * qsc);
          } else {
            cb0[off] = f2b((v + bias[col]) * qsc);
          }
        } else if constexpr (EPI == 2) {
          float u = v + bias[col];
          u = 0.5f * u * (1.0f + erff(u * 0.70710678118654752f));
          cb0[off] = f2b(u);
        } else if constexpr (EPI == 7) {
          Cfp[off] = v;
        } else {
          Cf[off] = v;
        }
      }
    }
  }
}

// ---------------- SA fused attention (Q in exp2 units, T13 defer-max, deferred l) ------
__global__ __launch_bounds__(256) void k_attn_sa(
    const unsigned short* __restrict__ Qp, const unsigned short* __restrict__ Kp,
    const unsigned short* __restrict__ Vp, unsigned short* __restrict__ Op, int Lk) {
  __shared__ unsigned short Ks[64][72];
  __shared__ unsigned short Vt[64][72];
  __shared__ float Ps[4][16][68];
  const int b = blockIdx.z;
  const int h = blockIdx.y, q0 = blockIdx.x * 64;
  const int t = threadIdx.x, lane = t & 63, w = t >> 6;
  const int l15 = lane & 15, l4 = lane >> 4;

  const int qrow = q0 + w * 16 + l15;
  const unsigned short* qptr = Qp + (size_t)(b * Sn + qrow) * En + h * 64 + l4 * 8;
  bf16x8 qf0 = *(const bf16x8*)qptr;
  bf16x8 qf1 = *(const bf16x8*)(qptr + 32);

  f32x4 oacc[4];
  #pragma unroll
  for (int i = 0; i < 4; i++) oacc[i] = (f32x4){0.f,0.f,0.f,0.f};
  float m_[4] = {-INFINITY, -INFINITY, -INFINITY, -INFINITY};
  float l_[4] = {0.f, 0.f, 0.f, 0.f};

  const int nkt = Lk / 64;
  for (int kt = 0; kt < nkt; ++kt) {
    __syncthreads();
    #pragma unroll
    for (int i = 0; i < 2; i++) {
      int ld = t + i * 256;
      int kr = ld >> 3, d8 = (ld & 7) * 8;
      size_t base = (size_t)(b * Lk + kt * 64 + kr) * En + h * 64 + d8;
      *(uint4*)&Ks[kr][d8] = *(const uint4*)(Kp + base);
      bf16x8 vv = *(const bf16x8*)(Vp + base);
      int colswz = kr ^ ((t & 7) << 3);
      #pragma unroll
      for (int j = 0; j < 8; j++) Vt[d8 + j][colswz] = ((unsigned short*)&vv)[j];
    }
    __syncthreads();

    f32x4 s[4];
    #pragma unroll
    for (int ni = 0; ni < 4; ni++) {
      s[ni] = (f32x4){0.f,0.f,0.f,0.f};
      bf16x8 kb0 = *(const bf16x8*)&Ks[ni*16 + l15][l4*8];
      bf16x8 kb1 = *(const bf16x8*)&Ks[ni*16 + l15][l4*8 + 32];
      s[ni] = __builtin_amdgcn_mfma_f32_16x16x32_bf16(qf0, kb0, s[ni], 0, 0, 0);
      s[ni] = __builtin_amdgcn_mfma_f32_16x16x32_bf16(qf1, kb1, s[ni], 0, 0, 0);
    }

    #pragma unroll
    for (int r = 0; r < 4; r++) {
      float mx = fmaxf(fmaxf(s[0][r], s[1][r]), fmaxf(s[2][r], s[3][r]));
      #pragma unroll
      for (int d2 = 1; d2 < 16; d2 <<= 1) mx = fmaxf(mx, __shfl_xor(mx, d2));
      float m = m_[r];
      if (mx > m + 8.f) {                    // T13: rescale only on large jump
        float alpha = exp2f(m - mx);
        l_[r] *= alpha;
        #pragma unroll
        for (int nd = 0; nd < 4; nd++) oacc[nd][r] *= alpha;
        m = mx; m_[r] = mx;
      }
      float p0 = exp2f(s[0][r] - m), p1 = exp2f(s[1][r] - m);
      float p2 = exp2f(s[2][r] - m), p3 = exp2f(s[3][r] - m);
      s[0][r] = p0; s[1][r] = p1; s[2][r] = p2; s[3][r] = p3;
      l_[r] += (p0 + p1) + (p2 + p3);        // per-lane partial; reduce at end
    }

    #pragma unroll
    for (int ni = 0; ni < 4; ni++)
      #pragma unroll
      for (int r = 0; r < 4; r++)
        Ps[w][l4*4 + r][ni*16 + l15] = s[ni][r];
    asm volatile("s_waitcnt lgkmcnt(0)" ::: "memory");

    #pragma unroll
    for (int half = 0; half < 2; half++) {
      float4 pv0 = *(const float4*)&Ps[w][l15][half*32 + l4*8];
      float4 pv1 = *(const float4*)&Ps[w][l15][half*32 + l4*8 + 4];
      bf16x8 pa;
      pa[0]=(short)f2b(pv0.x); pa[1]=(short)f2b(pv0.y); pa[2]=(short)f2b(pv0.z); pa[3]=(short)f2b(pv0.w);
      pa[4]=(short)f2b(pv1.x); pa[5]=(short)f2b(pv1.y); pa[6]=(short)f2b(pv1.z); pa[7]=(short)f2b(pv1.w);
      #pragma unroll
      for (int nd = 0; nd < 4; nd++) {
        int dd = nd*16 + l15;
        bf16x8 vb = *(const bf16x8*)&Vt[dd][(half*32 + l4*8) ^ (((dd >> 3) & 7) << 3)];
        oacc[nd] = __builtin_amdgcn_mfma_f32_16x16x32_bf16(pa, vb, oacc[nd], 0, 0, 0);
      }
    }
  }

  #pragma unroll
  for (int r = 0; r < 4; r++) {              // final 16-lane l reduce
    float lv = l_[r];
    #pragma unroll
    for (int d2 = 1; d2 < 16; d2 <<= 1) lv += __shfl_xor(lv, d2);
    l_[r] = lv;
  }
  #pragma unroll
  for (int nd = 0; nd < 4; nd++)
    #pragma unroll
    for (int r = 0; r < 4; r++) {
      int q = q0 + w*16 + l4*4 + r;
      Op[(size_t)(b * Sn + q) * En + h * 64 + nd*16 + l15] = f2b(oacc[nd][r] / l_[r]);
    }
}

// ------- MA attention: swapped QK^T (S^T fragments), in-register P redistribution -------
// Per lane: s[ni][r] = S[k=ni*16+l4*4+r][q=l15]; softmax per-lane (q=l15);
// PA frags assembled via cvt_pk + ds_bpermute (no Ps LDS round-trip).
__global__ __launch_bounds__(256, 2) void k_attn_ma(
    const unsigned short* __restrict__ Qp, const unsigned short* __restrict__ Kp,
    const unsigned short* __restrict__ Vp,
    unsigned short* __restrict__ PO, float* __restrict__ PM, float* __restrict__ PL) {
  constexpr int Lk = Sn * Kt;            // 8192
  constexpr int NTI = 8;                 // k-tiles per block (8192/64/16)
  __shared__ unsigned short Ks[2][64 * 64];
  __shared__ unsigned short Vt[2][64 * 64];
  const int sp = blockIdx.x, h = blockIdx.y, b = blockIdx.z;
  const int t = threadIdx.x, lane = t & 63, w = t >> 6;
  const int l15 = lane & 15, l4 = lane >> 4;
  const int l8 = lane >> 3, l7 = lane & 7;
  const int kswz = (l7 ^ l8) * 8;        // source pre-swizzle (row&7)
  const int rbase = w * 16;

  bf16x8 qf[4][2];
  #pragma unroll
  for (int qt = 0; qt < 4; qt++) {
    const unsigned short* qptr = Qp + (size_t)(b * Sn + w * 64 + qt * 16 + l15) * En + h * 64 + l4 * 8;
    qf[qt][0] = *(const bf16x8*)qptr;
    qf[qt][1] = *(const bf16x8*)(qptr + 32);
  }

  f32x4 oacc[4][4];
  #pragma unroll
  for (int i = 0; i < 4; i++)
    #pragma unroll
    for (int j = 0; j < 4; j++) oacc[i][j] = (f32x4){0.f,0.f,0.f,0.f};
  float m_[4] = {-INFINITY, -INFINITY, -INFINITY, -INFINITY};  // per qt, q = l15
  float l_[4] = {0.f, 0.f, 0.f, 0.f};

  const int kt0 = sp * NTI;
  auto stage = [&](int kt, int buf) {
    #pragma unroll
    for (int i = 0; i < 2; i++) {
      int row = rbase + i * 8 + l8;
      gload16(Kp + (size_t)(b * Lk + kt * 64 + row) * En + h * 64 + kswz,
              &Ks[buf][(rbase + i * 8) * 64]);
      gload16(Vp + ((size_t)b * 1024 + h * 64 + row) * (size_t)Lk + kt * 64 + kswz,
              &Vt[buf][(rbase + i * 8) * 64]);
    }
  };

  stage(kt0, 0);
  stage(kt0 + 1, 1);
  asm volatile("s_waitcnt vmcnt(4)" ::: "memory");   // tile0 landed (Q drained too)
  __builtin_amdgcn_s_barrier();
  MEMFENCE;

  union PU { unsigned u[4]; bf16x8 v; };

  for (int j = 0; j < NTI; ++j) {
    const int cur = j & 1;
    #pragma unroll
    for (int qt = 0; qt < 4; qt++) {
      f32x4 s[4];
      #pragma unroll
      for (int ni = 0; ni < 4; ni++) {
        s[ni] = (f32x4){0.f,0.f,0.f,0.f};
        int rowK = ni * 16 + l15, sw = (rowK & 7) * 8;
        bf16x8 kb0 = *(const bf16x8*)&Ks[cur][rowK * 64 + ((l4 * 8) ^ sw)];
        bf16x8 kb1 = *(const bf16x8*)&Ks[cur][rowK * 64 + ((l4 * 8 + 32) ^ sw)];
        // swapped operands: D = K · Q^T  ->  s[ni][r] = S[k=ni*16+l4*4+r][q=l15]
        s[ni] = __builtin_amdgcn_mfma_f32_16x16x32_bf16(kb0, qf[qt][0], s[ni], 0, 0, 0);
        s[ni] = __builtin_amdgcn_mfma_f32_16x16x32_bf16(kb1, qf[qt][1], s[ni], 0, 0, 0);
      }
      // ---- softmax for q = l15 (in-lane 16 + 2 cross-group shfl) ----
      float mx = s[0][0];
      #pragma unroll
      for (int ni = 0; ni < 4; ni++)
        #pragma unroll
        for (int r = 0; r < 4; r++) mx = fmaxf(mx, s[ni][r]);
      mx = fmaxf(mx, __shfl_xor(mx, 16));
      mx = fmaxf(mx, __shfl_xor(mx, 32));
      float mold = m_[qt];
      bool upd = mx > mold + 8.f;            // T13 defer-max (exp2 units)
      float mnew = upd ? mx : mold;
      m_[qt] = mnew;
      if (__any(upd)) {
        float am = mold - mnew;              // 0 when not updated
        l_[qt] *= exp2f(am);
        #pragma unroll
        for (int r = 0; r < 4; r++) {
          float amr = __shfl(am, (lane & 48) | (l4 * 4 + r), 64);
          float al = exp2f(amr);
          #pragma unroll
          for (int nd = 0; nd < 4; nd++) oacc[qt][nd][r] *= al;
        }
      }
      unsigned q32[4][2];
      float lacc = 0.f;
      #pragma unroll
      for (int ni = 0; ni < 4; ni++) {
        float p0 = exp2f(s[ni][0] - mnew), p1 = exp2f(s[ni][1] - mnew);
        float p2 = exp2f(s[ni][2] - mnew), p3 = exp2f(s[ni][3] - mnew);
        lacc += (p0 + p1) + (p2 + p3);
        q32[ni][0] = cvtpk(p0, p1);
        q32[ni][1] = cvtpk(p2, p3);
      }
      l_[qt] += lacc;
      // ---- PV: assemble A-frag via cross-lane redistribution ----
      #pragma unroll
      for (int half = 0; half < 2; half++) {
        PU pu;
        #pragma unroll
        for (int wd = 0; wd < 4; wd++) {
          int g = 2 * (l4 & 1) + (wd >> 1);
          int src = (g << 4) | l15;
          unsigned a0 = (unsigned)__shfl((int)q32[half * 2 + 0][wd & 1], src, 64);
          unsigned a1 = (unsigned)__shfl((int)q32[half * 2 + 1][wd & 1], src, 64);
          pu.u[wd] = (l4 & 2) ? a1 : a0;
        }
        #pragma unroll
        for (int nd = 0; nd < 4; nd++) {
          int dd = nd * 16 + l15;
          bf16x8 vb = *(const bf16x8*)&Vt[cur][dd * 64 + ((half * 32 + l4 * 8) ^ ((dd & 7) * 8))];
          oacc[qt][nd] = __builtin_amdgcn_mfma_f32_16x16x32_bf16(pu.v, vb, oacc[qt][nd], 0, 0, 0);
        }
      }
    }
    MEMFENCE; __builtin_amdgcn_s_barrier(); MEMFENCE;
    if (j + 2 < NTI) stage(kt0 + j + 2, cur);
    if (j + 1 < NTI) {
      if (j + 2 < NTI) asm volatile("s_waitcnt vmcnt(4)" ::: "memory");
      else             asm volatile("s_waitcnt vmcnt(0)" ::: "memory");
      __builtin_amdgcn_s_barrier();
      MEMFENCE;
    }
  }

  // final l reduce across the 4 l4-groups (each holds a disjoint k-subset)
  #pragma unroll
  for (int qt = 0; qt < 4; qt++) {
    float lv = l_[qt];
    lv += __shfl_xor(lv, 16);
    lv += __shfl_xor(lv, 32);
    l_[qt] = lv;
  }

  const int slot = (b * Hn + h) * 16 + sp;
  #pragma unroll
  for (int qt = 0; qt < 4; qt++)
    #pragma unroll
    for (int nd = 0; nd < 4; nd++)
      #pragma unroll
      for (int r = 0; r < 4; r++)
        PO[(size_t)slot * 16384 + (w*64 + qt*16 + l4*4 + r) * 64 + nd*16 + l15] = f2b(oacc[qt][nd][r]);
  if (lane < 16) {                            // l4==0: q = l15
    #pragma unroll
    for (int qt = 0; qt < 4; qt++) {
      PM[slot * 256 + w*64 + qt*16 + l15] = m_[qt];
      PL[slot * 256 + w*64 + qt*16 + l15] = l_[qt];
    }
  }
}

// ---------------- combine 16 split partials (bf16 PO, exp2 units) ----------------
__global__ __launch_bounds__(256) void k_attn_comb16(
    const unsigned short* __restrict__ PO, const float* __restrict__ PM,
    const float* __restrict__ PL, unsigned short* __restrict__ Op) {
  const int W = blockIdx.x * 4 + (threadIdx.x >> 6);  // (bh, q) row
  const int lane = threadIdx.x & 63;
  const int bh = W >> 8, q = W & 255;
  const int slotBase = bh * 16;
  float ms[16];
  float M = -INFINITY;
  #pragma unroll
  for (int s = 0; s < 16; s++) { ms[s] = PM[(slotBase + s) * 256 + q]; M = fmaxf(M, ms[s]); }
  float L = 0.f, acc = 0.f;
  #pragma unroll
  for (int s = 0; s < 16; s++) {
    float wgt = exp2f(ms[s] - M);
    L += PL[(slotBase + s) * 256 + q] * wgt;
    acc += wgt * b2f(PO[(size_t)(slotBase + s) * 16384 + q * 64 + lane]);
  }
  const int b = bh >> 4, h = bh & 15;
  Op[(size_t)(b * Sn + q) * En + h * 64 + lane] = f2b(acc / L);
}

// ------------- helpers for radix top-k (1024-thread blocks) -------------
DEVFN unsigned blk_exscan16(unsigned part, volatile unsigned* wsum, int lane, int wid) {
  unsigned v = part;
  #pragma unroll
  for (int d = 1; d < 64; d <<= 1) { unsigned o = __shfl_up(v, d); if (lane >= d) v += o; }
  if (lane == 63) wsum[wid] = v;
  __syncthreads();
  unsigned woff = 0;
  for (int i = 0; i < wid; i++) woff += wsum[i];
  unsigned r = woff + v - part;
  __syncthreads();
  return r;
}

DEVFN void find_thr16(const unsigned* hist, int NB, unsigned need,
                      int t, int lane, int wid, volatile unsigned* wsum,
                      volatile int* s_thr, volatile unsigned* s_above) {
  int per = NB >> 10;
  int lo = NB - per * (t + 1);
  unsigned part = 0;
  for (int j = 0; j < per; j++) part += hist[lo + j];
  unsigned ex = blk_exscan16(part, wsum, lane, wid);
  if (ex < need && ex + part >= need) {
    unsigned c = ex;
    for (int j = per - 1; j >= 0; j--) {
      unsigned h = hist[lo + j];
      if (c + h >= need) { *s_thr = lo + j; *s_above = c; break; }
      c += h;
    }
  }
  __syncthreads();
}

// ------- exact top-32: sampled threshold -> 1 compact pass -> in-LDS select -------
__global__ __launch_bounds__(1024) void k_topk16(
    const unsigned short* __restrict__ simsb, int* __restrict__ oidx) {
  const int n = blockIdx.x, t = threadIdx.x;
  const int lane = t & 63, wid = t >> 6;
  const u16x8* row8 = (const u16x8*)(simsb + (size_t)n * Mn);
  constexpr unsigned CAP = 2048;
  __shared__ unsigned hist[2048];
  __shared__ unsigned wsum[16];
  __shared__ int s_thr;
  __shared__ unsigned s_above;
  __shared__ unsigned h2[32];
  __shared__ unsigned s_cnt, s_na;
  __shared__ unsigned short ckey[CAP];
  __shared__ unsigned cidx[CAP];
  __shared__ int slist[32];
  __shared__ unsigned sL, sneedEq, scntEq, s_imin;

  for (int i = t; i < 2048; i += 1024) hist[i] = 0;
  if (t < 32) h2[t] = 0;
  if (t == 0) { s_cnt = 0; s_na = 0; }
  __syncthreads();

  // ---- sample pass: 1024 contiguous groups (16 KiB, middle of row) ----
  {
    u16x8 v = row8[3584 + t];
    #pragma unroll
    for (int j = 0; j < 8; j++) atomicAdd(&hist[okey16(v[j]) >> 5], 1u);
  }
  __syncthreads();
  find_thr16(hist, 2048, 32, t, lane, wid, wsum, &s_thr, &s_above);
  const unsigned base = ((unsigned)s_thr) << 5;

  // ---- full pass: compact keys >= base ----
  #pragma unroll
  for (int p = 0; p < 8; p++) {
    u16x8 v = row8[p * 1024 + t];
    unsigned i0 = (unsigned)(p * 1024 + t) * 8;
    #pragma unroll
    for (int j = 0; j < 8; j++) {
      unsigned k = okey16(v[j]);
      if (k >= base) {
        unsigned slot = atomicAdd(&s_cnt, 1u);
        if (slot < CAP) { ckey[slot] = (unsigned short)k; cidx[slot] = i0 + j; }
      }
    }
  }
  __syncthreads();
  const unsigned total = s_cnt;        // >= 32 guaranteed

  unsigned L, istar = 0xFFFFFFFFu;
  if (total <= CAP) {
    for (int i = t; i < 2048; i += 1024) hist[i] = 0;
    __syncthreads();
    for (unsigned i = t; i < total; i += 1024)
      atomicAdd(&hist[(unsigned)ckey[i] >> 5], 1u);
    __syncthreads();
    find_thr16(hist, 2048, 32, t, lane, wid, wsum, &s_thr, &s_above);
    const unsigned T1 = (unsigned)s_thr;
    const unsigned need2 = 32 - s_above;
    const unsigned cnt1 = hist[T1];
    if (cnt1 == need2) {
      L = T1 << 5;
    } else {
      for (unsigned i = t; i < total; i += 1024) {
        unsigned k = (unsigned)ckey[i];
        if ((k >> 5) == T1) atomicAdd(&h2[k & 31], 1u);
      }
      __syncthreads();
      if (t == 0) {
        unsigned cum = 0; int T3 = 0; unsigned above = 0;
        for (int j = 31; j >= 0; j--) {
          if (cum + h2[j] >= need2) { T3 = j; above = cum; break; }
          cum += h2[j];
        }
        sL = (T1 << 5) | (unsigned)T3;
        sneedEq = need2 - above;
        scntEq = h2[T3];
      }
      __syncthreads();
      L = sL;
      if (scntEq != sneedEq) {
        int prev = -1;
        for (unsigned j = 0; j < sneedEq; j++) {
          if (t == 0) s_imin = 0xFFFFFFFFu;
          __syncthreads();
          for (unsigned i = t; i < total; i += 1024)
            if ((unsigned)ckey[i] == L && (int)cidx[i] > prev) atomicMin(&s_imin, cidx[i]);
          __syncthreads();
          prev = (int)s_imin;
          __syncthreads();
        }
        istar = (unsigned)prev;
      }
    }
    __syncthreads();
    for (unsigned i = t; i < total; i += 1024) {
      unsigned k = (unsigned)ckey[i];
      if (k > L || (k == L && cidx[i] <= istar)) {
        unsigned s = atomicAdd(&s_na, 1u);
        slist[s] = (int)cidx[i];
      }
    }
    __syncthreads();
    if (t < 32) {
      int my = slist[t];
      int rank = 0;
      #pragma unroll
      for (int j = 0; j < 32; j++) rank += (slist[j] < my);
      oidx[n * Kt + rank] = my;
    }
  } else {
    // ======= fallback: full exact global algorithm =======
    for (int i = t; i < 2048; i += 1024) hist[i] = 0;
    __syncthreads();
    #pragma unroll
    for (int p = 0; p < 8; p++) {
      u16x8 v = row8[p * 1024 + t];
      #pragma unroll
      for (int j = 0; j < 8; j++) atomicAdd(&hist[okey16(v[j]) >> 5], 1u);
    }
    __syncthreads();
    find_thr16(hist, 2048, 32, t, lane, wid, wsum, &s_thr, &s_above);
    const unsigned T1 = (unsigned)s_thr;
    const unsigned need2 = 32 - s_above;
    const unsigned cnt1 = hist[T1];
    if (cnt1 == need2) {
      L = T1 << 5;
    } else {
      for (int p = 0; p < 8; p++) {
        u16x8 v = row8[p * 1024 + t];
        #pragma unroll
        for (int j = 0; j < 8; j++) {
          unsigned k = okey16(v[j]);
          if ((k >> 5) == T1) atomicAdd(&h2[k & 31], 1u);
        }
      }
      __syncthreads();
      if (t == 0) {
        unsigned cum = 0; int T3 = 0; unsigned above = 0;
        for (int j = 31; j >= 0; j--) {
          if (cum + h2[j] >= need2) { T3 = j; above = cum; break; }
          cum += h2[j];
        }
        sL = (T1 << 5) | (unsigned)T3;
        sneedEq = need2 - above;
        scntEq = h2[T3];
      }
      __syncthreads();
      L = sL;
      if (scntEq != sneedEq) {
        const unsigned short* rowp = simsb + (size_t)n * Mn;
        unsigned cntLoc = 0;
        for (int j = 0; j < 64; j++)
          if (okey16(rowp[t * 64 + j]) == L) cntLoc++;
        unsigned pre = blk_exscan16(cntLoc, wsum, lane, wid);
        unsigned c = 0;
        for (int j = 0; j < 64; j++)
          if (okey16(rowp[t * 64 + j]) == L) { if (pre + c < 32) slist[pre + c] = t * 64 + j; c++; }
        __syncthreads();
        istar = (unsigned)slist[sneedEq - 1];
        __syncthreads();
      }
    }
    __syncthreads();
    unsigned cnt = 0;
    for (int p = 0; p < 8; p++) {
      u16x8 v = row8[p * 1024 + t];
      unsigned i0 = (unsigned)(p * 1024 + t) * 8;
      #pragma unroll
      for (int j = 0; j < 8; j++) {
        unsigned k = okey16(v[j]);
        cnt += (k > L || (k == L && i0 + j <= istar));
      }
    }
    unsigned pos = blk_exscan16(cnt, wsum, lane, wid);
    for (int p = 0; p < 8; p++) {
      u16x8 v = row8[p * 1024 + t];
      unsigned i0 = (unsigned)(p * 1024 + t) * 8;
      #pragma unroll
      for (int j = 0; j < 8; j++) {
        unsigned k = okey16(v[j]);
        if (k > L || (k == L && i0 + j <= istar)) oidx[n * Kt + pos++] = (int)(i0 + j);
      }
    }
  }
}

// =============================== host ===============================
extern "C" void kernel_launch(void* const* d_in, const int* in_sizes, int n_in,
                              void* d_out, int out_size, void* d_ws, size_t ws_size,
                              hipStream_t stream) {
  (void)in_sizes; (void)n_in; (void)out_size;
  const float* x      = (const float*)d_in[0];
  const float* mem_k  = (const float*)d_in[1];
  const float* mem_v  = (const float*)d_in[2];
  const float* sa_w[4] = {(const float*)d_in[3], (const float*)d_in[4], (const float*)d_in[5], (const float*)d_in[6]};
  const float* sa_b[4] = {(const float*)d_in[7], (const float*)d_in[8], (const float*)d_in[9], (const float*)d_in[10]};
  const float* ma_w[4] = {(const float*)d_in[11], (const float*)d_in[12], (const float*)d_in[13], (const float*)d_in[14]};
  const float* ma_b[4] = {(const float*)d_in[15], (const float*)d_in[16], (const float*)d_in[17], (const float*)d_in[18]};
  const float* ln_g[3] = {(const float*)d_in[19], (const float*)d_in[21], (const float*)d_in[23]};
  const float* ln_b[3] = {(const float*)d_in[20], (const float*)d_in[22], (const float*)d_in[24]};
  const float* fc1_w = (const float*)d_in[25];
  const float* fc1_b = (const float*)d_in[26];
  const float* fc2_w = (const float*)d_in[27];
  const float* fc2_b = (const float*)d_in[28];
  float* out = (float*)d_out;

  char* ws = (char*)d_ws;
  size_t off = 0;
  auto alloc = [&](size_t bytes) -> char* {
    char* p = ws + off;
    off = (off + bytes + 255) & ~(size_t)255;
    return p;
  };

  unsigned short* wt[8];
  for (int i = 0; i < 8; i++) wt[i] = (unsigned short*)alloc((size_t)En * En * 2);  // contiguous
  unsigned short* fc1t  = (unsigned short*)alloc((size_t)FFn * En * 2);
  unsigned short* fc2t  = (unsigned short*)alloc((size_t)En * FFn * 2);
  unsigned short* xb    = (unsigned short*)alloc((size_t)NT * En * 2);
  unsigned short* Qb    = (unsigned short*)alloc((size_t)NT * En * 2);
  unsigned short* Kb    = (unsigned short*)alloc((size_t)NT * En * 2);
  unsigned short* Vb    = (unsigned short*)alloc((size_t)NT * En * 2);
  unsigned short* at1b  = (unsigned short*)alloc((size_t)NT * En * 2);
  float*          x1f   = (float*)alloc((size_t)NT * En * 4);
  unsigned short* x1b   = (unsigned short*)alloc((size_t)NT * En * 2);
  char*           simsRaw = alloc((size_t)NT * Mn * 4);                // 256 MiB region
  int*            idx   = (int*)alloc((size_t)NT * Kt * 4);
  unsigned short* K2b   = (unsigned short*)alloc((size_t)NT * Kt * En * 2);  // 64 MiB
  unsigned short* V2b   = (unsigned short*)alloc((size_t)NT * Kt * En * 2);  // V2t: [B][1024][8192]
  unsigned short* Q2b   = (unsigned short*)alloc((size_t)NT * En * 2);
  unsigned short* at2b  = (unsigned short*)alloc((size_t)NT * En * 2);
  float*          x2f   = (float*)alloc((size_t)NT * En * 4);
  unsigned short* x2b   = (unsigned short*)alloc((size_t)NT * En * 2);
  unsigned short* hb    = (unsigned short*)alloc((size_t)NT * FFn * 2);
  float*          pp    = (float*)alloc((size_t)4 * NT * En * 4);      // 16 MiB split-K partials
  float*          bcat_sa = (float*)alloc(3072 * 4);
  float*          bcat_ma = (float*)alloc(2048 * 4);

  if (off > ws_size) return;   // insufficient workspace: leave output poisoned (fail loudly)

  // Overlays within the 256 MiB sims region (uses strictly sequential):
  unsigned short* simsb = (unsigned short*)simsRaw;
  unsigned short* mkb = (unsigned short*)K2b;         // until sims GEMM done
  unsigned short* Ab2 = (unsigned short*)(simsRaw + (size_t)128 * 1024 * 1024);
  unsigned short* PO  = (unsigned short*)(simsRaw + (size_t)192 * 1024 * 1024);
  float* PM = (float*)(simsRaw + (size_t)224 * 1024 * 1024);
  float* PL = (float*)(simsRaw + (size_t)225 * 1024 * 1024);

  (void)hipFuncSetAttribute((const void*)&k_gemm256<5,1,0>,
                            hipFuncAttributeMaxDynamicSharedMemorySize, 131072);
  (void)hipFuncSetAttribute((const void*)&k_gemm256<6,2,1>,
                            hipFuncAttributeMaxDynamicSharedMemorySize, 131072);

  // ---- prep: weight transposes to bf16 [N][K], bias concats ----
  P8 p8;
  for (int i = 0; i < 4; i++) { p8.s[i] = sa_w[i]; p8.s[4 + i] = ma_w[i]; }
  k_transpose8<<<dim3(16, 16, 8), 256, 0, stream>>>(p8, wt[0]);
  k_transpose_bf16<<<dim3(64, 16), 256, 0, stream>>>(fc1_w, fc1t, En, FFn);
  k_transpose_bf16<<<dim3(16, 64), 256, 0, stream>>>(fc2_w, fc2t, FFn, En);
  k_concat3<<<dim3(12), 256, 0, stream>>>(sa_b[0], sa_b[1], sa_b[2], bcat_sa);
  k_concat3<<<dim3(8),  256, 0, stream>>>(ma_b[1], ma_b[2], ma_b[2], bcat_ma);

  k_cvt_bf16<<<dim3(NT * En / 4 / 256), 256, 0, stream>>>(x, xb, NT * En / 4);
  k_normcvt<<<dim3(Mn), 256, 0, stream>>>(mem_k, mkb);

  const dim3 g1(En / 128, NT / 128);        // (8,8)
  const dim3 g1s(En / 128, NT / 128, 4);    // split-K=4 -> 256 blocks

  // ---- self-attention (QKV fused, Q pre-scaled into exp2 units) ----
  k_gemm<0,3,true,1><<<dim3(24, 8), 256, 0, stream>>>(xb, wt[0], bcat_sa, nullptr, Qb, Kb, Vb, 3072, En);
  k_attn_sa<<<dim3(Sn / 64, Hn, Bn), 256, 0, stream>>>(Qb, Kb, Vb, at1b, Sn);
  k_gemm<7,1,false,4><<<g1s, 256, 0, stream>>>(at1b, wt[3], nullptr, pp, nullptr, nullptr, nullptr, En, En);
  k_layernorm4<<<NT, 256, 0, stream>>>(pp, sa_b[3], x, ln_g[0], ln_b[0], x1f, x1b);

  // ---- retrieval: sims in bf16 + sampled-threshold top-k ----
  k_gemm256<5,1,0><<<dim3(1024), 512, 131072, stream>>>(
      x1b, mkb, nullptr, nullptr, simsb, nullptr, Mn, En, NT / 256, Mn / 256);
  k_topk16<<<NT, 1024, 0, stream>>>(simsb, idx);

  // ---- memory cross-attention ----
  k_gathercvt<<<dim3(NT * Kt), 256, 0, stream>>>(mem_v, idx, Ab2);
  k_gemm256<6,2,1><<<dim3(1024), 512, 131072, stream>>>(
      Ab2, wt[5], bcat_ma, nullptr, K2b, V2b, 2048, En, NT * Kt / 256, 2048 / 256);
  k_gemm<0,1,true,1><<<g1, 256, 0, stream>>>(x1b, wt[4], ma_b[0], nullptr, Q2b, nullptr, nullptr, En, En);
  k_attn_ma<<<dim3(16, Hn, Bn), 256, 0, stream>>>(Q2b, K2b, V2b, PO, PM, PL);
  k_attn_comb16<<<dim3(Bn * Hn * Sn / 4), 256, 0, stream>>>(PO, PM, PL, at2b);
  k_gemm<7,1,false,4><<<g1s, 256, 0, stream>>>(at2b, wt[7], nullptr, pp, nullptr, nullptr, nullptr, En, En);
  k_layernorm4<<<NT, 256, 0, stream>>>(pp, ma_b[3], x1f, ln_g[1], ln_b[1], x2f, x2b);

  // ---- FFN ----
  k_gemm<2,1,false,1><<<dim3(FFn / 128, NT / 128), 256, 0, stream>>>(x2b, fc1t, fc1_b, nullptr, hb, nullptr, nullptr, FFn, En);
  k_gemm<7,1,false,4><<<g1s, 256, 0, stream>>>(hb, fc2t, nullptr, pp, nullptr, nullptr, nullptr, En, FFn);
  k_layernorm4<<<NT, 256, 0, stream>>>(pp, fc2_b, x2f, ln_g[2], ln_b[2], out, nullptr);
}